// Round 1
// baseline (956.417 us; speedup 1.0000x reference)
//
#include <hip/hip_runtime.h>
#include <math.h>

// TemporalWasteGNN: 3x GCNConv (symmetric-norm, self-loops) -> 2x LSTM(seq=1, h0=c0=0)
// -> two MLP heads. All fp32.
//
// Strategy:
//  - Build CSR (incoming edges per dst) on device once per launch: count -> 3-kernel
//    exclusive scan -> atomic-bump fill. Reused by all 3 GCN layers.
//  - Per GCN layer: transform kernel (X @ W, scaled by dinv[node] in epilogue) then
//    gather-aggregate kernel (no atomics in hot loop):
//      out[d][c] = relu( dinv[d] * (Hts[d][c] + sum_{s in N(d)} Hts[s][c]) + b[c] )
//    where Hts = (X@W) * dinv[row]  (self-loop term = dinv[d]^2 * h[d], exact PyG norm).
//  - LSTM with h0=c0=0: g = x@Wih^T + bih + bhh; only gates i,g,o needed (f unused).
//  - Heads fused into one kernel, one thread per node, weights in LDS (broadcast reads).

static __device__ __forceinline__ float sigmoidf_(float x){ return 1.f/(1.f+expf(-x)); }

// ---------------- CSR build ----------------
__global__ void count_kernel(const int* __restrict__ ei, int* __restrict__ deg, int E){
  int e = blockIdx.x*256 + threadIdx.x;
  if (e < E) atomicAdd(&deg[ei[E + e]], 1);
}

__global__ void scan_reduce_kernel(const int* __restrict__ deg, int* __restrict__ bsums, int n){
  __shared__ int sd[256];
  int base = blockIdx.x*1024 + threadIdx.x*4;
  int s = 0;
  #pragma unroll
  for (int j=0;j<4;++j){ int idx=base+j; if (idx<n) s += deg[idx]; }
  sd[threadIdx.x] = s; __syncthreads();
  for (int off=128; off>0; off>>=1){
    if (threadIdx.x < off) sd[threadIdx.x] += sd[threadIdx.x+off];
    __syncthreads();
  }
  if (threadIdx.x==0) bsums[blockIdx.x] = sd[0];
}

__global__ void scan_block_kernel(const int* __restrict__ bsums, int* __restrict__ boffs, int nb){
  __shared__ int ts[128];
  if (nb <= 128){
    int v = (threadIdx.x < nb) ? bsums[threadIdx.x] : 0;
    ts[threadIdx.x] = v; __syncthreads();
    for (int off=1; off<128; off<<=1){
      int t = (threadIdx.x>=off) ? ts[threadIdx.x-off] : 0;
      __syncthreads();
      ts[threadIdx.x] += t;
      __syncthreads();
    }
    if (threadIdx.x < nb) boffs[threadIdx.x] = ts[threadIdx.x] - v;   // exclusive
  } else if (threadIdx.x==0){
    int run=0;
    for (int b=0;b<nb;++b){ int t=bsums[b]; boffs[b]=run; run+=t; }
  }
}

__global__ void scan_final_kernel(const int* __restrict__ deg, const int* __restrict__ boffs,
                                  int* __restrict__ offs, int n, int E){
  __shared__ int ts[256];
  int base = blockIdx.x*1024 + threadIdx.x*4;
  int v[4]; int s=0;
  #pragma unroll
  for (int j=0;j<4;++j){ int idx=base+j; v[j] = (idx<n) ? deg[idx] : 0; s += v[j]; }
  ts[threadIdx.x] = s; __syncthreads();
  for (int off=1; off<256; off<<=1){
    int t = (threadIdx.x>=off) ? ts[threadIdx.x-off] : 0;
    __syncthreads();
    ts[threadIdx.x] += t;
    __syncthreads();
  }
  int excl = boffs[blockIdx.x] + (threadIdx.x ? ts[threadIdx.x-1] : 0);
  #pragma unroll
  for (int j=0;j<4;++j){ int idx=base+j; if (idx<n){ offs[idx]=excl; excl+=v[j]; } }
  if (blockIdx.x==0 && threadIdx.x==0) offs[n] = E;
}

__global__ void dinv_kernel(const int* __restrict__ deg, const int* __restrict__ offs,
                            int* __restrict__ cursor, float* __restrict__ dinv, int n){
  int i = blockIdx.x*256 + threadIdx.x;
  if (i < n){
    dinv[i] = rsqrtf((float)(deg[i] + 1));   // +1 self-loop; deg>=0 so always valid
    cursor[i] = offs[i];
  }
}

__global__ void fill_kernel(const int* __restrict__ ei, int* __restrict__ cursor,
                            int* __restrict__ csr, int E){
  int e = blockIdx.x*256 + threadIdx.x;
  if (e < E){
    int d = ei[E + e];
    int pos = atomicAdd(&cursor[d], 1);
    csr[pos] = ei[e];
  }
}

// ---------------- GCN transform: Y[n][c] = dinv[n] * sum_k X[n][k] * W[k][c] ----------------
// 256 threads = 4 nodes x 64 cols per iter, 4 iters (16 nodes/block). W staged in LDS.
template<int KD>
__global__ void transform_kernel(const float* __restrict__ X, const float* __restrict__ W,
                                 const float* __restrict__ dinv, float* __restrict__ Y, int n){
  __shared__ float Wl[KD*64];
  __shared__ float Xl[4*KD];
  for (int i=threadIdx.x; i<KD*64; i+=256) Wl[i] = W[i];
  const int lane = threadIdx.x & 63;
  const int sub  = threadIdx.x >> 6;
  for (int it=0; it<4; ++it){
    const int nodeBase = blockIdx.x*16 + it*4;
    __syncthreads();                               // Wl ready (it=0) / prev compute done
    for (int i=threadIdx.x; i<4*KD; i+=256){
      int gi = nodeBase*KD + i;                    // rows are contiguous
      Xl[i] = (gi < n*KD) ? X[gi] : 0.f;
    }
    __syncthreads();
    const int node = nodeBase + sub;
    if (node < n){
      float acc = 0.f;
      #pragma unroll 16
      for (int k=0; k<KD; ++k)
        acc = fmaf(Xl[sub*KD + k], Wl[k*64 + lane], acc);  // Xl broadcast, Wl 2-lanes/bank
      Y[node*64 + lane] = acc * dinv[node];
    }
  }
}

// ---------------- GCN aggregate: one wave per node, lane = feature column ----------------
__global__ void agg_kernel(const float* __restrict__ Hts, const float* __restrict__ dinv,
                           const int* __restrict__ offs, const int* __restrict__ csr,
                           const float* __restrict__ bias, float* __restrict__ Hout, int n){
  const int node = blockIdx.x*4 + (threadIdx.x >> 6);
  if (node >= n) return;
  const int lane = threadIdx.x & 63;
  float acc = Hts[node*64 + lane];                 // self-loop (already * dinv[node])
  const int beg = offs[node], end = offs[node+1];
  for (int j=beg; j<end; ++j){
    int s = csr[j];                                // wave-uniform broadcast load
    acc += Hts[s*64 + lane];                       // coalesced 256B row read
  }
  Hout[node*64 + lane] = fmaxf(fmaf(acc, dinv[node], bias[lane]), 0.f);
}

// ---------------- LSTM (seq=1, h0=c0=0): only i,g,o gates matter ----------------
// 256 threads = 8 nodes x 32 dims. Wih (128 x IN) staged padded to IN+1 (bank-conflict-free).
template<int IN>
__global__ void lstm_kernel(const float* __restrict__ X, const float* __restrict__ Wih,
                            const float* __restrict__ bih, const float* __restrict__ bhh,
                            float* __restrict__ Hout, int n){
  __shared__ float Wl[128*(IN+1)];
  __shared__ float bl[128];
  for (int i=threadIdx.x; i<128*IN; i+=256){
    int r = i / IN, k = i - r*IN;
    Wl[r*(IN+1) + k] = Wih[i];
  }
  for (int i=threadIdx.x; i<128; i+=256) bl[i] = bih[i] + bhh[i];
  __syncthreads();
  const int node = blockIdx.x*8 + (threadIdx.x >> 5);
  const int d    = threadIdx.x & 31;
  if (node >= n) return;
  const float* xr = X + node*IN;
  float gi = bl[d], gg = bl[64+d], go = bl[96+d];  // f gate (32..63) unused: c0=0
  #pragma unroll 8
  for (int k=0; k<IN; ++k){
    float xv = xr[k];
    gi = fmaf(xv, Wl[d      *(IN+1) + k], gi);
    gg = fmaf(xv, Wl[(64+d) *(IN+1) + k], gg);
    go = fmaf(xv, Wl[(96+d) *(IN+1) + k], go);
  }
  float c = sigmoidf_(gi) * tanhf(gg);
  Hout[node*32 + d] = sigmoidf_(go) * tanhf(c);
}

// ---------------- Heads: one thread per node, weights in LDS (broadcast reads) ----------------
__global__ void heads_kernel(const float* __restrict__ H,
                             const float* __restrict__ Wv1, const float* __restrict__ bv1,
                             const float* __restrict__ Wv2, const float* __restrict__ bv2,
                             const float* __restrict__ Wt1, const float* __restrict__ bt1,
                             const float* __restrict__ Wt2, const float* __restrict__ bt2,
                             float* __restrict__ out, int n){
  __shared__ float Wv1l[1024], Wt1l[1024], Wt2l[320], Wv2l[32], bv1l[32], bt1l[32], bt2l[10];
  for (int i=threadIdx.x; i<1024; i+=256){ Wv1l[i]=Wv1[i]; Wt1l[i]=Wt1[i]; }
  for (int i=threadIdx.x; i<320;  i+=256) Wt2l[i]=Wt2[i];
  if (threadIdx.x < 32){
    Wv2l[threadIdx.x]=Wv2[threadIdx.x];
    bv1l[threadIdx.x]=bv1[threadIdx.x];
    bt1l[threadIdx.x]=bt1[threadIdx.x];
  }
  if (threadIdx.x < 10) bt2l[threadIdx.x]=bt2[threadIdx.x];
  __syncthreads();
  const int node = blockIdx.x*256 + threadIdx.x;
  if (node >= n) return;
  float h[32];
  #pragma unroll
  for (int k=0;k<32;++k) h[k] = H[node*32 + k];
  float vol = bv2[0];
  float tacc[10];
  #pragma unroll
  for (int k=0;k<10;++k) tacc[k] = bt2l[k];
  for (int j=0;j<32;++j){
    float av = bv1l[j], at = bt1l[j];
    #pragma unroll
    for (int k=0;k<32;++k){
      av = fmaf(h[k], Wv1l[k*32 + j], av);
      at = fmaf(h[k], Wt1l[k*32 + j], at);
    }
    av = fmaxf(av, 0.f);
    at = fmaxf(at, 0.f);
    vol = fmaf(av, Wv2l[j], vol);
    #pragma unroll
    for (int k=0;k<10;++k) tacc[k] = fmaf(at, Wt2l[j*10 + k], tacc[k]);
  }
  out[node] = vol;                                 // volume_pred (N,1)
  #pragma unroll
  for (int k=0;k<10;++k) out[n + node*10 + k] = tacc[k];  // type_pred (N,10)
}

extern "C" void kernel_launch(void* const* d_in, const int* in_sizes, int n_in,
                              void* d_out, int out_size, void* d_ws, size_t ws_size,
                              hipStream_t stream){
  const float* x    = (const float*)d_in[0];
  const int*   ei   = (const int*)  d_in[1];
  const float* W1   = (const float*)d_in[2];  const float* b1   = (const float*)d_in[3];
  const float* W2   = (const float*)d_in[4];  const float* b2   = (const float*)d_in[5];
  const float* W3   = (const float*)d_in[6];  const float* b3   = (const float*)d_in[7];
  const float* Wih0 = (const float*)d_in[8];
  const float* bih0 = (const float*)d_in[10]; const float* bhh0 = (const float*)d_in[11];
  const float* Wih1 = (const float*)d_in[12];
  const float* bih1 = (const float*)d_in[14]; const float* bhh1 = (const float*)d_in[15];
  const float* Wv1  = (const float*)d_in[16]; const float* bv1  = (const float*)d_in[17];
  const float* Wv2  = (const float*)d_in[18]; const float* bv2  = (const float*)d_in[19];
  const float* Wt1  = (const float*)d_in[20]; const float* bt1  = (const float*)d_in[21];
  const float* Wt2  = (const float*)d_in[22]; const float* bt2  = (const float*)d_in[23];

  const int N  = in_sizes[0] / 128;
  const int E  = in_sizes[1] / 2;
  const int NB = (N + 1023) / 1024;

  char* w = (char*)d_ws;
  auto take = [&](size_t bytes)->char*{ char* p = w; w += (bytes + 255) & ~(size_t)255; return p; };
  int*   deg    = (int*)  take((size_t)N*4);
  int*   offs   = (int*)  take((size_t)(N+1)*4);
  int*   cursor = (int*)  take((size_t)N*4);
  int*   csr    = (int*)  take((size_t)E*4);
  float* dinv   = (float*)take((size_t)N*4);
  int*   bsums  = (int*)  take((size_t)NB*4);
  int*   boffs  = (int*)  take((size_t)NB*4);
  float* bufA   = (float*)take((size_t)N*64*4);
  float* bufB   = (float*)take((size_t)N*64*4);
  (void)ws_size; (void)n_in; (void)out_size;

  // --- CSR + normalization (once, reused by all 3 layers) ---
  hipMemsetAsync(deg, 0, (size_t)N*4, stream);
  count_kernel      <<<(E+255)/256, 256, 0, stream>>>(ei, deg, E);
  scan_reduce_kernel<<<NB,          256, 0, stream>>>(deg, bsums, N);
  scan_block_kernel <<<1,           128, 0, stream>>>(bsums, boffs, NB);
  scan_final_kernel <<<NB,          256, 0, stream>>>(deg, boffs, offs, N, E);
  dinv_kernel       <<<(N+255)/256, 256, 0, stream>>>(deg, offs, cursor, dinv, N);
  fill_kernel       <<<(E+255)/256, 256, 0, stream>>>(ei, cursor, csr, E);

  // --- GCN layers (ping-pong bufA/bufB) ---
  transform_kernel<128><<<(N+15)/16, 256, 0, stream>>>(x,    W1, dinv, bufA, N);
  agg_kernel           <<<(N+3)/4,   256, 0, stream>>>(bufA, dinv, offs, csr, b1, bufB, N);
  transform_kernel<64> <<<(N+15)/16, 256, 0, stream>>>(bufB, W2, dinv, bufA, N);
  agg_kernel           <<<(N+3)/4,   256, 0, stream>>>(bufA, dinv, offs, csr, b2, bufB, N);
  transform_kernel<64> <<<(N+15)/16, 256, 0, stream>>>(bufB, W3, dinv, bufA, N);
  agg_kernel           <<<(N+3)/4,   256, 0, stream>>>(bufA, dinv, offs, csr, b3, bufB, N);

  // --- LSTM x2 (seq_len=1, zero state) ---
  lstm_kernel<64><<<(N+7)/8, 256, 0, stream>>>(bufB, Wih0, bih0, bhh0, bufA, N);
  lstm_kernel<32><<<(N+7)/8, 256, 0, stream>>>(bufA, Wih1, bih1, bhh1, bufB, N);

  // --- Heads ---
  heads_kernel<<<(N+255)/256, 256, 0, stream>>>(bufB, Wv1, bv1, Wv2, bv2,
                                                Wt1, bt1, Wt2, bt2, (float*)d_out, N);
}

// Round 2
// 691.780 us; speedup vs baseline: 1.3825x; 1.3825x over previous
//
#include <hip/hip_runtime.h>
#include <math.h>

// TemporalWasteGNN: 3x GCNConv (symmetric-norm, self-loops) -> 2x LSTM(seq=1, h0=c0=0)
// -> two MLP heads. All fp32.
//
// R2: agg_kernel rebuilt for 4-way neighbor ILP (16 lanes x float4 per row, 4
// neighbor slots per wave, shfl_xor reduce) — attacks the latency-bound gather.
// count/fill vectorized to int4 edge loads (4 edges/thread).

static __device__ __forceinline__ float sigmoidf_(float x){ return 1.f/(1.f+expf(-x)); }

// ---------------- CSR build ----------------
__global__ void count_kernel(const int* __restrict__ dsts, int* __restrict__ deg, int E){
  int e = blockIdx.x*256 + threadIdx.x;
  if (e < E) atomicAdd(&deg[dsts[e]], 1);
}

__global__ void count_kernel_v4(const int* __restrict__ dsts, int* __restrict__ deg, int E4){
  int i = blockIdx.x*256 + threadIdx.x;
  if (i < E4){
    int4 d4 = ((const int4*)dsts)[i];
    atomicAdd(&deg[d4.x], 1); atomicAdd(&deg[d4.y], 1);
    atomicAdd(&deg[d4.z], 1); atomicAdd(&deg[d4.w], 1);
  }
}

__global__ void scan_reduce_kernel(const int* __restrict__ deg, int* __restrict__ bsums, int n){
  __shared__ int sd[256];
  int base = blockIdx.x*1024 + threadIdx.x*4;
  int s = 0;
  #pragma unroll
  for (int j=0;j<4;++j){ int idx=base+j; if (idx<n) s += deg[idx]; }
  sd[threadIdx.x] = s; __syncthreads();
  for (int off=128; off>0; off>>=1){
    if (threadIdx.x < off) sd[threadIdx.x] += sd[threadIdx.x+off];
    __syncthreads();
  }
  if (threadIdx.x==0) bsums[blockIdx.x] = sd[0];
}

__global__ void scan_block_kernel(const int* __restrict__ bsums, int* __restrict__ boffs, int nb){
  __shared__ int ts[128];
  if (nb <= 128){
    int v = (threadIdx.x < nb) ? bsums[threadIdx.x] : 0;
    ts[threadIdx.x] = v; __syncthreads();
    for (int off=1; off<128; off<<=1){
      int t = (threadIdx.x>=off) ? ts[threadIdx.x-off] : 0;
      __syncthreads();
      ts[threadIdx.x] += t;
      __syncthreads();
    }
    if (threadIdx.x < nb) boffs[threadIdx.x] = ts[threadIdx.x] - v;   // exclusive
  } else if (threadIdx.x==0){
    int run=0;
    for (int b=0;b<nb;++b){ int t=bsums[b]; boffs[b]=run; run+=t; }
  }
}

__global__ void scan_final_kernel(const int* __restrict__ deg, const int* __restrict__ boffs,
                                  int* __restrict__ offs, int n, int E){
  __shared__ int ts[256];
  int base = blockIdx.x*1024 + threadIdx.x*4;
  int v[4]; int s=0;
  #pragma unroll
  for (int j=0;j<4;++j){ int idx=base+j; v[j] = (idx<n) ? deg[idx] : 0; s += v[j]; }
  ts[threadIdx.x] = s; __syncthreads();
  for (int off=1; off<256; off<<=1){
    int t = (threadIdx.x>=off) ? ts[threadIdx.x-off] : 0;
    __syncthreads();
    ts[threadIdx.x] += t;
    __syncthreads();
  }
  int excl = boffs[blockIdx.x] + (threadIdx.x ? ts[threadIdx.x-1] : 0);
  #pragma unroll
  for (int j=0;j<4;++j){ int idx=base+j; if (idx<n){ offs[idx]=excl; excl+=v[j]; } }
  if (blockIdx.x==0 && threadIdx.x==0) offs[n] = E;
}

__global__ void dinv_kernel(const int* __restrict__ deg, const int* __restrict__ offs,
                            int* __restrict__ cursor, float* __restrict__ dinv, int n){
  int i = blockIdx.x*256 + threadIdx.x;
  if (i < n){
    dinv[i] = rsqrtf((float)(deg[i] + 1));   // +1 self-loop
    cursor[i] = offs[i];
  }
}

__global__ void fill_kernel(const int* __restrict__ ei, int* __restrict__ cursor,
                            int* __restrict__ csr, int E){
  int e = blockIdx.x*256 + threadIdx.x;
  if (e < E){
    int d = ei[E + e];
    int pos = atomicAdd(&cursor[d], 1);
    csr[pos] = ei[e];
  }
}

__global__ void fill_kernel_v4(const int* __restrict__ ei, int* __restrict__ cursor,
                               int* __restrict__ csr, int E, int E4){
  int i = blockIdx.x*256 + threadIdx.x;
  if (i < E4){
    int4 s4 = ((const int4*)ei)[i];
    int4 d4 = ((const int4*)(ei + E))[i];
    int p;
    p = atomicAdd(&cursor[d4.x], 1); csr[p] = s4.x;
    p = atomicAdd(&cursor[d4.y], 1); csr[p] = s4.y;
    p = atomicAdd(&cursor[d4.z], 1); csr[p] = s4.z;
    p = atomicAdd(&cursor[d4.w], 1); csr[p] = s4.w;
  }
}

// ---------------- GCN transform: Y[n][c] = dinv[n] * sum_k X[n][k] * W[k][c] ----------------
template<int KD>
__global__ void transform_kernel(const float* __restrict__ X, const float* __restrict__ W,
                                 const float* __restrict__ dinv, float* __restrict__ Y, int n){
  __shared__ float Wl[KD*64];
  __shared__ float Xl[4*KD];
  for (int i=threadIdx.x; i<KD*64; i+=256) Wl[i] = W[i];
  const int lane = threadIdx.x & 63;
  const int sub  = threadIdx.x >> 6;
  for (int it=0; it<4; ++it){
    const int nodeBase = blockIdx.x*16 + it*4;
    __syncthreads();
    for (int i=threadIdx.x; i<4*KD; i+=256){
      int gi = nodeBase*KD + i;
      Xl[i] = (gi < n*KD) ? X[gi] : 0.f;
    }
    __syncthreads();
    const int node = nodeBase + sub;
    if (node < n){
      float acc = 0.f;
      #pragma unroll 16
      for (int k=0; k<KD; ++k)
        acc = fmaf(Xl[sub*KD + k], Wl[k*64 + lane], acc);
      Y[node*64 + lane] = acc * dinv[node];
    }
  }
}

// ---------------- GCN aggregate: one wave per node, 4-way neighbor ILP ----------------
// Wave layout: lane = sub*16 + c4. Each 16-lane sub-group handles neighbor slot
// `sub` (j = beg+sub, step 4) and reads the row as 16 x float4 (256B coalesced).
// 4 independent csr loads + 4 independent row loads in flight per iteration.
__global__ void agg_kernel(const float* __restrict__ Hts, const float* __restrict__ dinv,
                           const int* __restrict__ offs, const int* __restrict__ csr,
                           const float* __restrict__ bias, float* __restrict__ Hout, int n){
  const int node = blockIdx.x*4 + (threadIdx.x >> 6);
  if (node >= n) return;
  const int lane = threadIdx.x & 63;
  const int c4   = lane & 15;     // float4 column group
  const int sub  = lane >> 4;     // neighbor slot 0..3
  const float4* __restrict__ H4 = (const float4*)Hts;
  float4 acc = make_float4(0.f, 0.f, 0.f, 0.f);
  const int beg = offs[node], end = offs[node+1];
  for (int j = beg + sub; j < end; j += 4){
    int s = csr[j];                      // 4 distinct addrs per wave (16-lane bcast each)
    float4 v = H4[s*16 + c4];            // 256B coalesced per sub-group
    acc.x += v.x; acc.y += v.y; acc.z += v.z; acc.w += v.w;
  }
  // reduce the 4 neighbor slots: xor-16 then xor-32
  acc.x += __shfl_xor(acc.x, 16); acc.y += __shfl_xor(acc.y, 16);
  acc.z += __shfl_xor(acc.z, 16); acc.w += __shfl_xor(acc.w, 16);
  acc.x += __shfl_xor(acc.x, 32); acc.y += __shfl_xor(acc.y, 32);
  acc.z += __shfl_xor(acc.z, 32); acc.w += __shfl_xor(acc.w, 32);
  if (sub == 0){
    float4 self = H4[node*16 + c4];      // self-loop term (already * dinv[node])
    float4 b4   = ((const float4*)bias)[c4];
    float  dv   = dinv[node];
    float4 o;
    o.x = fmaxf(fmaf(acc.x + self.x, dv, b4.x), 0.f);
    o.y = fmaxf(fmaf(acc.y + self.y, dv, b4.y), 0.f);
    o.z = fmaxf(fmaf(acc.z + self.z, dv, b4.z), 0.f);
    o.w = fmaxf(fmaf(acc.w + self.w, dv, b4.w), 0.f);
    ((float4*)Hout)[node*16 + c4] = o;
  }
}

// ---------------- LSTM (seq=1, h0=c0=0): only i,g,o gates matter ----------------
template<int IN>
__global__ void lstm_kernel(const float* __restrict__ X, const float* __restrict__ Wih,
                            const float* __restrict__ bih, const float* __restrict__ bhh,
                            float* __restrict__ Hout, int n){
  __shared__ float Wl[128*(IN+1)];
  __shared__ float bl[128];
  for (int i=threadIdx.x; i<128*IN; i+=256){
    int r = i / IN, k = i - r*IN;
    Wl[r*(IN+1) + k] = Wih[i];
  }
  for (int i=threadIdx.x; i<128; i+=256) bl[i] = bih[i] + bhh[i];
  __syncthreads();
  const int node = blockIdx.x*8 + (threadIdx.x >> 5);
  const int d    = threadIdx.x & 31;
  if (node >= n) return;
  const float* xr = X + node*IN;
  float gi = bl[d], gg = bl[64+d], go = bl[96+d];
  #pragma unroll 8
  for (int k=0; k<IN; ++k){
    float xv = xr[k];
    gi = fmaf(xv, Wl[d      *(IN+1) + k], gi);
    gg = fmaf(xv, Wl[(64+d) *(IN+1) + k], gg);
    go = fmaf(xv, Wl[(96+d) *(IN+1) + k], go);
  }
  float c = sigmoidf_(gi) * tanhf(gg);
  Hout[node*32 + d] = sigmoidf_(go) * tanhf(c);
}

// ---------------- Heads ----------------
__global__ void heads_kernel(const float* __restrict__ H,
                             const float* __restrict__ Wv1, const float* __restrict__ bv1,
                             const float* __restrict__ Wv2, const float* __restrict__ bv2,
                             const float* __restrict__ Wt1, const float* __restrict__ bt1,
                             const float* __restrict__ Wt2, const float* __restrict__ bt2,
                             float* __restrict__ out, int n){
  __shared__ float Wv1l[1024], Wt1l[1024], Wt2l[320], Wv2l[32], bv1l[32], bt1l[32], bt2l[10];
  for (int i=threadIdx.x; i<1024; i+=256){ Wv1l[i]=Wv1[i]; Wt1l[i]=Wt1[i]; }
  for (int i=threadIdx.x; i<320;  i+=256) Wt2l[i]=Wt2[i];
  if (threadIdx.x < 32){
    Wv2l[threadIdx.x]=Wv2[threadIdx.x];
    bv1l[threadIdx.x]=bv1[threadIdx.x];
    bt1l[threadIdx.x]=bt1[threadIdx.x];
  }
  if (threadIdx.x < 10) bt2l[threadIdx.x]=bt2[threadIdx.x];
  __syncthreads();
  const int node = blockIdx.x*256 + threadIdx.x;
  if (node >= n) return;
  float h[32];
  #pragma unroll
  for (int k=0;k<32;++k) h[k] = H[node*32 + k];
  float vol = bv2[0];
  float tacc[10];
  #pragma unroll
  for (int k=0;k<10;++k) tacc[k] = bt2l[k];
  for (int j=0;j<32;++j){
    float av = bv1l[j], at = bt1l[j];
    #pragma unroll
    for (int k=0;k<32;++k){
      av = fmaf(h[k], Wv1l[k*32 + j], av);
      at = fmaf(h[k], Wt1l[k*32 + j], at);
    }
    av = fmaxf(av, 0.f);
    at = fmaxf(at, 0.f);
    vol = fmaf(av, Wv2l[j], vol);
    #pragma unroll
    for (int k=0;k<10;++k) tacc[k] = fmaf(at, Wt2l[j*10 + k], tacc[k]);
  }
  out[node] = vol;
  #pragma unroll
  for (int k=0;k<10;++k) out[n + node*10 + k] = tacc[k];
}

extern "C" void kernel_launch(void* const* d_in, const int* in_sizes, int n_in,
                              void* d_out, int out_size, void* d_ws, size_t ws_size,
                              hipStream_t stream){
  const float* x    = (const float*)d_in[0];
  const int*   ei   = (const int*)  d_in[1];
  const float* W1   = (const float*)d_in[2];  const float* b1   = (const float*)d_in[3];
  const float* W2   = (const float*)d_in[4];  const float* b2   = (const float*)d_in[5];
  const float* W3   = (const float*)d_in[6];  const float* b3   = (const float*)d_in[7];
  const float* Wih0 = (const float*)d_in[8];
  const float* bih0 = (const float*)d_in[10]; const float* bhh0 = (const float*)d_in[11];
  const float* Wih1 = (const float*)d_in[12];
  const float* bih1 = (const float*)d_in[14]; const float* bhh1 = (const float*)d_in[15];
  const float* Wv1  = (const float*)d_in[16]; const float* bv1  = (const float*)d_in[17];
  const float* Wv2  = (const float*)d_in[18]; const float* bv2  = (const float*)d_in[19];
  const float* Wt1  = (const float*)d_in[20]; const float* bt1  = (const float*)d_in[21];
  const float* Wt2  = (const float*)d_in[22]; const float* bt2  = (const float*)d_in[23];

  const int N  = in_sizes[0] / 128;
  const int E  = in_sizes[1] / 2;
  const int NB = (N + 1023) / 1024;

  char* w = (char*)d_ws;
  auto take = [&](size_t bytes)->char*{ char* p = w; w += (bytes + 255) & ~(size_t)255; return p; };
  int*   deg    = (int*)  take((size_t)N*4);
  int*   offs   = (int*)  take((size_t)(N+1)*4);
  int*   cursor = (int*)  take((size_t)N*4);
  int*   csr    = (int*)  take((size_t)E*4);
  float* dinv   = (float*)take((size_t)N*4);
  int*   bsums  = (int*)  take((size_t)NB*4);
  int*   boffs  = (int*)  take((size_t)NB*4);
  float* bufA   = (float*)take((size_t)N*64*4);
  float* bufB   = (float*)take((size_t)N*64*4);
  (void)ws_size; (void)n_in; (void)out_size;

  // --- CSR + normalization (once, reused by all 3 layers) ---
  hipMemsetAsync(deg, 0, (size_t)N*4, stream);
  if ((E & 3) == 0){
    const int E4 = E >> 2;
    count_kernel_v4<<<(E4+255)/256, 256, 0, stream>>>(ei + E, deg, E4);
  } else {
    count_kernel   <<<(E+255)/256,  256, 0, stream>>>(ei + E, deg, E);
  }
  scan_reduce_kernel<<<NB,          256, 0, stream>>>(deg, bsums, N);
  scan_block_kernel <<<1,           128, 0, stream>>>(bsums, boffs, NB);
  scan_final_kernel <<<NB,          256, 0, stream>>>(deg, boffs, offs, N, E);
  dinv_kernel       <<<(N+255)/256, 256, 0, stream>>>(deg, offs, cursor, dinv, N);
  if ((E & 3) == 0){
    const int E4 = E >> 2;
    fill_kernel_v4<<<(E4+255)/256, 256, 0, stream>>>(ei, cursor, csr, E, E4);
  } else {
    fill_kernel   <<<(E+255)/256,  256, 0, stream>>>(ei, cursor, csr, E);
  }

  // --- GCN layers (ping-pong bufA/bufB) ---
  transform_kernel<128><<<(N+15)/16, 256, 0, stream>>>(x,    W1, dinv, bufA, N);
  agg_kernel           <<<(N+3)/4,   256, 0, stream>>>(bufA, dinv, offs, csr, b1, bufB, N);
  transform_kernel<64> <<<(N+15)/16, 256, 0, stream>>>(bufB, W2, dinv, bufA, N);
  agg_kernel           <<<(N+3)/4,   256, 0, stream>>>(bufA, dinv, offs, csr, b2, bufB, N);
  transform_kernel<64> <<<(N+15)/16, 256, 0, stream>>>(bufB, W3, dinv, bufA, N);
  agg_kernel           <<<(N+3)/4,   256, 0, stream>>>(bufA, dinv, offs, csr, b3, bufB, N);

  // --- LSTM x2 (seq_len=1, zero state) ---
  lstm_kernel<64><<<(N+7)/8, 256, 0, stream>>>(bufB, Wih0, bih0, bhh0, bufA, N);
  lstm_kernel<32><<<(N+7)/8, 256, 0, stream>>>(bufA, Wih1, bih1, bhh1, bufB, N);

  // --- Heads ---
  heads_kernel<<<(N+255)/256, 256, 0, stream>>>(bufB, Wv1, bv1, Wv2, bv2,
                                                Wt1, bt1, Wt2, bt2, (float*)d_out, N);
}

// Round 3
// 552.250 us; speedup vs baseline: 1.7319x; 1.2527x over previous
//
#include <hip/hip_runtime.h>
#include <math.h>

// TemporalWasteGNN: 3x GCNConv (symmetric-norm, self-loops) -> 2x LSTM(seq=1, h0=c0=0)
// -> two MLP heads. fp32 I/O, bf16 intermediate features.
//
// R3: (1) bucketed CSR build: bin edges by dst>>8 so deg/cursor atomics and csr
//     writes are block-local (kills the 17x HBM write amplification seen in R2).
//     (2) bf16 storage for transformed features + inter-layer activations:
//     halves the agg gather traffic. agg upgraded to 8-way neighbor ILP.

typedef unsigned int  u32;
typedef unsigned short u16;

static __device__ __forceinline__ float sigmoidf_(float x){ return 1.f/(1.f+expf(-x)); }
static __device__ __forceinline__ float bf2f(u16 u){ return __uint_as_float(((u32)u)<<16); }
static __device__ __forceinline__ u16   f2bf(float f){
  u32 x = __float_as_uint(f);
  return (u16)((x + 0x7fffu + ((x>>16)&1u)) >> 16);   // round-to-nearest-even
}

#define MAXBK 512   // buckets of 256 dst nodes; N <= 131072

// ---------------- bucketed CSR build ----------------
__global__ __launch_bounds__(512) void bucket_hist_kernel(const int* __restrict__ dstA,
                                                          int* __restrict__ bhist, int E){
  __shared__ int h[MAXBK];
  for (int i=threadIdx.x; i<MAXBK; i+=512) h[i]=0;
  __syncthreads();
  const int base = blockIdx.x*8192;
  #pragma unroll
  for (int j=0;j<16;++j){
    int e = base + j*512 + threadIdx.x;
    if (e < E) atomicAdd(&h[dstA[e]>>8], 1);
  }
  __syncthreads();
  for (int i=threadIdx.x; i<MAXBK; i+=512) if (h[i]) atomicAdd(&bhist[i], h[i]);
}

__global__ __launch_bounds__(512) void bucket_scan_kernel(const int* __restrict__ bhist,
                                                          int* __restrict__ bcur){
  __shared__ int ts[MAXBK];
  int v = bhist[threadIdx.x];
  ts[threadIdx.x] = v; __syncthreads();
  for (int off=1; off<MAXBK; off<<=1){
    int t = (threadIdx.x>=off) ? ts[threadIdx.x-off] : 0;
    __syncthreads();
    ts[threadIdx.x] += t;
    __syncthreads();
  }
  bcur[threadIdx.x] = ts[threadIdx.x] - v;   // exclusive prefix = bucket cursor start
}

// Bin edges into bucket-contiguous (srcB,dstB). Per block: LDS histogram with
// atomic-return ranks, ONE global atomic per touched bucket, then scatter.
// A bucket's bytes from one block are contiguous -> writes merge in that XCD's L2.
__global__ __launch_bounds__(512) void bin_kernel(const int* __restrict__ srcA,
                                                  const int* __restrict__ dstA,
                                                  int* __restrict__ bcur,
                                                  int* __restrict__ srcB,
                                                  int* __restrict__ dstB, int E){
  __shared__ int h[MAXBK];
  __shared__ int basev[MAXBK];
  for (int i=threadIdx.x; i<MAXBK; i+=512) h[i]=0;
  __syncthreads();
  const int base = blockIdx.x*8192;
  int br[16]; int dv[16];
  #pragma unroll
  for (int j=0;j<16;++j){
    int e = base + j*512 + threadIdx.x;
    if (e < E){
      int d = dstA[e]; int b = d>>8;
      int r = atomicAdd(&h[b], 1);
      br[j] = (b<<16) | r;                 // r < 8192 fits
      dv[j] = d;
    } else br[j] = -1;
  }
  __syncthreads();
  for (int i=threadIdx.x; i<MAXBK; i+=512){
    int c = h[i];
    basev[i] = c ? atomicAdd(&bcur[i], c) : 0;
  }
  __syncthreads();
  #pragma unroll
  for (int j=0;j<16;++j){
    if (br[j] >= 0){
      int e = base + j*512 + threadIdx.x;
      int pos = basev[br[j]>>16] + (br[j] & 0xffff);
      srcB[pos] = srcA[e];
      dstB[pos] = dv[j];
    }
  }
}

__global__ void count2_kernel(const int* __restrict__ dstB, int* __restrict__ deg, int E){
  int e = blockIdx.x*256 + threadIdx.x;
  if (e < E) atomicAdd(&deg[dstB[e]], 1);   // binned: block's atomics span ~1KB
}

__global__ void fill2_kernel(const int* __restrict__ srcB, const int* __restrict__ dstB,
                             int* __restrict__ cursor, int* __restrict__ csr, int E){
  int e = blockIdx.x*256 + threadIdx.x;
  if (e < E){
    int pos = atomicAdd(&cursor[dstB[e]], 1);
    csr[pos] = srcB[e];                     // binned: block's writes span ~16KB
  }
}

// fallback (N too large for bucketing) -------------
__global__ void count_kernel(const int* __restrict__ dsts, int* __restrict__ deg, int E){
  int e = blockIdx.x*256 + threadIdx.x;
  if (e < E) atomicAdd(&deg[dsts[e]], 1);
}
__global__ void fill_kernel(const int* __restrict__ ei, int* __restrict__ cursor,
                            int* __restrict__ csr, int E){
  int e = blockIdx.x*256 + threadIdx.x;
  if (e < E){
    int d = ei[E + e];
    int pos = atomicAdd(&cursor[d], 1);
    csr[pos] = ei[e];
  }
}

// ---------------- deg scan -> offs ----------------
__global__ void scan_reduce_kernel(const int* __restrict__ deg, int* __restrict__ bsums, int n){
  __shared__ int sd[256];
  int base = blockIdx.x*1024 + threadIdx.x*4;
  int s = 0;
  #pragma unroll
  for (int j=0;j<4;++j){ int idx=base+j; if (idx<n) s += deg[idx]; }
  sd[threadIdx.x] = s; __syncthreads();
  for (int off=128; off>0; off>>=1){
    if (threadIdx.x < off) sd[threadIdx.x] += sd[threadIdx.x+off];
    __syncthreads();
  }
  if (threadIdx.x==0) bsums[blockIdx.x] = sd[0];
}

__global__ void scan_block_kernel(const int* __restrict__ bsums, int* __restrict__ boffs, int nb){
  __shared__ int ts[128];
  if (nb <= 128){
    int v = (threadIdx.x < nb) ? bsums[threadIdx.x] : 0;
    ts[threadIdx.x] = v; __syncthreads();
    for (int off=1; off<128; off<<=1){
      int t = (threadIdx.x>=off) ? ts[threadIdx.x-off] : 0;
      __syncthreads();
      ts[threadIdx.x] += t;
      __syncthreads();
    }
    if (threadIdx.x < nb) boffs[threadIdx.x] = ts[threadIdx.x] - v;
  } else if (threadIdx.x==0){
    int run=0;
    for (int b=0;b<nb;++b){ int t=bsums[b]; boffs[b]=run; run+=t; }
  }
}

__global__ void scan_final_kernel(const int* __restrict__ deg, const int* __restrict__ boffs,
                                  int* __restrict__ offs, int n, int E){
  __shared__ int ts[256];
  int base = blockIdx.x*1024 + threadIdx.x*4;
  int v[4]; int s=0;
  #pragma unroll
  for (int j=0;j<4;++j){ int idx=base+j; v[j] = (idx<n) ? deg[idx] : 0; s += v[j]; }
  ts[threadIdx.x] = s; __syncthreads();
  for (int off=1; off<256; off<<=1){
    int t = (threadIdx.x>=off) ? ts[threadIdx.x-off] : 0;
    __syncthreads();
    ts[threadIdx.x] += t;
    __syncthreads();
  }
  int excl = boffs[blockIdx.x] + (threadIdx.x ? ts[threadIdx.x-1] : 0);
  #pragma unroll
  for (int j=0;j<4;++j){ int idx=base+j; if (idx<n){ offs[idx]=excl; excl+=v[j]; } }
  if (blockIdx.x==0 && threadIdx.x==0) offs[n] = E;
}

__global__ void dinv_kernel(const int* __restrict__ deg, const int* __restrict__ offs,
                            int* __restrict__ cursor, float* __restrict__ dinv, int n){
  int i = blockIdx.x*256 + threadIdx.x;
  if (i < n){
    dinv[i] = rsqrtf((float)(deg[i] + 1));
    cursor[i] = offs[i];
  }
}

// ---------------- GCN transform: Y[n][c] = bf16( dinv[n] * sum_k X[n][k] * W[k][c] ) ----------------
template<int KD, typename TIN>
__global__ void transform_kernel(const TIN* __restrict__ X, const float* __restrict__ W,
                                 const float* __restrict__ dinv, u16* __restrict__ Y, int n){
  __shared__ float Wl[KD*64];
  __shared__ float Xl[4*KD];
  for (int i=threadIdx.x; i<KD*64; i+=256) Wl[i] = W[i];
  const int lane = threadIdx.x & 63;
  const int sub  = threadIdx.x >> 6;
  for (int it=0; it<4; ++it){
    const int nodeBase = blockIdx.x*16 + it*4;
    __syncthreads();
    for (int i=threadIdx.x; i<4*KD; i+=256){
      int gi = nodeBase*KD + i;
      float v = 0.f;
      if (gi < n*KD){
        TIN t = X[gi];
        if constexpr (sizeof(TIN)==2) v = bf2f((u16)t); else v = (float)t;
      }
      Xl[i] = v;
    }
    __syncthreads();
    const int node = nodeBase + sub;
    if (node < n){
      float acc = 0.f;
      #pragma unroll 16
      for (int k=0; k<KD; ++k)
        acc = fmaf(Xl[sub*KD + k], Wl[k*64 + lane], acc);
      Y[node*64 + lane] = f2bf(acc * dinv[node]);
    }
  }
}

// ---------------- GCN aggregate: one wave per node, 8-way neighbor ILP (bf16 rows) ----------------
// lane = slot*8 + c8; slot handles neighbors j=beg+slot, step 8; c8 reads uint4
// (8 bf16, 16B) -> 8 lanes cover the 128B row. Reduce slots via xor 8/16/32.
__global__ void agg_kernel(const u16* __restrict__ Hts, const float* __restrict__ dinv,
                           const int* __restrict__ offs, const int* __restrict__ csr,
                           const float* __restrict__ bias, u16* __restrict__ Hout, int n){
  const int node = blockIdx.x*4 + (threadIdx.x >> 6);
  if (node >= n) return;
  const int lane = threadIdx.x & 63;
  const int c8   = lane & 7;
  const int slot = lane >> 3;
  const uint4* __restrict__ H = (const uint4*)Hts;     // row = 8 x uint4
  float acc[8];
  #pragma unroll
  for (int i=0;i<8;++i) acc[i]=0.f;
  const int beg = offs[node], end = offs[node+1];
  for (int j = beg + slot; j < end; j += 8){
    int s = csr[j];
    uint4 v = H[s*8 + c8];
    acc[0] += __uint_as_float(v.x<<16); acc[1] += __uint_as_float(v.x & 0xffff0000u);
    acc[2] += __uint_as_float(v.y<<16); acc[3] += __uint_as_float(v.y & 0xffff0000u);
    acc[4] += __uint_as_float(v.z<<16); acc[5] += __uint_as_float(v.z & 0xffff0000u);
    acc[6] += __uint_as_float(v.w<<16); acc[7] += __uint_as_float(v.w & 0xffff0000u);
  }
  #pragma unroll
  for (int i=0;i<8;++i) acc[i] += __shfl_xor(acc[i], 8);
  #pragma unroll
  for (int i=0;i<8;++i) acc[i] += __shfl_xor(acc[i], 16);
  #pragma unroll
  for (int i=0;i<8;++i) acc[i] += __shfl_xor(acc[i], 32);
  if (slot == 0){
    uint4 sv = H[node*8 + c8];                         // self-loop (already * dinv)
    float s[8];
    s[0]=__uint_as_float(sv.x<<16); s[1]=__uint_as_float(sv.x & 0xffff0000u);
    s[2]=__uint_as_float(sv.y<<16); s[3]=__uint_as_float(sv.y & 0xffff0000u);
    s[4]=__uint_as_float(sv.z<<16); s[5]=__uint_as_float(sv.z & 0xffff0000u);
    s[6]=__uint_as_float(sv.w<<16); s[7]=__uint_as_float(sv.w & 0xffff0000u);
    float4 b0 = ((const float4*)bias)[c8*2];
    float4 b1 = ((const float4*)bias)[c8*2+1];
    const float dv = dinv[node];
    float o[8];
    o[0]=fmaxf(fmaf(acc[0]+s[0],dv,b0.x),0.f); o[1]=fmaxf(fmaf(acc[1]+s[1],dv,b0.y),0.f);
    o[2]=fmaxf(fmaf(acc[2]+s[2],dv,b0.z),0.f); o[3]=fmaxf(fmaf(acc[3]+s[3],dv,b0.w),0.f);
    o[4]=fmaxf(fmaf(acc[4]+s[4],dv,b1.x),0.f); o[5]=fmaxf(fmaf(acc[5]+s[5],dv,b1.y),0.f);
    o[6]=fmaxf(fmaf(acc[6]+s[6],dv,b1.z),0.f); o[7]=fmaxf(fmaf(acc[7]+s[7],dv,b1.w),0.f);
    uint4 w;
    w.x = (u32)f2bf(o[0]) | ((u32)f2bf(o[1])<<16);
    w.y = (u32)f2bf(o[2]) | ((u32)f2bf(o[3])<<16);
    w.z = (u32)f2bf(o[4]) | ((u32)f2bf(o[5])<<16);
    w.w = (u32)f2bf(o[6]) | ((u32)f2bf(o[7])<<16);
    ((uint4*)Hout)[node*8 + c8] = w;
  }
}

// ---------------- LSTM (seq=1, h0=c0=0): only i,g,o gates matter ----------------
template<int IN, typename TIN>
__global__ void lstm_kernel(const TIN* __restrict__ X, const float* __restrict__ Wih,
                            const float* __restrict__ bih, const float* __restrict__ bhh,
                            float* __restrict__ Hout, int n){
  __shared__ float Wl[128*(IN+1)];
  __shared__ float bl[128];
  for (int i=threadIdx.x; i<128*IN; i+=256){
    int r = i / IN, k = i - r*IN;
    Wl[r*(IN+1) + k] = Wih[i];
  }
  for (int i=threadIdx.x; i<128; i+=256) bl[i] = bih[i] + bhh[i];
  __syncthreads();
  const int node = blockIdx.x*8 + (threadIdx.x >> 5);
  const int d    = threadIdx.x & 31;
  if (node >= n) return;
  const TIN* xr = X + node*IN;
  float gi = bl[d], gg = bl[64+d], go = bl[96+d];
  #pragma unroll 8
  for (int k=0; k<IN; ++k){
    float xv;
    TIN t = xr[k];
    if constexpr (sizeof(TIN)==2) xv = bf2f((u16)t); else xv = (float)t;
    gi = fmaf(xv, Wl[d      *(IN+1) + k], gi);
    gg = fmaf(xv, Wl[(64+d) *(IN+1) + k], gg);
    go = fmaf(xv, Wl[(96+d) *(IN+1) + k], go);
  }
  float c = sigmoidf_(gi) * tanhf(gg);
  Hout[node*32 + d] = sigmoidf_(go) * tanhf(c);
}

// ---------------- Heads ----------------
__global__ void heads_kernel(const float* __restrict__ H,
                             const float* __restrict__ Wv1, const float* __restrict__ bv1,
                             const float* __restrict__ Wv2, const float* __restrict__ bv2,
                             const float* __restrict__ Wt1, const float* __restrict__ bt1,
                             const float* __restrict__ Wt2, const float* __restrict__ bt2,
                             float* __restrict__ out, int n){
  __shared__ float Wv1l[1024], Wt1l[1024], Wt2l[320], Wv2l[32], bv1l[32], bt1l[32], bt2l[10];
  for (int i=threadIdx.x; i<1024; i+=256){ Wv1l[i]=Wv1[i]; Wt1l[i]=Wt1[i]; }
  for (int i=threadIdx.x; i<320;  i+=256) Wt2l[i]=Wt2[i];
  if (threadIdx.x < 32){
    Wv2l[threadIdx.x]=Wv2[threadIdx.x];
    bv1l[threadIdx.x]=bv1[threadIdx.x];
    bt1l[threadIdx.x]=bt1[threadIdx.x];
  }
  if (threadIdx.x < 10) bt2l[threadIdx.x]=bt2[threadIdx.x];
  __syncthreads();
  const int node = blockIdx.x*256 + threadIdx.x;
  if (node >= n) return;
  float h[32];
  #pragma unroll
  for (int k=0;k<32;++k) h[k] = H[node*32 + k];
  float vol = bv2[0];
  float tacc[10];
  #pragma unroll
  for (int k=0;k<10;++k) tacc[k] = bt2l[k];
  for (int j=0;j<32;++j){
    float av = bv1l[j], at = bt1l[j];
    #pragma unroll
    for (int k=0;k<32;++k){
      av = fmaf(h[k], Wv1l[k*32 + j], av);
      at = fmaf(h[k], Wt1l[k*32 + j], at);
    }
    av = fmaxf(av, 0.f);
    at = fmaxf(at, 0.f);
    vol = fmaf(av, Wv2l[j], vol);
    #pragma unroll
    for (int k=0;k<10;++k) tacc[k] = fmaf(at, Wt2l[j*10 + k], tacc[k]);
  }
  out[node] = vol;
  #pragma unroll
  for (int k=0;k<10;++k) out[n + node*10 + k] = tacc[k];
}

extern "C" void kernel_launch(void* const* d_in, const int* in_sizes, int n_in,
                              void* d_out, int out_size, void* d_ws, size_t ws_size,
                              hipStream_t stream){
  const float* x    = (const float*)d_in[0];
  const int*   ei   = (const int*)  d_in[1];
  const float* W1   = (const float*)d_in[2];  const float* b1   = (const float*)d_in[3];
  const float* W2   = (const float*)d_in[4];  const float* b2   = (const float*)d_in[5];
  const float* W3   = (const float*)d_in[6];  const float* b3   = (const float*)d_in[7];
  const float* Wih0 = (const float*)d_in[8];
  const float* bih0 = (const float*)d_in[10]; const float* bhh0 = (const float*)d_in[11];
  const float* Wih1 = (const float*)d_in[12];
  const float* bih1 = (const float*)d_in[14]; const float* bhh1 = (const float*)d_in[15];
  const float* Wv1  = (const float*)d_in[16]; const float* bv1  = (const float*)d_in[17];
  const float* Wv2  = (const float*)d_in[18]; const float* bv2  = (const float*)d_in[19];
  const float* Wt1  = (const float*)d_in[20]; const float* bt1  = (const float*)d_in[21];
  const float* Wt2  = (const float*)d_in[22]; const float* bt2  = (const float*)d_in[23];

  const int N  = in_sizes[0] / 128;
  const int E  = in_sizes[1] / 2;
  const int NB = (N + 1023) / 1024;
  const int EB = (E + 8191) / 8192;

  char* w = (char*)d_ws;
  auto take = [&](size_t bytes)->char*{ char* p = w; w += (bytes + 255) & ~(size_t)255; return p; };
  int*   deg    = (int*)  take((size_t)N*4);
  int*   offs   = (int*)  take((size_t)(N+1)*4);
  int*   cursor = (int*)  take((size_t)N*4);
  int*   csr    = (int*)  take((size_t)E*4);
  float* dinv   = (float*)take((size_t)N*4);
  int*   bsums  = (int*)  take((size_t)NB*4);
  int*   boffs  = (int*)  take((size_t)NB*4);
  int*   bhist  = (int*)  take((size_t)MAXBK*4);
  int*   bcur   = (int*)  take((size_t)MAXBK*4);
  int*   srcB   = (int*)  take((size_t)E*4);
  int*   dstB   = (int*)  take((size_t)E*4);
  u16*   bufTS  = (u16*)  take((size_t)N*64*2);   // transformed (pre-agg), bf16
  u16*   bufH   = (u16*)  take((size_t)N*64*2);   // post-agg activations, bf16
  float* lstmA  = (float*)srcB;                   // reuse: srcB+dstB free after fill2
  float* lstmB  = (float*)bufTS;                  // reuse: bufTS free after agg3
  (void)ws_size; (void)n_in; (void)out_size;

  // --- CSR build ---
  hipMemsetAsync(deg, 0, (size_t)N*4, stream);
  if (N <= MAXBK*256){
    hipMemsetAsync(bhist, 0, (size_t)MAXBK*4, stream);
    bucket_hist_kernel<<<EB, 512, 0, stream>>>(ei + E, bhist, E);
    bucket_scan_kernel<<<1,  512, 0, stream>>>(bhist, bcur);
    bin_kernel        <<<EB, 512, 0, stream>>>(ei, ei + E, bcur, srcB, dstB, E);
    count2_kernel     <<<(E+255)/256, 256, 0, stream>>>(dstB, deg, E);
  } else {
    count_kernel      <<<(E+255)/256, 256, 0, stream>>>(ei + E, deg, E);
  }
  scan_reduce_kernel<<<NB,          256, 0, stream>>>(deg, bsums, N);
  scan_block_kernel <<<1,           128, 0, stream>>>(bsums, boffs, NB);
  scan_final_kernel <<<NB,          256, 0, stream>>>(deg, boffs, offs, N, E);
  dinv_kernel       <<<(N+255)/256, 256, 0, stream>>>(deg, offs, cursor, dinv, N);
  if (N <= MAXBK*256){
    fill2_kernel<<<(E+255)/256, 256, 0, stream>>>(srcB, dstB, cursor, csr, E);
  } else {
    fill_kernel <<<(E+255)/256, 256, 0, stream>>>(ei, cursor, csr, E);
  }

  // --- GCN layers ---
  transform_kernel<128,float><<<(N+15)/16, 256, 0, stream>>>(x,    W1, dinv, bufTS, N);
  agg_kernel                 <<<(N+3)/4,   256, 0, stream>>>(bufTS, dinv, offs, csr, b1, bufH, N);
  transform_kernel<64,u16>   <<<(N+15)/16, 256, 0, stream>>>(bufH, W2, dinv, bufTS, N);
  agg_kernel                 <<<(N+3)/4,   256, 0, stream>>>(bufTS, dinv, offs, csr, b2, bufH, N);
  transform_kernel<64,u16>   <<<(N+15)/16, 256, 0, stream>>>(bufH, W3, dinv, bufTS, N);
  agg_kernel                 <<<(N+3)/4,   256, 0, stream>>>(bufTS, dinv, offs, csr, b3, bufH, N);

  // --- LSTM x2 (seq_len=1, zero state) ---
  lstm_kernel<64,u16>  <<<(N+7)/8, 256, 0, stream>>>(bufH,  Wih0, bih0, bhh0, lstmA, N);
  lstm_kernel<32,float><<<(N+7)/8, 256, 0, stream>>>(lstmA, Wih1, bih1, bhh1, lstmB, N);

  // --- Heads ---
  heads_kernel<<<(N+255)/256, 256, 0, stream>>>(lstmB, Wv1, bv1, Wv2, bv2,
                                                Wt1, bt1, Wt2, bt2, (float*)d_out, N);
}

// Round 4
// 433.223 us; speedup vs baseline: 2.2077x; 1.2747x over previous
//
#include <hip/hip_runtime.h>
#include <math.h>

// TemporalWasteGNN: 3x GCNConv (symmetric-norm, self-loops) -> 2x LSTM(seq=1, h0=c0=0)
// -> two MLP heads. fp32 I/O, bf16 intermediate features.
//
// R4: transform kernels rewritten as MFMA GEMMs (mfma_f32_16x16x32_bf16).
//     Per block: 128-node tile, X staged to LDS bf16 (+8 pad), W fragments
//     preloaded to registers -> K-loop is 2 ds_read_b128 + 8 MFMA per step.
//     R3's bucketed CSR build + bf16 8-way-ILP agg retained.

typedef unsigned int  u32;
typedef unsigned short u16;
typedef short bfrag  __attribute__((ext_vector_type(8)));   // 8 bf16 (4 VGPRs)
typedef float f32x4  __attribute__((ext_vector_type(4)));

static __device__ __forceinline__ float sigmoidf_(float x){ return 1.f/(1.f+expf(-x)); }
static __device__ __forceinline__ float bf2f(u16 u){ return __uint_as_float(((u32)u)<<16); }
static __device__ __forceinline__ u16   f2bf(float f){
  u32 x = __float_as_uint(f);
  return (u16)((x + 0x7fffu + ((x>>16)&1u)) >> 16);   // round-to-nearest-even
}

#define MAXBK 512   // buckets of 256 dst nodes; N <= 131072

// ---------------- bucketed CSR build ----------------
__global__ __launch_bounds__(512) void bucket_hist_kernel(const int* __restrict__ dstA,
                                                          int* __restrict__ bhist, int E){
  __shared__ int h[MAXBK];
  for (int i=threadIdx.x; i<MAXBK; i+=512) h[i]=0;
  __syncthreads();
  const int base = blockIdx.x*8192;
  #pragma unroll
  for (int j=0;j<16;++j){
    int e = base + j*512 + threadIdx.x;
    if (e < E) atomicAdd(&h[dstA[e]>>8], 1);
  }
  __syncthreads();
  for (int i=threadIdx.x; i<MAXBK; i+=512) if (h[i]) atomicAdd(&bhist[i], h[i]);
}

__global__ __launch_bounds__(512) void bucket_scan_kernel(const int* __restrict__ bhist,
                                                          int* __restrict__ bcur){
  __shared__ int ts[MAXBK];
  int v = bhist[threadIdx.x];
  ts[threadIdx.x] = v; __syncthreads();
  for (int off=1; off<MAXBK; off<<=1){
    int t = (threadIdx.x>=off) ? ts[threadIdx.x-off] : 0;
    __syncthreads();
    ts[threadIdx.x] += t;
    __syncthreads();
  }
  bcur[threadIdx.x] = ts[threadIdx.x] - v;   // exclusive prefix
}

__global__ __launch_bounds__(512) void bin_kernel(const int* __restrict__ srcA,
                                                  const int* __restrict__ dstA,
                                                  int* __restrict__ bcur,
                                                  int* __restrict__ srcB,
                                                  int* __restrict__ dstB, int E){
  __shared__ int h[MAXBK];
  __shared__ int basev[MAXBK];
  for (int i=threadIdx.x; i<MAXBK; i+=512) h[i]=0;
  __syncthreads();
  const int base = blockIdx.x*8192;
  int br[16]; int dv[16];
  #pragma unroll
  for (int j=0;j<16;++j){
    int e = base + j*512 + threadIdx.x;
    if (e < E){
      int d = dstA[e]; int b = d>>8;
      int r = atomicAdd(&h[b], 1);
      br[j] = (b<<16) | r;
      dv[j] = d;
    } else br[j] = -1;
  }
  __syncthreads();
  for (int i=threadIdx.x; i<MAXBK; i+=512){
    int c = h[i];
    basev[i] = c ? atomicAdd(&bcur[i], c) : 0;
  }
  __syncthreads();
  #pragma unroll
  for (int j=0;j<16;++j){
    if (br[j] >= 0){
      int e = base + j*512 + threadIdx.x;
      int pos = basev[br[j]>>16] + (br[j] & 0xffff);
      srcB[pos] = srcA[e];
      dstB[pos] = dv[j];
    }
  }
}

__global__ void count2_kernel(const int* __restrict__ dstB, int* __restrict__ deg, int E){
  int e = blockIdx.x*256 + threadIdx.x;
  if (e < E) atomicAdd(&deg[dstB[e]], 1);
}

__global__ void fill2_kernel(const int* __restrict__ srcB, const int* __restrict__ dstB,
                             int* __restrict__ cursor, int* __restrict__ csr, int E){
  int e = blockIdx.x*256 + threadIdx.x;
  if (e < E){
    int pos = atomicAdd(&cursor[dstB[e]], 1);
    csr[pos] = srcB[e];
  }
}

// fallback (N too large for bucketing)
__global__ void count_kernel(const int* __restrict__ dsts, int* __restrict__ deg, int E){
  int e = blockIdx.x*256 + threadIdx.x;
  if (e < E) atomicAdd(&deg[dsts[e]], 1);
}
__global__ void fill_kernel(const int* __restrict__ ei, int* __restrict__ cursor,
                            int* __restrict__ csr, int E){
  int e = blockIdx.x*256 + threadIdx.x;
  if (e < E){
    int d = ei[E + e];
    int pos = atomicAdd(&cursor[d], 1);
    csr[pos] = ei[e];
  }
}

// ---------------- deg scan -> offs ----------------
__global__ void scan_reduce_kernel(const int* __restrict__ deg, int* __restrict__ bsums, int n){
  __shared__ int sd[256];
  int base = blockIdx.x*1024 + threadIdx.x*4;
  int s = 0;
  #pragma unroll
  for (int j=0;j<4;++j){ int idx=base+j; if (idx<n) s += deg[idx]; }
  sd[threadIdx.x] = s; __syncthreads();
  for (int off=128; off>0; off>>=1){
    if (threadIdx.x < off) sd[threadIdx.x] += sd[threadIdx.x+off];
    __syncthreads();
  }
  if (threadIdx.x==0) bsums[blockIdx.x] = sd[0];
}

__global__ void scan_block_kernel(const int* __restrict__ bsums, int* __restrict__ boffs, int nb){
  __shared__ int ts[128];
  if (nb <= 128){
    int v = (threadIdx.x < nb) ? bsums[threadIdx.x] : 0;
    ts[threadIdx.x] = v; __syncthreads();
    for (int off=1; off<128; off<<=1){
      int t = (threadIdx.x>=off) ? ts[threadIdx.x-off] : 0;
      __syncthreads();
      ts[threadIdx.x] += t;
      __syncthreads();
    }
    if (threadIdx.x < nb) boffs[threadIdx.x] = ts[threadIdx.x] - v;
  } else if (threadIdx.x==0){
    int run=0;
    for (int b=0;b<nb;++b){ int t=bsums[b]; boffs[b]=run; run+=t; }
  }
}

__global__ void scan_final_kernel(const int* __restrict__ deg, const int* __restrict__ boffs,
                                  int* __restrict__ offs, int n, int E){
  __shared__ int ts[256];
  int base = blockIdx.x*1024 + threadIdx.x*4;
  int v[4]; int s=0;
  #pragma unroll
  for (int j=0;j<4;++j){ int idx=base+j; v[j] = (idx<n) ? deg[idx] : 0; s += v[j]; }
  ts[threadIdx.x] = s; __syncthreads();
  for (int off=1; off<256; off<<=1){
    int t = (threadIdx.x>=off) ? ts[threadIdx.x-off] : 0;
    __syncthreads();
    ts[threadIdx.x] += t;
    __syncthreads();
  }
  int excl = boffs[blockIdx.x] + (threadIdx.x ? ts[threadIdx.x-1] : 0);
  #pragma unroll
  for (int j=0;j<4;++j){ int idx=base+j; if (idx<n){ offs[idx]=excl; excl+=v[j]; } }
  if (blockIdx.x==0 && threadIdx.x==0) offs[n] = E;
}

__global__ void dinv_kernel(const int* __restrict__ deg, const int* __restrict__ offs,
                            int* __restrict__ cursor, float* __restrict__ dinv, int n){
  int i = blockIdx.x*256 + threadIdx.x;
  if (i < n){
    dinv[i] = rsqrtf((float)(deg[i] + 1));
    cursor[i] = offs[i];
  }
}

// ---------------- GCN transform via MFMA: Y[n][c] = bf16( dinv[n] * (X@W)[n][c] ) ----------------
// Block = 256 thr (4 waves) x 128-node tile. X staged to LDS bf16 with +8 row pad
// (2-way banks = free). W staged as [K/8][64][8] so B-frags are contiguous b128,
// then preloaded into registers. Per wave: 32 nodes x 64 cols, K-loop of
// {2 ds_read_b128 + 8 mfma}. Fragment maps: A row=lane&15,k=8*(lane>>4)+j;
// C/D col=lane&15,row=4*(lane>>4)+reg [m89-verified].
template<int KD, typename TIN>
__global__ __launch_bounds__(256) void transform_mfma(const TIN* __restrict__ X,
                                                      const float* __restrict__ W,
                                                      const float* __restrict__ dinv,
                                                      u16* __restrict__ Y, int n){
  constexpr int XLD = KD + 8;
  __shared__ u16 Xl[128*XLD];
  __shared__ u16 Wl[KD*64];          // layout [KD/8][64][8]
  __shared__ float Dl[128];
  const int tid  = threadIdx.x;
  const int base = blockIdx.x*128;

  // stage W (bf16, subtiled)
  for (int i = tid; i < KD*64; i += 256){
    int k = i >> 6, col = i & 63;
    Wl[((k>>3)<<9) + (col<<3) + (k&7)] = f2bf(W[i]);
  }
  // stage dinv
  if (tid < 128){
    int nd = base + tid;
    Dl[tid] = (nd < n) ? dinv[nd] : 0.f;
  }
  // stage X tile -> bf16 LDS
  if constexpr (sizeof(TIN)==4){
    #pragma unroll
    for (int j = 0; j < (128*KD)/1024; ++j){
      int e4   = tid + j*256;                 // float4 index
      int elem = e4*4;
      int row  = elem / KD, k = elem % KD;
      int gn   = base + row;
      uint2 w2 = make_uint2(0u, 0u);
      if (gn < n){
        float4 v = ((const float4*)X)[(size_t)gn*(KD/4) + (k>>2)];
        w2.x = (u32)f2bf(v.x) | ((u32)f2bf(v.y)<<16);
        w2.y = (u32)f2bf(v.z) | ((u32)f2bf(v.w)<<16);
      }
      *((uint2*)&Xl[row*XLD + k]) = w2;
    }
  } else {
    #pragma unroll
    for (int j = 0; j < (128*KD)/1024; ++j){
      int e4   = tid + j*256;                 // 4-bf16 index
      int elem = e4*4;
      int row  = elem / KD, k = elem % KD;
      int gn   = base + row;
      uint2 v = make_uint2(0u, 0u);
      if (gn < n) v = *((const uint2*)(X + (size_t)gn*KD + k));
      *((uint2*)&Xl[row*XLD + k]) = v;
    }
  }
  __syncthreads();

  const int lane = tid & 63, wv = tid >> 6;
  const int c = lane & 15, g = lane >> 4;

  // preload W fragments (shared by all node tiles)
  bfrag wf[KD/32][4];
  #pragma unroll
  for (int kk=0; kk<KD/32; ++kk)
    #pragma unroll
    for (int nt=0; nt<4; ++nt)
      wf[kk][nt] = *((const bfrag*)&Wl[((kk*4+g)<<9) + ((nt*16+c)<<3)]);

  f32x4 acc[2][4];
  #pragma unroll
  for (int rs=0;rs<2;++rs)
    #pragma unroll
    for (int nt=0;nt<4;++nt)
      acc[rs][nt] = (f32x4){0.f,0.f,0.f,0.f};

  #pragma unroll
  for (int kk=0; kk<KD/32; ++kk){
    bfrag a0 = *((const bfrag*)&Xl[(wv*32      + c)*XLD + kk*32 + g*8]);
    bfrag a1 = *((const bfrag*)&Xl[(wv*32 + 16 + c)*XLD + kk*32 + g*8]);
    #pragma unroll
    for (int nt=0; nt<4; ++nt){
      acc[0][nt] = __builtin_amdgcn_mfma_f32_16x16x32_bf16(a0, wf[kk][nt], acc[0][nt], 0,0,0);
      acc[1][nt] = __builtin_amdgcn_mfma_f32_16x16x32_bf16(a1, wf[kk][nt], acc[1][nt], 0,0,0);
    }
  }

  #pragma unroll
  for (int rs=0;rs<2;++rs){
    int nl0 = wv*32 + rs*16 + g*4;
    #pragma unroll
    for (int r=0;r<4;++r){
      int node = base + nl0 + r;
      if (node < n){
        float dv = Dl[nl0 + r];
        #pragma unroll
        for (int nt=0;nt<4;++nt)
          Y[(size_t)node*64 + nt*16 + c] = f2bf(acc[rs][nt][r] * dv);
      }
    }
  }
}

// ---------------- GCN aggregate: one wave per node, 8-way neighbor ILP (bf16 rows) ----------------
__global__ void agg_kernel(const u16* __restrict__ Hts, const float* __restrict__ dinv,
                           const int* __restrict__ offs, const int* __restrict__ csr,
                           const float* __restrict__ bias, u16* __restrict__ Hout, int n){
  const int node = blockIdx.x*4 + (threadIdx.x >> 6);
  if (node >= n) return;
  const int lane = threadIdx.x & 63;
  const int c8   = lane & 7;
  const int slot = lane >> 3;
  const uint4* __restrict__ H = (const uint4*)Hts;
  float acc[8];
  #pragma unroll
  for (int i=0;i<8;++i) acc[i]=0.f;
  const int beg = offs[node], end = offs[node+1];
  for (int j = beg + slot; j < end; j += 8){
    int s = csr[j];
    uint4 v = H[s*8 + c8];
    acc[0] += __uint_as_float(v.x<<16); acc[1] += __uint_as_float(v.x & 0xffff0000u);
    acc[2] += __uint_as_float(v.y<<16); acc[3] += __uint_as_float(v.y & 0xffff0000u);
    acc[4] += __uint_as_float(v.z<<16); acc[5] += __uint_as_float(v.z & 0xffff0000u);
    acc[6] += __uint_as_float(v.w<<16); acc[7] += __uint_as_float(v.w & 0xffff0000u);
  }
  #pragma unroll
  for (int i=0;i<8;++i) acc[i] += __shfl_xor(acc[i], 8);
  #pragma unroll
  for (int i=0;i<8;++i) acc[i] += __shfl_xor(acc[i], 16);
  #pragma unroll
  for (int i=0;i<8;++i) acc[i] += __shfl_xor(acc[i], 32);
  if (slot == 0){
    uint4 sv = H[node*8 + c8];
    float s[8];
    s[0]=__uint_as_float(sv.x<<16); s[1]=__uint_as_float(sv.x & 0xffff0000u);
    s[2]=__uint_as_float(sv.y<<16); s[3]=__uint_as_float(sv.y & 0xffff0000u);
    s[4]=__uint_as_float(sv.z<<16); s[5]=__uint_as_float(sv.z & 0xffff0000u);
    s[6]=__uint_as_float(sv.w<<16); s[7]=__uint_as_float(sv.w & 0xffff0000u);
    float4 b0 = ((const float4*)bias)[c8*2];
    float4 b1 = ((const float4*)bias)[c8*2+1];
    const float dv = dinv[node];
    float o[8];
    o[0]=fmaxf(fmaf(acc[0]+s[0],dv,b0.x),0.f); o[1]=fmaxf(fmaf(acc[1]+s[1],dv,b0.y),0.f);
    o[2]=fmaxf(fmaf(acc[2]+s[2],dv,b0.z),0.f); o[3]=fmaxf(fmaf(acc[3]+s[3],dv,b0.w),0.f);
    o[4]=fmaxf(fmaf(acc[4]+s[4],dv,b1.x),0.f); o[5]=fmaxf(fmaf(acc[5]+s[5],dv,b1.y),0.f);
    o[6]=fmaxf(fmaf(acc[6]+s[6],dv,b1.z),0.f); o[7]=fmaxf(fmaf(acc[7]+s[7],dv,b1.w),0.f);
    uint4 w;
    w.x = (u32)f2bf(o[0]) | ((u32)f2bf(o[1])<<16);
    w.y = (u32)f2bf(o[2]) | ((u32)f2bf(o[3])<<16);
    w.z = (u32)f2bf(o[4]) | ((u32)f2bf(o[5])<<16);
    w.w = (u32)f2bf(o[6]) | ((u32)f2bf(o[7])<<16);
    ((uint4*)Hout)[node*8 + c8] = w;
  }
}

// ---------------- LSTM (seq=1, h0=c0=0): only i,g,o gates matter ----------------
template<int IN, typename TIN>
__global__ void lstm_kernel(const TIN* __restrict__ X, const float* __restrict__ Wih,
                            const float* __restrict__ bih, const float* __restrict__ bhh,
                            float* __restrict__ Hout, int n){
  __shared__ float Wl[128*(IN+1)];
  __shared__ float bl[128];
  for (int i=threadIdx.x; i<128*IN; i+=256){
    int r = i / IN, k = i - r*IN;
    Wl[r*(IN+1) + k] = Wih[i];
  }
  for (int i=threadIdx.x; i<128; i+=256) bl[i] = bih[i] + bhh[i];
  __syncthreads();
  const int node = blockIdx.x*8 + (threadIdx.x >> 5);
  const int d    = threadIdx.x & 31;
  if (node >= n) return;
  const TIN* xr = X + (size_t)node*IN;
  float gi = bl[d], gg = bl[64+d], go = bl[96+d];
  #pragma unroll 8
  for (int k=0; k<IN; ++k){
    float xv;
    TIN t = xr[k];
    if constexpr (sizeof(TIN)==2) xv = bf2f((u16)t); else xv = (float)t;
    gi = fmaf(xv, Wl[d      *(IN+1) + k], gi);
    gg = fmaf(xv, Wl[(64+d) *(IN+1) + k], gg);
    go = fmaf(xv, Wl[(96+d) *(IN+1) + k], go);
  }
  float c = sigmoidf_(gi) * tanhf(gg);
  Hout[(size_t)node*32 + d] = sigmoidf_(go) * tanhf(c);
}

// ---------------- Heads ----------------
__global__ void heads_kernel(const float* __restrict__ H,
                             const float* __restrict__ Wv1, const float* __restrict__ bv1,
                             const float* __restrict__ Wv2, const float* __restrict__ bv2,
                             const float* __restrict__ Wt1, const float* __restrict__ bt1,
                             const float* __restrict__ Wt2, const float* __restrict__ bt2,
                             float* __restrict__ out, int n){
  __shared__ float Wv1l[1024], Wt1l[1024], Wt2l[320], Wv2l[32], bv1l[32], bt1l[32], bt2l[10];
  for (int i=threadIdx.x; i<1024; i+=256){ Wv1l[i]=Wv1[i]; Wt1l[i]=Wt1[i]; }
  for (int i=threadIdx.x; i<320;  i+=256) Wt2l[i]=Wt2[i];
  if (threadIdx.x < 32){
    Wv2l[threadIdx.x]=Wv2[threadIdx.x];
    bv1l[threadIdx.x]=bv1[threadIdx.x];
    bt1l[threadIdx.x]=bt1[threadIdx.x];
  }
  if (threadIdx.x < 10) bt2l[threadIdx.x]=bt2[threadIdx.x];
  __syncthreads();
  const int node = blockIdx.x*256 + threadIdx.x;
  if (node >= n) return;
  float h[32];
  #pragma unroll
  for (int k=0;k<32;++k) h[k] = H[(size_t)node*32 + k];
  float vol = bv2[0];
  float tacc[10];
  #pragma unroll
  for (int k=0;k<10;++k) tacc[k] = bt2l[k];
  for (int j=0;j<32;++j){
    float av = bv1l[j], at = bt1l[j];
    #pragma unroll
    for (int k=0;k<32;++k){
      av = fmaf(h[k], Wv1l[k*32 + j], av);
      at = fmaf(h[k], Wt1l[k*32 + j], at);
    }
    av = fmaxf(av, 0.f);
    at = fmaxf(at, 0.f);
    vol = fmaf(av, Wv2l[j], vol);
    #pragma unroll
    for (int k=0;k<10;++k) tacc[k] = fmaf(at, Wt2l[j*10 + k], tacc[k]);
  }
  out[node] = vol;
  #pragma unroll
  for (int k=0;k<10;++k) out[n + (size_t)node*10 + k] = tacc[k];
}

extern "C" void kernel_launch(void* const* d_in, const int* in_sizes, int n_in,
                              void* d_out, int out_size, void* d_ws, size_t ws_size,
                              hipStream_t stream){
  const float* x    = (const float*)d_in[0];
  const int*   ei   = (const int*)  d_in[1];
  const float* W1   = (const float*)d_in[2];  const float* b1   = (const float*)d_in[3];
  const float* W2   = (const float*)d_in[4];  const float* b2   = (const float*)d_in[5];
  const float* W3   = (const float*)d_in[6];  const float* b3   = (const float*)d_in[7];
  const float* Wih0 = (const float*)d_in[8];
  const float* bih0 = (const float*)d_in[10]; const float* bhh0 = (const float*)d_in[11];
  const float* Wih1 = (const float*)d_in[12];
  const float* bih1 = (const float*)d_in[14]; const float* bhh1 = (const float*)d_in[15];
  const float* Wv1  = (const float*)d_in[16]; const float* bv1  = (const float*)d_in[17];
  const float* Wv2  = (const float*)d_in[18]; const float* bv2  = (const float*)d_in[19];
  const float* Wt1  = (const float*)d_in[20]; const float* bt1  = (const float*)d_in[21];
  const float* Wt2  = (const float*)d_in[22]; const float* bt2  = (const float*)d_in[23];

  const int N  = in_sizes[0] / 128;
  const int E  = in_sizes[1] / 2;
  const int NB = (N + 1023) / 1024;
  const int EB = (E + 8191) / 8192;

  char* w = (char*)d_ws;
  auto take = [&](size_t bytes)->char*{ char* p = w; w += (bytes + 255) & ~(size_t)255; return p; };
  int*   deg    = (int*)  take((size_t)N*4);
  int*   offs   = (int*)  take((size_t)(N+1)*4);
  int*   cursor = (int*)  take((size_t)N*4);
  int*   csr    = (int*)  take((size_t)E*4);
  float* dinv   = (float*)take((size_t)N*4);
  int*   bsums  = (int*)  take((size_t)NB*4);
  int*   boffs  = (int*)  take((size_t)NB*4);
  int*   bhist  = (int*)  take((size_t)MAXBK*4);
  int*   bcur   = (int*)  take((size_t)MAXBK*4);
  int*   srcB   = (int*)  take((size_t)E*4);
  int*   dstB   = (int*)  take((size_t)E*4);
  u16*   bufTS  = (u16*)  take((size_t)N*64*2);   // transformed (pre-agg), bf16
  u16*   bufH   = (u16*)  take((size_t)N*64*2);   // post-agg activations, bf16
  float* lstmA  = (float*)srcB;                   // reuse after fill2
  float* lstmB  = (float*)bufTS;                  // reuse after agg3
  (void)ws_size; (void)n_in; (void)out_size;

  // --- CSR build ---
  hipMemsetAsync(deg, 0, (size_t)N*4, stream);
  if (N <= MAXBK*256){
    hipMemsetAsync(bhist, 0, (size_t)MAXBK*4, stream);
    bucket_hist_kernel<<<EB, 512, 0, stream>>>(ei + E, bhist, E);
    bucket_scan_kernel<<<1,  512, 0, stream>>>(bhist, bcur);
    bin_kernel        <<<EB, 512, 0, stream>>>(ei, ei + E, bcur, srcB, dstB, E);
    count2_kernel     <<<(E+255)/256, 256, 0, stream>>>(dstB, deg, E);
  } else {
    count_kernel      <<<(E+255)/256, 256, 0, stream>>>(ei + E, deg, E);
  }
  scan_reduce_kernel<<<NB,          256, 0, stream>>>(deg, bsums, N);
  scan_block_kernel <<<1,           128, 0, stream>>>(bsums, boffs, NB);
  scan_final_kernel <<<NB,          256, 0, stream>>>(deg, boffs, offs, N, E);
  dinv_kernel       <<<(N+255)/256, 256, 0, stream>>>(deg, offs, cursor, dinv, N);
  if (N <= MAXBK*256){
    fill2_kernel<<<(E+255)/256, 256, 0, stream>>>(srcB, dstB, cursor, csr, E);
  } else {
    fill_kernel <<<(E+255)/256, 256, 0, stream>>>(ei, cursor, csr, E);
  }

  // --- GCN layers (MFMA transforms) ---
  const int TB = (N + 127) / 128;
  transform_mfma<128,float><<<TB, 256, 0, stream>>>(x,    W1, dinv, bufTS, N);
  agg_kernel               <<<(N+3)/4, 256, 0, stream>>>(bufTS, dinv, offs, csr, b1, bufH, N);
  transform_mfma<64,u16>   <<<TB, 256, 0, stream>>>(bufH, W2, dinv, bufTS, N);
  agg_kernel               <<<(N+3)/4, 256, 0, stream>>>(bufTS, dinv, offs, csr, b2, bufH, N);
  transform_mfma<64,u16>   <<<TB, 256, 0, stream>>>(bufH, W3, dinv, bufTS, N);
  agg_kernel               <<<(N+3)/4, 256, 0, stream>>>(bufTS, dinv, offs, csr, b3, bufH, N);

  // --- LSTM x2 (seq_len=1, zero state) ---
  lstm_kernel<64,u16>  <<<(N+7)/8, 256, 0, stream>>>(bufH,  Wih0, bih0, bhh0, lstmA, N);
  lstm_kernel<32,float><<<(N+7)/8, 256, 0, stream>>>(lstmA, Wih1, bih1, bhh1, lstmB, N);

  // --- Heads ---
  heads_kernel<<<(N+255)/256, 256, 0, stream>>>(lstmB, Wv1, bv1, Wv2, bv2,
                                                Wt1, bt1, Wt2, bt2, (float*)d_out, N);
}

// Round 6
// 365.472 us; speedup vs baseline: 2.6169x; 1.1854x over previous
//
#include <hip/hip_runtime.h>
#include <math.h>

// TemporalWasteGNN: 3x GCNConv (symmetric-norm, self-loops) -> 2x LSTM(seq=1, h0=c0=0)
// -> two MLP heads. fp32 I/O, bf16 intermediate features.
//
// R6: R5's fused lstm+heads tail, precision-repaired (R5 failed Output 1 by 3%):
//   - Wih0 staged as hi/lo bf16 pair; gate GEMM uses 2-term B-split MFMA
//     (== fp32-weight fidelity; A operand X is already exact bf16).
//   - h1/h2 stored as hi/lo bf16 pairs; lstm1/heads use 2-term A-split MFMA.
//   - X LDS tile dropped (A-frags loaded straight from global, row-coalesced);
//     H2 aliases the dead W0 LDS region -> 57.8KB LDS, 2 blocks/CU.
// R3 bucketed CSR build, R4 MFMA transforms, bf16 8-way-ILP agg retained.

typedef unsigned int  u32;
typedef unsigned short u16;
typedef short bfrag  __attribute__((ext_vector_type(8)));   // 8 bf16 (4 VGPRs)
typedef float f32x4  __attribute__((ext_vector_type(4)));

static __device__ __forceinline__ float sigmoidf_(float x){ return 1.f/(1.f+expf(-x)); }
static __device__ __forceinline__ float bf2f(u16 u){ return __uint_as_float(((u32)u)<<16); }
static __device__ __forceinline__ u16   f2bf(float f){
  u32 x = __float_as_uint(f);
  return (u16)((x + 0x7fffu + ((x>>16)&1u)) >> 16);   // round-to-nearest-even
}

#define MAXBK 512   // buckets of 256 dst nodes; N <= 131072

// ---------------- bucketed CSR build ----------------
__global__ __launch_bounds__(512) void bucket_hist_kernel(const int* __restrict__ dstA,
                                                          int* __restrict__ bhist, int E){
  __shared__ int h[MAXBK];
  for (int i=threadIdx.x; i<MAXBK; i+=512) h[i]=0;
  __syncthreads();
  const int base = blockIdx.x*8192;
  #pragma unroll
  for (int j=0;j<16;++j){
    int e = base + j*512 + threadIdx.x;
    if (e < E) atomicAdd(&h[dstA[e]>>8], 1);
  }
  __syncthreads();
  for (int i=threadIdx.x; i<MAXBK; i+=512) if (h[i]) atomicAdd(&bhist[i], h[i]);
}

__global__ __launch_bounds__(512) void bucket_scan_kernel(const int* __restrict__ bhist,
                                                          int* __restrict__ bcur){
  __shared__ int ts[MAXBK];
  int v = bhist[threadIdx.x];
  ts[threadIdx.x] = v; __syncthreads();
  for (int off=1; off<MAXBK; off<<=1){
    int t = (threadIdx.x>=off) ? ts[threadIdx.x-off] : 0;
    __syncthreads();
    ts[threadIdx.x] += t;
    __syncthreads();
  }
  bcur[threadIdx.x] = ts[threadIdx.x] - v;   // exclusive prefix
}

__global__ __launch_bounds__(512) void bin_kernel(const int* __restrict__ srcA,
                                                  const int* __restrict__ dstA,
                                                  int* __restrict__ bcur,
                                                  int* __restrict__ srcB,
                                                  int* __restrict__ dstB, int E){
  __shared__ int h[MAXBK];
  __shared__ int basev[MAXBK];
  for (int i=threadIdx.x; i<MAXBK; i+=512) h[i]=0;
  __syncthreads();
  const int base = blockIdx.x*8192;
  int br[16]; int dv[16];
  #pragma unroll
  for (int j=0;j<16;++j){
    int e = base + j*512 + threadIdx.x;
    if (e < E){
      int d = dstA[e]; int b = d>>8;
      int r = atomicAdd(&h[b], 1);
      br[j] = (b<<16) | r;
      dv[j] = d;
    } else br[j] = -1;
  }
  __syncthreads();
  for (int i=threadIdx.x; i<MAXBK; i+=512){
    int c = h[i];
    basev[i] = c ? atomicAdd(&bcur[i], c) : 0;
  }
  __syncthreads();
  #pragma unroll
  for (int j=0;j<16;++j){
    if (br[j] >= 0){
      int e = base + j*512 + threadIdx.x;
      int pos = basev[br[j]>>16] + (br[j] & 0xffff);
      srcB[pos] = srcA[e];
      dstB[pos] = dv[j];
    }
  }
}

__global__ void count2_kernel(const int* __restrict__ dstB, int* __restrict__ deg, int E){
  int e = blockIdx.x*256 + threadIdx.x;
  if (e < E) atomicAdd(&deg[dstB[e]], 1);
}

__global__ void fill2_kernel(const int* __restrict__ srcB, const int* __restrict__ dstB,
                             int* __restrict__ cursor, int* __restrict__ csr, int E){
  int e = blockIdx.x*256 + threadIdx.x;
  if (e < E){
    int pos = atomicAdd(&cursor[dstB[e]], 1);
    csr[pos] = srcB[e];
  }
}

// fallback (N too large for bucketing)
__global__ void count_kernel(const int* __restrict__ dsts, int* __restrict__ deg, int E){
  int e = blockIdx.x*256 + threadIdx.x;
  if (e < E) atomicAdd(&deg[dsts[e]], 1);
}
__global__ void fill_kernel(const int* __restrict__ ei, int* __restrict__ cursor,
                            int* __restrict__ csr, int E){
  int e = blockIdx.x*256 + threadIdx.x;
  if (e < E){
    int d = ei[E + e];
    int pos = atomicAdd(&cursor[d], 1);
    csr[pos] = ei[e];
  }
}

// ---------------- deg scan -> offs ----------------
__global__ void scan_reduce_kernel(const int* __restrict__ deg, int* __restrict__ bsums, int n){
  __shared__ int sd[256];
  int base = blockIdx.x*1024 + threadIdx.x*4;
  int s = 0;
  #pragma unroll
  for (int j=0;j<4;++j){ int idx=base+j; if (idx<n) s += deg[idx]; }
  sd[threadIdx.x] = s; __syncthreads();
  for (int off=128; off>0; off>>=1){
    if (threadIdx.x < off) sd[threadIdx.x] += sd[threadIdx.x+off];
    __syncthreads();
  }
  if (threadIdx.x==0) bsums[blockIdx.x] = sd[0];
}

__global__ void scan_block_kernel(const int* __restrict__ bsums, int* __restrict__ boffs, int nb){
  __shared__ int ts[128];
  if (nb <= 128){
    int v = (threadIdx.x < nb) ? bsums[threadIdx.x] : 0;
    ts[threadIdx.x] = v; __syncthreads();
    for (int off=1; off<128; off<<=1){
      int t = (threadIdx.x>=off) ? ts[threadIdx.x-off] : 0;
      __syncthreads();
      ts[threadIdx.x] += t;
      __syncthreads();
    }
    if (threadIdx.x < nb) boffs[threadIdx.x] = ts[threadIdx.x] - v;
  } else if (threadIdx.x==0){
    int run=0;
    for (int b=0;b<nb;++b){ int t=bsums[b]; boffs[b]=run; run+=t; }
  }
}

__global__ void scan_final_kernel(const int* __restrict__ deg, const int* __restrict__ boffs,
                                  int* __restrict__ offs, int n, int E){
  __shared__ int ts[256];
  int base = blockIdx.x*1024 + threadIdx.x*4;
  int v[4]; int s=0;
  #pragma unroll
  for (int j=0;j<4;++j){ int idx=base+j; v[j] = (idx<n) ? deg[idx] : 0; s += v[j]; }
  ts[threadIdx.x] = s; __syncthreads();
  for (int off=1; off<256; off<<=1){
    int t = (threadIdx.x>=off) ? ts[threadIdx.x-off] : 0;
    __syncthreads();
    ts[threadIdx.x] += t;
    __syncthreads();
  }
  int excl = boffs[blockIdx.x] + (threadIdx.x ? ts[threadIdx.x-1] : 0);
  #pragma unroll
  for (int j=0;j<4;++j){ int idx=base+j; if (idx<n){ offs[idx]=excl; excl+=v[j]; } }
  if (blockIdx.x==0 && threadIdx.x==0) offs[n] = E;
}

__global__ void dinv_kernel(const int* __restrict__ deg, const int* __restrict__ offs,
                            int* __restrict__ cursor, float* __restrict__ dinv, int n){
  int i = blockIdx.x*256 + threadIdx.x;
  if (i < n){
    dinv[i] = rsqrtf((float)(deg[i] + 1));
    cursor[i] = offs[i];
  }
}

// ---------------- GCN transform via MFMA (verified in R4) ----------------
template<int KD, typename TIN>
__global__ __launch_bounds__(256) void transform_mfma(const TIN* __restrict__ X,
                                                      const float* __restrict__ W,
                                                      const float* __restrict__ dinv,
                                                      u16* __restrict__ Y, int n){
  constexpr int XLD = KD + 8;
  __shared__ u16 Xl[128*XLD];
  __shared__ u16 Wl[KD*64];          // layout [KD/8][64][8]
  __shared__ float Dl[128];
  const int tid  = threadIdx.x;
  const int base = blockIdx.x*128;

  for (int i = tid; i < KD*64; i += 256){
    int k = i >> 6, col = i & 63;
    Wl[((k>>3)<<9) + (col<<3) + (k&7)] = f2bf(W[i]);
  }
  if (tid < 128){
    int nd = base + tid;
    Dl[tid] = (nd < n) ? dinv[nd] : 0.f;
  }
  if constexpr (sizeof(TIN)==4){
    #pragma unroll
    for (int j = 0; j < (128*KD)/1024; ++j){
      int e4   = tid + j*256;
      int elem = e4*4;
      int row  = elem / KD, k = elem % KD;
      int gn   = base + row;
      uint2 w2 = make_uint2(0u, 0u);
      if (gn < n){
        float4 v = ((const float4*)X)[(size_t)gn*(KD/4) + (k>>2)];
        w2.x = (u32)f2bf(v.x) | ((u32)f2bf(v.y)<<16);
        w2.y = (u32)f2bf(v.z) | ((u32)f2bf(v.w)<<16);
      }
      *((uint2*)&Xl[row*XLD + k]) = w2;
    }
  } else {
    #pragma unroll
    for (int j = 0; j < (128*KD)/1024; ++j){
      int e4   = tid + j*256;
      int elem = e4*4;
      int row  = elem / KD, k = elem % KD;
      int gn   = base + row;
      uint2 v = make_uint2(0u, 0u);
      if (gn < n) v = *((const uint2*)(X + (size_t)gn*KD + k));
      *((uint2*)&Xl[row*XLD + k]) = v;
    }
  }
  __syncthreads();

  const int lane = tid & 63, wv = tid >> 6;
  const int c = lane & 15, g = lane >> 4;

  bfrag wf[KD/32][4];
  #pragma unroll
  for (int kk=0; kk<KD/32; ++kk)
    #pragma unroll
    for (int nt=0; nt<4; ++nt)
      wf[kk][nt] = *((const bfrag*)&Wl[((kk*4+g)<<9) + ((nt*16+c)<<3)]);

  f32x4 acc[2][4];
  #pragma unroll
  for (int rs=0;rs<2;++rs)
    #pragma unroll
    for (int nt=0;nt<4;++nt)
      acc[rs][nt] = (f32x4){0.f,0.f,0.f,0.f};

  #pragma unroll
  for (int kk=0; kk<KD/32; ++kk){
    bfrag a0 = *((const bfrag*)&Xl[(wv*32      + c)*XLD + kk*32 + g*8]);
    bfrag a1 = *((const bfrag*)&Xl[(wv*32 + 16 + c)*XLD + kk*32 + g*8]);
    #pragma unroll
    for (int nt=0; nt<4; ++nt){
      acc[0][nt] = __builtin_amdgcn_mfma_f32_16x16x32_bf16(a0, wf[kk][nt], acc[0][nt], 0,0,0);
      acc[1][nt] = __builtin_amdgcn_mfma_f32_16x16x32_bf16(a1, wf[kk][nt], acc[1][nt], 0,0,0);
    }
  }

  #pragma unroll
  for (int rs=0;rs<2;++rs){
    int nl0 = wv*32 + rs*16 + g*4;
    #pragma unroll
    for (int r=0;r<4;++r){
      int node = base + nl0 + r;
      if (node < n){
        float dv = Dl[nl0 + r];
        #pragma unroll
        for (int nt=0;nt<4;++nt)
          Y[(size_t)node*64 + nt*16 + c] = f2bf(acc[rs][nt][r] * dv);
      }
    }
  }
}

// ---------------- GCN aggregate: one wave per node, 8-way neighbor ILP (bf16 rows) ----------------
__global__ void agg_kernel(const u16* __restrict__ Hts, const float* __restrict__ dinv,
                           const int* __restrict__ offs, const int* __restrict__ csr,
                           const float* __restrict__ bias, u16* __restrict__ Hout, int n){
  const int node = blockIdx.x*4 + (threadIdx.x >> 6);
  if (node >= n) return;
  const int lane = threadIdx.x & 63;
  const int c8   = lane & 7;
  const int slot = lane >> 3;
  const uint4* __restrict__ H = (const uint4*)Hts;
  float acc[8];
  #pragma unroll
  for (int i=0;i<8;++i) acc[i]=0.f;
  const int beg = offs[node], end = offs[node+1];
  for (int j = beg + slot; j < end; j += 8){
    int s = csr[j];
    uint4 v = H[s*8 + c8];
    acc[0] += __uint_as_float(v.x<<16); acc[1] += __uint_as_float(v.x & 0xffff0000u);
    acc[2] += __uint_as_float(v.y<<16); acc[3] += __uint_as_float(v.y & 0xffff0000u);
    acc[4] += __uint_as_float(v.z<<16); acc[5] += __uint_as_float(v.z & 0xffff0000u);
    acc[6] += __uint_as_float(v.w<<16); acc[7] += __uint_as_float(v.w & 0xffff0000u);
  }
  #pragma unroll
  for (int i=0;i<8;++i) acc[i] += __shfl_xor(acc[i], 8);
  #pragma unroll
  for (int i=0;i<8;++i) acc[i] += __shfl_xor(acc[i], 16);
  #pragma unroll
  for (int i=0;i<8;++i) acc[i] += __shfl_xor(acc[i], 32);
  if (slot == 0){
    uint4 sv = H[node*8 + c8];
    float s[8];
    s[0]=__uint_as_float(sv.x<<16); s[1]=__uint_as_float(sv.x & 0xffff0000u);
    s[2]=__uint_as_float(sv.y<<16); s[3]=__uint_as_float(sv.y & 0xffff0000u);
    s[4]=__uint_as_float(sv.z<<16); s[5]=__uint_as_float(sv.z & 0xffff0000u);
    s[6]=__uint_as_float(sv.w<<16); s[7]=__uint_as_float(sv.w & 0xffff0000u);
    float4 b0 = ((const float4*)bias)[c8*2];
    float4 b1 = ((const float4*)bias)[c8*2+1];
    const float dv = dinv[node];
    float o[8];
    o[0]=fmaxf(fmaf(acc[0]+s[0],dv,b0.x),0.f); o[1]=fmaxf(fmaf(acc[1]+s[1],dv,b0.y),0.f);
    o[2]=fmaxf(fmaf(acc[2]+s[2],dv,b0.z),0.f); o[3]=fmaxf(fmaf(acc[3]+s[3],dv,b0.w),0.f);
    o[4]=fmaxf(fmaf(acc[4]+s[4],dv,b1.x),0.f); o[5]=fmaxf(fmaf(acc[5]+s[5],dv,b1.y),0.f);
    o[6]=fmaxf(fmaf(acc[6]+s[6],dv,b1.z),0.f); o[7]=fmaxf(fmaf(acc[7]+s[7],dv,b1.w),0.f);
    uint4 w;
    w.x = (u32)f2bf(o[0]) | ((u32)f2bf(o[1])<<16);
    w.y = (u32)f2bf(o[2]) | ((u32)f2bf(o[3])<<16);
    w.z = (u32)f2bf(o[4]) | ((u32)f2bf(o[5])<<16);
    w.w = (u32)f2bf(o[6]) | ((u32)f2bf(o[7])<<16);
    ((uint4*)Hout)[node*8 + c8] = w;
  }
}

// ---------------- Fused LSTM x2 + heads (hi/lo split MFMA, ~fp32 fidelity) ----------------
// Gate GEMM layout as R5 (only i,g,o staged; col j -> Wih row (j<32?j:j+32)).
// Wih0 split hi/lo (B-split, 2-term MFMA == fp32 weights; A = exact bf16 X).
// h1/h2 stored hi/lo bf16 pairs (stride 40); lstm1/heads use A-split 2-term.
// X A-frags loaded straight from global (wave consumes full 128B rows).
// LDS pool (u16): W0hi[6144] W0lo[6144] W1[3072] WH[2048] H1hi[5120] H1lo[5120]
//   = 55.3KB; H2hi/H2lo alias W0hi/W0lo after lstm0 (sync-separated).
__global__ __launch_bounds__(256) void lstm_heads_fused(
    const u16* __restrict__ X,
    const float* __restrict__ Wih0, const float* __restrict__ bih0, const float* __restrict__ bhh0,
    const float* __restrict__ Wih1, const float* __restrict__ bih1, const float* __restrict__ bhh1,
    const float* __restrict__ Wv1, const float* __restrict__ bv1,
    const float* __restrict__ Wv2, const float* __restrict__ bv2,
    const float* __restrict__ Wt1, const float* __restrict__ bt1,
    const float* __restrict__ Wt2, const float* __restrict__ bt2,
    float* __restrict__ out, int n)
{
  __shared__ u16 pool[27648];
  __shared__ float b0l[96], b1l[96], bv1l[32], bt1l[32], Wv2l[32], Wt2l[320], bt2l[10];
  u16* W0hi = pool;            // 6144  [k/8][96][8]
  u16* W0lo = pool + 6144;     // 6144
  u16* W1l  = pool + 12288;    // 3072  [k/8][96][8]
  u16* WHl  = pool + 15360;    // 2048  [k/8][64][8]
  u16* H1hi = pool + 17408;    // 5120  stride 40
  u16* H1lo = pool + 22528;    // 5120
  u16* H2hi = pool;            // aliases W0hi (free after lstm0)
  u16* H2lo = pool + 5120;     // aliases W0hi/W0lo

  const int tid  = threadIdx.x;
  const int base = blockIdx.x*128;

  // ---- stage weights/biases ----
  for (int i=tid; i<64*96; i+=256){          // Wih0 gates, hi/lo bf16 subtiled
    int j = i >> 6, k = i & 63;
    int row = (j < 32) ? j : j + 32;
    float w = Wih0[row*64 + k];
    u16 hi = f2bf(w);
    int idx = ((k>>3)*768) + (j<<3) + (k&7);
    W0hi[idx] = hi;
    W0lo[idx] = f2bf(w - bf2f(hi));
  }
  for (int i=tid; i<32*96; i+=256){          // Wih1 gates (single bf16)
    int j = i >> 5, k = i & 31;
    int row = (j < 32) ? j : j + 32;
    W1l[((k>>3)*768) + (j<<3) + (k&7)] = f2bf(Wih1[row*32 + k]);
  }
  for (int i=tid; i<32*64; i+=256){          // Wv1 | Wt1 (single bf16)
    int j = i >> 5, k = i & 31;
    float v = (j < 32) ? Wv1[k*32 + j] : Wt1[k*32 + (j-32)];
    WHl[((k>>3)*512) + (j<<3) + (k&7)] = f2bf(v);
  }
  if (tid < 96){
    int row = (tid < 32) ? tid : tid + 32;
    b0l[tid] = bih0[row] + bhh0[row];
    b1l[tid] = bih1[row] + bhh1[row];
  } else if (tid < 128){
    int d = tid - 96;
    bv1l[d] = bv1[d]; bt1l[d] = bt1[d]; Wv2l[d] = Wv2[d];
  }
  for (int i=tid; i<320; i+=256) Wt2l[i] = Wt2[i];
  if (tid >= 128 && tid < 138) bt2l[tid-128] = bt2[tid-128];
  __syncthreads();

  const int lane = tid & 63, wv = tid >> 6;
  const int c = lane & 15, g = lane >> 4;
  const float bv2v = bv2[0];

  // ---- lstm0: gates = X @ W0^T (K=64, 96 cols), A from global ----
  {
    int r0 = base + wv*32 + c;      if (r0 > n-1) r0 = n-1;
    int r1 = base + wv*32 + 16 + c; if (r1 > n-1) r1 = n-1;
    bfrag a0[2], a1[2];
    #pragma unroll
    for (int kk=0; kk<2; ++kk){
      a0[kk] = *((const bfrag*)(X + (size_t)r0*64 + kk*32 + g*8));
      a1[kk] = *((const bfrag*)(X + (size_t)r1*64 + kk*32 + g*8));
    }
    f32x4 acc[2][6];
    #pragma unroll
    for (int rs=0;rs<2;++rs)
      #pragma unroll
      for (int nt=0;nt<6;++nt) acc[rs][nt] = (f32x4){0.f,0.f,0.f,0.f};
    #pragma unroll
    for (int kk=0; kk<2; ++kk){
      #pragma unroll
      for (int nt=0; nt<6; ++nt){
        int widx = (kk*4+g)*768 + ((nt*16+c)<<3);
        bfrag bh = *((const bfrag*)&W0hi[widx]);
        bfrag bl = *((const bfrag*)&W0lo[widx]);
        acc[0][nt] = __builtin_amdgcn_mfma_f32_16x16x32_bf16(a0[kk], bh, acc[0][nt], 0,0,0);
        acc[0][nt] = __builtin_amdgcn_mfma_f32_16x16x32_bf16(a0[kk], bl, acc[0][nt], 0,0,0);
        acc[1][nt] = __builtin_amdgcn_mfma_f32_16x16x32_bf16(a1[kk], bh, acc[1][nt], 0,0,0);
        acc[1][nt] = __builtin_amdgcn_mfma_f32_16x16x32_bf16(a1[kk], bl, acc[1][nt], 0,0,0);
      }
    }
    #pragma unroll
    for (int rs=0;rs<2;++rs)
      #pragma unroll
      for (int r=0;r<4;++r){
        int rl = wv*32 + rs*16 + g*4 + r;
        #pragma unroll
        for (int half=0; half<2; ++half){
          float iv = acc[rs][0+half][r] + b0l[half*16 + c];
          float gv = acc[rs][2+half][r] + b0l[32 + half*16 + c];
          float ov = acc[rs][4+half][r] + b0l[64 + half*16 + c];
          float cc = sigmoidf_(iv) * tanhf(gv);
          float hv = sigmoidf_(ov) * tanhf(cc);
          u16 hi = f2bf(hv);
          H1hi[rl*40 + half*16 + c] = hi;
          H1lo[rl*40 + half*16 + c] = f2bf(hv - bf2f(hi));
        }
      }
  }
  __syncthreads();                           // W0 reads done; H1 visible

  // ---- lstm1: gates = H1 @ W1^T (K=32, 96 cols), A-split 2-term ----
  {
    bfrag w1f[6];
    #pragma unroll
    for (int nt=0; nt<6; ++nt)
      w1f[nt] = *((const bfrag*)&W1l[g*768 + ((nt*16+c)<<3)]);
    bfrag a0h = *((const bfrag*)&H1hi[(wv*32      + c)*40 + g*8]);
    bfrag a0l = *((const bfrag*)&H1lo[(wv*32      + c)*40 + g*8]);
    bfrag a1h = *((const bfrag*)&H1hi[(wv*32 + 16 + c)*40 + g*8]);
    bfrag a1l = *((const bfrag*)&H1lo[(wv*32 + 16 + c)*40 + g*8]);
    f32x4 acc[2][6];
    #pragma unroll
    for (int rs=0;rs<2;++rs)
      #pragma unroll
      for (int nt=0;nt<6;++nt) acc[rs][nt] = (f32x4){0.f,0.f,0.f,0.f};
    #pragma unroll
    for (int nt=0; nt<6; ++nt){
      acc[0][nt] = __builtin_amdgcn_mfma_f32_16x16x32_bf16(a0h, w1f[nt], acc[0][nt], 0,0,0);
      acc[0][nt] = __builtin_amdgcn_mfma_f32_16x16x32_bf16(a0l, w1f[nt], acc[0][nt], 0,0,0);
      acc[1][nt] = __builtin_amdgcn_mfma_f32_16x16x32_bf16(a1h, w1f[nt], acc[1][nt], 0,0,0);
      acc[1][nt] = __builtin_amdgcn_mfma_f32_16x16x32_bf16(a1l, w1f[nt], acc[1][nt], 0,0,0);
    }
    __syncthreads();                         // W0 frag reads fully done before H2 overwrite
    #pragma unroll
    for (int rs=0;rs<2;++rs)
      #pragma unroll
      for (int r=0;r<4;++r){
        int rl = wv*32 + rs*16 + g*4 + r;
        #pragma unroll
        for (int half=0; half<2; ++half){
          float iv = acc[rs][0+half][r] + b1l[half*16 + c];
          float gv = acc[rs][2+half][r] + b1l[32 + half*16 + c];
          float ov = acc[rs][4+half][r] + b1l[64 + half*16 + c];
          float cc = sigmoidf_(iv) * tanhf(gv);
          float hv = sigmoidf_(ov) * tanhf(cc);
          u16 hi = f2bf(hv);
          H2hi[rl*40 + half*16 + c] = hi;
          H2lo[rl*40 + half*16 + c] = f2bf(hv - bf2f(hi));
        }
      }
  }
  __syncthreads();

  // ---- heads: [v1 | t1] = relu(H2 @ [Wv1|Wt1] + b), A-split, then 32->1 / 32->10 ----
  {
    bfrag whf[4];
    #pragma unroll
    for (int nt=0; nt<4; ++nt)
      whf[nt] = *((const bfrag*)&WHl[g*512 + ((nt*16+c)<<3)]);
    bfrag a0h = *((const bfrag*)&H2hi[(wv*32      + c)*40 + g*8]);
    bfrag a0l = *((const bfrag*)&H2lo[(wv*32      + c)*40 + g*8]);
    bfrag a1h = *((const bfrag*)&H2hi[(wv*32 + 16 + c)*40 + g*8]);
    bfrag a1l = *((const bfrag*)&H2lo[(wv*32 + 16 + c)*40 + g*8]);
    f32x4 acc[2][4];
    #pragma unroll
    for (int rs=0;rs<2;++rs)
      #pragma unroll
      for (int nt=0;nt<4;++nt) acc[rs][nt] = (f32x4){0.f,0.f,0.f,0.f};
    #pragma unroll
    for (int nt=0; nt<4; ++nt){
      acc[0][nt] = __builtin_amdgcn_mfma_f32_16x16x32_bf16(a0h, whf[nt], acc[0][nt], 0,0,0);
      acc[0][nt] = __builtin_amdgcn_mfma_f32_16x16x32_bf16(a0l, whf[nt], acc[0][nt], 0,0,0);
      acc[1][nt] = __builtin_amdgcn_mfma_f32_16x16x32_bf16(a1h, whf[nt], acc[1][nt], 0,0,0);
      acc[1][nt] = __builtin_amdgcn_mfma_f32_16x16x32_bf16(a1l, whf[nt], acc[1][nt], 0,0,0);
    }
    const float wv2a = Wv2l[c], wv2b = Wv2l[c+16];
    float wt2a[10], wt2b[10];
    #pragma unroll
    for (int k=0;k<10;++k){ wt2a[k] = Wt2l[c*10+k]; wt2b[k] = Wt2l[(c+16)*10+k]; }
    #pragma unroll
    for (int rs=0;rs<2;++rs)
      #pragma unroll
      for (int r=0;r<4;++r){
        int node = base + wv*32 + rs*16 + g*4 + r;
        float va = fmaxf(acc[rs][0][r] + bv1l[c],    0.f);
        float vb = fmaxf(acc[rs][1][r] + bv1l[c+16], 0.f);
        float ta = fmaxf(acc[rs][2][r] + bt1l[c],    0.f);
        float tb = fmaxf(acc[rs][3][r] + bt1l[c+16], 0.f);
        float pv = va*wv2a + vb*wv2b;
        pv += __shfl_xor(pv, 1); pv += __shfl_xor(pv, 2);
        pv += __shfl_xor(pv, 4); pv += __shfl_xor(pv, 8);
        float tk[10];
        #pragma unroll
        for (int k=0;k<10;++k) tk[k] = ta*wt2a[k] + tb*wt2b[k];
        #pragma unroll
        for (int k=0;k<10;++k) tk[k] += __shfl_xor(tk[k], 1);
        #pragma unroll
        for (int k=0;k<10;++k) tk[k] += __shfl_xor(tk[k], 2);
        #pragma unroll
        for (int k=0;k<10;++k) tk[k] += __shfl_xor(tk[k], 4);
        #pragma unroll
        for (int k=0;k<10;++k) tk[k] += __shfl_xor(tk[k], 8);
        if (c == 0 && node < n){
          out[node] = pv + bv2v;
          #pragma unroll
          for (int k=0;k<10;++k) out[n + (size_t)node*10 + k] = tk[k] + bt2l[k];
        }
      }
  }
}

extern "C" void kernel_launch(void* const* d_in, const int* in_sizes, int n_in,
                              void* d_out, int out_size, void* d_ws, size_t ws_size,
                              hipStream_t stream){
  const float* x    = (const float*)d_in[0];
  const int*   ei   = (const int*)  d_in[1];
  const float* W1   = (const float*)d_in[2];  const float* b1   = (const float*)d_in[3];
  const float* W2   = (const float*)d_in[4];  const float* b2   = (const float*)d_in[5];
  const float* W3   = (const float*)d_in[6];  const float* b3   = (const float*)d_in[7];
  const float* Wih0 = (const float*)d_in[8];
  const float* bih0 = (const float*)d_in[10]; const float* bhh0 = (const float*)d_in[11];
  const float* Wih1 = (const float*)d_in[12];
  const float* bih1 = (const float*)d_in[14]; const float* bhh1 = (const float*)d_in[15];
  const float* Wv1  = (const float*)d_in[16]; const float* bv1  = (const float*)d_in[17];
  const float* Wv2  = (const float*)d_in[18]; const float* bv2  = (const float*)d_in[19];
  const float* Wt1  = (const float*)d_in[20]; const float* bt1  = (const float*)d_in[21];
  const float* Wt2  = (const float*)d_in[22]; const float* bt2  = (const float*)d_in[23];

  const int N  = in_sizes[0] / 128;
  const int E  = in_sizes[1] / 2;
  const int NB = (N + 1023) / 1024;
  const int EB = (E + 8191) / 8192;

  char* w = (char*)d_ws;
  auto take = [&](size_t bytes)->char*{ char* p = w; w += (bytes + 255) & ~(size_t)255; return p; };
  int*   deg    = (int*)  take((size_t)N*4);
  int*   offs   = (int*)  take((size_t)(N+1)*4);
  int*   cursor = (int*)  take((size_t)N*4);
  int*   csr    = (int*)  take((size_t)E*4);
  float* dinv   = (float*)take((size_t)N*4);
  int*   bsums  = (int*)  take((size_t)NB*4);
  int*   boffs  = (int*)  take((size_t)NB*4);
  int*   bhist  = (int*)  take((size_t)MAXBK*4);
  int*   bcur   = (int*)  take((size_t)MAXBK*4);
  int*   srcB   = (int*)  take((size_t)E*4);
  int*   dstB   = (int*)  take((size_t)E*4);
  u16*   bufTS  = (u16*)  take((size_t)N*64*2);   // transformed (pre-agg), bf16
  u16*   bufH   = (u16*)  take((size_t)N*64*2);   // post-agg activations, bf16
  (void)ws_size; (void)n_in; (void)out_size;

  // --- CSR build ---
  hipMemsetAsync(deg, 0, (size_t)N*4, stream);
  if (N <= MAXBK*256){
    hipMemsetAsync(bhist, 0, (size_t)MAXBK*4, stream);
    bucket_hist_kernel<<<EB, 512, 0, stream>>>(ei + E, bhist, E);
    bucket_scan_kernel<<<1,  512, 0, stream>>>(bhist, bcur);
    bin_kernel        <<<EB, 512, 0, stream>>>(ei, ei + E, bcur, srcB, dstB, E);
    count2_kernel     <<<(E+255)/256, 256, 0, stream>>>(dstB, deg, E);
  } else {
    count_kernel      <<<(E+255)/256, 256, 0, stream>>>(ei + E, deg, E);
  }
  scan_reduce_kernel<<<NB,          256, 0, stream>>>(deg, bsums, N);
  scan_block_kernel <<<1,           128, 0, stream>>>(bsums, boffs, NB);
  scan_final_kernel <<<NB,          256, 0, stream>>>(deg, boffs, offs, N, E);
  dinv_kernel       <<<(N+255)/256, 256, 0, stream>>>(deg, offs, cursor, dinv, N);
  if (N <= MAXBK*256){
    fill2_kernel<<<(E+255)/256, 256, 0, stream>>>(srcB, dstB, cursor, csr, E);
  } else {
    fill_kernel <<<(E+255)/256, 256, 0, stream>>>(ei, cursor, csr, E);
  }

  // --- GCN layers (MFMA transforms) ---
  const int TB = (N + 127) / 128;
  transform_mfma<128,float><<<TB, 256, 0, stream>>>(x,    W1, dinv, bufTS, N);
  agg_kernel               <<<(N+3)/4, 256, 0, stream>>>(bufTS, dinv, offs, csr, b1, bufH, N);
  transform_mfma<64,u16>   <<<TB, 256, 0, stream>>>(bufH, W2, dinv, bufTS, N);
  agg_kernel               <<<(N+3)/4, 256, 0, stream>>>(bufTS, dinv, offs, csr, b2, bufH, N);
  transform_mfma<64,u16>   <<<TB, 256, 0, stream>>>(bufH, W3, dinv, bufTS, N);
  agg_kernel               <<<(N+3)/4, 256, 0, stream>>>(bufTS, dinv, offs, csr, b3, bufH, N);

  // --- fused LSTM x2 + heads ---
  lstm_heads_fused<<<TB, 256, 0, stream>>>(bufH,
                                           Wih0, bih0, bhh0, Wih1, bih1, bhh1,
                                           Wv1, bv1, Wv2, bv2, Wt1, bt1, Wt2, bt2,
                                           (float*)d_out, N);
}

// Round 7
// 354.110 us; speedup vs baseline: 2.7009x; 1.0321x over previous
//
#include <hip/hip_runtime.h>
#include <math.h>

// TemporalWasteGNN: 3x GCNConv (symmetric-norm, self-loops) -> 2x LSTM(seq=1, h0=c0=0)
// -> two MLP heads. fp32 I/O, bf16 intermediate features.
//
// R7: single change vs R6 (which passed): libm tanhf/expf (~50-100 branchy VALU
//     insts via __ocml) replaced with native v_exp_f32/v_rcp_f32 sequences
//     (4-5 insts) in the fused tail. The tail computes 12.8M transcendentals;
//     this cuts its VALU bill ~8x. Numerics: ~2ulp -> ~1e-6 error, negligible
//     vs the bf16 budget. All memory layouts identical to R6.
// R3 bucketed CSR build, R4 MFMA transforms, R6 hi/lo-split fused tail retained.

typedef unsigned int  u32;
typedef unsigned short u16;
typedef short bfrag  __attribute__((ext_vector_type(8)));   // 8 bf16 (4 VGPRs)
typedef float f32x4  __attribute__((ext_vector_type(4)));

#define LOG2E 1.44269504088896f
static __device__ __forceinline__ float fast_sigmoid(float x){
  // 1/(1+e^-x) : v_exp_f32 + v_rcp_f32, ~2ulp
  float t = __builtin_amdgcn_exp2f(-x * LOG2E);
  return __builtin_amdgcn_rcpf(1.f + t);
}
static __device__ __forceinline__ float fast_tanh(float x){
  // 1 - 2/(e^{2x}+1); correct saturation at +/-inf
  float t = __builtin_amdgcn_exp2f(x * (2.f * LOG2E));
  return 1.f - 2.f * __builtin_amdgcn_rcpf(t + 1.f);
}
static __device__ __forceinline__ float bf2f(u16 u){ return __uint_as_float(((u32)u)<<16); }
static __device__ __forceinline__ u16   f2bf(float f){
  u32 x = __float_as_uint(f);
  return (u16)((x + 0x7fffu + ((x>>16)&1u)) >> 16);   // round-to-nearest-even
}

#define MAXBK 512   // buckets of 256 dst nodes; N <= 131072

// ---------------- bucketed CSR build ----------------
__global__ __launch_bounds__(512) void bucket_hist_kernel(const int* __restrict__ dstA,
                                                          int* __restrict__ bhist, int E){
  __shared__ int h[MAXBK];
  for (int i=threadIdx.x; i<MAXBK; i+=512) h[i]=0;
  __syncthreads();
  const int base = blockIdx.x*8192;
  #pragma unroll
  for (int j=0;j<16;++j){
    int e = base + j*512 + threadIdx.x;
    if (e < E) atomicAdd(&h[dstA[e]>>8], 1);
  }
  __syncthreads();
  for (int i=threadIdx.x; i<MAXBK; i+=512) if (h[i]) atomicAdd(&bhist[i], h[i]);
}

__global__ __launch_bounds__(512) void bucket_scan_kernel(const int* __restrict__ bhist,
                                                          int* __restrict__ bcur){
  __shared__ int ts[MAXBK];
  int v = bhist[threadIdx.x];
  ts[threadIdx.x] = v; __syncthreads();
  for (int off=1; off<MAXBK; off<<=1){
    int t = (threadIdx.x>=off) ? ts[threadIdx.x-off] : 0;
    __syncthreads();
    ts[threadIdx.x] += t;
    __syncthreads();
  }
  bcur[threadIdx.x] = ts[threadIdx.x] - v;   // exclusive prefix
}

__global__ __launch_bounds__(512) void bin_kernel(const int* __restrict__ srcA,
                                                  const int* __restrict__ dstA,
                                                  int* __restrict__ bcur,
                                                  int* __restrict__ srcB,
                                                  int* __restrict__ dstB, int E){
  __shared__ int h[MAXBK];
  __shared__ int basev[MAXBK];
  for (int i=threadIdx.x; i<MAXBK; i+=512) h[i]=0;
  __syncthreads();
  const int base = blockIdx.x*8192;
  int br[16]; int dv[16];
  #pragma unroll
  for (int j=0;j<16;++j){
    int e = base + j*512 + threadIdx.x;
    if (e < E){
      int d = dstA[e]; int b = d>>8;
      int r = atomicAdd(&h[b], 1);
      br[j] = (b<<16) | r;
      dv[j] = d;
    } else br[j] = -1;
  }
  __syncthreads();
  for (int i=threadIdx.x; i<MAXBK; i+=512){
    int c = h[i];
    basev[i] = c ? atomicAdd(&bcur[i], c) : 0;
  }
  __syncthreads();
  #pragma unroll
  for (int j=0;j<16;++j){
    if (br[j] >= 0){
      int e = base + j*512 + threadIdx.x;
      int pos = basev[br[j]>>16] + (br[j] & 0xffff);
      srcB[pos] = srcA[e];
      dstB[pos] = dv[j];
    }
  }
}

__global__ void count2_kernel(const int* __restrict__ dstB, int* __restrict__ deg, int E){
  int e = blockIdx.x*256 + threadIdx.x;
  if (e < E) atomicAdd(&deg[dstB[e]], 1);
}

__global__ void fill2_kernel(const int* __restrict__ srcB, const int* __restrict__ dstB,
                             int* __restrict__ cursor, int* __restrict__ csr, int E){
  int e = blockIdx.x*256 + threadIdx.x;
  if (e < E){
    int pos = atomicAdd(&cursor[dstB[e]], 1);
    csr[pos] = srcB[e];
  }
}

// fallback (N too large for bucketing)
__global__ void count_kernel(const int* __restrict__ dsts, int* __restrict__ deg, int E){
  int e = blockIdx.x*256 + threadIdx.x;
  if (e < E) atomicAdd(&deg[dsts[e]], 1);
}
__global__ void fill_kernel(const int* __restrict__ ei, int* __restrict__ cursor,
                            int* __restrict__ csr, int E){
  int e = blockIdx.x*256 + threadIdx.x;
  if (e < E){
    int d = ei[E + e];
    int pos = atomicAdd(&cursor[d], 1);
    csr[pos] = ei[e];
  }
}

// ---------------- deg scan -> offs ----------------
__global__ void scan_reduce_kernel(const int* __restrict__ deg, int* __restrict__ bsums, int n){
  __shared__ int sd[256];
  int base = blockIdx.x*1024 + threadIdx.x*4;
  int s = 0;
  #pragma unroll
  for (int j=0;j<4;++j){ int idx=base+j; if (idx<n) s += deg[idx]; }
  sd[threadIdx.x] = s; __syncthreads();
  for (int off=128; off>0; off>>=1){
    if (threadIdx.x < off) sd[threadIdx.x] += sd[threadIdx.x+off];
    __syncthreads();
  }
  if (threadIdx.x==0) bsums[blockIdx.x] = sd[0];
}

__global__ void scan_block_kernel(const int* __restrict__ bsums, int* __restrict__ boffs, int nb){
  __shared__ int ts[128];
  if (nb <= 128){
    int v = (threadIdx.x < nb) ? bsums[threadIdx.x] : 0;
    ts[threadIdx.x] = v; __syncthreads();
    for (int off=1; off<128; off<<=1){
      int t = (threadIdx.x>=off) ? ts[threadIdx.x-off] : 0;
      __syncthreads();
      ts[threadIdx.x] += t;
      __syncthreads();
    }
    if (threadIdx.x < nb) boffs[threadIdx.x] = ts[threadIdx.x] - v;
  } else if (threadIdx.x==0){
    int run=0;
    for (int b=0;b<nb;++b){ int t=bsums[b]; boffs[b]=run; run+=t; }
  }
}

__global__ void scan_final_kernel(const int* __restrict__ deg, const int* __restrict__ boffs,
                                  int* __restrict__ offs, int n, int E){
  __shared__ int ts[256];
  int base = blockIdx.x*1024 + threadIdx.x*4;
  int v[4]; int s=0;
  #pragma unroll
  for (int j=0;j<4;++j){ int idx=base+j; v[j] = (idx<n) ? deg[idx] : 0; s += v[j]; }
  ts[threadIdx.x] = s; __syncthreads();
  for (int off=1; off<256; off<<=1){
    int t = (threadIdx.x>=off) ? ts[threadIdx.x-off] : 0;
    __syncthreads();
    ts[threadIdx.x] += t;
    __syncthreads();
  }
  int excl = boffs[blockIdx.x] + (threadIdx.x ? ts[threadIdx.x-1] : 0);
  #pragma unroll
  for (int j=0;j<4;++j){ int idx=base+j; if (idx<n){ offs[idx]=excl; excl+=v[j]; } }
  if (blockIdx.x==0 && threadIdx.x==0) offs[n] = E;
}

__global__ void dinv_kernel(const int* __restrict__ deg, const int* __restrict__ offs,
                            int* __restrict__ cursor, float* __restrict__ dinv, int n){
  int i = blockIdx.x*256 + threadIdx.x;
  if (i < n){
    dinv[i] = rsqrtf((float)(deg[i] + 1));
    cursor[i] = offs[i];
  }
}

// ---------------- GCN transform via MFMA (verified in R4) ----------------
template<int KD, typename TIN>
__global__ __launch_bounds__(256) void transform_mfma(const TIN* __restrict__ X,
                                                      const float* __restrict__ W,
                                                      const float* __restrict__ dinv,
                                                      u16* __restrict__ Y, int n){
  constexpr int XLD = KD + 8;
  __shared__ u16 Xl[128*XLD];
  __shared__ u16 Wl[KD*64];          // layout [KD/8][64][8]
  __shared__ float Dl[128];
  const int tid  = threadIdx.x;
  const int base = blockIdx.x*128;

  for (int i = tid; i < KD*64; i += 256){
    int k = i >> 6, col = i & 63;
    Wl[((k>>3)<<9) + (col<<3) + (k&7)] = f2bf(W[i]);
  }
  if (tid < 128){
    int nd = base + tid;
    Dl[tid] = (nd < n) ? dinv[nd] : 0.f;
  }
  if constexpr (sizeof(TIN)==4){
    #pragma unroll
    for (int j = 0; j < (128*KD)/1024; ++j){
      int e4   = tid + j*256;
      int elem = e4*4;
      int row  = elem / KD, k = elem % KD;
      int gn   = base + row;
      uint2 w2 = make_uint2(0u, 0u);
      if (gn < n){
        float4 v = ((const float4*)X)[(size_t)gn*(KD/4) + (k>>2)];
        w2.x = (u32)f2bf(v.x) | ((u32)f2bf(v.y)<<16);
        w2.y = (u32)f2bf(v.z) | ((u32)f2bf(v.w)<<16);
      }
      *((uint2*)&Xl[row*XLD + k]) = w2;
    }
  } else {
    #pragma unroll
    for (int j = 0; j < (128*KD)/1024; ++j){
      int e4   = tid + j*256;
      int elem = e4*4;
      int row  = elem / KD, k = elem % KD;
      int gn   = base + row;
      uint2 v = make_uint2(0u, 0u);
      if (gn < n) v = *((const uint2*)(X + (size_t)gn*KD + k));
      *((uint2*)&Xl[row*XLD + k]) = v;
    }
  }
  __syncthreads();

  const int lane = tid & 63, wv = tid >> 6;
  const int c = lane & 15, g = lane >> 4;

  bfrag wf[KD/32][4];
  #pragma unroll
  for (int kk=0; kk<KD/32; ++kk)
    #pragma unroll
    for (int nt=0; nt<4; ++nt)
      wf[kk][nt] = *((const bfrag*)&Wl[((kk*4+g)<<9) + ((nt*16+c)<<3)]);

  f32x4 acc[2][4];
  #pragma unroll
  for (int rs=0;rs<2;++rs)
    #pragma unroll
    for (int nt=0;nt<4;++nt)
      acc[rs][nt] = (f32x4){0.f,0.f,0.f,0.f};

  #pragma unroll
  for (int kk=0; kk<KD/32; ++kk){
    bfrag a0 = *((const bfrag*)&Xl[(wv*32      + c)*XLD + kk*32 + g*8]);
    bfrag a1 = *((const bfrag*)&Xl[(wv*32 + 16 + c)*XLD + kk*32 + g*8]);
    #pragma unroll
    for (int nt=0; nt<4; ++nt){
      acc[0][nt] = __builtin_amdgcn_mfma_f32_16x16x32_bf16(a0, wf[kk][nt], acc[0][nt], 0,0,0);
      acc[1][nt] = __builtin_amdgcn_mfma_f32_16x16x32_bf16(a1, wf[kk][nt], acc[1][nt], 0,0,0);
    }
  }

  #pragma unroll
  for (int rs=0;rs<2;++rs){
    int nl0 = wv*32 + rs*16 + g*4;
    #pragma unroll
    for (int r=0;r<4;++r){
      int node = base + nl0 + r;
      if (node < n){
        float dv = Dl[nl0 + r];
        #pragma unroll
        for (int nt=0;nt<4;++nt)
          Y[(size_t)node*64 + nt*16 + c] = f2bf(acc[rs][nt][r] * dv);
      }
    }
  }
}

// ---------------- GCN aggregate: one wave per node, 8-way neighbor ILP (bf16 rows) ----------------
__global__ void agg_kernel(const u16* __restrict__ Hts, const float* __restrict__ dinv,
                           const int* __restrict__ offs, const int* __restrict__ csr,
                           const float* __restrict__ bias, u16* __restrict__ Hout, int n){
  const int node = blockIdx.x*4 + (threadIdx.x >> 6);
  if (node >= n) return;
  const int lane = threadIdx.x & 63;
  const int c8   = lane & 7;
  const int slot = lane >> 3;
  const uint4* __restrict__ H = (const uint4*)Hts;
  float acc[8];
  #pragma unroll
  for (int i=0;i<8;++i) acc[i]=0.f;
  const int beg = offs[node], end = offs[node+1];
  for (int j = beg + slot; j < end; j += 8){
    int s = csr[j];
    uint4 v = H[s*8 + c8];
    acc[0] += __uint_as_float(v.x<<16); acc[1] += __uint_as_float(v.x & 0xffff0000u);
    acc[2] += __uint_as_float(v.y<<16); acc[3] += __uint_as_float(v.y & 0xffff0000u);
    acc[4] += __uint_as_float(v.z<<16); acc[5] += __uint_as_float(v.z & 0xffff0000u);
    acc[6] += __uint_as_float(v.w<<16); acc[7] += __uint_as_float(v.w & 0xffff0000u);
  }
  #pragma unroll
  for (int i=0;i<8;++i) acc[i] += __shfl_xor(acc[i], 8);
  #pragma unroll
  for (int i=0;i<8;++i) acc[i] += __shfl_xor(acc[i], 16);
  #pragma unroll
  for (int i=0;i<8;++i) acc[i] += __shfl_xor(acc[i], 32);
  if (slot == 0){
    uint4 sv = H[node*8 + c8];
    float s[8];
    s[0]=__uint_as_float(sv.x<<16); s[1]=__uint_as_float(sv.x & 0xffff0000u);
    s[2]=__uint_as_float(sv.y<<16); s[3]=__uint_as_float(sv.y & 0xffff0000u);
    s[4]=__uint_as_float(sv.z<<16); s[5]=__uint_as_float(sv.z & 0xffff0000u);
    s[6]=__uint_as_float(sv.w<<16); s[7]=__uint_as_float(sv.w & 0xffff0000u);
    float4 b0 = ((const float4*)bias)[c8*2];
    float4 b1 = ((const float4*)bias)[c8*2+1];
    const float dv = dinv[node];
    float o[8];
    o[0]=fmaxf(fmaf(acc[0]+s[0],dv,b0.x),0.f); o[1]=fmaxf(fmaf(acc[1]+s[1],dv,b0.y),0.f);
    o[2]=fmaxf(fmaf(acc[2]+s[2],dv,b0.z),0.f); o[3]=fmaxf(fmaf(acc[3]+s[3],dv,b0.w),0.f);
    o[4]=fmaxf(fmaf(acc[4]+s[4],dv,b1.x),0.f); o[5]=fmaxf(fmaf(acc[5]+s[5],dv,b1.y),0.f);
    o[6]=fmaxf(fmaf(acc[6]+s[6],dv,b1.z),0.f); o[7]=fmaxf(fmaf(acc[7]+s[7],dv,b1.w),0.f);
    uint4 w;
    w.x = (u32)f2bf(o[0]) | ((u32)f2bf(o[1])<<16);
    w.y = (u32)f2bf(o[2]) | ((u32)f2bf(o[3])<<16);
    w.z = (u32)f2bf(o[4]) | ((u32)f2bf(o[5])<<16);
    w.w = (u32)f2bf(o[6]) | ((u32)f2bf(o[7])<<16);
    ((uint4*)Hout)[node*8 + c8] = w;
  }
}

// ---------------- Fused LSTM x2 + heads (hi/lo split MFMA, native transcendentals) ----------------
__global__ __launch_bounds__(256) void lstm_heads_fused(
    const u16* __restrict__ X,
    const float* __restrict__ Wih0, const float* __restrict__ bih0, const float* __restrict__ bhh0,
    const float* __restrict__ Wih1, const float* __restrict__ bih1, const float* __restrict__ bhh1,
    const float* __restrict__ Wv1, const float* __restrict__ bv1,
    const float* __restrict__ Wv2, const float* __restrict__ bv2,
    const float* __restrict__ Wt1, const float* __restrict__ bt1,
    const float* __restrict__ Wt2, const float* __restrict__ bt2,
    float* __restrict__ out, int n)
{
  __shared__ u16 pool[27648];
  __shared__ float b0l[96], b1l[96], bv1l[32], bt1l[32], Wv2l[32], Wt2l[320], bt2l[10];
  u16* W0hi = pool;            // 6144  [k/8][96][8]
  u16* W0lo = pool + 6144;     // 6144
  u16* W1l  = pool + 12288;    // 3072  [k/8][96][8]
  u16* WHl  = pool + 15360;    // 2048  [k/8][64][8]
  u16* H1hi = pool + 17408;    // 5120  stride 40
  u16* H1lo = pool + 22528;    // 5120
  u16* H2hi = pool;            // aliases W0hi (free after lstm0)
  u16* H2lo = pool + 5120;     // aliases W0hi/W0lo

  const int tid  = threadIdx.x;
  const int base = blockIdx.x*128;

  // ---- stage weights/biases ----
  for (int i=tid; i<64*96; i+=256){          // Wih0 gates, hi/lo bf16 subtiled
    int j = i >> 6, k = i & 63;
    int row = (j < 32) ? j : j + 32;
    float w = Wih0[row*64 + k];
    u16 hi = f2bf(w);
    int idx = ((k>>3)*768) + (j<<3) + (k&7);
    W0hi[idx] = hi;
    W0lo[idx] = f2bf(w - bf2f(hi));
  }
  for (int i=tid; i<32*96; i+=256){          // Wih1 gates (single bf16)
    int j = i >> 5, k = i & 31;
    int row = (j < 32) ? j : j + 32;
    W1l[((k>>3)*768) + (j<<3) + (k&7)] = f2bf(Wih1[row*32 + k]);
  }
  for (int i=tid; i<32*64; i+=256){          // Wv1 | Wt1 (single bf16)
    int j = i >> 5, k = i & 31;
    float v = (j < 32) ? Wv1[k*32 + j] : Wt1[k*32 + (j-32)];
    WHl[((k>>3)*512) + (j<<3) + (k&7)] = f2bf(v);
  }
  if (tid < 96){
    int row = (tid < 32) ? tid : tid + 32;
    b0l[tid] = bih0[row] + bhh0[row];
    b1l[tid] = bih1[row] + bhh1[row];
  } else if (tid < 128){
    int d = tid - 96;
    bv1l[d] = bv1[d]; bt1l[d] = bt1[d]; Wv2l[d] = Wv2[d];
  }
  for (int i=tid; i<320; i+=256) Wt2l[i] = Wt2[i];
  if (tid >= 128 && tid < 138) bt2l[tid-128] = bt2[tid-128];
  __syncthreads();

  const int lane = tid & 63, wv = tid >> 6;
  const int c = lane & 15, g = lane >> 4;
  const float bv2v = bv2[0];

  // ---- lstm0: gates = X @ W0^T (K=64, 96 cols), A from global ----
  {
    int r0 = base + wv*32 + c;      if (r0 > n-1) r0 = n-1;
    int r1 = base + wv*32 + 16 + c; if (r1 > n-1) r1 = n-1;
    bfrag a0[2], a1[2];
    #pragma unroll
    for (int kk=0; kk<2; ++kk){
      a0[kk] = *((const bfrag*)(X + (size_t)r0*64 + kk*32 + g*8));
      a1[kk] = *((const bfrag*)(X + (size_t)r1*64 + kk*32 + g*8));
    }
    f32x4 acc[2][6];
    #pragma unroll
    for (int rs=0;rs<2;++rs)
      #pragma unroll
      for (int nt=0;nt<6;++nt) acc[rs][nt] = (f32x4){0.f,0.f,0.f,0.f};
    #pragma unroll
    for (int kk=0; kk<2; ++kk){
      #pragma unroll
      for (int nt=0; nt<6; ++nt){
        int widx = (kk*4+g)*768 + ((nt*16+c)<<3);
        bfrag bh = *((const bfrag*)&W0hi[widx]);
        bfrag bl = *((const bfrag*)&W0lo[widx]);
        acc[0][nt] = __builtin_amdgcn_mfma_f32_16x16x32_bf16(a0[kk], bh, acc[0][nt], 0,0,0);
        acc[0][nt] = __builtin_amdgcn_mfma_f32_16x16x32_bf16(a0[kk], bl, acc[0][nt], 0,0,0);
        acc[1][nt] = __builtin_amdgcn_mfma_f32_16x16x32_bf16(a1[kk], bh, acc[1][nt], 0,0,0);
        acc[1][nt] = __builtin_amdgcn_mfma_f32_16x16x32_bf16(a1[kk], bl, acc[1][nt], 0,0,0);
      }
    }
    #pragma unroll
    for (int rs=0;rs<2;++rs)
      #pragma unroll
      for (int r=0;r<4;++r){
        int rl = wv*32 + rs*16 + g*4 + r;
        #pragma unroll
        for (int half=0; half<2; ++half){
          float iv = acc[rs][0+half][r] + b0l[half*16 + c];
          float gv = acc[rs][2+half][r] + b0l[32 + half*16 + c];
          float ov = acc[rs][4+half][r] + b0l[64 + half*16 + c];
          float cc = fast_sigmoid(iv) * fast_tanh(gv);
          float hv = fast_sigmoid(ov) * fast_tanh(cc);
          u16 hi = f2bf(hv);
          H1hi[rl*40 + half*16 + c] = hi;
          H1lo[rl*40 + half*16 + c] = f2bf(hv - bf2f(hi));
        }
      }
  }
  __syncthreads();                           // W0 reads done; H1 visible

  // ---- lstm1: gates = H1 @ W1^T (K=32, 96 cols), A-split 2-term ----
  {
    bfrag w1f[6];
    #pragma unroll
    for (int nt=0; nt<6; ++nt)
      w1f[nt] = *((const bfrag*)&W1l[g*768 + ((nt*16+c)<<3)]);
    bfrag a0h = *((const bfrag*)&H1hi[(wv*32      + c)*40 + g*8]);
    bfrag a0l = *((const bfrag*)&H1lo[(wv*32      + c)*40 + g*8]);
    bfrag a1h = *((const bfrag*)&H1hi[(wv*32 + 16 + c)*40 + g*8]);
    bfrag a1l = *((const bfrag*)&H1lo[(wv*32 + 16 + c)*40 + g*8]);
    f32x4 acc[2][6];
    #pragma unroll
    for (int rs=0;rs<2;++rs)
      #pragma unroll
      for (int nt=0;nt<6;++nt) acc[rs][nt] = (f32x4){0.f,0.f,0.f,0.f};
    #pragma unroll
    for (int nt=0; nt<6; ++nt){
      acc[0][nt] = __builtin_amdgcn_mfma_f32_16x16x32_bf16(a0h, w1f[nt], acc[0][nt], 0,0,0);
      acc[0][nt] = __builtin_amdgcn_mfma_f32_16x16x32_bf16(a0l, w1f[nt], acc[0][nt], 0,0,0);
      acc[1][nt] = __builtin_amdgcn_mfma_f32_16x16x32_bf16(a1h, w1f[nt], acc[1][nt], 0,0,0);
      acc[1][nt] = __builtin_amdgcn_mfma_f32_16x16x32_bf16(a1l, w1f[nt], acc[1][nt], 0,0,0);
    }
    __syncthreads();                         // W0 frag reads fully done before H2 overwrite
    #pragma unroll
    for (int rs=0;rs<2;++rs)
      #pragma unroll
      for (int r=0;r<4;++r){
        int rl = wv*32 + rs*16 + g*4 + r;
        #pragma unroll
        for (int half=0; half<2; ++half){
          float iv = acc[rs][0+half][r] + b1l[half*16 + c];
          float gv = acc[rs][2+half][r] + b1l[32 + half*16 + c];
          float ov = acc[rs][4+half][r] + b1l[64 + half*16 + c];
          float cc = fast_sigmoid(iv) * fast_tanh(gv);
          float hv = fast_sigmoid(ov) * fast_tanh(cc);
          u16 hi = f2bf(hv);
          H2hi[rl*40 + half*16 + c] = hi;
          H2lo[rl*40 + half*16 + c] = f2bf(hv - bf2f(hi));
        }
      }
  }
  __syncthreads();

  // ---- heads: [v1 | t1] = relu(H2 @ [Wv1|Wt1] + b), A-split, then 32->1 / 32->10 ----
  {
    bfrag whf[4];
    #pragma unroll
    for (int nt=0; nt<4; ++nt)
      whf[nt] = *((const bfrag*)&WHl[g*512 + ((nt*16+c)<<3)]);
    bfrag a0h = *((const bfrag*)&H2hi[(wv*32      + c)*40 + g*8]);
    bfrag a0l = *((const bfrag*)&H2lo[(wv*32      + c)*40 + g*8]);
    bfrag a1h = *((const bfrag*)&H2hi[(wv*32 + 16 + c)*40 + g*8]);
    bfrag a1l = *((const bfrag*)&H2lo[(wv*32 + 16 + c)*40 + g*8]);
    f32x4 acc[2][4];
    #pragma unroll
    for (int rs=0;rs<2;++rs)
      #pragma unroll
      for (int nt=0;nt<4;++nt) acc[rs][nt] = (f32x4){0.f,0.f,0.f,0.f};
    #pragma unroll
    for (int nt=0; nt<4; ++nt){
      acc[0][nt] = __builtin_amdgcn_mfma_f32_16x16x32_bf16(a0h, whf[nt], acc[0][nt], 0,0,0);
      acc[0][nt] = __builtin_amdgcn_mfma_f32_16x16x32_bf16(a0l, whf[nt], acc[0][nt], 0,0,0);
      acc[1][nt] = __builtin_amdgcn_mfma_f32_16x16x32_bf16(a1h, whf[nt], acc[1][nt], 0,0,0);
      acc[1][nt] = __builtin_amdgcn_mfma_f32_16x16x32_bf16(a1l, whf[nt], acc[1][nt], 0,0,0);
    }
    const float wv2a = Wv2l[c], wv2b = Wv2l[c+16];
    float wt2a[10], wt2b[10];
    #pragma unroll
    for (int k=0;k<10;++k){ wt2a[k] = Wt2l[c*10+k]; wt2b[k] = Wt2l[(c+16)*10+k]; }
    #pragma unroll
    for (int rs=0;rs<2;++rs)
      #pragma unroll
      for (int r=0;r<4;++r){
        int node = base + wv*32 + rs*16 + g*4 + r;
        float va = fmaxf(acc[rs][0][r] + bv1l[c],    0.f);
        float vb = fmaxf(acc[rs][1][r] + bv1l[c+16], 0.f);
        float ta = fmaxf(acc[rs][2][r] + bt1l[c],    0.f);
        float tb = fmaxf(acc[rs][3][r] + bt1l[c+16], 0.f);
        float pv = va*wv2a + vb*wv2b;
        pv += __shfl_xor(pv, 1); pv += __shfl_xor(pv, 2);
        pv += __shfl_xor(pv, 4); pv += __shfl_xor(pv, 8);
        float tk[10];
        #pragma unroll
        for (int k=0;k<10;++k) tk[k] = ta*wt2a[k] + tb*wt2b[k];
        #pragma unroll
        for (int k=0;k<10;++k) tk[k] += __shfl_xor(tk[k], 1);
        #pragma unroll
        for (int k=0;k<10;++k) tk[k] += __shfl_xor(tk[k], 2);
        #pragma unroll
        for (int k=0;k<10;++k) tk[k] += __shfl_xor(tk[k], 4);
        #pragma unroll
        for (int k=0;k<10;++k) tk[k] += __shfl_xor(tk[k], 8);
        if (c == 0 && node < n){
          out[node] = pv + bv2v;
          #pragma unroll
          for (int k=0;k<10;++k) out[n + (size_t)node*10 + k] = tk[k] + bt2l[k];
        }
      }
  }
}

extern "C" void kernel_launch(void* const* d_in, const int* in_sizes, int n_in,
                              void* d_out, int out_size, void* d_ws, size_t ws_size,
                              hipStream_t stream){
  const float* x    = (const float*)d_in[0];
  const int*   ei   = (const int*)  d_in[1];
  const float* W1   = (const float*)d_in[2];  const float* b1   = (const float*)d_in[3];
  const float* W2   = (const float*)d_in[4];  const float* b2   = (const float*)d_in[5];
  const float* W3   = (const float*)d_in[6];  const float* b3   = (const float*)d_in[7];
  const float* Wih0 = (const float*)d_in[8];
  const float* bih0 = (const float*)d_in[10]; const float* bhh0 = (const float*)d_in[11];
  const float* Wih1 = (const float*)d_in[12];
  const float* bih1 = (const float*)d_in[14]; const float* bhh1 = (const float*)d_in[15];
  const float* Wv1  = (const float*)d_in[16]; const float* bv1  = (const float*)d_in[17];
  const float* Wv2  = (const float*)d_in[18]; const float* bv2  = (const float*)d_in[19];
  const float* Wt1  = (const float*)d_in[20]; const float* bt1  = (const float*)d_in[21];
  const float* Wt2  = (const float*)d_in[22]; const float* bt2  = (const float*)d_in[23];

  const int N  = in_sizes[0] / 128;
  const int E  = in_sizes[1] / 2;
  const int NB = (N + 1023) / 1024;
  const int EB = (E + 8191) / 8192;

  char* w = (char*)d_ws;
  auto take = [&](size_t bytes)->char*{ char* p = w; w += (bytes + 255) & ~(size_t)255; return p; };
  int*   deg    = (int*)  take((size_t)N*4);
  int*   offs   = (int*)  take((size_t)(N+1)*4);
  int*   cursor = (int*)  take((size_t)N*4);
  int*   csr    = (int*)  take((size_t)E*4);
  float* dinv   = (float*)take((size_t)N*4);
  int*   bsums  = (int*)  take((size_t)NB*4);
  int*   boffs  = (int*)  take((size_t)NB*4);
  int*   bhist  = (int*)  take((size_t)MAXBK*4);
  int*   bcur   = (int*)  take((size_t)MAXBK*4);
  int*   srcB   = (int*)  take((size_t)E*4);
  int*   dstB   = (int*)  take((size_t)E*4);
  u16*   bufTS  = (u16*)  take((size_t)N*64*2);   // transformed (pre-agg), bf16
  u16*   bufH   = (u16*)  take((size_t)N*64*2);   // post-agg activations, bf16
  (void)ws_size; (void)n_in; (void)out_size;

  // --- CSR build ---
  hipMemsetAsync(deg, 0, (size_t)N*4, stream);
  if (N <= MAXBK*256){
    hipMemsetAsync(bhist, 0, (size_t)MAXBK*4, stream);
    bucket_hist_kernel<<<EB, 512, 0, stream>>>(ei + E, bhist, E);
    bucket_scan_kernel<<<1,  512, 0, stream>>>(bhist, bcur);
    bin_kernel        <<<EB, 512, 0, stream>>>(ei, ei + E, bcur, srcB, dstB, E);
    count2_kernel     <<<(E+255)/256, 256, 0, stream>>>(dstB, deg, E);
  } else {
    count_kernel      <<<(E+255)/256, 256, 0, stream>>>(ei + E, deg, E);
  }
  scan_reduce_kernel<<<NB,          256, 0, stream>>>(deg, bsums, N);
  scan_block_kernel <<<1,           128, 0, stream>>>(bsums, boffs, NB);
  scan_final_kernel <<<NB,          256, 0, stream>>>(deg, boffs, offs, N, E);
  dinv_kernel       <<<(N+255)/256, 256, 0, stream>>>(deg, offs, cursor, dinv, N);
  if (N <= MAXBK*256){
    fill2_kernel<<<(E+255)/256, 256, 0, stream>>>(srcB, dstB, cursor, csr, E);
  } else {
    fill_kernel <<<(E+255)/256, 256, 0, stream>>>(ei, cursor, csr, E);
  }

  // --- GCN layers (MFMA transforms) ---
  const int TB = (N + 127) / 128;
  transform_mfma<128,float><<<TB, 256, 0, stream>>>(x,    W1, dinv, bufTS, N);
  agg_kernel               <<<(N+3)/4, 256, 0, stream>>>(bufTS, dinv, offs, csr, b1, bufH, N);
  transform_mfma<64,u16>   <<<TB, 256, 0, stream>>>(bufH, W2, dinv, bufTS, N);
  agg_kernel               <<<(N+3)/4, 256, 0, stream>>>(bufTS, dinv, offs, csr, b2, bufH, N);
  transform_mfma<64,u16>   <<<TB, 256, 0, stream>>>(bufH, W3, dinv, bufTS, N);
  agg_kernel               <<<(N+3)/4, 256, 0, stream>>>(bufTS, dinv, offs, csr, b3, bufH, N);

  // --- fused LSTM x2 + heads ---
  lstm_heads_fused<<<TB, 256, 0, stream>>>(bufH,
                                           Wih0, bih0, bhh0, Wih1, bih1, bhh1,
                                           Wv1, bv1, Wv2, bv2, Wt1, bt1, Wt2, bt2,
                                           (float*)d_out, N);
}

// Round 8
// 345.758 us; speedup vs baseline: 2.7661x; 1.0242x over previous
//
#include <hip/hip_runtime.h>
#include <math.h>

// TemporalWasteGNN: 3x GCNConv (symmetric-norm, self-loops) -> 2x LSTM(seq=1, h0=c0=0)
// -> two MLP heads. fp32 I/O, bf16 intermediate features.
//
// R8: tail weight staging hoisted into a run-once prep kernel (R7 counters:
//     occupancy 18%, 1.37M LDS bank conflicts from 782x redundant subtiled
//     scatter staging). Tail now reads weight fragments directly from a
//     pre-converted global slab (L2-resident); LDS 57.8KB -> ~23KB (H1 only,
//     H2 aliased) -> ~4-5 blocks/CU. Math bit-identical to R7.
// R3 bucketed CSR build, R4 MFMA transforms, R7 native transcendentals kept.

typedef unsigned int  u32;
typedef unsigned short u16;
typedef short bfrag  __attribute__((ext_vector_type(8)));   // 8 bf16 (4 VGPRs)
typedef float f32x4  __attribute__((ext_vector_type(4)));

#define LOG2E 1.44269504088896f
static __device__ __forceinline__ float fast_sigmoid(float x){
  float t = __builtin_amdgcn_exp2f(-x * LOG2E);
  return __builtin_amdgcn_rcpf(1.f + t);
}
static __device__ __forceinline__ float fast_tanh(float x){
  float t = __builtin_amdgcn_exp2f(x * (2.f * LOG2E));
  return 1.f - 2.f * __builtin_amdgcn_rcpf(t + 1.f);
}
static __device__ __forceinline__ float bf2f(u16 u){ return __uint_as_float(((u32)u)<<16); }
static __device__ __forceinline__ u16   f2bf(float f){
  u32 x = __float_as_uint(f);
  return (u16)((x + 0x7fffu + ((x>>16)&1u)) >> 16);   // round-to-nearest-even
}

#define MAXBK 512   // buckets of 256 dst nodes; N <= 131072

// ---------------- bucketed CSR build ----------------
__global__ __launch_bounds__(512) void bucket_hist_kernel(const int* __restrict__ dstA,
                                                          int* __restrict__ bhist, int E){
  __shared__ int h[MAXBK];
  for (int i=threadIdx.x; i<MAXBK; i+=512) h[i]=0;
  __syncthreads();
  const int base = blockIdx.x*8192;
  #pragma unroll
  for (int j=0;j<16;++j){
    int e = base + j*512 + threadIdx.x;
    if (e < E) atomicAdd(&h[dstA[e]>>8], 1);
  }
  __syncthreads();
  for (int i=threadIdx.x; i<MAXBK; i+=512) if (h[i]) atomicAdd(&bhist[i], h[i]);
}

__global__ __launch_bounds__(512) void bucket_scan_kernel(const int* __restrict__ bhist,
                                                          int* __restrict__ bcur){
  __shared__ int ts[MAXBK];
  int v = bhist[threadIdx.x];
  ts[threadIdx.x] = v; __syncthreads();
  for (int off=1; off<MAXBK; off<<=1){
    int t = (threadIdx.x>=off) ? ts[threadIdx.x-off] : 0;
    __syncthreads();
    ts[threadIdx.x] += t;
    __syncthreads();
  }
  bcur[threadIdx.x] = ts[threadIdx.x] - v;   // exclusive prefix
}

__global__ __launch_bounds__(512) void bin_kernel(const int* __restrict__ srcA,
                                                  const int* __restrict__ dstA,
                                                  int* __restrict__ bcur,
                                                  int* __restrict__ srcB,
                                                  int* __restrict__ dstB, int E){
  __shared__ int h[MAXBK];
  __shared__ int basev[MAXBK];
  for (int i=threadIdx.x; i<MAXBK; i+=512) h[i]=0;
  __syncthreads();
  const int base = blockIdx.x*8192;
  int br[16]; int dv[16];
  #pragma unroll
  for (int j=0;j<16;++j){
    int e = base + j*512 + threadIdx.x;
    if (e < E){
      int d = dstA[e]; int b = d>>8;
      int r = atomicAdd(&h[b], 1);
      br[j] = (b<<16) | r;
      dv[j] = d;
    } else br[j] = -1;
  }
  __syncthreads();
  for (int i=threadIdx.x; i<MAXBK; i+=512){
    int c = h[i];
    basev[i] = c ? atomicAdd(&bcur[i], c) : 0;
  }
  __syncthreads();
  #pragma unroll
  for (int j=0;j<16;++j){
    if (br[j] >= 0){
      int e = base + j*512 + threadIdx.x;
      int pos = basev[br[j]>>16] + (br[j] & 0xffff);
      srcB[pos] = srcA[e];
      dstB[pos] = dv[j];
    }
  }
}

__global__ void count2_kernel(const int* __restrict__ dstB, int* __restrict__ deg, int E){
  int e = blockIdx.x*256 + threadIdx.x;
  if (e < E) atomicAdd(&deg[dstB[e]], 1);
}

__global__ void fill2_kernel(const int* __restrict__ srcB, const int* __restrict__ dstB,
                             int* __restrict__ cursor, int* __restrict__ csr, int E){
  int e = blockIdx.x*256 + threadIdx.x;
  if (e < E){
    int pos = atomicAdd(&cursor[dstB[e]], 1);
    csr[pos] = srcB[e];
  }
}

// fallback (N too large for bucketing)
__global__ void count_kernel(const int* __restrict__ dsts, int* __restrict__ deg, int E){
  int e = blockIdx.x*256 + threadIdx.x;
  if (e < E) atomicAdd(&deg[dsts[e]], 1);
}
__global__ void fill_kernel(const int* __restrict__ ei, int* __restrict__ cursor,
                            int* __restrict__ csr, int E){
  int e = blockIdx.x*256 + threadIdx.x;
  if (e < E){
    int d = ei[E + e];
    int pos = atomicAdd(&cursor[d], 1);
    csr[pos] = ei[e];
  }
}

// ---------------- deg scan -> offs ----------------
__global__ void scan_reduce_kernel(const int* __restrict__ deg, int* __restrict__ bsums, int n){
  __shared__ int sd[256];
  int base = blockIdx.x*1024 + threadIdx.x*4;
  int s = 0;
  #pragma unroll
  for (int j=0;j<4;++j){ int idx=base+j; if (idx<n) s += deg[idx]; }
  sd[threadIdx.x] = s; __syncthreads();
  for (int off=128; off>0; off>>=1){
    if (threadIdx.x < off) sd[threadIdx.x] += sd[threadIdx.x+off];
    __syncthreads();
  }
  if (threadIdx.x==0) bsums[blockIdx.x] = sd[0];
}

__global__ void scan_block_kernel(const int* __restrict__ bsums, int* __restrict__ boffs, int nb){
  __shared__ int ts[128];
  if (nb <= 128){
    int v = (threadIdx.x < nb) ? bsums[threadIdx.x] : 0;
    ts[threadIdx.x] = v; __syncthreads();
    for (int off=1; off<128; off<<=1){
      int t = (threadIdx.x>=off) ? ts[threadIdx.x-off] : 0;
      __syncthreads();
      ts[threadIdx.x] += t;
      __syncthreads();
    }
    if (threadIdx.x < nb) boffs[threadIdx.x] = ts[threadIdx.x] - v;
  } else if (threadIdx.x==0){
    int run=0;
    for (int b=0;b<nb;++b){ int t=bsums[b]; boffs[b]=run; run+=t; }
  }
}

__global__ void scan_final_kernel(const int* __restrict__ deg, const int* __restrict__ boffs,
                                  int* __restrict__ offs, int n, int E){
  __shared__ int ts[256];
  int base = blockIdx.x*1024 + threadIdx.x*4;
  int v[4]; int s=0;
  #pragma unroll
  for (int j=0;j<4;++j){ int idx=base+j; v[j] = (idx<n) ? deg[idx] : 0; s += v[j]; }
  ts[threadIdx.x] = s; __syncthreads();
  for (int off=1; off<256; off<<=1){
    int t = (threadIdx.x>=off) ? ts[threadIdx.x-off] : 0;
    __syncthreads();
    ts[threadIdx.x] += t;
    __syncthreads();
  }
  int excl = boffs[blockIdx.x] + (threadIdx.x ? ts[threadIdx.x-1] : 0);
  #pragma unroll
  for (int j=0;j<4;++j){ int idx=base+j; if (idx<n){ offs[idx]=excl; excl+=v[j]; } }
  if (blockIdx.x==0 && threadIdx.x==0) offs[n] = E;
}

__global__ void dinv_kernel(const int* __restrict__ deg, const int* __restrict__ offs,
                            int* __restrict__ cursor, float* __restrict__ dinv, int n){
  int i = blockIdx.x*256 + threadIdx.x;
  if (i < n){
    dinv[i] = rsqrtf((float)(deg[i] + 1));
    cursor[i] = offs[i];
  }
}

// ---------------- run-once tail-weight prep ----------------
// wbuf (u16): W0hi[0,6144) W0lo[6144,12288) W1[12288,15360) WH[15360,17408)
// bbuf (f32): b0[0,96) b1[96,192)
__global__ void prep_tail_kernel(const float* __restrict__ Wih0, const float* __restrict__ Wih1,
                                 const float* __restrict__ Wv1,  const float* __restrict__ Wt1,
                                 const float* __restrict__ bih0, const float* __restrict__ bhh0,
                                 const float* __restrict__ bih1, const float* __restrict__ bhh1,
                                 u16* __restrict__ wbuf, float* __restrict__ bbuf){
  int tid = blockIdx.x*256 + threadIdx.x;
  if (tid < 6144){                                  // Wih0 hi/lo, [k/8][96][8]
    int kg = tid / 768, rem = tid % 768;
    int j = rem >> 3, k = kg*8 + (rem & 7);
    int row = (j < 32) ? j : j + 32;
    float w = Wih0[row*64 + k];
    u16 hi = f2bf(w);
    wbuf[tid] = hi;
    wbuf[6144 + tid] = f2bf(w - bf2f(hi));
  } else if (tid < 9216){                           // Wih1, [k/8][96][8]
    int t = tid - 6144;
    int kg = t / 768, rem = t % 768;
    int j = rem >> 3, k = kg*8 + (rem & 7);
    int row = (j < 32) ? j : j + 32;
    wbuf[12288 + t] = f2bf(Wih1[row*32 + k]);
  } else if (tid < 11264){                          // Wv1|Wt1, [k/8][64][8]
    int t = tid - 9216;
    int kg = t / 512, rem = t % 512;
    int j = rem >> 3, k = kg*8 + (rem & 7);
    float v = (j < 32) ? Wv1[k*32 + j] : Wt1[k*32 + (j-32)];
    wbuf[15360 + t] = f2bf(v);
  } else if (tid < 11360){                          // b0 (i,g,o combined)
    int t = tid - 11264;
    int row = (t < 32) ? t : t + 32;
    bbuf[t] = bih0[row] + bhh0[row];
  } else if (tid < 11456){                          // b1
    int t = tid - 11360;
    int row = (t < 32) ? t : t + 32;
    bbuf[96 + t] = bih1[row] + bhh1[row];
  }
}

// ---------------- GCN transform via MFMA (verified in R4) ----------------
template<int KD, typename TIN>
__global__ __launch_bounds__(256) void transform_mfma(const TIN* __restrict__ X,
                                                      const float* __restrict__ W,
                                                      const float* __restrict__ dinv,
                                                      u16* __restrict__ Y, int n){
  constexpr int XLD = KD + 8;
  __shared__ u16 Xl[128*XLD];
  __shared__ u16 Wl[KD*64];          // layout [KD/8][64][8]
  __shared__ float Dl[128];
  const int tid  = threadIdx.x;
  const int base = blockIdx.x*128;

  for (int i = tid; i < KD*64; i += 256){
    int k = i >> 6, col = i & 63;
    Wl[((k>>3)<<9) + (col<<3) + (k&7)] = f2bf(W[i]);
  }
  if (tid < 128){
    int nd = base + tid;
    Dl[tid] = (nd < n) ? dinv[nd] : 0.f;
  }
  if constexpr (sizeof(TIN)==4){
    #pragma unroll
    for (int j = 0; j < (128*KD)/1024; ++j){
      int e4   = tid + j*256;
      int elem = e4*4;
      int row  = elem / KD, k = elem % KD;
      int gn   = base + row;
      uint2 w2 = make_uint2(0u, 0u);
      if (gn < n){
        float4 v = ((const float4*)X)[(size_t)gn*(KD/4) + (k>>2)];
        w2.x = (u32)f2bf(v.x) | ((u32)f2bf(v.y)<<16);
        w2.y = (u32)f2bf(v.z) | ((u32)f2bf(v.w)<<16);
      }
      *((uint2*)&Xl[row*XLD + k]) = w2;
    }
  } else {
    #pragma unroll
    for (int j = 0; j < (128*KD)/1024; ++j){
      int e4   = tid + j*256;
      int elem = e4*4;
      int row  = elem / KD, k = elem % KD;
      int gn   = base + row;
      uint2 v = make_uint2(0u, 0u);
      if (gn < n) v = *((const uint2*)(X + (size_t)gn*KD + k));
      *((uint2*)&Xl[row*XLD + k]) = v;
    }
  }
  __syncthreads();

  const int lane = tid & 63, wv = tid >> 6;
  const int c = lane & 15, g = lane >> 4;

  bfrag wf[KD/32][4];
  #pragma unroll
  for (int kk=0; kk<KD/32; ++kk)
    #pragma unroll
    for (int nt=0; nt<4; ++nt)
      wf[kk][nt] = *((const bfrag*)&Wl[((kk*4+g)<<9) + ((nt*16+c)<<3)]);

  f32x4 acc[2][4];
  #pragma unroll
  for (int rs=0;rs<2;++rs)
    #pragma unroll
    for (int nt=0;nt<4;++nt)
      acc[rs][nt] = (f32x4){0.f,0.f,0.f,0.f};

  #pragma unroll
  for (int kk=0; kk<KD/32; ++kk){
    bfrag a0 = *((const bfrag*)&Xl[(wv*32      + c)*XLD + kk*32 + g*8]);
    bfrag a1 = *((const bfrag*)&Xl[(wv*32 + 16 + c)*XLD + kk*32 + g*8]);
    #pragma unroll
    for (int nt=0; nt<4; ++nt){
      acc[0][nt] = __builtin_amdgcn_mfma_f32_16x16x32_bf16(a0, wf[kk][nt], acc[0][nt], 0,0,0);
      acc[1][nt] = __builtin_amdgcn_mfma_f32_16x16x32_bf16(a1, wf[kk][nt], acc[1][nt], 0,0,0);
    }
  }

  #pragma unroll
  for (int rs=0;rs<2;++rs){
    int nl0 = wv*32 + rs*16 + g*4;
    #pragma unroll
    for (int r=0;r<4;++r){
      int node = base + nl0 + r;
      if (node < n){
        float dv = Dl[nl0 + r];
        #pragma unroll
        for (int nt=0;nt<4;++nt)
          Y[(size_t)node*64 + nt*16 + c] = f2bf(acc[rs][nt][r] * dv);
      }
    }
  }
}

// ---------------- GCN aggregate: one wave per node, 8-way neighbor ILP (bf16 rows) ----------------
__global__ void agg_kernel(const u16* __restrict__ Hts, const float* __restrict__ dinv,
                           const int* __restrict__ offs, const int* __restrict__ csr,
                           const float* __restrict__ bias, u16* __restrict__ Hout, int n){
  const int node = blockIdx.x*4 + (threadIdx.x >> 6);
  if (node >= n) return;
  const int lane = threadIdx.x & 63;
  const int c8   = lane & 7;
  const int slot = lane >> 3;
  const uint4* __restrict__ H = (const uint4*)Hts;
  float acc[8];
  #pragma unroll
  for (int i=0;i<8;++i) acc[i]=0.f;
  const int beg = offs[node], end = offs[node+1];
  for (int j = beg + slot; j < end; j += 8){
    int s = csr[j];
    uint4 v = H[s*8 + c8];
    acc[0] += __uint_as_float(v.x<<16); acc[1] += __uint_as_float(v.x & 0xffff0000u);
    acc[2] += __uint_as_float(v.y<<16); acc[3] += __uint_as_float(v.y & 0xffff0000u);
    acc[4] += __uint_as_float(v.z<<16); acc[5] += __uint_as_float(v.z & 0xffff0000u);
    acc[6] += __uint_as_float(v.w<<16); acc[7] += __uint_as_float(v.w & 0xffff0000u);
  }
  #pragma unroll
  for (int i=0;i<8;++i) acc[i] += __shfl_xor(acc[i], 8);
  #pragma unroll
  for (int i=0;i<8;++i) acc[i] += __shfl_xor(acc[i], 16);
  #pragma unroll
  for (int i=0;i<8;++i) acc[i] += __shfl_xor(acc[i], 32);
  if (slot == 0){
    uint4 sv = H[node*8 + c8];
    float s[8];
    s[0]=__uint_as_float(sv.x<<16); s[1]=__uint_as_float(sv.x & 0xffff0000u);
    s[2]=__uint_as_float(sv.y<<16); s[3]=__uint_as_float(sv.y & 0xffff0000u);
    s[4]=__uint_as_float(sv.z<<16); s[5]=__uint_as_float(sv.z & 0xffff0000u);
    s[6]=__uint_as_float(sv.w<<16); s[7]=__uint_as_float(sv.w & 0xffff0000u);
    float4 b0 = ((const float4*)bias)[c8*2];
    float4 b1 = ((const float4*)bias)[c8*2+1];
    const float dv = dinv[node];
    float o[8];
    o[0]=fmaxf(fmaf(acc[0]+s[0],dv,b0.x),0.f); o[1]=fmaxf(fmaf(acc[1]+s[1],dv,b0.y),0.f);
    o[2]=fmaxf(fmaf(acc[2]+s[2],dv,b0.z),0.f); o[3]=fmaxf(fmaf(acc[3]+s[3],dv,b0.w),0.f);
    o[4]=fmaxf(fmaf(acc[4]+s[4],dv,b1.x),0.f); o[5]=fmaxf(fmaf(acc[5]+s[5],dv,b1.y),0.f);
    o[6]=fmaxf(fmaf(acc[6]+s[6],dv,b1.z),0.f); o[7]=fmaxf(fmaf(acc[7]+s[7],dv,b1.w),0.f);
    uint4 w;
    w.x = (u32)f2bf(o[0]) | ((u32)f2bf(o[1])<<16);
    w.y = (u32)f2bf(o[2]) | ((u32)f2bf(o[3])<<16);
    w.z = (u32)f2bf(o[4]) | ((u32)f2bf(o[5])<<16);
    w.w = (u32)f2bf(o[6]) | ((u32)f2bf(o[7])<<16);
    ((uint4*)Hout)[node*8 + c8] = w;
  }
}

// ---------------- Fused LSTM x2 + heads (weights from prepped global slab) ----------------
// Math bit-identical to R7; weight fragments read directly from wbuf (L2-hot,
// 16B/lane coalesced). LDS: only H1 hi/lo (20.5KB, H2 aliases it) + biases.
__global__ __launch_bounds__(256) void lstm_heads_fused(
    const u16* __restrict__ X,
    const u16* __restrict__ wbuf, const float* __restrict__ bbuf,
    const float* __restrict__ bv1, const float* __restrict__ Wv2,
    const float* __restrict__ bv2, const float* __restrict__ bt1,
    const float* __restrict__ Wt2, const float* __restrict__ bt2,
    float* __restrict__ out, int n)
{
  const u16* W0hi = wbuf;
  const u16* W0lo = wbuf + 6144;
  const u16* W1g  = wbuf + 12288;
  const u16* WHg  = wbuf + 15360;

  __shared__ u16 Hpool[10240];               // H1hi[0,5120) H1lo[5120,10240); H2 aliases
  __shared__ float b0l[96], b1l[96], bv1l[32], bt1l[32], Wv2l[32], Wt2l[320], bt2l[10];
  u16* H1hi = Hpool;
  u16* H1lo = Hpool + 5120;
  u16* H2hi = Hpool;
  u16* H2lo = Hpool + 5120;

  const int tid  = threadIdx.x;
  const int base = blockIdx.x*128;

  // ---- stage small bias/scalar arrays ----
  if (tid < 96)              b0l[tid] = bbuf[tid];
  else if (tid < 192)        b1l[tid-96] = bbuf[tid];
  else if (tid < 224){ int d=tid-192; bv1l[d]=bv1[d]; }
  else if (tid < 256){ int d=tid-224; bt1l[d]=bt1[d]; Wv2l[d]=Wv2[d]; }
  for (int i=tid; i<320; i+=256) Wt2l[i] = Wt2[i];
  if (tid < 10) bt2l[tid] = bt2[tid];
  __syncthreads();

  const int lane = tid & 63, wv = tid >> 6;
  const int c = lane & 15, g = lane >> 4;
  const float bv2v = bv2[0];

  // ---- lstm0: gates = X @ W0^T (K=64, 96 cols), A + B from global ----
  {
    int r0 = base + wv*32 + c;      if (r0 > n-1) r0 = n-1;
    int r1 = base + wv*32 + 16 + c; if (r1 > n-1) r1 = n-1;
    bfrag a0[2], a1[2];
    #pragma unroll
    for (int kk=0; kk<2; ++kk){
      a0[kk] = *((const bfrag*)(X + (size_t)r0*64 + kk*32 + g*8));
      a1[kk] = *((const bfrag*)(X + (size_t)r1*64 + kk*32 + g*8));
    }
    f32x4 acc[2][6];
    #pragma unroll
    for (int rs=0;rs<2;++rs)
      #pragma unroll
      for (int nt=0;nt<6;++nt) acc[rs][nt] = (f32x4){0.f,0.f,0.f,0.f};
    #pragma unroll
    for (int kk=0; kk<2; ++kk){
      #pragma unroll
      for (int nt=0; nt<6; ++nt){
        int widx = (kk*4+g)*768 + ((nt*16+c)<<3);
        bfrag bh = *((const bfrag*)&W0hi[widx]);
        bfrag bl = *((const bfrag*)&W0lo[widx]);
        acc[0][nt] = __builtin_amdgcn_mfma_f32_16x16x32_bf16(a0[kk], bh, acc[0][nt], 0,0,0);
        acc[0][nt] = __builtin_amdgcn_mfma_f32_16x16x32_bf16(a0[kk], bl, acc[0][nt], 0,0,0);
        acc[1][nt] = __builtin_amdgcn_mfma_f32_16x16x32_bf16(a1[kk], bh, acc[1][nt], 0,0,0);
        acc[1][nt] = __builtin_amdgcn_mfma_f32_16x16x32_bf16(a1[kk], bl, acc[1][nt], 0,0,0);
      }
    }
    #pragma unroll
    for (int rs=0;rs<2;++rs)
      #pragma unroll
      for (int r=0;r<4;++r){
        int rl = wv*32 + rs*16 + g*4 + r;
        #pragma unroll
        for (int half=0; half<2; ++half){
          float iv = acc[rs][0+half][r] + b0l[half*16 + c];
          float gv = acc[rs][2+half][r] + b0l[32 + half*16 + c];
          float ov = acc[rs][4+half][r] + b0l[64 + half*16 + c];
          float cc = fast_sigmoid(iv) * fast_tanh(gv);
          float hv = fast_sigmoid(ov) * fast_tanh(cc);
          u16 hi = f2bf(hv);
          H1hi[rl*40 + half*16 + c] = hi;
          H1lo[rl*40 + half*16 + c] = f2bf(hv - bf2f(hi));
        }
      }
  }
  __syncthreads();                           // H1 visible

  // ---- lstm1: gates = H1 @ W1^T (K=32, 96 cols), A-split 2-term ----
  {
    bfrag w1f[6];
    #pragma unroll
    for (int nt=0; nt<6; ++nt)
      w1f[nt] = *((const bfrag*)&W1g[g*768 + ((nt*16+c)<<3)]);
    bfrag a0h = *((const bfrag*)&H1hi[(wv*32      + c)*40 + g*8]);
    bfrag a0l = *((const bfrag*)&H1lo[(wv*32      + c)*40 + g*8]);
    bfrag a1h = *((const bfrag*)&H1hi[(wv*32 + 16 + c)*40 + g*8]);
    bfrag a1l = *((const bfrag*)&H1lo[(wv*32 + 16 + c)*40 + g*8]);
    f32x4 acc[2][6];
    #pragma unroll
    for (int rs=0;rs<2;++rs)
      #pragma unroll
      for (int nt=0;nt<6;++nt) acc[rs][nt] = (f32x4){0.f,0.f,0.f,0.f};
    #pragma unroll
    for (int nt=0; nt<6; ++nt){
      acc[0][nt] = __builtin_amdgcn_mfma_f32_16x16x32_bf16(a0h, w1f[nt], acc[0][nt], 0,0,0);
      acc[0][nt] = __builtin_amdgcn_mfma_f32_16x16x32_bf16(a0l, w1f[nt], acc[0][nt], 0,0,0);
      acc[1][nt] = __builtin_amdgcn_mfma_f32_16x16x32_bf16(a1h, w1f[nt], acc[1][nt], 0,0,0);
      acc[1][nt] = __builtin_amdgcn_mfma_f32_16x16x32_bf16(a1l, w1f[nt], acc[1][nt], 0,0,0);
    }
    __syncthreads();                         // H1 reads complete before H2 overwrite
    #pragma unroll
    for (int rs=0;rs<2;++rs)
      #pragma unroll
      for (int r=0;r<4;++r){
        int rl = wv*32 + rs*16 + g*4 + r;
        #pragma unroll
        for (int half=0; half<2; ++half){
          float iv = acc[rs][0+half][r] + b1l[half*16 + c];
          float gv = acc[rs][2+half][r] + b1l[32 + half*16 + c];
          float ov = acc[rs][4+half][r] + b1l[64 + half*16 + c];
          float cc = fast_sigmoid(iv) * fast_tanh(gv);
          float hv = fast_sigmoid(ov) * fast_tanh(cc);
          u16 hi = f2bf(hv);
          H2hi[rl*40 + half*16 + c] = hi;
          H2lo[rl*40 + half*16 + c] = f2bf(hv - bf2f(hi));
        }
      }
  }
  __syncthreads();

  // ---- heads: [v1 | t1] = relu(H2 @ [Wv1|Wt1] + b), A-split, then 32->1 / 32->10 ----
  {
    bfrag whf[4];
    #pragma unroll
    for (int nt=0; nt<4; ++nt)
      whf[nt] = *((const bfrag*)&WHg[g*512 + ((nt*16+c)<<3)]);
    bfrag a0h = *((const bfrag*)&H2hi[(wv*32      + c)*40 + g*8]);
    bfrag a0l = *((const bfrag*)&H2lo[(wv*32      + c)*40 + g*8]);
    bfrag a1h = *((const bfrag*)&H2hi[(wv*32 + 16 + c)*40 + g*8]);
    bfrag a1l = *((const bfrag*)&H2lo[(wv*32 + 16 + c)*40 + g*8]);
    f32x4 acc[2][4];
    #pragma unroll
    for (int rs=0;rs<2;++rs)
      #pragma unroll
      for (int nt=0;nt<4;++nt) acc[rs][nt] = (f32x4){0.f,0.f,0.f,0.f};
    #pragma unroll
    for (int nt=0; nt<4; ++nt){
      acc[0][nt] = __builtin_amdgcn_mfma_f32_16x16x32_bf16(a0h, whf[nt], acc[0][nt], 0,0,0);
      acc[0][nt] = __builtin_amdgcn_mfma_f32_16x16x32_bf16(a0l, whf[nt], acc[0][nt], 0,0,0);
      acc[1][nt] = __builtin_amdgcn_mfma_f32_16x16x32_bf16(a1h, whf[nt], acc[1][nt], 0,0,0);
      acc[1][nt] = __builtin_amdgcn_mfma_f32_16x16x32_bf16(a1l, whf[nt], acc[1][nt], 0,0,0);
    }
    const float wv2a = Wv2l[c], wv2b = Wv2l[c+16];
    float wt2a[10], wt2b[10];
    #pragma unroll
    for (int k=0;k<10;++k){ wt2a[k] = Wt2l[c*10+k]; wt2b[k] = Wt2l[(c+16)*10+k]; }
    #pragma unroll
    for (int rs=0;rs<2;++rs)
      #pragma unroll
      for (int r=0;r<4;++r){
        int node = base + wv*32 + rs*16 + g*4 + r;
        float va = fmaxf(acc[rs][0][r] + bv1l[c],    0.f);
        float vb = fmaxf(acc[rs][1][r] + bv1l[c+16], 0.f);
        float ta = fmaxf(acc[rs][2][r] + bt1l[c],    0.f);
        float tb = fmaxf(acc[rs][3][r] + bt1l[c+16], 0.f);
        float pv = va*wv2a + vb*wv2b;
        pv += __shfl_xor(pv, 1); pv += __shfl_xor(pv, 2);
        pv += __shfl_xor(pv, 4); pv += __shfl_xor(pv, 8);
        float tk[10];
        #pragma unroll
        for (int k=0;k<10;++k) tk[k] = ta*wt2a[k] + tb*wt2b[k];
        #pragma unroll
        for (int k=0;k<10;++k) tk[k] += __shfl_xor(tk[k], 1);
        #pragma unroll
        for (int k=0;k<10;++k) tk[k] += __shfl_xor(tk[k], 2);
        #pragma unroll
        for (int k=0;k<10;++k) tk[k] += __shfl_xor(tk[k], 4);
        #pragma unroll
        for (int k=0;k<10;++k) tk[k] += __shfl_xor(tk[k], 8);
        if (c == 0 && node < n){
          out[node] = pv + bv2v;
          #pragma unroll
          for (int k=0;k<10;++k) out[n + (size_t)node*10 + k] = tk[k] + bt2l[k];
        }
      }
  }
}

extern "C" void kernel_launch(void* const* d_in, const int* in_sizes, int n_in,
                              void* d_out, int out_size, void* d_ws, size_t ws_size,
                              hipStream_t stream){
  const float* x    = (const float*)d_in[0];
  const int*   ei   = (const int*)  d_in[1];
  const float* W1   = (const float*)d_in[2];  const float* b1   = (const float*)d_in[3];
  const float* W2   = (const float*)d_in[4];  const float* b2   = (const float*)d_in[5];
  const float* W3   = (const float*)d_in[6];  const float* b3   = (const float*)d_in[7];
  const float* Wih0 = (const float*)d_in[8];
  const float* bih0 = (const float*)d_in[10]; const float* bhh0 = (const float*)d_in[11];
  const float* Wih1 = (const float*)d_in[12];
  const float* bih1 = (const float*)d_in[14]; const float* bhh1 = (const float*)d_in[15];
  const float* Wv1  = (const float*)d_in[16]; const float* bv1  = (const float*)d_in[17];
  const float* Wv2  = (const float*)d_in[18]; const float* bv2  = (const float*)d_in[19];
  const float* Wt1  = (const float*)d_in[20]; const float* bt1  = (const float*)d_in[21];
  const float* Wt2  = (const float*)d_in[22]; const float* bt2  = (const float*)d_in[23];

  const int N  = in_sizes[0] / 128;
  const int E  = in_sizes[1] / 2;
  const int NB = (N + 1023) / 1024;
  const int EB = (E + 8191) / 8192;

  char* w = (char*)d_ws;
  auto take = [&](size_t bytes)->char*{ char* p = w; w += (bytes + 255) & ~(size_t)255; return p; };
  int*   deg    = (int*)  take((size_t)N*4);
  int*   offs   = (int*)  take((size_t)(N+1)*4);
  int*   cursor = (int*)  take((size_t)N*4);
  int*   csr    = (int*)  take((size_t)E*4);
  float* dinv   = (float*)take((size_t)N*4);
  int*   bsums  = (int*)  take((size_t)NB*4);
  int*   boffs  = (int*)  take((size_t)NB*4);
  int*   bhist  = (int*)  take((size_t)MAXBK*4);
  int*   bcur   = (int*)  take((size_t)MAXBK*4);
  int*   srcB   = (int*)  take((size_t)E*4);
  int*   dstB   = (int*)  take((size_t)E*4);
  u16*   wbuf   = (u16*)  take((size_t)17408*2);  // prepped tail weights
  float* bbuf   = (float*)take((size_t)192*4);    // prepped tail biases
  u16*   bufTS  = (u16*)  take((size_t)N*64*2);   // transformed (pre-agg), bf16
  u16*   bufH   = (u16*)  take((size_t)N*64*2);   // post-agg activations, bf16
  (void)ws_size; (void)n_in; (void)out_size;

  // --- run-once tail weight prep (overlaps CSR build region) ---
  prep_tail_kernel<<<45, 256, 0, stream>>>(Wih0, Wih1, Wv1, Wt1,
                                           bih0, bhh0, bih1, bhh1, wbuf, bbuf);

  // --- CSR build ---
  hipMemsetAsync(deg, 0, (size_t)N*4, stream);
  if (N <= MAXBK*256){
    hipMemsetAsync(bhist, 0, (size_t)MAXBK*4, stream);
    bucket_hist_kernel<<<EB, 512, 0, stream>>>(ei + E, bhist, E);
    bucket_scan_kernel<<<1,  512, 0, stream>>>(bhist, bcur);
    bin_kernel        <<<EB, 512, 0, stream>>>(ei, ei + E, bcur, srcB, dstB, E);
    count2_kernel     <<<(E+255)/256, 256, 0, stream>>>(dstB, deg, E);
  } else {
    count_kernel      <<<(E+255)/256, 256, 0, stream>>>(ei + E, deg, E);
  }
  scan_reduce_kernel<<<NB,          256, 0, stream>>>(deg, bsums, N);
  scan_block_kernel <<<1,           128, 0, stream>>>(bsums, boffs, NB);
  scan_final_kernel <<<NB,          256, 0, stream>>>(deg, boffs, offs, N, E);
  dinv_kernel       <<<(N+255)/256, 256, 0, stream>>>(deg, offs, cursor, dinv, N);
  if (N <= MAXBK*256){
    fill2_kernel<<<(E+255)/256, 256, 0, stream>>>(srcB, dstB, cursor, csr, E);
  } else {
    fill_kernel <<<(E+255)/256, 256, 0, stream>>>(ei, cursor, csr, E);
  }

  // --- GCN layers (MFMA transforms) ---
  const int TB = (N + 127) / 128;
  transform_mfma<128,float><<<TB, 256, 0, stream>>>(x,    W1, dinv, bufTS, N);
  agg_kernel               <<<(N+3)/4, 256, 0, stream>>>(bufTS, dinv, offs, csr, b1, bufH, N);
  transform_mfma<64,u16>   <<<TB, 256, 0, stream>>>(bufH, W2, dinv, bufTS, N);
  agg_kernel               <<<(N+3)/4, 256, 0, stream>>>(bufTS, dinv, offs, csr, b2, bufH, N);
  transform_mfma<64,u16>   <<<TB, 256, 0, stream>>>(bufH, W3, dinv, bufTS, N);
  agg_kernel               <<<(N+3)/4, 256, 0, stream>>>(bufTS, dinv, offs, csr, b3, bufH, N);

  // --- fused LSTM x2 + heads ---
  lstm_heads_fused<<<TB, 256, 0, stream>>>(bufH, wbuf, bbuf,
                                           bv1, Wv2, bv2, bt1, Wt2, bt2,
                                           (float*)d_out, N);
}

// Round 9
// 332.264 us; speedup vs baseline: 2.8785x; 1.0406x over previous
//
#include <hip/hip_runtime.h>
#include <math.h>

// TemporalWasteGNN: 3x GCNConv (symmetric-norm, self-loops) -> 2x LSTM(seq=1, h0=c0=0)
// -> two MLP heads. fp32 I/O, bf16 intermediate features.
//
// R9: fused tail restructured for latency (R8: 25% occ, 12 waves/CU, 352
//     shfl/thread serial head reduction):
//     - 16 rows/wave (64 nodes/block, grid 782->1563, ~24 waves/CU).
//     - heads 32->1 / 32->10 contractions now a 2nd MFMA pass against
//       prep-built Wv2/Wt2 lane fragments; zero shuffles in the tail.
//     - relu'd [v1|t1] staged in LDS as single bf16 (adds ~4e-5 err, negligible).
// R3 bucketed CSR build, R4 MFMA transforms, R7 native transcendentals,
// R8 prepped weight slab retained.

typedef unsigned int  u32;
typedef unsigned short u16;
typedef short bfrag  __attribute__((ext_vector_type(8)));   // 8 bf16 (4 VGPRs)
typedef float f32x4  __attribute__((ext_vector_type(4)));

#define LOG2E 1.44269504088896f
static __device__ __forceinline__ float fast_sigmoid(float x){
  float t = __builtin_amdgcn_exp2f(-x * LOG2E);
  return __builtin_amdgcn_rcpf(1.f + t);
}
static __device__ __forceinline__ float fast_tanh(float x){
  float t = __builtin_amdgcn_exp2f(x * (2.f * LOG2E));
  return 1.f - 2.f * __builtin_amdgcn_rcpf(t + 1.f);
}
static __device__ __forceinline__ float bf2f(u16 u){ return __uint_as_float(((u32)u)<<16); }
static __device__ __forceinline__ u16   f2bf(float f){
  u32 x = __float_as_uint(f);
  return (u16)((x + 0x7fffu + ((x>>16)&1u)) >> 16);   // round-to-nearest-even
}

#define MAXBK 512   // buckets of 256 dst nodes; N <= 131072

// ---------------- bucketed CSR build ----------------
__global__ __launch_bounds__(512) void bucket_hist_kernel(const int* __restrict__ dstA,
                                                          int* __restrict__ bhist, int E){
  __shared__ int h[MAXBK];
  for (int i=threadIdx.x; i<MAXBK; i+=512) h[i]=0;
  __syncthreads();
  const int base = blockIdx.x*8192;
  #pragma unroll
  for (int j=0;j<16;++j){
    int e = base + j*512 + threadIdx.x;
    if (e < E) atomicAdd(&h[dstA[e]>>8], 1);
  }
  __syncthreads();
  for (int i=threadIdx.x; i<MAXBK; i+=512) if (h[i]) atomicAdd(&bhist[i], h[i]);
}

__global__ __launch_bounds__(512) void bucket_scan_kernel(const int* __restrict__ bhist,
                                                          int* __restrict__ bcur){
  __shared__ int ts[MAXBK];
  int v = bhist[threadIdx.x];
  ts[threadIdx.x] = v; __syncthreads();
  for (int off=1; off<MAXBK; off<<=1){
    int t = (threadIdx.x>=off) ? ts[threadIdx.x-off] : 0;
    __syncthreads();
    ts[threadIdx.x] += t;
    __syncthreads();
  }
  bcur[threadIdx.x] = ts[threadIdx.x] - v;   // exclusive prefix
}

__global__ __launch_bounds__(512) void bin_kernel(const int* __restrict__ srcA,
                                                  const int* __restrict__ dstA,
                                                  int* __restrict__ bcur,
                                                  int* __restrict__ srcB,
                                                  int* __restrict__ dstB, int E){
  __shared__ int h[MAXBK];
  __shared__ int basev[MAXBK];
  for (int i=threadIdx.x; i<MAXBK; i+=512) h[i]=0;
  __syncthreads();
  const int base = blockIdx.x*8192;
  int br[16]; int dv[16];
  #pragma unroll
  for (int j=0;j<16;++j){
    int e = base + j*512 + threadIdx.x;
    if (e < E){
      int d = dstA[e]; int b = d>>8;
      int r = atomicAdd(&h[b], 1);
      br[j] = (b<<16) | r;
      dv[j] = d;
    } else br[j] = -1;
  }
  __syncthreads();
  for (int i=threadIdx.x; i<MAXBK; i+=512){
    int c = h[i];
    basev[i] = c ? atomicAdd(&bcur[i], c) : 0;
  }
  __syncthreads();
  #pragma unroll
  for (int j=0;j<16;++j){
    if (br[j] >= 0){
      int e = base + j*512 + threadIdx.x;
      int pos = basev[br[j]>>16] + (br[j] & 0xffff);
      srcB[pos] = srcA[e];
      dstB[pos] = dv[j];
    }
  }
}

__global__ void count2_kernel(const int* __restrict__ dstB, int* __restrict__ deg, int E){
  int e = blockIdx.x*256 + threadIdx.x;
  if (e < E) atomicAdd(&deg[dstB[e]], 1);
}

__global__ void fill2_kernel(const int* __restrict__ srcB, const int* __restrict__ dstB,
                             int* __restrict__ cursor, int* __restrict__ csr, int E){
  int e = blockIdx.x*256 + threadIdx.x;
  if (e < E){
    int pos = atomicAdd(&cursor[dstB[e]], 1);
    csr[pos] = srcB[e];
  }
}

// fallback (N too large for bucketing)
__global__ void count_kernel(const int* __restrict__ dsts, int* __restrict__ deg, int E){
  int e = blockIdx.x*256 + threadIdx.x;
  if (e < E) atomicAdd(&deg[dsts[e]], 1);
}
__global__ void fill_kernel(const int* __restrict__ ei, int* __restrict__ cursor,
                            int* __restrict__ csr, int E){
  int e = blockIdx.x*256 + threadIdx.x;
  if (e < E){
    int d = ei[E + e];
    int pos = atomicAdd(&cursor[d], 1);
    csr[pos] = ei[e];
  }
}

// ---------------- deg scan -> offs ----------------
__global__ void scan_reduce_kernel(const int* __restrict__ deg, int* __restrict__ bsums, int n){
  __shared__ int sd[256];
  int base = blockIdx.x*1024 + threadIdx.x*4;
  int s = 0;
  #pragma unroll
  for (int j=0;j<4;++j){ int idx=base+j; if (idx<n) s += deg[idx]; }
  sd[threadIdx.x] = s; __syncthreads();
  for (int off=128; off>0; off>>=1){
    if (threadIdx.x < off) sd[threadIdx.x] += sd[threadIdx.x+off];
    __syncthreads();
  }
  if (threadIdx.x==0) bsums[blockIdx.x] = sd[0];
}

__global__ void scan_block_kernel(const int* __restrict__ bsums, int* __restrict__ boffs, int nb){
  __shared__ int ts[128];
  if (nb <= 128){
    int v = (threadIdx.x < nb) ? bsums[threadIdx.x] : 0;
    ts[threadIdx.x] = v; __syncthreads();
    for (int off=1; off<128; off<<=1){
      int t = (threadIdx.x>=off) ? ts[threadIdx.x-off] : 0;
      __syncthreads();
      ts[threadIdx.x] += t;
      __syncthreads();
    }
    if (threadIdx.x < nb) boffs[threadIdx.x] = ts[threadIdx.x] - v;
  } else if (threadIdx.x==0){
    int run=0;
    for (int b=0;b<nb;++b){ int t=bsums[b]; boffs[b]=run; run+=t; }
  }
}

__global__ void scan_final_kernel(const int* __restrict__ deg, const int* __restrict__ boffs,
                                  int* __restrict__ offs, int n, int E){
  __shared__ int ts[256];
  int base = blockIdx.x*1024 + threadIdx.x*4;
  int v[4]; int s=0;
  #pragma unroll
  for (int j=0;j<4;++j){ int idx=base+j; v[j] = (idx<n) ? deg[idx] : 0; s += v[j]; }
  ts[threadIdx.x] = s; __syncthreads();
  for (int off=1; off<256; off<<=1){
    int t = (threadIdx.x>=off) ? ts[threadIdx.x-off] : 0;
    __syncthreads();
    ts[threadIdx.x] += t;
    __syncthreads();
  }
  int excl = boffs[blockIdx.x] + (threadIdx.x ? ts[threadIdx.x-1] : 0);
  #pragma unroll
  for (int j=0;j<4;++j){ int idx=base+j; if (idx<n){ offs[idx]=excl; excl+=v[j]; } }
  if (blockIdx.x==0 && threadIdx.x==0) offs[n] = E;
}

__global__ void dinv_kernel(const int* __restrict__ deg, const int* __restrict__ offs,
                            int* __restrict__ cursor, float* __restrict__ dinv, int n){
  int i = blockIdx.x*256 + threadIdx.x;
  if (i < n){
    dinv[i] = rsqrtf((float)(deg[i] + 1));
    cursor[i] = offs[i];
  }
}

// ---------------- run-once tail-weight prep ----------------
// wbuf (u16): W0hi[0,6144) W0lo[6144,12288) W1[12288,15360) WH[15360,17408)
//             BV[17408,17920) BT[17920,18432)  (lane-indexed K=32 B-fragments)
// bbuf (f32): b0[0,96) b1[96,192)
__global__ void prep_tail_kernel(const float* __restrict__ Wih0, const float* __restrict__ Wih1,
                                 const float* __restrict__ Wv1,  const float* __restrict__ Wt1,
                                 const float* __restrict__ Wv2,  const float* __restrict__ Wt2,
                                 const float* __restrict__ bih0, const float* __restrict__ bhh0,
                                 const float* __restrict__ bih1, const float* __restrict__ bhh1,
                                 u16* __restrict__ wbuf, float* __restrict__ bbuf){
  int tid = blockIdx.x*256 + threadIdx.x;
  if (tid < 6144){                                  // Wih0 hi/lo, [k/8][96][8]
    int kg = tid / 768, rem = tid % 768;
    int j = rem >> 3, k = kg*8 + (rem & 7);
    int row = (j < 32) ? j : j + 32;
    float w = Wih0[row*64 + k];
    u16 hi = f2bf(w);
    wbuf[tid] = hi;
    wbuf[6144 + tid] = f2bf(w - bf2f(hi));
  } else if (tid < 9216){                           // Wih1, [k/8][96][8]
    int t = tid - 6144;
    int kg = t / 768, rem = t % 768;
    int j = rem >> 3, k = kg*8 + (rem & 7);
    int row = (j < 32) ? j : j + 32;
    wbuf[12288 + t] = f2bf(Wih1[row*32 + k]);
  } else if (tid < 11264){                          // Wv1|Wt1, [k/8][64][8]
    int t = tid - 9216;
    int kg = t / 512, rem = t % 512;
    int j = rem >> 3, k = kg*8 + (rem & 7);
    float v = (j < 32) ? Wv1[k*32 + j] : Wt1[k*32 + (j-32)];
    wbuf[15360 + t] = f2bf(v);
  } else if (tid < 11360){                          // b0 (i,g,o combined)
    int t = tid - 11264;
    int row = (t < 32) ? t : t + 32;
    bbuf[t] = bih0[row] + bhh0[row];
  } else if (tid < 11456){                          // b1
    int t = tid - 11360;
    int row = (t < 32) ? t : t + 32;
    bbuf[96 + t] = bih1[row] + bhh1[row];
  } else if (tid < 12480){                          // BV/BT lane fragments (K=32)
    int t = tid - 11456;
    int slab = t >> 9, within = t & 511;
    int lane = within >> 3, j = within & 7;
    int cc = lane & 15, gg = lane >> 4;
    float v;
    if (slab == 0) v = (cc == 0) ? Wv2[gg*8 + j] : 0.f;
    else           v = (cc < 10) ? Wt2[(gg*8 + j)*10 + cc] : 0.f;
    wbuf[17408 + slab*512 + within] = f2bf(v);
  }
}

// ---------------- GCN transform via MFMA (verified in R4) ----------------
template<int KD, typename TIN>
__global__ __launch_bounds__(256) void transform_mfma(const TIN* __restrict__ X,
                                                      const float* __restrict__ W,
                                                      const float* __restrict__ dinv,
                                                      u16* __restrict__ Y, int n){
  constexpr int XLD = KD + 8;
  __shared__ u16 Xl[128*XLD];
  __shared__ u16 Wl[KD*64];          // layout [KD/8][64][8]
  __shared__ float Dl[128];
  const int tid  = threadIdx.x;
  const int base = blockIdx.x*128;

  for (int i = tid; i < KD*64; i += 256){
    int k = i >> 6, col = i & 63;
    Wl[((k>>3)<<9) + (col<<3) + (k&7)] = f2bf(W[i]);
  }
  if (tid < 128){
    int nd = base + tid;
    Dl[tid] = (nd < n) ? dinv[nd] : 0.f;
  }
  if constexpr (sizeof(TIN)==4){
    #pragma unroll
    for (int j = 0; j < (128*KD)/1024; ++j){
      int e4   = tid + j*256;
      int elem = e4*4;
      int row  = elem / KD, k = elem % KD;
      int gn   = base + row;
      uint2 w2 = make_uint2(0u, 0u);
      if (gn < n){
        float4 v = ((const float4*)X)[(size_t)gn*(KD/4) + (k>>2)];
        w2.x = (u32)f2bf(v.x) | ((u32)f2bf(v.y)<<16);
        w2.y = (u32)f2bf(v.z) | ((u32)f2bf(v.w)<<16);
      }
      *((uint2*)&Xl[row*XLD + k]) = w2;
    }
  } else {
    #pragma unroll
    for (int j = 0; j < (128*KD)/1024; ++j){
      int e4   = tid + j*256;
      int elem = e4*4;
      int row  = elem / KD, k = elem % KD;
      int gn   = base + row;
      uint2 v = make_uint2(0u, 0u);
      if (gn < n) v = *((const uint2*)(X + (size_t)gn*KD + k));
      *((uint2*)&Xl[row*XLD + k]) = v;
    }
  }
  __syncthreads();

  const int lane = tid & 63, wv = tid >> 6;
  const int c = lane & 15, g = lane >> 4;

  bfrag wf[KD/32][4];
  #pragma unroll
  for (int kk=0; kk<KD/32; ++kk)
    #pragma unroll
    for (int nt=0; nt<4; ++nt)
      wf[kk][nt] = *((const bfrag*)&Wl[((kk*4+g)<<9) + ((nt*16+c)<<3)]);

  f32x4 acc[2][4];
  #pragma unroll
  for (int rs=0;rs<2;++rs)
    #pragma unroll
    for (int nt=0;nt<4;++nt)
      acc[rs][nt] = (f32x4){0.f,0.f,0.f,0.f};

  #pragma unroll
  for (int kk=0; kk<KD/32; ++kk){
    bfrag a0 = *((const bfrag*)&Xl[(wv*32      + c)*XLD + kk*32 + g*8]);
    bfrag a1 = *((const bfrag*)&Xl[(wv*32 + 16 + c)*XLD + kk*32 + g*8]);
    #pragma unroll
    for (int nt=0; nt<4; ++nt){
      acc[0][nt] = __builtin_amdgcn_mfma_f32_16x16x32_bf16(a0, wf[kk][nt], acc[0][nt], 0,0,0);
      acc[1][nt] = __builtin_amdgcn_mfma_f32_16x16x32_bf16(a1, wf[kk][nt], acc[1][nt], 0,0,0);
    }
  }

  #pragma unroll
  for (int rs=0;rs<2;++rs){
    int nl0 = wv*32 + rs*16 + g*4;
    #pragma unroll
    for (int r=0;r<4;++r){
      int node = base + nl0 + r;
      if (node < n){
        float dv = Dl[nl0 + r];
        #pragma unroll
        for (int nt=0;nt<4;++nt)
          Y[(size_t)node*64 + nt*16 + c] = f2bf(acc[rs][nt][r] * dv);
      }
    }
  }
}

// ---------------- GCN aggregate: one wave per node, 8-way neighbor ILP (bf16 rows) ----------------
__global__ void agg_kernel(const u16* __restrict__ Hts, const float* __restrict__ dinv,
                           const int* __restrict__ offs, const int* __restrict__ csr,
                           const float* __restrict__ bias, u16* __restrict__ Hout, int n){
  const int node = blockIdx.x*4 + (threadIdx.x >> 6);
  if (node >= n) return;
  const int lane = threadIdx.x & 63;
  const int c8   = lane & 7;
  const int slot = lane >> 3;
  const uint4* __restrict__ H = (const uint4*)Hts;
  float acc[8];
  #pragma unroll
  for (int i=0;i<8;++i) acc[i]=0.f;
  const int beg = offs[node], end = offs[node+1];
  for (int j = beg + slot; j < end; j += 8){
    int s = csr[j];
    uint4 v = H[s*8 + c8];
    acc[0] += __uint_as_float(v.x<<16); acc[1] += __uint_as_float(v.x & 0xffff0000u);
    acc[2] += __uint_as_float(v.y<<16); acc[3] += __uint_as_float(v.y & 0xffff0000u);
    acc[4] += __uint_as_float(v.z<<16); acc[5] += __uint_as_float(v.z & 0xffff0000u);
    acc[6] += __uint_as_float(v.w<<16); acc[7] += __uint_as_float(v.w & 0xffff0000u);
  }
  #pragma unroll
  for (int i=0;i<8;++i) acc[i] += __shfl_xor(acc[i], 8);
  #pragma unroll
  for (int i=0;i<8;++i) acc[i] += __shfl_xor(acc[i], 16);
  #pragma unroll
  for (int i=0;i<8;++i) acc[i] += __shfl_xor(acc[i], 32);
  if (slot == 0){
    uint4 sv = H[node*8 + c8];
    float s[8];
    s[0]=__uint_as_float(sv.x<<16); s[1]=__uint_as_float(sv.x & 0xffff0000u);
    s[2]=__uint_as_float(sv.y<<16); s[3]=__uint_as_float(sv.y & 0xffff0000u);
    s[4]=__uint_as_float(sv.z<<16); s[5]=__uint_as_float(sv.z & 0xffff0000u);
    s[6]=__uint_as_float(sv.w<<16); s[7]=__uint_as_float(sv.w & 0xffff0000u);
    float4 b0 = ((const float4*)bias)[c8*2];
    float4 b1 = ((const float4*)bias)[c8*2+1];
    const float dv = dinv[node];
    float o[8];
    o[0]=fmaxf(fmaf(acc[0]+s[0],dv,b0.x),0.f); o[1]=fmaxf(fmaf(acc[1]+s[1],dv,b0.y),0.f);
    o[2]=fmaxf(fmaf(acc[2]+s[2],dv,b0.z),0.f); o[3]=fmaxf(fmaf(acc[3]+s[3],dv,b0.w),0.f);
    o[4]=fmaxf(fmaf(acc[4]+s[4],dv,b1.x),0.f); o[5]=fmaxf(fmaf(acc[5]+s[5],dv,b1.y),0.f);
    o[6]=fmaxf(fmaf(acc[6]+s[6],dv,b1.z),0.f); o[7]=fmaxf(fmaf(acc[7]+s[7],dv,b1.w),0.f);
    uint4 w;
    w.x = (u32)f2bf(o[0]) | ((u32)f2bf(o[1])<<16);
    w.y = (u32)f2bf(o[2]) | ((u32)f2bf(o[3])<<16);
    w.z = (u32)f2bf(o[4]) | ((u32)f2bf(o[5])<<16);
    w.w = (u32)f2bf(o[6]) | ((u32)f2bf(o[7])<<16);
    ((uint4*)Hout)[node*8 + c8] = w;
  }
}

// ---------------- Fused LSTM x2 + heads: 16 rows/wave, zero shuffles ----------------
// Block = 256 thr (4 waves) x 64 nodes; wave wv owns rows [wv*16, wv*16+16).
// lstm0: 24 MFMA (B hi/lo split); lstm1: 12 (A hi/lo); heads p1: 8 (A hi/lo);
// heads p2: 2 MFMA vs prep-built Wv2/Wt2 lane fragments -> direct C-write.
__global__ __launch_bounds__(256) void lstm_heads_fused(
    const u16* __restrict__ X,
    const u16* __restrict__ wbuf, const float* __restrict__ bbuf,
    const float* __restrict__ bv1, const float* __restrict__ bv2,
    const float* __restrict__ bt1, const float* __restrict__ bt2,
    float* __restrict__ out, int n)
{
  const u16* W0hi = wbuf;
  const u16* W0lo = wbuf + 6144;
  const u16* W1g  = wbuf + 12288;
  const u16* WHg  = wbuf + 15360;
  const u16* BVg  = wbuf + 17408;
  const u16* BTg  = wbuf + 17920;

  __shared__ u16 Hpool[5120];       // H1hi[0,2560) H1lo[2560,5120); H2 aliases (barrier-sep)
  __shared__ u16 VT[4608];          // 64 rows x 72: relu'd [v1(0-31) | t1(32-63)], bf16
  __shared__ float b0l[96], b1l[96], bv1l[32], bt1l[32], bt2l[10];
  u16* H1hi = Hpool;  u16* H1lo = Hpool + 2560;
  u16* H2hi = Hpool;  u16* H2lo = Hpool + 2560;

  const int tid  = threadIdx.x;
  const int base = blockIdx.x*64;

  if (tid < 96)            b0l[tid] = bbuf[tid];
  else if (tid < 192)      b1l[tid-96] = bbuf[tid];
  else if (tid < 224){ int d=tid-192; bv1l[d]=bv1[d]; }
  else               { int d=tid-224; bt1l[d]=bt1[d]; }
  if (tid < 10) bt2l[tid] = bt2[tid];
  __syncthreads();

  const int lane = tid & 63, wv = tid >> 6;
  const int c = lane & 15, g = lane >> 4;
  const float bv2v = bv2[0];

  // ---- lstm0: gates = X @ W0^T (K=64, 96 cols) ----
  {
    int r0 = base + wv*16 + c; if (r0 > n-1) r0 = n-1;
    bfrag a0[2];
    a0[0] = *((const bfrag*)(X + (size_t)r0*64      + g*8));
    a0[1] = *((const bfrag*)(X + (size_t)r0*64 + 32 + g*8));
    f32x4 acc[6];
    #pragma unroll
    for (int nt=0;nt<6;++nt) acc[nt] = (f32x4){0.f,0.f,0.f,0.f};
    #pragma unroll
    for (int kk=0; kk<2; ++kk){
      #pragma unroll
      for (int nt=0; nt<6; ++nt){
        int widx = (kk*4+g)*768 + ((nt*16+c)<<3);
        bfrag bh = *((const bfrag*)&W0hi[widx]);
        bfrag bl = *((const bfrag*)&W0lo[widx]);
        acc[nt] = __builtin_amdgcn_mfma_f32_16x16x32_bf16(a0[kk], bh, acc[nt], 0,0,0);
        acc[nt] = __builtin_amdgcn_mfma_f32_16x16x32_bf16(a0[kk], bl, acc[nt], 0,0,0);
      }
    }
    #pragma unroll
    for (int r=0;r<4;++r){
      int rl = wv*16 + g*4 + r;
      #pragma unroll
      for (int half=0; half<2; ++half){
        float iv = acc[0+half][r] + b0l[half*16 + c];
        float gv = acc[2+half][r] + b0l[32 + half*16 + c];
        float ov = acc[4+half][r] + b0l[64 + half*16 + c];
        float cc = fast_sigmoid(iv) * fast_tanh(gv);
        float hv = fast_sigmoid(ov) * fast_tanh(cc);
        u16 hi = f2bf(hv);
        H1hi[rl*40 + half*16 + c] = hi;
        H1lo[rl*40 + half*16 + c] = f2bf(hv - bf2f(hi));
      }
    }
  }
  __syncthreads();                           // H1 visible

  // ---- lstm1: gates = H1 @ W1^T (K=32, 96 cols), A-split 2-term ----
  {
    bfrag w1f[6];
    #pragma unroll
    for (int nt=0; nt<6; ++nt)
      w1f[nt] = *((const bfrag*)&W1g[g*768 + ((nt*16+c)<<3)]);
    bfrag ah = *((const bfrag*)&H1hi[(wv*16 + c)*40 + g*8]);
    bfrag al = *((const bfrag*)&H1lo[(wv*16 + c)*40 + g*8]);
    f32x4 acc[6];
    #pragma unroll
    for (int nt=0;nt<6;++nt) acc[nt] = (f32x4){0.f,0.f,0.f,0.f};
    #pragma unroll
    for (int nt=0; nt<6; ++nt){
      acc[nt] = __builtin_amdgcn_mfma_f32_16x16x32_bf16(ah, w1f[nt], acc[nt], 0,0,0);
      acc[nt] = __builtin_amdgcn_mfma_f32_16x16x32_bf16(al, w1f[nt], acc[nt], 0,0,0);
    }
    __syncthreads();                         // all H1 reads complete before H2 overwrite
    #pragma unroll
    for (int r=0;r<4;++r){
      int rl = wv*16 + g*4 + r;
      #pragma unroll
      for (int half=0; half<2; ++half){
        float iv = acc[0+half][r] + b1l[half*16 + c];
        float gv = acc[2+half][r] + b1l[32 + half*16 + c];
        float ov = acc[4+half][r] + b1l[64 + half*16 + c];
        float cc = fast_sigmoid(iv) * fast_tanh(gv);
        float hv = fast_sigmoid(ov) * fast_tanh(cc);
        u16 hi = f2bf(hv);
        H2hi[rl*40 + half*16 + c] = hi;
        H2lo[rl*40 + half*16 + c] = f2bf(hv - bf2f(hi));
      }
    }
  }
  __syncthreads();                           // H2 visible

  // ---- heads p1: [v1|t1] = relu(H2 @ [Wv1|Wt1] + b) -> VT (bf16) ----
  {
    bfrag whf[4];
    #pragma unroll
    for (int nt=0; nt<4; ++nt)
      whf[nt] = *((const bfrag*)&WHg[g*512 + ((nt*16+c)<<3)]);
    bfrag ah = *((const bfrag*)&H2hi[(wv*16 + c)*40 + g*8]);
    bfrag al = *((const bfrag*)&H2lo[(wv*16 + c)*40 + g*8]);
    f32x4 acc[4];
    #pragma unroll
    for (int nt=0;nt<4;++nt) acc[nt] = (f32x4){0.f,0.f,0.f,0.f};
    #pragma unroll
    for (int nt=0; nt<4; ++nt){
      acc[nt] = __builtin_amdgcn_mfma_f32_16x16x32_bf16(ah, whf[nt], acc[nt], 0,0,0);
      acc[nt] = __builtin_amdgcn_mfma_f32_16x16x32_bf16(al, whf[nt], acc[nt], 0,0,0);
    }
    #pragma unroll
    for (int r=0;r<4;++r){
      int rl = wv*16 + g*4 + r;
      VT[rl*72      + c] = f2bf(fmaxf(acc[0][r] + bv1l[c],    0.f));
      VT[rl*72 + 16 + c] = f2bf(fmaxf(acc[1][r] + bv1l[c+16], 0.f));
      VT[rl*72 + 32 + c] = f2bf(fmaxf(acc[2][r] + bt1l[c],    0.f));
      VT[rl*72 + 48 + c] = f2bf(fmaxf(acc[3][r] + bt1l[c+16], 0.f));
    }
  }
  __syncthreads();                           // VT visible

  // ---- heads p2: vol = v1 @ Wv2, type = t1 @ Wt2 via MFMA, direct C-write ----
  {
    bfrag av = *((const bfrag*)&VT[(wv*16 + c)*72      + g*8]);
    bfrag at = *((const bfrag*)&VT[(wv*16 + c)*72 + 32 + g*8]);
    bfrag bv = *((const bfrag*)(BVg + lane*8));
    bfrag bt = *((const bfrag*)(BTg + lane*8));
    f32x4 accv = (f32x4){0.f,0.f,0.f,0.f};
    f32x4 acct = (f32x4){0.f,0.f,0.f,0.f};
    accv = __builtin_amdgcn_mfma_f32_16x16x32_bf16(av, bv, accv, 0,0,0);
    acct = __builtin_amdgcn_mfma_f32_16x16x32_bf16(at, bt, acct, 0,0,0);
    #pragma unroll
    for (int r=0;r<4;++r){
      int node = base + wv*16 + g*4 + r;
      if (node < n){
        if (c == 0)  out[node] = accv[r] + bv2v;
        if (c < 10)  out[n + (size_t)node*10 + c] = acct[r] + bt2l[c];
      }
    }
  }
}

extern "C" void kernel_launch(void* const* d_in, const int* in_sizes, int n_in,
                              void* d_out, int out_size, void* d_ws, size_t ws_size,
                              hipStream_t stream){
  const float* x    = (const float*)d_in[0];
  const int*   ei   = (const int*)  d_in[1];
  const float* W1   = (const float*)d_in[2];  const float* b1   = (const float*)d_in[3];
  const float* W2   = (const float*)d_in[4];  const float* b2   = (const float*)d_in[5];
  const float* W3   = (const float*)d_in[6];  const float* b3   = (const float*)d_in[7];
  const float* Wih0 = (const float*)d_in[8];
  const float* bih0 = (const float*)d_in[10]; const float* bhh0 = (const float*)d_in[11];
  const float* Wih1 = (const float*)d_in[12];
  const float* bih1 = (const float*)d_in[14]; const float* bhh1 = (const float*)d_in[15];
  const float* Wv1  = (const float*)d_in[16]; const float* bv1  = (const float*)d_in[17];
  const float* Wv2  = (const float*)d_in[18]; const float* bv2  = (const float*)d_in[19];
  const float* Wt1  = (const float*)d_in[20]; const float* bt1  = (const float*)d_in[21];
  const float* Wt2  = (const float*)d_in[22]; const float* bt2  = (const float*)d_in[23];

  const int N  = in_sizes[0] / 128;
  const int E  = in_sizes[1] / 2;
  const int NB = (N + 1023) / 1024;
  const int EB = (E + 8191) / 8192;

  char* w = (char*)d_ws;
  auto take = [&](size_t bytes)->char*{ char* p = w; w += (bytes + 255) & ~(size_t)255; return p; };
  int*   deg    = (int*)  take((size_t)N*4);
  int*   offs   = (int*)  take((size_t)(N+1)*4);
  int*   cursor = (int*)  take((size_t)N*4);
  int*   csr    = (int*)  take((size_t)E*4);
  float* dinv   = (float*)take((size_t)N*4);
  int*   bsums  = (int*)  take((size_t)NB*4);
  int*   boffs  = (int*)  take((size_t)NB*4);
  int*   bhist  = (int*)  take((size_t)MAXBK*4);
  int*   bcur   = (int*)  take((size_t)MAXBK*4);
  int*   srcB   = (int*)  take((size_t)E*4);
  int*   dstB   = (int*)  take((size_t)E*4);
  u16*   wbuf   = (u16*)  take((size_t)18432*2);  // prepped tail weights + BV/BT frags
  float* bbuf   = (float*)take((size_t)192*4);    // prepped tail biases
  u16*   bufTS  = (u16*)  take((size_t)N*64*2);   // transformed (pre-agg), bf16
  u16*   bufH   = (u16*)  take((size_t)N*64*2);   // post-agg activations, bf16
  (void)ws_size; (void)n_in; (void)out_size;

  // --- run-once tail weight prep ---
  prep_tail_kernel<<<49, 256, 0, stream>>>(Wih0, Wih1, Wv1, Wt1, Wv2, Wt2,
                                           bih0, bhh0, bih1, bhh1, wbuf, bbuf);

  // --- CSR build ---
  hipMemsetAsync(deg, 0, (size_t)N*4, stream);
  if (N <= MAXBK*256){
    hipMemsetAsync(bhist, 0, (size_t)MAXBK*4, stream);
    bucket_hist_kernel<<<EB, 512, 0, stream>>>(ei + E, bhist, E);
    bucket_scan_kernel<<<1,  512, 0, stream>>>(bhist, bcur);
    bin_kernel        <<<EB, 512, 0, stream>>>(ei, ei + E, bcur, srcB, dstB, E);
    count2_kernel     <<<(E+255)/256, 256, 0, stream>>>(dstB, deg, E);
  } else {
    count_kernel      <<<(E+255)/256, 256, 0, stream>>>(ei + E, deg, E);
  }
  scan_reduce_kernel<<<NB,          256, 0, stream>>>(deg, bsums, N);
  scan_block_kernel <<<1,           128, 0, stream>>>(bsums, boffs, NB);
  scan_final_kernel <<<NB,          256, 0, stream>>>(deg, boffs, offs, N, E);
  dinv_kernel       <<<(N+255)/256, 256, 0, stream>>>(deg, offs, cursor, dinv, N);
  if (N <= MAXBK*256){
    fill2_kernel<<<(E+255)/256, 256, 0, stream>>>(srcB, dstB, cursor, csr, E);
  } else {
    fill_kernel <<<(E+255)/256, 256, 0, stream>>>(ei, cursor, csr, E);
  }

  // --- GCN layers (MFMA transforms) ---
  const int TB = (N + 127) / 128;
  transform_mfma<128,float><<<TB, 256, 0, stream>>>(x,    W1, dinv, bufTS, N);
  agg_kernel               <<<(N+3)/4, 256, 0, stream>>>(bufTS, dinv, offs, csr, b1, bufH, N);
  transform_mfma<64,u16>   <<<TB, 256, 0, stream>>>(bufH, W2, dinv, bufTS, N);
  agg_kernel               <<<(N+3)/4, 256, 0, stream>>>(bufTS, dinv, offs, csr, b2, bufH, N);
  transform_mfma<64,u16>   <<<TB, 256, 0, stream>>>(bufH, W3, dinv, bufTS, N);
  agg_kernel               <<<(N+3)/4, 256, 0, stream>>>(bufTS, dinv, offs, csr, b3, bufH, N);

  // --- fused LSTM x2 + heads (64 nodes/block) ---
  const int TB2 = (N + 63) / 64;
  lstm_heads_fused<<<TB2, 256, 0, stream>>>(bufH, wbuf, bbuf,
                                            bv1, bv2, bt1, bt2,
                                            (float*)d_out, N);
}

// Round 10
// 261.899 us; speedup vs baseline: 3.6519x; 1.2687x over previous
//
#include <hip/hip_runtime.h>
#include <math.h>

// TemporalWasteGNN: 3x GCNConv (symmetric-norm, self-loops) -> 2x LSTM(seq=1, h0=c0=0)
// -> two MLP heads. fp32 I/O, bf16 intermediate features.
//
// R10: CSR build collapsed (was ~65us over 6 kernels): bin now writes ONE packed
//      u32/edge (src | (dst&255)<<24); new bucket_finalize kernel (1 block per
//      256-node bucket) does per-node count/scan/offs/dinv/csr-scatter fully in
//      LDS while the bucket's ~16KB of edges are L2-hot. Replaces count2 +
//      3 scan kernels + dinv + fill2 + deg memset.
// R3 bucket binning, R4 MFMA transforms, R7 native transcendentals, R8 prepped
// weight slab, R9 16-row/wave zero-shuffle tail — all byte-identical.

typedef unsigned int  u32;
typedef unsigned short u16;
typedef short bfrag  __attribute__((ext_vector_type(8)));   // 8 bf16 (4 VGPRs)
typedef float f32x4  __attribute__((ext_vector_type(4)));

#define LOG2E 1.44269504088896f
static __device__ __forceinline__ float fast_sigmoid(float x){
  float t = __builtin_amdgcn_exp2f(-x * LOG2E);
  return __builtin_amdgcn_rcpf(1.f + t);
}
static __device__ __forceinline__ float fast_tanh(float x){
  float t = __builtin_amdgcn_exp2f(x * (2.f * LOG2E));
  return 1.f - 2.f * __builtin_amdgcn_rcpf(t + 1.f);
}
static __device__ __forceinline__ float bf2f(u16 u){ return __uint_as_float(((u32)u)<<16); }
static __device__ __forceinline__ u16   f2bf(float f){
  u32 x = __float_as_uint(f);
  return (u16)((x + 0x7fffu + ((x>>16)&1u)) >> 16);   // round-to-nearest-even
}

#define MAXBK 512   // buckets of 256 dst nodes; N <= 131072 (src must fit 24 bits)

// ---------------- bucketed CSR build ----------------
__global__ __launch_bounds__(512) void bucket_hist_kernel(const int* __restrict__ dstA,
                                                          int* __restrict__ bhist, int E){
  __shared__ int h[MAXBK];
  for (int i=threadIdx.x; i<MAXBK; i+=512) h[i]=0;
  __syncthreads();
  const int base = blockIdx.x*8192;
  #pragma unroll
  for (int j=0;j<16;++j){
    int e = base + j*512 + threadIdx.x;
    if (e < E) atomicAdd(&h[dstA[e]>>8], 1);
  }
  __syncthreads();
  for (int i=threadIdx.x; i<MAXBK; i+=512) if (h[i]) atomicAdd(&bhist[i], h[i]);
}

// exclusive prefix -> bcur (mutable cursors for bin) AND bstart (immutable)
__global__ __launch_bounds__(512) void bucket_scan_kernel(const int* __restrict__ bhist,
                                                          int* __restrict__ bcur,
                                                          int* __restrict__ bstart){
  __shared__ int ts[MAXBK];
  int v = bhist[threadIdx.x];
  ts[threadIdx.x] = v; __syncthreads();
  for (int off=1; off<MAXBK; off<<=1){
    int t = (threadIdx.x>=off) ? ts[threadIdx.x-off] : 0;
    __syncthreads();
    ts[threadIdx.x] += t;
    __syncthreads();
  }
  int ex = ts[threadIdx.x] - v;
  bcur[threadIdx.x]   = ex;
  bstart[threadIdx.x] = ex;
  if (threadIdx.x == MAXBK-1) bstart[MAXBK] = ts[threadIdx.x];   // = E
}

// bin edges into bucket-contiguous packed stream: src | (dst&255)<<24
__global__ __launch_bounds__(512) void bin_kernel(const int* __restrict__ srcA,
                                                  const int* __restrict__ dstA,
                                                  int* __restrict__ bcur,
                                                  u32* __restrict__ packed, int E){
  __shared__ int h[MAXBK];
  __shared__ int basev[MAXBK];
  for (int i=threadIdx.x; i<MAXBK; i+=512) h[i]=0;
  __syncthreads();
  const int base = blockIdx.x*8192;
  int br[16]; int dv[16];
  #pragma unroll
  for (int j=0;j<16;++j){
    int e = base + j*512 + threadIdx.x;
    if (e < E){
      int d = dstA[e]; int b = d>>8;
      int r = atomicAdd(&h[b], 1);
      br[j] = (b<<16) | r;                 // b<512 (9b) | r<8192 (13b)
      dv[j] = d;
    } else br[j] = -1;
  }
  __syncthreads();
  for (int i=threadIdx.x; i<MAXBK; i+=512){
    int c = h[i];
    basev[i] = c ? atomicAdd(&bcur[i], c) : 0;
  }
  __syncthreads();
  #pragma unroll
  for (int j=0;j<16;++j){
    if (br[j] >= 0){
      int e = base + j*512 + threadIdx.x;
      int pos = basev[br[j]>>16] + (br[j] & 0xffff);
      packed[pos] = (u32)srcA[e] | ((u32)(dv[j] & 255) << 24);
    }
  }
}

// one block per bucket: per-node count -> scan -> offs/dinv -> csr scatter, all LDS
__global__ __launch_bounds__(512) void bucket_finalize_kernel(
    const u32* __restrict__ packed, const int* __restrict__ bstart,
    int* __restrict__ offs, float* __restrict__ dinv,
    int* __restrict__ csr, int n, int E){
  __shared__ int cnt[256];
  __shared__ int sc[256];
  __shared__ int cur[256];
  const int b = blockIdx.x;
  const int start = bstart[b], end = bstart[b+1];
  for (int i=threadIdx.x; i<256; i+=512){ cnt[i]=0; cur[i]=0; }
  __syncthreads();
  for (int e = start + threadIdx.x; e < end; e += 512)
    atomicAdd(&cnt[packed[e] >> 24], 1);
  __syncthreads();
  if (threadIdx.x < 256) sc[threadIdx.x] = cnt[threadIdx.x];
  __syncthreads();
  for (int off=1; off<256; off<<=1){
    int t = 0;
    if (threadIdx.x < 256 && threadIdx.x >= off) t = sc[threadIdx.x-off];
    __syncthreads();
    if (threadIdx.x < 256) sc[threadIdx.x] += t;
    __syncthreads();
  }
  if (threadIdx.x < 256){
    int ex = sc[threadIdx.x] - cnt[threadIdx.x];      // exclusive
    sc[threadIdx.x] = ex;
    int node = b*256 + threadIdx.x;
    if (node < n){
      offs[node] = start + ex;
      dinv[node] = rsqrtf((float)(cnt[threadIdx.x] + 1));
    }
  }
  if (b == 0 && threadIdx.x == 0) offs[n] = E;
  __syncthreads();
  for (int e = start + threadIdx.x; e < end; e += 512){
    u32 v = packed[e];
    int loc = v >> 24;
    int pos = start + sc[loc] + atomicAdd(&cur[loc], 1);
    csr[pos] = (int)(v & 0xFFFFFFu);
  }
}

// fallback (N too large for bucketing) -------------
__global__ void count_kernel(const int* __restrict__ dsts, int* __restrict__ deg, int E){
  int e = blockIdx.x*256 + threadIdx.x;
  if (e < E) atomicAdd(&deg[dsts[e]], 1);
}
__global__ void fill_kernel(const int* __restrict__ ei, int* __restrict__ cursor,
                            int* __restrict__ csr, int E){
  int e = blockIdx.x*256 + threadIdx.x;
  if (e < E){
    int d = ei[E + e];
    int pos = atomicAdd(&cursor[d], 1);
    csr[pos] = ei[e];
  }
}

__global__ void scan_reduce_kernel(const int* __restrict__ deg, int* __restrict__ bsums, int n){
  __shared__ int sd[256];
  int base = blockIdx.x*1024 + threadIdx.x*4;
  int s = 0;
  #pragma unroll
  for (int j=0;j<4;++j){ int idx=base+j; if (idx<n) s += deg[idx]; }
  sd[threadIdx.x] = s; __syncthreads();
  for (int off=128; off>0; off>>=1){
    if (threadIdx.x < off) sd[threadIdx.x] += sd[threadIdx.x+off];
    __syncthreads();
  }
  if (threadIdx.x==0) bsums[blockIdx.x] = sd[0];
}

__global__ void scan_block_kernel(const int* __restrict__ bsums, int* __restrict__ boffs, int nb){
  __shared__ int ts[128];
  if (nb <= 128){
    int v = (threadIdx.x < nb) ? bsums[threadIdx.x] : 0;
    ts[threadIdx.x] = v; __syncthreads();
    for (int off=1; off<128; off<<=1){
      int t = (threadIdx.x>=off) ? ts[threadIdx.x-off] : 0;
      __syncthreads();
      ts[threadIdx.x] += t;
      __syncthreads();
    }
    if (threadIdx.x < nb) boffs[threadIdx.x] = ts[threadIdx.x] - v;
  } else if (threadIdx.x==0){
    int run=0;
    for (int b=0;b<nb;++b){ int t=bsums[b]; boffs[b]=run; run+=t; }
  }
}

__global__ void scan_final_kernel(const int* __restrict__ deg, const int* __restrict__ boffs,
                                  int* __restrict__ offs, int n, int E){
  __shared__ int ts[256];
  int base = blockIdx.x*1024 + threadIdx.x*4;
  int v[4]; int s=0;
  #pragma unroll
  for (int j=0;j<4;++j){ int idx=base+j; v[j] = (idx<n) ? deg[idx] : 0; s += v[j]; }
  ts[threadIdx.x] = s; __syncthreads();
  for (int off=1; off<256; off<<=1){
    int t = (threadIdx.x>=off) ? ts[threadIdx.x-off] : 0;
    __syncthreads();
    ts[threadIdx.x] += t;
    __syncthreads();
  }
  int excl = boffs[blockIdx.x] + (threadIdx.x ? ts[threadIdx.x-1] : 0);
  #pragma unroll
  for (int j=0;j<4;++j){ int idx=base+j; if (idx<n){ offs[idx]=excl; excl+=v[j]; } }
  if (blockIdx.x==0 && threadIdx.x==0) offs[n] = E;
}

__global__ void dinv_kernel(const int* __restrict__ deg, const int* __restrict__ offs,
                            int* __restrict__ cursor, float* __restrict__ dinv, int n){
  int i = blockIdx.x*256 + threadIdx.x;
  if (i < n){
    dinv[i] = rsqrtf((float)(deg[i] + 1));
    cursor[i] = offs[i];
  }
}

// ---------------- run-once tail-weight prep ----------------
// wbuf (u16): W0hi[0,6144) W0lo[6144,12288) W1[12288,15360) WH[15360,17408)
//             BV[17408,17920) BT[17920,18432)  (lane-indexed K=32 B-fragments)
// bbuf (f32): b0[0,96) b1[96,192)
__global__ void prep_tail_kernel(const float* __restrict__ Wih0, const float* __restrict__ Wih1,
                                 const float* __restrict__ Wv1,  const float* __restrict__ Wt1,
                                 const float* __restrict__ Wv2,  const float* __restrict__ Wt2,
                                 const float* __restrict__ bih0, const float* __restrict__ bhh0,
                                 const float* __restrict__ bih1, const float* __restrict__ bhh1,
                                 u16* __restrict__ wbuf, float* __restrict__ bbuf){
  int tid = blockIdx.x*256 + threadIdx.x;
  if (tid < 6144){                                  // Wih0 hi/lo, [k/8][96][8]
    int kg = tid / 768, rem = tid % 768;
    int j = rem >> 3, k = kg*8 + (rem & 7);
    int row = (j < 32) ? j : j + 32;
    float w = Wih0[row*64 + k];
    u16 hi = f2bf(w);
    wbuf[tid] = hi;
    wbuf[6144 + tid] = f2bf(w - bf2f(hi));
  } else if (tid < 9216){                           // Wih1, [k/8][96][8]
    int t = tid - 6144;
    int kg = t / 768, rem = t % 768;
    int j = rem >> 3, k = kg*8 + (rem & 7);
    int row = (j < 32) ? j : j + 32;
    wbuf[12288 + t] = f2bf(Wih1[row*32 + k]);
  } else if (tid < 11264){                          // Wv1|Wt1, [k/8][64][8]
    int t = tid - 9216;
    int kg = t / 512, rem = t % 512;
    int j = rem >> 3, k = kg*8 + (rem & 7);
    float v = (j < 32) ? Wv1[k*32 + j] : Wt1[k*32 + (j-32)];
    wbuf[15360 + t] = f2bf(v);
  } else if (tid < 11360){                          // b0 (i,g,o combined)
    int t = tid - 11264;
    int row = (t < 32) ? t : t + 32;
    bbuf[t] = bih0[row] + bhh0[row];
  } else if (tid < 11456){                          // b1
    int t = tid - 11360;
    int row = (t < 32) ? t : t + 32;
    bbuf[96 + t] = bih1[row] + bhh1[row];
  } else if (tid < 12480){                          // BV/BT lane fragments (K=32)
    int t = tid - 11456;
    int slab = t >> 9, within = t & 511;
    int lane = within >> 3, j = within & 7;
    int cc = lane & 15, gg = lane >> 4;
    float v;
    if (slab == 0) v = (cc == 0) ? Wv2[gg*8 + j] : 0.f;
    else           v = (cc < 10) ? Wt2[(gg*8 + j)*10 + cc] : 0.f;
    wbuf[17408 + slab*512 + within] = f2bf(v);
  }
}

// ---------------- GCN transform via MFMA (verified in R4) ----------------
template<int KD, typename TIN>
__global__ __launch_bounds__(256) void transform_mfma(const TIN* __restrict__ X,
                                                      const float* __restrict__ W,
                                                      const float* __restrict__ dinv,
                                                      u16* __restrict__ Y, int n){
  constexpr int XLD = KD + 8;
  __shared__ u16 Xl[128*XLD];
  __shared__ u16 Wl[KD*64];          // layout [KD/8][64][8]
  __shared__ float Dl[128];
  const int tid  = threadIdx.x;
  const int base = blockIdx.x*128;

  for (int i = tid; i < KD*64; i += 256){
    int k = i >> 6, col = i & 63;
    Wl[((k>>3)<<9) + (col<<3) + (k&7)] = f2bf(W[i]);
  }
  if (tid < 128){
    int nd = base + tid;
    Dl[tid] = (nd < n) ? dinv[nd] : 0.f;
  }
  if constexpr (sizeof(TIN)==4){
    #pragma unroll
    for (int j = 0; j < (128*KD)/1024; ++j){
      int e4   = tid + j*256;
      int elem = e4*4;
      int row  = elem / KD, k = elem % KD;
      int gn   = base + row;
      uint2 w2 = make_uint2(0u, 0u);
      if (gn < n){
        float4 v = ((const float4*)X)[(size_t)gn*(KD/4) + (k>>2)];
        w2.x = (u32)f2bf(v.x) | ((u32)f2bf(v.y)<<16);
        w2.y = (u32)f2bf(v.z) | ((u32)f2bf(v.w)<<16);
      }
      *((uint2*)&Xl[row*XLD + k]) = w2;
    }
  } else {
    #pragma unroll
    for (int j = 0; j < (128*KD)/1024; ++j){
      int e4   = tid + j*256;
      int elem = e4*4;
      int row  = elem / KD, k = elem % KD;
      int gn   = base + row;
      uint2 v = make_uint2(0u, 0u);
      if (gn < n) v = *((const uint2*)(X + (size_t)gn*KD + k));
      *((uint2*)&Xl[row*XLD + k]) = v;
    }
  }
  __syncthreads();

  const int lane = tid & 63, wv = tid >> 6;
  const int c = lane & 15, g = lane >> 4;

  bfrag wf[KD/32][4];
  #pragma unroll
  for (int kk=0; kk<KD/32; ++kk)
    #pragma unroll
    for (int nt=0; nt<4; ++nt)
      wf[kk][nt] = *((const bfrag*)&Wl[((kk*4+g)<<9) + ((nt*16+c)<<3)]);

  f32x4 acc[2][4];
  #pragma unroll
  for (int rs=0;rs<2;++rs)
    #pragma unroll
    for (int nt=0;nt<4;++nt)
      acc[rs][nt] = (f32x4){0.f,0.f,0.f,0.f};

  #pragma unroll
  for (int kk=0; kk<KD/32; ++kk){
    bfrag a0 = *((const bfrag*)&Xl[(wv*32      + c)*XLD + kk*32 + g*8]);
    bfrag a1 = *((const bfrag*)&Xl[(wv*32 + 16 + c)*XLD + kk*32 + g*8]);
    #pragma unroll
    for (int nt=0; nt<4; ++nt){
      acc[0][nt] = __builtin_amdgcn_mfma_f32_16x16x32_bf16(a0, wf[kk][nt], acc[0][nt], 0,0,0);
      acc[1][nt] = __builtin_amdgcn_mfma_f32_16x16x32_bf16(a1, wf[kk][nt], acc[1][nt], 0,0,0);
    }
  }

  #pragma unroll
  for (int rs=0;rs<2;++rs){
    int nl0 = wv*32 + rs*16 + g*4;
    #pragma unroll
    for (int r=0;r<4;++r){
      int node = base + nl0 + r;
      if (node < n){
        float dv = Dl[nl0 + r];
        #pragma unroll
        for (int nt=0;nt<4;++nt)
          Y[(size_t)node*64 + nt*16 + c] = f2bf(acc[rs][nt][r] * dv);
      }
    }
  }
}

// ---------------- GCN aggregate: one wave per node, 8-way neighbor ILP (bf16 rows) ----------------
__global__ void agg_kernel(const u16* __restrict__ Hts, const float* __restrict__ dinv,
                           const int* __restrict__ offs, const int* __restrict__ csr,
                           const float* __restrict__ bias, u16* __restrict__ Hout, int n){
  const int node = blockIdx.x*4 + (threadIdx.x >> 6);
  if (node >= n) return;
  const int lane = threadIdx.x & 63;
  const int c8   = lane & 7;
  const int slot = lane >> 3;
  const uint4* __restrict__ H = (const uint4*)Hts;
  float acc[8];
  #pragma unroll
  for (int i=0;i<8;++i) acc[i]=0.f;
  const int beg = offs[node], end = offs[node+1];
  for (int j = beg + slot; j < end; j += 8){
    int s = csr[j];
    uint4 v = H[s*8 + c8];
    acc[0] += __uint_as_float(v.x<<16); acc[1] += __uint_as_float(v.x & 0xffff0000u);
    acc[2] += __uint_as_float(v.y<<16); acc[3] += __uint_as_float(v.y & 0xffff0000u);
    acc[4] += __uint_as_float(v.z<<16); acc[5] += __uint_as_float(v.z & 0xffff0000u);
    acc[6] += __uint_as_float(v.w<<16); acc[7] += __uint_as_float(v.w & 0xffff0000u);
  }
  #pragma unroll
  for (int i=0;i<8;++i) acc[i] += __shfl_xor(acc[i], 8);
  #pragma unroll
  for (int i=0;i<8;++i) acc[i] += __shfl_xor(acc[i], 16);
  #pragma unroll
  for (int i=0;i<8;++i) acc[i] += __shfl_xor(acc[i], 32);
  if (slot == 0){
    uint4 sv = H[node*8 + c8];
    float s[8];
    s[0]=__uint_as_float(sv.x<<16); s[1]=__uint_as_float(sv.x & 0xffff0000u);
    s[2]=__uint_as_float(sv.y<<16); s[3]=__uint_as_float(sv.y & 0xffff0000u);
    s[4]=__uint_as_float(sv.z<<16); s[5]=__uint_as_float(sv.z & 0xffff0000u);
    s[6]=__uint_as_float(sv.w<<16); s[7]=__uint_as_float(sv.w & 0xffff0000u);
    float4 b0 = ((const float4*)bias)[c8*2];
    float4 b1 = ((const float4*)bias)[c8*2+1];
    const float dv = dinv[node];
    float o[8];
    o[0]=fmaxf(fmaf(acc[0]+s[0],dv,b0.x),0.f); o[1]=fmaxf(fmaf(acc[1]+s[1],dv,b0.y),0.f);
    o[2]=fmaxf(fmaf(acc[2]+s[2],dv,b0.z),0.f); o[3]=fmaxf(fmaf(acc[3]+s[3],dv,b0.w),0.f);
    o[4]=fmaxf(fmaf(acc[4]+s[4],dv,b1.x),0.f); o[5]=fmaxf(fmaf(acc[5]+s[5],dv,b1.y),0.f);
    o[6]=fmaxf(fmaf(acc[6]+s[6],dv,b1.z),0.f); o[7]=fmaxf(fmaf(acc[7]+s[7],dv,b1.w),0.f);
    uint4 w;
    w.x = (u32)f2bf(o[0]) | ((u32)f2bf(o[1])<<16);
    w.y = (u32)f2bf(o[2]) | ((u32)f2bf(o[3])<<16);
    w.z = (u32)f2bf(o[4]) | ((u32)f2bf(o[5])<<16);
    w.w = (u32)f2bf(o[6]) | ((u32)f2bf(o[7])<<16);
    ((uint4*)Hout)[node*8 + c8] = w;
  }
}

// ---------------- Fused LSTM x2 + heads: 16 rows/wave, zero shuffles (R9, verified) ----------------
__global__ __launch_bounds__(256) void lstm_heads_fused(
    const u16* __restrict__ X,
    const u16* __restrict__ wbuf, const float* __restrict__ bbuf,
    const float* __restrict__ bv1, const float* __restrict__ bv2,
    const float* __restrict__ bt1, const float* __restrict__ bt2,
    float* __restrict__ out, int n)
{
  const u16* W0hi = wbuf;
  const u16* W0lo = wbuf + 6144;
  const u16* W1g  = wbuf + 12288;
  const u16* WHg  = wbuf + 15360;
  const u16* BVg  = wbuf + 17408;
  const u16* BTg  = wbuf + 17920;

  __shared__ u16 Hpool[5120];       // H1hi[0,2560) H1lo[2560,5120); H2 aliases (barrier-sep)
  __shared__ u16 VT[4608];          // 64 rows x 72: relu'd [v1(0-31) | t1(32-63)], bf16
  __shared__ float b0l[96], b1l[96], bv1l[32], bt1l[32], bt2l[10];
  u16* H1hi = Hpool;  u16* H1lo = Hpool + 2560;
  u16* H2hi = Hpool;  u16* H2lo = Hpool + 2560;

  const int tid  = threadIdx.x;
  const int base = blockIdx.x*64;

  if (tid < 96)            b0l[tid] = bbuf[tid];
  else if (tid < 192)      b1l[tid-96] = bbuf[tid];
  else if (tid < 224){ int d=tid-192; bv1l[d]=bv1[d]; }
  else               { int d=tid-224; bt1l[d]=bt1[d]; }
  if (tid < 10) bt2l[tid] = bt2[tid];
  __syncthreads();

  const int lane = tid & 63, wv = tid >> 6;
  const int c = lane & 15, g = lane >> 4;
  const float bv2v = bv2[0];

  // ---- lstm0: gates = X @ W0^T (K=64, 96 cols) ----
  {
    int r0 = base + wv*16 + c; if (r0 > n-1) r0 = n-1;
    bfrag a0[2];
    a0[0] = *((const bfrag*)(X + (size_t)r0*64      + g*8));
    a0[1] = *((const bfrag*)(X + (size_t)r0*64 + 32 + g*8));
    f32x4 acc[6];
    #pragma unroll
    for (int nt=0;nt<6;++nt) acc[nt] = (f32x4){0.f,0.f,0.f,0.f};
    #pragma unroll
    for (int kk=0; kk<2; ++kk){
      #pragma unroll
      for (int nt=0; nt<6; ++nt){
        int widx = (kk*4+g)*768 + ((nt*16+c)<<3);
        bfrag bh = *((const bfrag*)&W0hi[widx]);
        bfrag bl = *((const bfrag*)&W0lo[widx]);
        acc[nt] = __builtin_amdgcn_mfma_f32_16x16x32_bf16(a0[kk], bh, acc[nt], 0,0,0);
        acc[nt] = __builtin_amdgcn_mfma_f32_16x16x32_bf16(a0[kk], bl, acc[nt], 0,0,0);
      }
    }
    #pragma unroll
    for (int r=0;r<4;++r){
      int rl = wv*16 + g*4 + r;
      #pragma unroll
      for (int half=0; half<2; ++half){
        float iv = acc[0+half][r] + b0l[half*16 + c];
        float gv = acc[2+half][r] + b0l[32 + half*16 + c];
        float ov = acc[4+half][r] + b0l[64 + half*16 + c];
        float cc = fast_sigmoid(iv) * fast_tanh(gv);
        float hv = fast_sigmoid(ov) * fast_tanh(cc);
        u16 hi = f2bf(hv);
        H1hi[rl*40 + half*16 + c] = hi;
        H1lo[rl*40 + half*16 + c] = f2bf(hv - bf2f(hi));
      }
    }
  }
  __syncthreads();                           // H1 visible

  // ---- lstm1: gates = H1 @ W1^T (K=32, 96 cols), A-split 2-term ----
  {
    bfrag w1f[6];
    #pragma unroll
    for (int nt=0; nt<6; ++nt)
      w1f[nt] = *((const bfrag*)&W1g[g*768 + ((nt*16+c)<<3)]);
    bfrag ah = *((const bfrag*)&H1hi[(wv*16 + c)*40 + g*8]);
    bfrag al = *((const bfrag*)&H1lo[(wv*16 + c)*40 + g*8]);
    f32x4 acc[6];
    #pragma unroll
    for (int nt=0;nt<6;++nt) acc[nt] = (f32x4){0.f,0.f,0.f,0.f};
    #pragma unroll
    for (int nt=0; nt<6; ++nt){
      acc[nt] = __builtin_amdgcn_mfma_f32_16x16x32_bf16(ah, w1f[nt], acc[nt], 0,0,0);
      acc[nt] = __builtin_amdgcn_mfma_f32_16x16x32_bf16(al, w1f[nt], acc[nt], 0,0,0);
    }
    __syncthreads();                         // all H1 reads complete before H2 overwrite
    #pragma unroll
    for (int r=0;r<4;++r){
      int rl = wv*16 + g*4 + r;
      #pragma unroll
      for (int half=0; half<2; ++half){
        float iv = acc[0+half][r] + b1l[half*16 + c];
        float gv = acc[2+half][r] + b1l[32 + half*16 + c];
        float ov = acc[4+half][r] + b1l[64 + half*16 + c];
        float cc = fast_sigmoid(iv) * fast_tanh(gv);
        float hv = fast_sigmoid(ov) * fast_tanh(cc);
        u16 hi = f2bf(hv);
        H2hi[rl*40 + half*16 + c] = hi;
        H2lo[rl*40 + half*16 + c] = f2bf(hv - bf2f(hi));
      }
    }
  }
  __syncthreads();                           // H2 visible

  // ---- heads p1: [v1|t1] = relu(H2 @ [Wv1|Wt1] + b) -> VT (bf16) ----
  {
    bfrag whf[4];
    #pragma unroll
    for (int nt=0; nt<4; ++nt)
      whf[nt] = *((const bfrag*)&WHg[g*512 + ((nt*16+c)<<3)]);
    bfrag ah = *((const bfrag*)&H2hi[(wv*16 + c)*40 + g*8]);
    bfrag al = *((const bfrag*)&H2lo[(wv*16 + c)*40 + g*8]);
    f32x4 acc[4];
    #pragma unroll
    for (int nt=0;nt<4;++nt) acc[nt] = (f32x4){0.f,0.f,0.f,0.f};
    #pragma unroll
    for (int nt=0; nt<4; ++nt){
      acc[nt] = __builtin_amdgcn_mfma_f32_16x16x32_bf16(ah, whf[nt], acc[nt], 0,0,0);
      acc[nt] = __builtin_amdgcn_mfma_f32_16x16x32_bf16(al, whf[nt], acc[nt], 0,0,0);
    }
    #pragma unroll
    for (int r=0;r<4;++r){
      int rl = wv*16 + g*4 + r;
      VT[rl*72      + c] = f2bf(fmaxf(acc[0][r] + bv1l[c],    0.f));
      VT[rl*72 + 16 + c] = f2bf(fmaxf(acc[1][r] + bv1l[c+16], 0.f));
      VT[rl*72 + 32 + c] = f2bf(fmaxf(acc[2][r] + bt1l[c],    0.f));
      VT[rl*72 + 48 + c] = f2bf(fmaxf(acc[3][r] + bt1l[c+16], 0.f));
    }
  }
  __syncthreads();                           // VT visible

  // ---- heads p2: vol = v1 @ Wv2, type = t1 @ Wt2 via MFMA, direct C-write ----
  {
    bfrag av = *((const bfrag*)&VT[(wv*16 + c)*72      + g*8]);
    bfrag at = *((const bfrag*)&VT[(wv*16 + c)*72 + 32 + g*8]);
    bfrag bv = *((const bfrag*)(BVg + lane*8));
    bfrag bt = *((const bfrag*)(BTg + lane*8));
    f32x4 accv = (f32x4){0.f,0.f,0.f,0.f};
    f32x4 acct = (f32x4){0.f,0.f,0.f,0.f};
    accv = __builtin_amdgcn_mfma_f32_16x16x32_bf16(av, bv, accv, 0,0,0);
    acct = __builtin_amdgcn_mfma_f32_16x16x32_bf16(at, bt, acct, 0,0,0);
    #pragma unroll
    for (int r=0;r<4;++r){
      int node = base + wv*16 + g*4 + r;
      if (node < n){
        if (c == 0)  out[node] = accv[r] + bv2v;
        if (c < 10)  out[n + (size_t)node*10 + c] = acct[r] + bt2l[c];
      }
    }
  }
}

extern "C" void kernel_launch(void* const* d_in, const int* in_sizes, int n_in,
                              void* d_out, int out_size, void* d_ws, size_t ws_size,
                              hipStream_t stream){
  const float* x    = (const float*)d_in[0];
  const int*   ei   = (const int*)  d_in[1];
  const float* W1   = (const float*)d_in[2];  const float* b1   = (const float*)d_in[3];
  const float* W2   = (const float*)d_in[4];  const float* b2   = (const float*)d_in[5];
  const float* W3   = (const float*)d_in[6];  const float* b3   = (const float*)d_in[7];
  const float* Wih0 = (const float*)d_in[8];
  const float* bih0 = (const float*)d_in[10]; const float* bhh0 = (const float*)d_in[11];
  const float* Wih1 = (const float*)d_in[12];
  const float* bih1 = (const float*)d_in[14]; const float* bhh1 = (const float*)d_in[15];
  const float* Wv1  = (const float*)d_in[16]; const float* bv1  = (const float*)d_in[17];
  const float* Wv2  = (const float*)d_in[18]; const float* bv2  = (const float*)d_in[19];
  const float* Wt1  = (const float*)d_in[20]; const float* bt1  = (const float*)d_in[21];
  const float* Wt2  = (const float*)d_in[22]; const float* bt2  = (const float*)d_in[23];

  const int N  = in_sizes[0] / 128;
  const int E  = in_sizes[1] / 2;
  const int NB = (N + 1023) / 1024;
  const int EB = (E + 8191) / 8192;

  char* w = (char*)d_ws;
  auto take = [&](size_t bytes)->char*{ char* p = w; w += (bytes + 255) & ~(size_t)255; return p; };
  int*   deg    = (int*)  take((size_t)N*4);          // fallback only
  int*   offs   = (int*)  take((size_t)(N+1)*4);
  int*   cursor = (int*)  take((size_t)N*4);          // fallback only
  int*   csr    = (int*)  take((size_t)E*4);
  float* dinv   = (float*)take((size_t)N*4);
  int*   bsums  = (int*)  take((size_t)NB*4);         // fallback only
  int*   boffs  = (int*)  take((size_t)NB*4);         // fallback only
  int*   bhist  = (int*)  take((size_t)MAXBK*4);
  int*   bcur   = (int*)  take((size_t)MAXBK*4);
  int*   bstart = (int*)  take((size_t)(MAXBK+1)*4);
  u32*   packed = (u32*)  take((size_t)E*4);
  u16*   wbuf   = (u16*)  take((size_t)18432*2);      // prepped tail weights + BV/BT frags
  float* bbuf   = (float*)take((size_t)192*4);        // prepped tail biases
  u16*   bufTS  = (u16*)  take((size_t)N*64*2);       // transformed (pre-agg), bf16
  u16*   bufH   = (u16*)  take((size_t)N*64*2);       // post-agg activations, bf16
  (void)ws_size; (void)n_in; (void)out_size;

  // --- run-once tail weight prep ---
  prep_tail_kernel<<<49, 256, 0, stream>>>(Wih0, Wih1, Wv1, Wt1, Wv2, Wt2,
                                           bih0, bhh0, bih1, bhh1, wbuf, bbuf);

  // --- CSR build ---
  if (N <= MAXBK*256){
    const int NBK = (N + 255) / 256;
    hipMemsetAsync(bhist, 0, (size_t)MAXBK*4, stream);
    bucket_hist_kernel    <<<EB,  512, 0, stream>>>(ei + E, bhist, E);
    bucket_scan_kernel    <<<1,   512, 0, stream>>>(bhist, bcur, bstart);
    bin_kernel            <<<EB,  512, 0, stream>>>(ei, ei + E, bcur, packed, E);
    bucket_finalize_kernel<<<NBK, 512, 0, stream>>>(packed, bstart, offs, dinv, csr, N, E);
  } else {
    hipMemsetAsync(deg, 0, (size_t)N*4, stream);
    count_kernel      <<<(E+255)/256, 256, 0, stream>>>(ei + E, deg, E);
    scan_reduce_kernel<<<NB,          256, 0, stream>>>(deg, bsums, N);
    scan_block_kernel <<<1,           128, 0, stream>>>(bsums, boffs, NB);
    scan_final_kernel <<<NB,          256, 0, stream>>>(deg, boffs, offs, N, E);
    dinv_kernel       <<<(N+255)/256, 256, 0, stream>>>(deg, offs, cursor, dinv, N);
    fill_kernel       <<<(E+255)/256, 256, 0, stream>>>(ei, cursor, csr, E);
  }

  // --- GCN layers (MFMA transforms) ---
  const int TB = (N + 127) / 128;
  transform_mfma<128,float><<<TB, 256, 0, stream>>>(x,    W1, dinv, bufTS, N);
  agg_kernel               <<<(N+3)/4, 256, 0, stream>>>(bufTS, dinv, offs, csr, b1, bufH, N);
  transform_mfma<64,u16>   <<<TB, 256, 0, stream>>>(bufH, W2, dinv, bufTS, N);
  agg_kernel               <<<(N+3)/4, 256, 0, stream>>>(bufTS, dinv, offs, csr, b2, bufH, N);
  transform_mfma<64,u16>   <<<TB, 256, 0, stream>>>(bufH, W3, dinv, bufTS, N);
  agg_kernel               <<<(N+3)/4, 256, 0, stream>>>(bufTS, dinv, offs, csr, b3, bufH, N);

  // --- fused LSTM x2 + heads (64 nodes/block) ---
  const int TB2 = (N + 63) / 64;
  lstm_heads_fused<<<TB2, 256, 0, stream>>>(bufH, wbuf, bbuf,
                                            bv1, bv2, bt1, bt2,
                                            (float*)d_out, N);
}

// Round 11
// 244.911 us; speedup vs baseline: 3.9052x; 1.0694x over previous
//
#include <hip/hip_runtime.h>
#include <math.h>

// TemporalWasteGNN: 3x GCNConv (symmetric-norm, self-loops) -> 2x LSTM(seq=1, h0=c0=0)
// -> two MLP heads. fp32 I/O, bf16 intermediate features.
//
// R11: agg_kernel relayout: 8 nodes/wave x 8 lanes/row (full 128B bf16 row per
//      8-lane group), each group walks its node's whole adjacency serially.
//      Eliminates the per-node 24-shfl reduction epilogue (R10 counters showed
//      epilogue VALU dominated: deg=16 -> 2-iter loop vs ~100-inst epilogue).
//      ~3.5x fewer wave-insts/node; same MLP (8 gather chains/wave); same bytes.
// R10 packed single-pass CSR build, R4 MFMA transforms, R7 native
// transcendentals, R8/R9 prepped-slab zero-shuffle tail — all byte-identical.

typedef unsigned int  u32;
typedef unsigned short u16;
typedef short bfrag  __attribute__((ext_vector_type(8)));   // 8 bf16 (4 VGPRs)
typedef float f32x4  __attribute__((ext_vector_type(4)));

#define LOG2E 1.44269504088896f
static __device__ __forceinline__ float fast_sigmoid(float x){
  float t = __builtin_amdgcn_exp2f(-x * LOG2E);
  return __builtin_amdgcn_rcpf(1.f + t);
}
static __device__ __forceinline__ float fast_tanh(float x){
  float t = __builtin_amdgcn_exp2f(x * (2.f * LOG2E));
  return 1.f - 2.f * __builtin_amdgcn_rcpf(t + 1.f);
}
static __device__ __forceinline__ float bf2f(u16 u){ return __uint_as_float(((u32)u)<<16); }
static __device__ __forceinline__ u16   f2bf(float f){
  u32 x = __float_as_uint(f);
  return (u16)((x + 0x7fffu + ((x>>16)&1u)) >> 16);   // round-to-nearest-even
}

#define MAXBK 512   // buckets of 256 dst nodes; N <= 131072 (src must fit 24 bits)

// ---------------- bucketed CSR build ----------------
__global__ __launch_bounds__(512) void bucket_hist_kernel(const int* __restrict__ dstA,
                                                          int* __restrict__ bhist, int E){
  __shared__ int h[MAXBK];
  for (int i=threadIdx.x; i<MAXBK; i+=512) h[i]=0;
  __syncthreads();
  const int base = blockIdx.x*8192;
  #pragma unroll
  for (int j=0;j<16;++j){
    int e = base + j*512 + threadIdx.x;
    if (e < E) atomicAdd(&h[dstA[e]>>8], 1);
  }
  __syncthreads();
  for (int i=threadIdx.x; i<MAXBK; i+=512) if (h[i]) atomicAdd(&bhist[i], h[i]);
}

// exclusive prefix -> bcur (mutable cursors for bin) AND bstart (immutable)
__global__ __launch_bounds__(512) void bucket_scan_kernel(const int* __restrict__ bhist,
                                                          int* __restrict__ bcur,
                                                          int* __restrict__ bstart){
  __shared__ int ts[MAXBK];
  int v = bhist[threadIdx.x];
  ts[threadIdx.x] = v; __syncthreads();
  for (int off=1; off<MAXBK; off<<=1){
    int t = (threadIdx.x>=off) ? ts[threadIdx.x-off] : 0;
    __syncthreads();
    ts[threadIdx.x] += t;
    __syncthreads();
  }
  int ex = ts[threadIdx.x] - v;
  bcur[threadIdx.x]   = ex;
  bstart[threadIdx.x] = ex;
  if (threadIdx.x == MAXBK-1) bstart[MAXBK] = ts[threadIdx.x];   // = E
}

// bin edges into bucket-contiguous packed stream: src | (dst&255)<<24
__global__ __launch_bounds__(512) void bin_kernel(const int* __restrict__ srcA,
                                                  const int* __restrict__ dstA,
                                                  int* __restrict__ bcur,
                                                  u32* __restrict__ packed, int E){
  __shared__ int h[MAXBK];
  __shared__ int basev[MAXBK];
  for (int i=threadIdx.x; i<MAXBK; i+=512) h[i]=0;
  __syncthreads();
  const int base = blockIdx.x*8192;
  int br[16]; int dv[16];
  #pragma unroll
  for (int j=0;j<16;++j){
    int e = base + j*512 + threadIdx.x;
    if (e < E){
      int d = dstA[e]; int b = d>>8;
      int r = atomicAdd(&h[b], 1);
      br[j] = (b<<16) | r;                 // b<512 (9b) | r<8192 (13b)
      dv[j] = d;
    } else br[j] = -1;
  }
  __syncthreads();
  for (int i=threadIdx.x; i<MAXBK; i+=512){
    int c = h[i];
    basev[i] = c ? atomicAdd(&bcur[i], c) : 0;
  }
  __syncthreads();
  #pragma unroll
  for (int j=0;j<16;++j){
    if (br[j] >= 0){
      int e = base + j*512 + threadIdx.x;
      int pos = basev[br[j]>>16] + (br[j] & 0xffff);
      packed[pos] = (u32)srcA[e] | ((u32)(dv[j] & 255) << 24);
    }
  }
}

// one block per bucket: per-node count -> scan -> offs/dinv -> csr scatter, all LDS
__global__ __launch_bounds__(512) void bucket_finalize_kernel(
    const u32* __restrict__ packed, const int* __restrict__ bstart,
    int* __restrict__ offs, float* __restrict__ dinv,
    int* __restrict__ csr, int n, int E){
  __shared__ int cnt[256];
  __shared__ int sc[256];
  __shared__ int cur[256];
  const int b = blockIdx.x;
  const int start = bstart[b], end = bstart[b+1];
  for (int i=threadIdx.x; i<256; i+=512){ cnt[i]=0; cur[i]=0; }
  __syncthreads();
  for (int e = start + threadIdx.x; e < end; e += 512)
    atomicAdd(&cnt[packed[e] >> 24], 1);
  __syncthreads();
  if (threadIdx.x < 256) sc[threadIdx.x] = cnt[threadIdx.x];
  __syncthreads();
  for (int off=1; off<256; off<<=1){
    int t = 0;
    if (threadIdx.x < 256 && threadIdx.x >= off) t = sc[threadIdx.x-off];
    __syncthreads();
    if (threadIdx.x < 256) sc[threadIdx.x] += t;
    __syncthreads();
  }
  if (threadIdx.x < 256){
    int ex = sc[threadIdx.x] - cnt[threadIdx.x];      // exclusive
    sc[threadIdx.x] = ex;
    int node = b*256 + threadIdx.x;
    if (node < n){
      offs[node] = start + ex;
      dinv[node] = rsqrtf((float)(cnt[threadIdx.x] + 1));
    }
  }
  if (b == 0 && threadIdx.x == 0) offs[n] = E;
  __syncthreads();
  for (int e = start + threadIdx.x; e < end; e += 512){
    u32 v = packed[e];
    int loc = v >> 24;
    int pos = start + sc[loc] + atomicAdd(&cur[loc], 1);
    csr[pos] = (int)(v & 0xFFFFFFu);
  }
}

// fallback (N too large for bucketing) -------------
__global__ void count_kernel(const int* __restrict__ dsts, int* __restrict__ deg, int E){
  int e = blockIdx.x*256 + threadIdx.x;
  if (e < E) atomicAdd(&deg[dsts[e]], 1);
}
__global__ void fill_kernel(const int* __restrict__ ei, int* __restrict__ cursor,
                            int* __restrict__ csr, int E){
  int e = blockIdx.x*256 + threadIdx.x;
  if (e < E){
    int d = ei[E + e];
    int pos = atomicAdd(&cursor[d], 1);
    csr[pos] = ei[e];
  }
}

__global__ void scan_reduce_kernel(const int* __restrict__ deg, int* __restrict__ bsums, int n){
  __shared__ int sd[256];
  int base = blockIdx.x*1024 + threadIdx.x*4;
  int s = 0;
  #pragma unroll
  for (int j=0;j<4;++j){ int idx=base+j; if (idx<n) s += deg[idx]; }
  sd[threadIdx.x] = s; __syncthreads();
  for (int off=128; off>0; off>>=1){
    if (threadIdx.x < off) sd[threadIdx.x] += sd[threadIdx.x+off];
    __syncthreads();
  }
  if (threadIdx.x==0) bsums[blockIdx.x] = sd[0];
}

__global__ void scan_block_kernel(const int* __restrict__ bsums, int* __restrict__ boffs, int nb){
  __shared__ int ts[128];
  if (nb <= 128){
    int v = (threadIdx.x < nb) ? bsums[threadIdx.x] : 0;
    ts[threadIdx.x] = v; __syncthreads();
    for (int off=1; off<128; off<<=1){
      int t = (threadIdx.x>=off) ? ts[threadIdx.x-off] : 0;
      __syncthreads();
      ts[threadIdx.x] += t;
      __syncthreads();
    }
    if (threadIdx.x < nb) boffs[threadIdx.x] = ts[threadIdx.x] - v;
  } else if (threadIdx.x==0){
    int run=0;
    for (int b=0;b<nb;++b){ int t=bsums[b]; boffs[b]=run; run+=t; }
  }
}

__global__ void scan_final_kernel(const int* __restrict__ deg, const int* __restrict__ boffs,
                                  int* __restrict__ offs, int n, int E){
  __shared__ int ts[256];
  int base = blockIdx.x*1024 + threadIdx.x*4;
  int v[4]; int s=0;
  #pragma unroll
  for (int j=0;j<4;++j){ int idx=base+j; v[j] = (idx<n) ? deg[idx] : 0; s += v[j]; }
  ts[threadIdx.x] = s; __syncthreads();
  for (int off=1; off<256; off<<=1){
    int t = (threadIdx.x>=off) ? ts[threadIdx.x-off] : 0;
    __syncthreads();
    ts[threadIdx.x] += t;
    __syncthreads();
  }
  int excl = boffs[blockIdx.x] + (threadIdx.x ? ts[threadIdx.x-1] : 0);
  #pragma unroll
  for (int j=0;j<4;++j){ int idx=base+j; if (idx<n){ offs[idx]=excl; excl+=v[j]; } }
  if (blockIdx.x==0 && threadIdx.x==0) offs[n] = E;
}

__global__ void dinv_kernel(const int* __restrict__ deg, const int* __restrict__ offs,
                            int* __restrict__ cursor, float* __restrict__ dinv, int n){
  int i = blockIdx.x*256 + threadIdx.x;
  if (i < n){
    dinv[i] = rsqrtf((float)(deg[i] + 1));
    cursor[i] = offs[i];
  }
}

// ---------------- run-once tail-weight prep ----------------
// wbuf (u16): W0hi[0,6144) W0lo[6144,12288) W1[12288,15360) WH[15360,17408)
//             BV[17408,17920) BT[17920,18432)  (lane-indexed K=32 B-fragments)
// bbuf (f32): b0[0,96) b1[96,192)
__global__ void prep_tail_kernel(const float* __restrict__ Wih0, const float* __restrict__ Wih1,
                                 const float* __restrict__ Wv1,  const float* __restrict__ Wt1,
                                 const float* __restrict__ Wv2,  const float* __restrict__ Wt2,
                                 const float* __restrict__ bih0, const float* __restrict__ bhh0,
                                 const float* __restrict__ bih1, const float* __restrict__ bhh1,
                                 u16* __restrict__ wbuf, float* __restrict__ bbuf){
  int tid = blockIdx.x*256 + threadIdx.x;
  if (tid < 6144){                                  // Wih0 hi/lo, [k/8][96][8]
    int kg = tid / 768, rem = tid % 768;
    int j = rem >> 3, k = kg*8 + (rem & 7);
    int row = (j < 32) ? j : j + 32;
    float w = Wih0[row*64 + k];
    u16 hi = f2bf(w);
    wbuf[tid] = hi;
    wbuf[6144 + tid] = f2bf(w - bf2f(hi));
  } else if (tid < 9216){                           // Wih1, [k/8][96][8]
    int t = tid - 6144;
    int kg = t / 768, rem = t % 768;
    int j = rem >> 3, k = kg*8 + (rem & 7);
    int row = (j < 32) ? j : j + 32;
    wbuf[12288 + t] = f2bf(Wih1[row*32 + k]);
  } else if (tid < 11264){                          // Wv1|Wt1, [k/8][64][8]
    int t = tid - 9216;
    int kg = t / 512, rem = t % 512;
    int j = rem >> 3, k = kg*8 + (rem & 7);
    float v = (j < 32) ? Wv1[k*32 + j] : Wt1[k*32 + (j-32)];
    wbuf[15360 + t] = f2bf(v);
  } else if (tid < 11360){                          // b0 (i,g,o combined)
    int t = tid - 11264;
    int row = (t < 32) ? t : t + 32;
    bbuf[t] = bih0[row] + bhh0[row];
  } else if (tid < 11456){                          // b1
    int t = tid - 11360;
    int row = (t < 32) ? t : t + 32;
    bbuf[96 + t] = bih1[row] + bhh1[row];
  } else if (tid < 12480){                          // BV/BT lane fragments (K=32)
    int t = tid - 11456;
    int slab = t >> 9, within = t & 511;
    int lane = within >> 3, j = within & 7;
    int cc = lane & 15, gg = lane >> 4;
    float v;
    if (slab == 0) v = (cc == 0) ? Wv2[gg*8 + j] : 0.f;
    else           v = (cc < 10) ? Wt2[(gg*8 + j)*10 + cc] : 0.f;
    wbuf[17408 + slab*512 + within] = f2bf(v);
  }
}

// ---------------- GCN transform via MFMA (verified in R4) ----------------
template<int KD, typename TIN>
__global__ __launch_bounds__(256) void transform_mfma(const TIN* __restrict__ X,
                                                      const float* __restrict__ W,
                                                      const float* __restrict__ dinv,
                                                      u16* __restrict__ Y, int n){
  constexpr int XLD = KD + 8;
  __shared__ u16 Xl[128*XLD];
  __shared__ u16 Wl[KD*64];          // layout [KD/8][64][8]
  __shared__ float Dl[128];
  const int tid  = threadIdx.x;
  const int base = blockIdx.x*128;

  for (int i = tid; i < KD*64; i += 256){
    int k = i >> 6, col = i & 63;
    Wl[((k>>3)<<9) + (col<<3) + (k&7)] = f2bf(W[i]);
  }
  if (tid < 128){
    int nd = base + tid;
    Dl[tid] = (nd < n) ? dinv[nd] : 0.f;
  }
  if constexpr (sizeof(TIN)==4){
    #pragma unroll
    for (int j = 0; j < (128*KD)/1024; ++j){
      int e4   = tid + j*256;
      int elem = e4*4;
      int row  = elem / KD, k = elem % KD;
      int gn   = base + row;
      uint2 w2 = make_uint2(0u, 0u);
      if (gn < n){
        float4 v = ((const float4*)X)[(size_t)gn*(KD/4) + (k>>2)];
        w2.x = (u32)f2bf(v.x) | ((u32)f2bf(v.y)<<16);
        w2.y = (u32)f2bf(v.z) | ((u32)f2bf(v.w)<<16);
      }
      *((uint2*)&Xl[row*XLD + k]) = w2;
    }
  } else {
    #pragma unroll
    for (int j = 0; j < (128*KD)/1024; ++j){
      int e4   = tid + j*256;
      int elem = e4*4;
      int row  = elem / KD, k = elem % KD;
      int gn   = base + row;
      uint2 v = make_uint2(0u, 0u);
      if (gn < n) v = *((const uint2*)(X + (size_t)gn*KD + k));
      *((uint2*)&Xl[row*XLD + k]) = v;
    }
  }
  __syncthreads();

  const int lane = tid & 63, wv = tid >> 6;
  const int c = lane & 15, g = lane >> 4;

  bfrag wf[KD/32][4];
  #pragma unroll
  for (int kk=0; kk<KD/32; ++kk)
    #pragma unroll
    for (int nt=0; nt<4; ++nt)
      wf[kk][nt] = *((const bfrag*)&Wl[((kk*4+g)<<9) + ((nt*16+c)<<3)]);

  f32x4 acc[2][4];
  #pragma unroll
  for (int rs=0;rs<2;++rs)
    #pragma unroll
    for (int nt=0;nt<4;++nt)
      acc[rs][nt] = (f32x4){0.f,0.f,0.f,0.f};

  #pragma unroll
  for (int kk=0; kk<KD/32; ++kk){
    bfrag a0 = *((const bfrag*)&Xl[(wv*32      + c)*XLD + kk*32 + g*8]);
    bfrag a1 = *((const bfrag*)&Xl[(wv*32 + 16 + c)*XLD + kk*32 + g*8]);
    #pragma unroll
    for (int nt=0; nt<4; ++nt){
      acc[0][nt] = __builtin_amdgcn_mfma_f32_16x16x32_bf16(a0, wf[kk][nt], acc[0][nt], 0,0,0);
      acc[1][nt] = __builtin_amdgcn_mfma_f32_16x16x32_bf16(a1, wf[kk][nt], acc[1][nt], 0,0,0);
    }
  }

  #pragma unroll
  for (int rs=0;rs<2;++rs){
    int nl0 = wv*32 + rs*16 + g*4;
    #pragma unroll
    for (int r=0;r<4;++r){
      int node = base + nl0 + r;
      if (node < n){
        float dv = Dl[nl0 + r];
        #pragma unroll
        for (int nt=0;nt<4;++nt)
          Y[(size_t)node*64 + nt*16 + c] = f2bf(acc[rs][nt][r] * dv);
      }
    }
  }
}

// ---------------- GCN aggregate: 8 nodes/wave, 8 lanes cover the 128B row ----------------
// lane = (s = node sub 0..7, c8 = 16B column group 0..7). Each 8-lane group
// walks its node's whole adjacency serially: no cross-lane reduce, no shfl
// epilogue. csr[j] is uniform across the group (broadcast); 8 independent
// gather chains per wave keep MLP equal to the old slot design.
__global__ void agg_kernel(const u16* __restrict__ Hts, const float* __restrict__ dinv,
                           const int* __restrict__ offs, const int* __restrict__ csr,
                           const float* __restrict__ bias, u16* __restrict__ Hout, int n){
  const int lane = threadIdx.x & 63;
  const int wv   = threadIdx.x >> 6;
  const int s    = lane >> 3;
  const int c8   = lane & 7;
  const int node = blockIdx.x*32 + wv*8 + s;
  if (node >= n) return;
  const uint4* __restrict__ H = (const uint4*)Hts;
  float acc[8];
  #pragma unroll
  for (int i=0;i<8;++i) acc[i]=0.f;
  const int beg = offs[node], end = offs[node+1];
  for (int j = beg; j < end; ++j){
    int src = csr[j];                      // uniform over the node's 8 lanes
    uint4 v = H[(size_t)src*8 + c8];       // 8 lanes x 16B = full 128B row
    acc[0] += __uint_as_float(v.x<<16); acc[1] += __uint_as_float(v.x & 0xffff0000u);
    acc[2] += __uint_as_float(v.y<<16); acc[3] += __uint_as_float(v.y & 0xffff0000u);
    acc[4] += __uint_as_float(v.z<<16); acc[5] += __uint_as_float(v.z & 0xffff0000u);
    acc[6] += __uint_as_float(v.w<<16); acc[7] += __uint_as_float(v.w & 0xffff0000u);
  }
  uint4 sv = H[(size_t)node*8 + c8];       // self-loop (already * dinv[node])
  float sf[8];
  sf[0]=__uint_as_float(sv.x<<16); sf[1]=__uint_as_float(sv.x & 0xffff0000u);
  sf[2]=__uint_as_float(sv.y<<16); sf[3]=__uint_as_float(sv.y & 0xffff0000u);
  sf[4]=__uint_as_float(sv.z<<16); sf[5]=__uint_as_float(sv.z & 0xffff0000u);
  sf[6]=__uint_as_float(sv.w<<16); sf[7]=__uint_as_float(sv.w & 0xffff0000u);
  float4 b0 = ((const float4*)bias)[c8*2];
  float4 b1 = ((const float4*)bias)[c8*2+1];
  const float dv = dinv[node];
  float o[8];
  o[0]=fmaxf(fmaf(acc[0]+sf[0],dv,b0.x),0.f); o[1]=fmaxf(fmaf(acc[1]+sf[1],dv,b0.y),0.f);
  o[2]=fmaxf(fmaf(acc[2]+sf[2],dv,b0.z),0.f); o[3]=fmaxf(fmaf(acc[3]+sf[3],dv,b0.w),0.f);
  o[4]=fmaxf(fmaf(acc[4]+sf[4],dv,b1.x),0.f); o[5]=fmaxf(fmaf(acc[5]+sf[5],dv,b1.y),0.f);
  o[6]=fmaxf(fmaf(acc[6]+sf[6],dv,b1.z),0.f); o[7]=fmaxf(fmaf(acc[7]+sf[7],dv,b1.w),0.f);
  uint4 w;
  w.x = (u32)f2bf(o[0]) | ((u32)f2bf(o[1])<<16);
  w.y = (u32)f2bf(o[2]) | ((u32)f2bf(o[3])<<16);
  w.z = (u32)f2bf(o[4]) | ((u32)f2bf(o[5])<<16);
  w.w = (u32)f2bf(o[6]) | ((u32)f2bf(o[7])<<16);
  ((uint4*)Hout)[(size_t)node*8 + c8] = w;
}

// ---------------- Fused LSTM x2 + heads: 16 rows/wave, zero shuffles (R9, verified) ----------------
__global__ __launch_bounds__(256) void lstm_heads_fused(
    const u16* __restrict__ X,
    const u16* __restrict__ wbuf, const float* __restrict__ bbuf,
    const float* __restrict__ bv1, const float* __restrict__ bv2,
    const float* __restrict__ bt1, const float* __restrict__ bt2,
    float* __restrict__ out, int n)
{
  const u16* W0hi = wbuf;
  const u16* W0lo = wbuf + 6144;
  const u16* W1g  = wbuf + 12288;
  const u16* WHg  = wbuf + 15360;
  const u16* BVg  = wbuf + 17408;
  const u16* BTg  = wbuf + 17920;

  __shared__ u16 Hpool[5120];       // H1hi[0,2560) H1lo[2560,5120); H2 aliases (barrier-sep)
  __shared__ u16 VT[4608];          // 64 rows x 72: relu'd [v1(0-31) | t1(32-63)], bf16
  __shared__ float b0l[96], b1l[96], bv1l[32], bt1l[32], bt2l[10];
  u16* H1hi = Hpool;  u16* H1lo = Hpool + 2560;
  u16* H2hi = Hpool;  u16* H2lo = Hpool + 2560;

  const int tid  = threadIdx.x;
  const int base = blockIdx.x*64;

  if (tid < 96)            b0l[tid] = bbuf[tid];
  else if (tid < 192)      b1l[tid-96] = bbuf[tid];
  else if (tid < 224){ int d=tid-192; bv1l[d]=bv1[d]; }
  else               { int d=tid-224; bt1l[d]=bt1[d]; }
  if (tid < 10) bt2l[tid] = bt2[tid];
  __syncthreads();

  const int lane = tid & 63, wv = tid >> 6;
  const int c = lane & 15, g = lane >> 4;
  const float bv2v = bv2[0];

  // ---- lstm0: gates = X @ W0^T (K=64, 96 cols) ----
  {
    int r0 = base + wv*16 + c; if (r0 > n-1) r0 = n-1;
    bfrag a0[2];
    a0[0] = *((const bfrag*)(X + (size_t)r0*64      + g*8));
    a0[1] = *((const bfrag*)(X + (size_t)r0*64 + 32 + g*8));
    f32x4 acc[6];
    #pragma unroll
    for (int nt=0;nt<6;++nt) acc[nt] = (f32x4){0.f,0.f,0.f,0.f};
    #pragma unroll
    for (int kk=0; kk<2; ++kk){
      #pragma unroll
      for (int nt=0; nt<6; ++nt){
        int widx = (kk*4+g)*768 + ((nt*16+c)<<3);
        bfrag bh = *((const bfrag*)&W0hi[widx]);
        bfrag bl = *((const bfrag*)&W0lo[widx]);
        acc[nt] = __builtin_amdgcn_mfma_f32_16x16x32_bf16(a0[kk], bh, acc[nt], 0,0,0);
        acc[nt] = __builtin_amdgcn_mfma_f32_16x16x32_bf16(a0[kk], bl, acc[nt], 0,0,0);
      }
    }
    #pragma unroll
    for (int r=0;r<4;++r){
      int rl = wv*16 + g*4 + r;
      #pragma unroll
      for (int half=0; half<2; ++half){
        float iv = acc[0+half][r] + b0l[half*16 + c];
        float gv = acc[2+half][r] + b0l[32 + half*16 + c];
        float ov = acc[4+half][r] + b0l[64 + half*16 + c];
        float cc = fast_sigmoid(iv) * fast_tanh(gv);
        float hv = fast_sigmoid(ov) * fast_tanh(cc);
        u16 hi = f2bf(hv);
        H1hi[rl*40 + half*16 + c] = hi;
        H1lo[rl*40 + half*16 + c] = f2bf(hv - bf2f(hi));
      }
    }
  }
  __syncthreads();                           // H1 visible

  // ---- lstm1: gates = H1 @ W1^T (K=32, 96 cols), A-split 2-term ----
  {
    bfrag w1f[6];
    #pragma unroll
    for (int nt=0; nt<6; ++nt)
      w1f[nt] = *((const bfrag*)&W1g[g*768 + ((nt*16+c)<<3)]);
    bfrag ah = *((const bfrag*)&H1hi[(wv*16 + c)*40 + g*8]);
    bfrag al = *((const bfrag*)&H1lo[(wv*16 + c)*40 + g*8]);
    f32x4 acc[6];
    #pragma unroll
    for (int nt=0;nt<6;++nt) acc[nt] = (f32x4){0.f,0.f,0.f,0.f};
    #pragma unroll
    for (int nt=0; nt<6; ++nt){
      acc[nt] = __builtin_amdgcn_mfma_f32_16x16x32_bf16(ah, w1f[nt], acc[nt], 0,0,0);
      acc[nt] = __builtin_amdgcn_mfma_f32_16x16x32_bf16(al, w1f[nt], acc[nt], 0,0,0);
    }
    __syncthreads();                         // all H1 reads complete before H2 overwrite
    #pragma unroll
    for (int r=0;r<4;++r){
      int rl = wv*16 + g*4 + r;
      #pragma unroll
      for (int half=0; half<2; ++half){
        float iv = acc[0+half][r] + b1l[half*16 + c];
        float gv = acc[2+half][r] + b1l[32 + half*16 + c];
        float ov = acc[4+half][r] + b1l[64 + half*16 + c];
        float cc = fast_sigmoid(iv) * fast_tanh(gv);
        float hv = fast_sigmoid(ov) * fast_tanh(cc);
        u16 hi = f2bf(hv);
        H2hi[rl*40 + half*16 + c] = hi;
        H2lo[rl*40 + half*16 + c] = f2bf(hv - bf2f(hi));
      }
    }
  }
  __syncthreads();                           // H2 visible

  // ---- heads p1: [v1|t1] = relu(H2 @ [Wv1|Wt1] + b) -> VT (bf16) ----
  {
    bfrag whf[4];
    #pragma unroll
    for (int nt=0; nt<4; ++nt)
      whf[nt] = *((const bfrag*)&WHg[g*512 + ((nt*16+c)<<3)]);
    bfrag ah = *((const bfrag*)&H2hi[(wv*16 + c)*40 + g*8]);
    bfrag al = *((const bfrag*)&H2lo[(wv*16 + c)*40 + g*8]);
    f32x4 acc[4];
    #pragma unroll
    for (int nt=0;nt<4;++nt) acc[nt] = (f32x4){0.f,0.f,0.f,0.f};
    #pragma unroll
    for (int nt=0; nt<4; ++nt){
      acc[nt] = __builtin_amdgcn_mfma_f32_16x16x32_bf16(ah, whf[nt], acc[nt], 0,0,0);
      acc[nt] = __builtin_amdgcn_mfma_f32_16x16x32_bf16(al, whf[nt], acc[nt], 0,0,0);
    }
    #pragma unroll
    for (int r=0;r<4;++r){
      int rl = wv*16 + g*4 + r;
      VT[rl*72      + c] = f2bf(fmaxf(acc[0][r] + bv1l[c],    0.f));
      VT[rl*72 + 16 + c] = f2bf(fmaxf(acc[1][r] + bv1l[c+16], 0.f));
      VT[rl*72 + 32 + c] = f2bf(fmaxf(acc[2][r] + bt1l[c],    0.f));
      VT[rl*72 + 48 + c] = f2bf(fmaxf(acc[3][r] + bt1l[c+16], 0.f));
    }
  }
  __syncthreads();                           // VT visible

  // ---- heads p2: vol = v1 @ Wv2, type = t1 @ Wt2 via MFMA, direct C-write ----
  {
    bfrag av = *((const bfrag*)&VT[(wv*16 + c)*72      + g*8]);
    bfrag at = *((const bfrag*)&VT[(wv*16 + c)*72 + 32 + g*8]);
    bfrag bv = *((const bfrag*)(BVg + lane*8));
    bfrag bt = *((const bfrag*)(BTg + lane*8));
    f32x4 accv = (f32x4){0.f,0.f,0.f,0.f};
    f32x4 acct = (f32x4){0.f,0.f,0.f,0.f};
    accv = __builtin_amdgcn_mfma_f32_16x16x32_bf16(av, bv, accv, 0,0,0);
    acct = __builtin_amdgcn_mfma_f32_16x16x32_bf16(at, bt, acct, 0,0,0);
    #pragma unroll
    for (int r=0;r<4;++r){
      int node = base + wv*16 + g*4 + r;
      if (node < n){
        if (c == 0)  out[node] = accv[r] + bv2v;
        if (c < 10)  out[n + (size_t)node*10 + c] = acct[r] + bt2l[c];
      }
    }
  }
}

extern "C" void kernel_launch(void* const* d_in, const int* in_sizes, int n_in,
                              void* d_out, int out_size, void* d_ws, size_t ws_size,
                              hipStream_t stream){
  const float* x    = (const float*)d_in[0];
  const int*   ei   = (const int*)  d_in[1];
  const float* W1   = (const float*)d_in[2];  const float* b1   = (const float*)d_in[3];
  const float* W2   = (const float*)d_in[4];  const float* b2   = (const float*)d_in[5];
  const float* W3   = (const float*)d_in[6];  const float* b3   = (const float*)d_in[7];
  const float* Wih0 = (const float*)d_in[8];
  const float* bih0 = (const float*)d_in[10]; const float* bhh0 = (const float*)d_in[11];
  const float* Wih1 = (const float*)d_in[12];
  const float* bih1 = (const float*)d_in[14]; const float* bhh1 = (const float*)d_in[15];
  const float* Wv1  = (const float*)d_in[16]; const float* bv1  = (const float*)d_in[17];
  const float* Wv2  = (const float*)d_in[18]; const float* bv2  = (const float*)d_in[19];
  const float* Wt1  = (const float*)d_in[20]; const float* bt1  = (const float*)d_in[21];
  const float* Wt2  = (const float*)d_in[22]; const float* bt2  = (const float*)d_in[23];

  const int N  = in_sizes[0] / 128;
  const int E  = in_sizes[1] / 2;
  const int NB = (N + 1023) / 1024;
  const int EB = (E + 8191) / 8192;

  char* w = (char*)d_ws;
  auto take = [&](size_t bytes)->char*{ char* p = w; w += (bytes + 255) & ~(size_t)255; return p; };
  int*   deg    = (int*)  take((size_t)N*4);          // fallback only
  int*   offs   = (int*)  take((size_t)(N+1)*4);
  int*   cursor = (int*)  take((size_t)N*4);          // fallback only
  int*   csr    = (int*)  take((size_t)E*4);
  float* dinv   = (float*)take((size_t)N*4);
  int*   bsums  = (int*)  take((size_t)NB*4);         // fallback only
  int*   boffs  = (int*)  take((size_t)NB*4);         // fallback only
  int*   bhist  = (int*)  take((size_t)MAXBK*4);
  int*   bcur   = (int*)  take((size_t)MAXBK*4);
  int*   bstart = (int*)  take((size_t)(MAXBK+1)*4);
  u32*   packed = (u32*)  take((size_t)E*4);
  u16*   wbuf   = (u16*)  take((size_t)18432*2);      // prepped tail weights + BV/BT frags
  float* bbuf   = (float*)take((size_t)192*4);        // prepped tail biases
  u16*   bufTS  = (u16*)  take((size_t)N*64*2);       // transformed (pre-agg), bf16
  u16*   bufH   = (u16*)  take((size_t)N*64*2);       // post-agg activations, bf16
  (void)ws_size; (void)n_in; (void)out_size;

  // --- run-once tail weight prep ---
  prep_tail_kernel<<<49, 256, 0, stream>>>(Wih0, Wih1, Wv1, Wt1, Wv2, Wt2,
                                           bih0, bhh0, bih1, bhh1, wbuf, bbuf);

  // --- CSR build ---
  if (N <= MAXBK*256){
    const int NBK = (N + 255) / 256;
    hipMemsetAsync(bhist, 0, (size_t)MAXBK*4, stream);
    bucket_hist_kernel    <<<EB,  512, 0, stream>>>(ei + E, bhist, E);
    bucket_scan_kernel    <<<1,   512, 0, stream>>>(bhist, bcur, bstart);
    bin_kernel            <<<EB,  512, 0, stream>>>(ei, ei + E, bcur, packed, E);
    bucket_finalize_kernel<<<NBK, 512, 0, stream>>>(packed, bstart, offs, dinv, csr, N, E);
  } else {
    hipMemsetAsync(deg, 0, (size_t)N*4, stream);
    count_kernel      <<<(E+255)/256, 256, 0, stream>>>(ei + E, deg, E);
    scan_reduce_kernel<<<NB,          256, 0, stream>>>(deg, bsums, N);
    scan_block_kernel <<<1,           128, 0, stream>>>(bsums, boffs, NB);
    scan_final_kernel <<<NB,          256, 0, stream>>>(deg, boffs, offs, N, E);
    dinv_kernel       <<<(N+255)/256, 256, 0, stream>>>(deg, offs, cursor, dinv, N);
    fill_kernel       <<<(E+255)/256, 256, 0, stream>>>(ei, cursor, csr, E);
  }

  // --- GCN layers (MFMA transforms) ---
  const int TB  = (N + 127) / 128;
  const int AB  = (N + 31) / 32;
  transform_mfma<128,float><<<TB, 256, 0, stream>>>(x,    W1, dinv, bufTS, N);
  agg_kernel               <<<AB, 256, 0, stream>>>(bufTS, dinv, offs, csr, b1, bufH, N);
  transform_mfma<64,u16>   <<<TB, 256, 0, stream>>>(bufH, W2, dinv, bufTS, N);
  agg_kernel               <<<AB, 256, 0, stream>>>(bufTS, dinv, offs, csr, b2, bufH, N);
  transform_mfma<64,u16>   <<<TB, 256, 0, stream>>>(bufH, W3, dinv, bufTS, N);
  agg_kernel               <<<AB, 256, 0, stream>>>(bufTS, dinv, offs, csr, b3, bufH, N);

  // --- fused LSTM x2 + heads (64 nodes/block) ---
  const int TB2 = (N + 63) / 64;
  lstm_heads_fused<<<TB2, 256, 0, stream>>>(bufH, wbuf, bbuf,
                                            bv1, bv2, bt1, bt2,
                                            (float*)d_out, N);
}

// Round 12
// 214.228 us; speedup vs baseline: 4.4645x; 1.1432x over previous
//
#include <hip/hip_runtime.h>
#include <math.h>

// TemporalWasteGNN: 3x GCNConv (symmetric-norm, self-loops) -> 2x LSTM(seq=1, h0=c0=0)
// -> two MLP heads. fp32 I/O, bf16 intermediate features.
//
// R12: single change vs R11: agg gather loop 4-deep software-pipelined
//      (batch 4 csr loads -> issue 4 independent row loads -> accumulate).
//      R11 counters showed latency-bound (VALU 20%, HBM 25%, ~1 load in
//      flight per node chain). FP order per node unchanged -> bit-identical.
// R10 packed single-pass CSR build, R4 MFMA transforms, R7 native
// transcendentals, R8/R9 prepped-slab zero-shuffle tail — all byte-identical.

typedef unsigned int  u32;
typedef unsigned short u16;
typedef short bfrag  __attribute__((ext_vector_type(8)));   // 8 bf16 (4 VGPRs)
typedef float f32x4  __attribute__((ext_vector_type(4)));

#define LOG2E 1.44269504088896f
static __device__ __forceinline__ float fast_sigmoid(float x){
  float t = __builtin_amdgcn_exp2f(-x * LOG2E);
  return __builtin_amdgcn_rcpf(1.f + t);
}
static __device__ __forceinline__ float fast_tanh(float x){
  float t = __builtin_amdgcn_exp2f(x * (2.f * LOG2E));
  return 1.f - 2.f * __builtin_amdgcn_rcpf(t + 1.f);
}
static __device__ __forceinline__ float bf2f(u16 u){ return __uint_as_float(((u32)u)<<16); }
static __device__ __forceinline__ u16   f2bf(float f){
  u32 x = __float_as_uint(f);
  return (u16)((x + 0x7fffu + ((x>>16)&1u)) >> 16);   // round-to-nearest-even
}

#define MAXBK 512   // buckets of 256 dst nodes; N <= 131072 (src must fit 24 bits)

// ---------------- bucketed CSR build ----------------
__global__ __launch_bounds__(512) void bucket_hist_kernel(const int* __restrict__ dstA,
                                                          int* __restrict__ bhist, int E){
  __shared__ int h[MAXBK];
  for (int i=threadIdx.x; i<MAXBK; i+=512) h[i]=0;
  __syncthreads();
  const int base = blockIdx.x*8192;
  #pragma unroll
  for (int j=0;j<16;++j){
    int e = base + j*512 + threadIdx.x;
    if (e < E) atomicAdd(&h[dstA[e]>>8], 1);
  }
  __syncthreads();
  for (int i=threadIdx.x; i<MAXBK; i+=512) if (h[i]) atomicAdd(&bhist[i], h[i]);
}

// exclusive prefix -> bcur (mutable cursors for bin) AND bstart (immutable)
__global__ __launch_bounds__(512) void bucket_scan_kernel(const int* __restrict__ bhist,
                                                          int* __restrict__ bcur,
                                                          int* __restrict__ bstart){
  __shared__ int ts[MAXBK];
  int v = bhist[threadIdx.x];
  ts[threadIdx.x] = v; __syncthreads();
  for (int off=1; off<MAXBK; off<<=1){
    int t = (threadIdx.x>=off) ? ts[threadIdx.x-off] : 0;
    __syncthreads();
    ts[threadIdx.x] += t;
    __syncthreads();
  }
  int ex = ts[threadIdx.x] - v;
  bcur[threadIdx.x]   = ex;
  bstart[threadIdx.x] = ex;
  if (threadIdx.x == MAXBK-1) bstart[MAXBK] = ts[threadIdx.x];   // = E
}

// bin edges into bucket-contiguous packed stream: src | (dst&255)<<24
__global__ __launch_bounds__(512) void bin_kernel(const int* __restrict__ srcA,
                                                  const int* __restrict__ dstA,
                                                  int* __restrict__ bcur,
                                                  u32* __restrict__ packed, int E){
  __shared__ int h[MAXBK];
  __shared__ int basev[MAXBK];
  for (int i=threadIdx.x; i<MAXBK; i+=512) h[i]=0;
  __syncthreads();
  const int base = blockIdx.x*8192;
  int br[16]; int dv[16];
  #pragma unroll
  for (int j=0;j<16;++j){
    int e = base + j*512 + threadIdx.x;
    if (e < E){
      int d = dstA[e]; int b = d>>8;
      int r = atomicAdd(&h[b], 1);
      br[j] = (b<<16) | r;                 // b<512 (9b) | r<8192 (13b)
      dv[j] = d;
    } else br[j] = -1;
  }
  __syncthreads();
  for (int i=threadIdx.x; i<MAXBK; i+=512){
    int c = h[i];
    basev[i] = c ? atomicAdd(&bcur[i], c) : 0;
  }
  __syncthreads();
  #pragma unroll
  for (int j=0;j<16;++j){
    if (br[j] >= 0){
      int e = base + j*512 + threadIdx.x;
      int pos = basev[br[j]>>16] + (br[j] & 0xffff);
      packed[pos] = (u32)srcA[e] | ((u32)(dv[j] & 255) << 24);
    }
  }
}

// one block per bucket: per-node count -> scan -> offs/dinv -> csr scatter, all LDS
__global__ __launch_bounds__(512) void bucket_finalize_kernel(
    const u32* __restrict__ packed, const int* __restrict__ bstart,
    int* __restrict__ offs, float* __restrict__ dinv,
    int* __restrict__ csr, int n, int E){
  __shared__ int cnt[256];
  __shared__ int sc[256];
  __shared__ int cur[256];
  const int b = blockIdx.x;
  const int start = bstart[b], end = bstart[b+1];
  for (int i=threadIdx.x; i<256; i+=512){ cnt[i]=0; cur[i]=0; }
  __syncthreads();
  for (int e = start + threadIdx.x; e < end; e += 512)
    atomicAdd(&cnt[packed[e] >> 24], 1);
  __syncthreads();
  if (threadIdx.x < 256) sc[threadIdx.x] = cnt[threadIdx.x];
  __syncthreads();
  for (int off=1; off<256; off<<=1){
    int t = 0;
    if (threadIdx.x < 256 && threadIdx.x >= off) t = sc[threadIdx.x-off];
    __syncthreads();
    if (threadIdx.x < 256) sc[threadIdx.x] += t;
    __syncthreads();
  }
  if (threadIdx.x < 256){
    int ex = sc[threadIdx.x] - cnt[threadIdx.x];      // exclusive
    sc[threadIdx.x] = ex;
    int node = b*256 + threadIdx.x;
    if (node < n){
      offs[node] = start + ex;
      dinv[node] = rsqrtf((float)(cnt[threadIdx.x] + 1));
    }
  }
  if (b == 0 && threadIdx.x == 0) offs[n] = E;
  __syncthreads();
  for (int e = start + threadIdx.x; e < end; e += 512){
    u32 v = packed[e];
    int loc = v >> 24;
    int pos = start + sc[loc] + atomicAdd(&cur[loc], 1);
    csr[pos] = (int)(v & 0xFFFFFFu);
  }
}

// fallback (N too large for bucketing) -------------
__global__ void count_kernel(const int* __restrict__ dsts, int* __restrict__ deg, int E){
  int e = blockIdx.x*256 + threadIdx.x;
  if (e < E) atomicAdd(&deg[dsts[e]], 1);
}
__global__ void fill_kernel(const int* __restrict__ ei, int* __restrict__ cursor,
                            int* __restrict__ csr, int E){
  int e = blockIdx.x*256 + threadIdx.x;
  if (e < E){
    int d = ei[E + e];
    int pos = atomicAdd(&cursor[d], 1);
    csr[pos] = ei[e];
  }
}

__global__ void scan_reduce_kernel(const int* __restrict__ deg, int* __restrict__ bsums, int n){
  __shared__ int sd[256];
  int base = blockIdx.x*1024 + threadIdx.x*4;
  int s = 0;
  #pragma unroll
  for (int j=0;j<4;++j){ int idx=base+j; if (idx<n) s += deg[idx]; }
  sd[threadIdx.x] = s; __syncthreads();
  for (int off=128; off>0; off>>=1){
    if (threadIdx.x < off) sd[threadIdx.x] += sd[threadIdx.x+off];
    __syncthreads();
  }
  if (threadIdx.x==0) bsums[blockIdx.x] = sd[0];
}

__global__ void scan_block_kernel(const int* __restrict__ bsums, int* __restrict__ boffs, int nb){
  __shared__ int ts[128];
  if (nb <= 128){
    int v = (threadIdx.x < nb) ? bsums[threadIdx.x] : 0;
    ts[threadIdx.x] = v; __syncthreads();
    for (int off=1; off<128; off<<=1){
      int t = (threadIdx.x>=off) ? ts[threadIdx.x-off] : 0;
      __syncthreads();
      ts[threadIdx.x] += t;
      __syncthreads();
    }
    if (threadIdx.x < nb) boffs[threadIdx.x] = ts[threadIdx.x] - v;
  } else if (threadIdx.x==0){
    int run=0;
    for (int b=0;b<nb;++b){ int t=bsums[b]; boffs[b]=run; run+=t; }
  }
}

__global__ void scan_final_kernel(const int* __restrict__ deg, const int* __restrict__ boffs,
                                  int* __restrict__ offs, int n, int E){
  __shared__ int ts[256];
  int base = blockIdx.x*1024 + threadIdx.x*4;
  int v[4]; int s=0;
  #pragma unroll
  for (int j=0;j<4;++j){ int idx=base+j; v[j] = (idx<n) ? deg[idx] : 0; s += v[j]; }
  ts[threadIdx.x] = s; __syncthreads();
  for (int off=1; off<256; off<<=1){
    int t = (threadIdx.x>=off) ? ts[threadIdx.x-off] : 0;
    __syncthreads();
    ts[threadIdx.x] += t;
    __syncthreads();
  }
  int excl = boffs[blockIdx.x] + (threadIdx.x ? ts[threadIdx.x-1] : 0);
  #pragma unroll
  for (int j=0;j<4;++j){ int idx=base+j; if (idx<n){ offs[idx]=excl; excl+=v[j]; } }
  if (blockIdx.x==0 && threadIdx.x==0) offs[n] = E;
}

__global__ void dinv_kernel(const int* __restrict__ deg, const int* __restrict__ offs,
                            int* __restrict__ cursor, float* __restrict__ dinv, int n){
  int i = blockIdx.x*256 + threadIdx.x;
  if (i < n){
    dinv[i] = rsqrtf((float)(deg[i] + 1));
    cursor[i] = offs[i];
  }
}

// ---------------- run-once tail-weight prep ----------------
// wbuf (u16): W0hi[0,6144) W0lo[6144,12288) W1[12288,15360) WH[15360,17408)
//             BV[17408,17920) BT[17920,18432)  (lane-indexed K=32 B-fragments)
// bbuf (f32): b0[0,96) b1[96,192)
__global__ void prep_tail_kernel(const float* __restrict__ Wih0, const float* __restrict__ Wih1,
                                 const float* __restrict__ Wv1,  const float* __restrict__ Wt1,
                                 const float* __restrict__ Wv2,  const float* __restrict__ Wt2,
                                 const float* __restrict__ bih0, const float* __restrict__ bhh0,
                                 const float* __restrict__ bih1, const float* __restrict__ bhh1,
                                 u16* __restrict__ wbuf, float* __restrict__ bbuf){
  int tid = blockIdx.x*256 + threadIdx.x;
  if (tid < 6144){                                  // Wih0 hi/lo, [k/8][96][8]
    int kg = tid / 768, rem = tid % 768;
    int j = rem >> 3, k = kg*8 + (rem & 7);
    int row = (j < 32) ? j : j + 32;
    float w = Wih0[row*64 + k];
    u16 hi = f2bf(w);
    wbuf[tid] = hi;
    wbuf[6144 + tid] = f2bf(w - bf2f(hi));
  } else if (tid < 9216){                           // Wih1, [k/8][96][8]
    int t = tid - 6144;
    int kg = t / 768, rem = t % 768;
    int j = rem >> 3, k = kg*8 + (rem & 7);
    int row = (j < 32) ? j : j + 32;
    wbuf[12288 + t] = f2bf(Wih1[row*32 + k]);
  } else if (tid < 11264){                          // Wv1|Wt1, [k/8][64][8]
    int t = tid - 9216;
    int kg = t / 512, rem = t % 512;
    int j = rem >> 3, k = kg*8 + (rem & 7);
    float v = (j < 32) ? Wv1[k*32 + j] : Wt1[k*32 + (j-32)];
    wbuf[15360 + t] = f2bf(v);
  } else if (tid < 11360){                          // b0 (i,g,o combined)
    int t = tid - 11264;
    int row = (t < 32) ? t : t + 32;
    bbuf[t] = bih0[row] + bhh0[row];
  } else if (tid < 11456){                          // b1
    int t = tid - 11360;
    int row = (t < 32) ? t : t + 32;
    bbuf[96 + t] = bih1[row] + bhh1[row];
  } else if (tid < 12480){                          // BV/BT lane fragments (K=32)
    int t = tid - 11456;
    int slab = t >> 9, within = t & 511;
    int lane = within >> 3, j = within & 7;
    int cc = lane & 15, gg = lane >> 4;
    float v;
    if (slab == 0) v = (cc == 0) ? Wv2[gg*8 + j] : 0.f;
    else           v = (cc < 10) ? Wt2[(gg*8 + j)*10 + cc] : 0.f;
    wbuf[17408 + slab*512 + within] = f2bf(v);
  }
}

// ---------------- GCN transform via MFMA (verified in R4) ----------------
template<int KD, typename TIN>
__global__ __launch_bounds__(256) void transform_mfma(const TIN* __restrict__ X,
                                                      const float* __restrict__ W,
                                                      const float* __restrict__ dinv,
                                                      u16* __restrict__ Y, int n){
  constexpr int XLD = KD + 8;
  __shared__ u16 Xl[128*XLD];
  __shared__ u16 Wl[KD*64];          // layout [KD/8][64][8]
  __shared__ float Dl[128];
  const int tid  = threadIdx.x;
  const int base = blockIdx.x*128;

  for (int i = tid; i < KD*64; i += 256){
    int k = i >> 6, col = i & 63;
    Wl[((k>>3)<<9) + (col<<3) + (k&7)] = f2bf(W[i]);
  }
  if (tid < 128){
    int nd = base + tid;
    Dl[tid] = (nd < n) ? dinv[nd] : 0.f;
  }
  if constexpr (sizeof(TIN)==4){
    #pragma unroll
    for (int j = 0; j < (128*KD)/1024; ++j){
      int e4   = tid + j*256;
      int elem = e4*4;
      int row  = elem / KD, k = elem % KD;
      int gn   = base + row;
      uint2 w2 = make_uint2(0u, 0u);
      if (gn < n){
        float4 v = ((const float4*)X)[(size_t)gn*(KD/4) + (k>>2)];
        w2.x = (u32)f2bf(v.x) | ((u32)f2bf(v.y)<<16);
        w2.y = (u32)f2bf(v.z) | ((u32)f2bf(v.w)<<16);
      }
      *((uint2*)&Xl[row*XLD + k]) = w2;
    }
  } else {
    #pragma unroll
    for (int j = 0; j < (128*KD)/1024; ++j){
      int e4   = tid + j*256;
      int elem = e4*4;
      int row  = elem / KD, k = elem % KD;
      int gn   = base + row;
      uint2 v = make_uint2(0u, 0u);
      if (gn < n) v = *((const uint2*)(X + (size_t)gn*KD + k));
      *((uint2*)&Xl[row*XLD + k]) = v;
    }
  }
  __syncthreads();

  const int lane = tid & 63, wv = tid >> 6;
  const int c = lane & 15, g = lane >> 4;

  bfrag wf[KD/32][4];
  #pragma unroll
  for (int kk=0; kk<KD/32; ++kk)
    #pragma unroll
    for (int nt=0; nt<4; ++nt)
      wf[kk][nt] = *((const bfrag*)&Wl[((kk*4+g)<<9) + ((nt*16+c)<<3)]);

  f32x4 acc[2][4];
  #pragma unroll
  for (int rs=0;rs<2;++rs)
    #pragma unroll
    for (int nt=0;nt<4;++nt)
      acc[rs][nt] = (f32x4){0.f,0.f,0.f,0.f};

  #pragma unroll
  for (int kk=0; kk<KD/32; ++kk){
    bfrag a0 = *((const bfrag*)&Xl[(wv*32      + c)*XLD + kk*32 + g*8]);
    bfrag a1 = *((const bfrag*)&Xl[(wv*32 + 16 + c)*XLD + kk*32 + g*8]);
    #pragma unroll
    for (int nt=0; nt<4; ++nt){
      acc[0][nt] = __builtin_amdgcn_mfma_f32_16x16x32_bf16(a0, wf[kk][nt], acc[0][nt], 0,0,0);
      acc[1][nt] = __builtin_amdgcn_mfma_f32_16x16x32_bf16(a1, wf[kk][nt], acc[1][nt], 0,0,0);
    }
  }

  #pragma unroll
  for (int rs=0;rs<2;++rs){
    int nl0 = wv*32 + rs*16 + g*4;
    #pragma unroll
    for (int r=0;r<4;++r){
      int node = base + nl0 + r;
      if (node < n){
        float dv = Dl[nl0 + r];
        #pragma unroll
        for (int nt=0;nt<4;++nt)
          Y[(size_t)node*64 + nt*16 + c] = f2bf(acc[rs][nt][r] * dv);
      }
    }
  }
}

// ---------------- GCN aggregate: 8 nodes/wave x 8 lanes/row, 4-deep pipelined gather ----------------
// lane = (s = node sub 0..7, c8 = 16B column group 0..7). Each 8-lane group
// walks its node's adjacency; main loop batches 4 csr loads then issues 4
// independent row loads (4 in flight per chain, 32 per wave). FP accumulate
// order per node identical to the serial loop.
__global__ void agg_kernel(const u16* __restrict__ Hts, const float* __restrict__ dinv,
                           const int* __restrict__ offs, const int* __restrict__ csr,
                           const float* __restrict__ bias, u16* __restrict__ Hout, int n){
  const int lane = threadIdx.x & 63;
  const int wv   = threadIdx.x >> 6;
  const int s    = lane >> 3;
  const int c8   = lane & 7;
  const int node = blockIdx.x*32 + wv*8 + s;
  if (node >= n) return;
  const uint4* __restrict__ H = (const uint4*)Hts;
  float acc[8];
  #pragma unroll
  for (int i=0;i<8;++i) acc[i]=0.f;
  const int beg = offs[node], end = offs[node+1];

  #define ACC8(v) do{ \
    acc[0] += __uint_as_float((v).x<<16); acc[1] += __uint_as_float((v).x & 0xffff0000u); \
    acc[2] += __uint_as_float((v).y<<16); acc[3] += __uint_as_float((v).y & 0xffff0000u); \
    acc[4] += __uint_as_float((v).z<<16); acc[5] += __uint_as_float((v).z & 0xffff0000u); \
    acc[6] += __uint_as_float((v).w<<16); acc[7] += __uint_as_float((v).w & 0xffff0000u); }while(0)

  int j = beg;
  for (; j + 4 <= end; j += 4){
    int s0 = csr[j], s1 = csr[j+1], s2 = csr[j+2], s3 = csr[j+3];
    uint4 v0 = H[(size_t)s0*8 + c8];
    uint4 v1 = H[(size_t)s1*8 + c8];
    uint4 v2 = H[(size_t)s2*8 + c8];
    uint4 v3 = H[(size_t)s3*8 + c8];
    ACC8(v0); ACC8(v1); ACC8(v2); ACC8(v3);
  }
  for (; j < end; ++j){
    int src = csr[j];
    uint4 v = H[(size_t)src*8 + c8];
    ACC8(v);
  }
  #undef ACC8

  uint4 sv = H[(size_t)node*8 + c8];       // self-loop (already * dinv[node])
  float sf[8];
  sf[0]=__uint_as_float(sv.x<<16); sf[1]=__uint_as_float(sv.x & 0xffff0000u);
  sf[2]=__uint_as_float(sv.y<<16); sf[3]=__uint_as_float(sv.y & 0xffff0000u);
  sf[4]=__uint_as_float(sv.z<<16); sf[5]=__uint_as_float(sv.z & 0xffff0000u);
  sf[6]=__uint_as_float(sv.w<<16); sf[7]=__uint_as_float(sv.w & 0xffff0000u);
  float4 b0 = ((const float4*)bias)[c8*2];
  float4 b1 = ((const float4*)bias)[c8*2+1];
  const float dv = dinv[node];
  float o[8];
  o[0]=fmaxf(fmaf(acc[0]+sf[0],dv,b0.x),0.f); o[1]=fmaxf(fmaf(acc[1]+sf[1],dv,b0.y),0.f);
  o[2]=fmaxf(fmaf(acc[2]+sf[2],dv,b0.z),0.f); o[3]=fmaxf(fmaf(acc[3]+sf[3],dv,b0.w),0.f);
  o[4]=fmaxf(fmaf(acc[4]+sf[4],dv,b1.x),0.f); o[5]=fmaxf(fmaf(acc[5]+sf[5],dv,b1.y),0.f);
  o[6]=fmaxf(fmaf(acc[6]+sf[6],dv,b1.z),0.f); o[7]=fmaxf(fmaf(acc[7]+sf[7],dv,b1.w),0.f);
  uint4 w;
  w.x = (u32)f2bf(o[0]) | ((u32)f2bf(o[1])<<16);
  w.y = (u32)f2bf(o[2]) | ((u32)f2bf(o[3])<<16);
  w.z = (u32)f2bf(o[4]) | ((u32)f2bf(o[5])<<16);
  w.w = (u32)f2bf(o[6]) | ((u32)f2bf(o[7])<<16);
  ((uint4*)Hout)[(size_t)node*8 + c8] = w;
}

// ---------------- Fused LSTM x2 + heads: 16 rows/wave, zero shuffles (R9, verified) ----------------
__global__ __launch_bounds__(256) void lstm_heads_fused(
    const u16* __restrict__ X,
    const u16* __restrict__ wbuf, const float* __restrict__ bbuf,
    const float* __restrict__ bv1, const float* __restrict__ bv2,
    const float* __restrict__ bt1, const float* __restrict__ bt2,
    float* __restrict__ out, int n)
{
  const u16* W0hi = wbuf;
  const u16* W0lo = wbuf + 6144;
  const u16* W1g  = wbuf + 12288;
  const u16* WHg  = wbuf + 15360;
  const u16* BVg  = wbuf + 17408;
  const u16* BTg  = wbuf + 17920;

  __shared__ u16 Hpool[5120];       // H1hi[0,2560) H1lo[2560,5120); H2 aliases (barrier-sep)
  __shared__ u16 VT[4608];          // 64 rows x 72: relu'd [v1(0-31) | t1(32-63)], bf16
  __shared__ float b0l[96], b1l[96], bv1l[32], bt1l[32], bt2l[10];
  u16* H1hi = Hpool;  u16* H1lo = Hpool + 2560;
  u16* H2hi = Hpool;  u16* H2lo = Hpool + 2560;

  const int tid  = threadIdx.x;
  const int base = blockIdx.x*64;

  if (tid < 96)            b0l[tid] = bbuf[tid];
  else if (tid < 192)      b1l[tid-96] = bbuf[tid];
  else if (tid < 224){ int d=tid-192; bv1l[d]=bv1[d]; }
  else               { int d=tid-224; bt1l[d]=bt1[d]; }
  if (tid < 10) bt2l[tid] = bt2[tid];
  __syncthreads();

  const int lane = tid & 63, wv = tid >> 6;
  const int c = lane & 15, g = lane >> 4;
  const float bv2v = bv2[0];

  // ---- lstm0: gates = X @ W0^T (K=64, 96 cols) ----
  {
    int r0 = base + wv*16 + c; if (r0 > n-1) r0 = n-1;
    bfrag a0[2];
    a0[0] = *((const bfrag*)(X + (size_t)r0*64      + g*8));
    a0[1] = *((const bfrag*)(X + (size_t)r0*64 + 32 + g*8));
    f32x4 acc[6];
    #pragma unroll
    for (int nt=0;nt<6;++nt) acc[nt] = (f32x4){0.f,0.f,0.f,0.f};
    #pragma unroll
    for (int kk=0; kk<2; ++kk){
      #pragma unroll
      for (int nt=0; nt<6; ++nt){
        int widx = (kk*4+g)*768 + ((nt*16+c)<<3);
        bfrag bh = *((const bfrag*)&W0hi[widx]);
        bfrag bl = *((const bfrag*)&W0lo[widx]);
        acc[nt] = __builtin_amdgcn_mfma_f32_16x16x32_bf16(a0[kk], bh, acc[nt], 0,0,0);
        acc[nt] = __builtin_amdgcn_mfma_f32_16x16x32_bf16(a0[kk], bl, acc[nt], 0,0,0);
      }
    }
    #pragma unroll
    for (int r=0;r<4;++r){
      int rl = wv*16 + g*4 + r;
      #pragma unroll
      for (int half=0; half<2; ++half){
        float iv = acc[0+half][r] + b0l[half*16 + c];
        float gv = acc[2+half][r] + b0l[32 + half*16 + c];
        float ov = acc[4+half][r] + b0l[64 + half*16 + c];
        float cc = fast_sigmoid(iv) * fast_tanh(gv);
        float hv = fast_sigmoid(ov) * fast_tanh(cc);
        u16 hi = f2bf(hv);
        H1hi[rl*40 + half*16 + c] = hi;
        H1lo[rl*40 + half*16 + c] = f2bf(hv - bf2f(hi));
      }
    }
  }
  __syncthreads();                           // H1 visible

  // ---- lstm1: gates = H1 @ W1^T (K=32, 96 cols), A-split 2-term ----
  {
    bfrag w1f[6];
    #pragma unroll
    for (int nt=0; nt<6; ++nt)
      w1f[nt] = *((const bfrag*)&W1g[g*768 + ((nt*16+c)<<3)]);
    bfrag ah = *((const bfrag*)&H1hi[(wv*16 + c)*40 + g*8]);
    bfrag al = *((const bfrag*)&H1lo[(wv*16 + c)*40 + g*8]);
    f32x4 acc[6];
    #pragma unroll
    for (int nt=0;nt<6;++nt) acc[nt] = (f32x4){0.f,0.f,0.f,0.f};
    #pragma unroll
    for (int nt=0; nt<6; ++nt){
      acc[nt] = __builtin_amdgcn_mfma_f32_16x16x32_bf16(ah, w1f[nt], acc[nt], 0,0,0);
      acc[nt] = __builtin_amdgcn_mfma_f32_16x16x32_bf16(al, w1f[nt], acc[nt], 0,0,0);
    }
    __syncthreads();                         // all H1 reads complete before H2 overwrite
    #pragma unroll
    for (int r=0;r<4;++r){
      int rl = wv*16 + g*4 + r;
      #pragma unroll
      for (int half=0; half<2; ++half){
        float iv = acc[0+half][r] + b1l[half*16 + c];
        float gv = acc[2+half][r] + b1l[32 + half*16 + c];
        float ov = acc[4+half][r] + b1l[64 + half*16 + c];
        float cc = fast_sigmoid(iv) * fast_tanh(gv);
        float hv = fast_sigmoid(ov) * fast_tanh(cc);
        u16 hi = f2bf(hv);
        H2hi[rl*40 + half*16 + c] = hi;
        H2lo[rl*40 + half*16 + c] = f2bf(hv - bf2f(hi));
      }
    }
  }
  __syncthreads();                           // H2 visible

  // ---- heads p1: [v1|t1] = relu(H2 @ [Wv1|Wt1] + b) -> VT (bf16) ----
  {
    bfrag whf[4];
    #pragma unroll
    for (int nt=0; nt<4; ++nt)
      whf[nt] = *((const bfrag*)&WHg[g*512 + ((nt*16+c)<<3)]);
    bfrag ah = *((const bfrag*)&H2hi[(wv*16 + c)*40 + g*8]);
    bfrag al = *((const bfrag*)&H2lo[(wv*16 + c)*40 + g*8]);
    f32x4 acc[4];
    #pragma unroll
    for (int nt=0;nt<4;++nt) acc[nt] = (f32x4){0.f,0.f,0.f,0.f};
    #pragma unroll
    for (int nt=0; nt<4; ++nt){
      acc[nt] = __builtin_amdgcn_mfma_f32_16x16x32_bf16(ah, whf[nt], acc[nt], 0,0,0);
      acc[nt] = __builtin_amdgcn_mfma_f32_16x16x32_bf16(al, whf[nt], acc[nt], 0,0,0);
    }
    #pragma unroll
    for (int r=0;r<4;++r){
      int rl = wv*16 + g*4 + r;
      VT[rl*72      + c] = f2bf(fmaxf(acc[0][r] + bv1l[c],    0.f));
      VT[rl*72 + 16 + c] = f2bf(fmaxf(acc[1][r] + bv1l[c+16], 0.f));
      VT[rl*72 + 32 + c] = f2bf(fmaxf(acc[2][r] + bt1l[c],    0.f));
      VT[rl*72 + 48 + c] = f2bf(fmaxf(acc[3][r] + bt1l[c+16], 0.f));
    }
  }
  __syncthreads();                           // VT visible

  // ---- heads p2: vol = v1 @ Wv2, type = t1 @ Wt2 via MFMA, direct C-write ----
  {
    bfrag av = *((const bfrag*)&VT[(wv*16 + c)*72      + g*8]);
    bfrag at = *((const bfrag*)&VT[(wv*16 + c)*72 + 32 + g*8]);
    bfrag bv = *((const bfrag*)(BVg + lane*8));
    bfrag bt = *((const bfrag*)(BTg + lane*8));
    f32x4 accv = (f32x4){0.f,0.f,0.f,0.f};
    f32x4 acct = (f32x4){0.f,0.f,0.f,0.f};
    accv = __builtin_amdgcn_mfma_f32_16x16x32_bf16(av, bv, accv, 0,0,0);
    acct = __builtin_amdgcn_mfma_f32_16x16x32_bf16(at, bt, acct, 0,0,0);
    #pragma unroll
    for (int r=0;r<4;++r){
      int node = base + wv*16 + g*4 + r;
      if (node < n){
        if (c == 0)  out[node] = accv[r] + bv2v;
        if (c < 10)  out[n + (size_t)node*10 + c] = acct[r] + bt2l[c];
      }
    }
  }
}

extern "C" void kernel_launch(void* const* d_in, const int* in_sizes, int n_in,
                              void* d_out, int out_size, void* d_ws, size_t ws_size,
                              hipStream_t stream){
  const float* x    = (const float*)d_in[0];
  const int*   ei   = (const int*)  d_in[1];
  const float* W1   = (const float*)d_in[2];  const float* b1   = (const float*)d_in[3];
  const float* W2   = (const float*)d_in[4];  const float* b2   = (const float*)d_in[5];
  const float* W3   = (const float*)d_in[6];  const float* b3   = (const float*)d_in[7];
  const float* Wih0 = (const float*)d_in[8];
  const float* bih0 = (const float*)d_in[10]; const float* bhh0 = (const float*)d_in[11];
  const float* Wih1 = (const float*)d_in[12];
  const float* bih1 = (const float*)d_in[14]; const float* bhh1 = (const float*)d_in[15];
  const float* Wv1  = (const float*)d_in[16]; const float* bv1  = (const float*)d_in[17];
  const float* Wv2  = (const float*)d_in[18]; const float* bv2  = (const float*)d_in[19];
  const float* Wt1  = (const float*)d_in[20]; const float* bt1  = (const float*)d_in[21];
  const float* Wt2  = (const float*)d_in[22]; const float* bt2  = (const float*)d_in[23];

  const int N  = in_sizes[0] / 128;
  const int E  = in_sizes[1] / 2;
  const int NB = (N + 1023) / 1024;
  const int EB = (E + 8191) / 8192;

  char* w = (char*)d_ws;
  auto take = [&](size_t bytes)->char*{ char* p = w; w += (bytes + 255) & ~(size_t)255; return p; };
  int*   deg    = (int*)  take((size_t)N*4);          // fallback only
  int*   offs   = (int*)  take((size_t)(N+1)*4);
  int*   cursor = (int*)  take((size_t)N*4);          // fallback only
  int*   csr    = (int*)  take((size_t)E*4);
  float* dinv   = (float*)take((size_t)N*4);
  int*   bsums  = (int*)  take((size_t)NB*4);         // fallback only
  int*   boffs  = (int*)  take((size_t)NB*4);         // fallback only
  int*   bhist  = (int*)  take((size_t)MAXBK*4);
  int*   bcur   = (int*)  take((size_t)MAXBK*4);
  int*   bstart = (int*)  take((size_t)(MAXBK+1)*4);
  u32*   packed = (u32*)  take((size_t)E*4);
  u16*   wbuf   = (u16*)  take((size_t)18432*2);      // prepped tail weights + BV/BT frags
  float* bbuf   = (float*)take((size_t)192*4);        // prepped tail biases
  u16*   bufTS  = (u16*)  take((size_t)N*64*2);       // transformed (pre-agg), bf16
  u16*   bufH   = (u16*)  take((size_t)N*64*2);       // post-agg activations, bf16
  (void)ws_size; (void)n_in; (void)out_size;

  // --- run-once tail weight prep ---
  prep_tail_kernel<<<49, 256, 0, stream>>>(Wih0, Wih1, Wv1, Wt1, Wv2, Wt2,
                                           bih0, bhh0, bih1, bhh1, wbuf, bbuf);

  // --- CSR build ---
  if (N <= MAXBK*256){
    const int NBK = (N + 255) / 256;
    hipMemsetAsync(bhist, 0, (size_t)MAXBK*4, stream);
    bucket_hist_kernel    <<<EB,  512, 0, stream>>>(ei + E, bhist, E);
    bucket_scan_kernel    <<<1,   512, 0, stream>>>(bhist, bcur, bstart);
    bin_kernel            <<<EB,  512, 0, stream>>>(ei, ei + E, bcur, packed, E);
    bucket_finalize_kernel<<<NBK, 512, 0, stream>>>(packed, bstart, offs, dinv, csr, N, E);
  } else {
    hipMemsetAsync(deg, 0, (size_t)N*4, stream);
    count_kernel      <<<(E+255)/256, 256, 0, stream>>>(ei + E, deg, E);
    scan_reduce_kernel<<<NB,          256, 0, stream>>>(deg, bsums, N);
    scan_block_kernel <<<1,           128, 0, stream>>>(bsums, boffs, NB);
    scan_final_kernel <<<NB,          256, 0, stream>>>(deg, boffs, offs, N, E);
    dinv_kernel       <<<(N+255)/256, 256, 0, stream>>>(deg, offs, cursor, dinv, N);
    fill_kernel       <<<(E+255)/256, 256, 0, stream>>>(ei, cursor, csr, E);
  }

  // --- GCN layers (MFMA transforms) ---
  const int TB  = (N + 127) / 128;
  const int AB  = (N + 31) / 32;
  transform_mfma<128,float><<<TB, 256, 0, stream>>>(x,    W1, dinv, bufTS, N);
  agg_kernel               <<<AB, 256, 0, stream>>>(bufTS, dinv, offs, csr, b1, bufH, N);
  transform_mfma<64,u16>   <<<TB, 256, 0, stream>>>(bufH, W2, dinv, bufTS, N);
  agg_kernel               <<<AB, 256, 0, stream>>>(bufTS, dinv, offs, csr, b2, bufH, N);
  transform_mfma<64,u16>   <<<TB, 256, 0, stream>>>(bufH, W3, dinv, bufTS, N);
  agg_kernel               <<<AB, 256, 0, stream>>>(bufTS, dinv, offs, csr, b3, bufH, N);

  // --- fused LSTM x2 + heads (64 nodes/block) ---
  const int TB2 = (N + 63) / 64;
  lstm_heads_fused<<<TB2, 256, 0, stream>>>(bufH, wbuf, bbuf,
                                            bv1, bv2, bt1, bt2,
                                            (float*)d_out, N);
}

// Round 13
// 200.042 us; speedup vs baseline: 4.7811x; 1.0709x over previous
//
#include <hip/hip_runtime.h>
#include <math.h>

// TemporalWasteGNN: 3x GCNConv (symmetric-norm, self-loops) -> 2x LSTM(seq=1, h0=c0=0)
// -> two MLP heads. fp32 I/O, bf16 intermediate features.
//
// R13: GCN weights W1/W2/W3 prepped once into bf16 subtiled global slabs
//      (extends prep_tail_kernel). transform_mfma loses its per-block W
//      conversion + LDS scatter (R12 counters: 700K bank conflicts, 17% occ,
//      51.7KB LDS). LDS now Xl-only (35/19KB -> 4/8 blocks/CU). bhist zeroing
//      folded into prep (removes our memset dispatch). Numerics bit-identical.
// R10 packed CSR build, R11/R12 pipelined 8-node/wave agg, R7 native
// transcendentals, R8/R9 prepped-slab zero-shuffle tail — all byte-identical.

typedef unsigned int  u32;
typedef unsigned short u16;
typedef short bfrag  __attribute__((ext_vector_type(8)));   // 8 bf16 (4 VGPRs)
typedef float f32x4  __attribute__((ext_vector_type(4)));

#define LOG2E 1.44269504088896f
static __device__ __forceinline__ float fast_sigmoid(float x){
  float t = __builtin_amdgcn_exp2f(-x * LOG2E);
  return __builtin_amdgcn_rcpf(1.f + t);
}
static __device__ __forceinline__ float fast_tanh(float x){
  float t = __builtin_amdgcn_exp2f(x * (2.f * LOG2E));
  return 1.f - 2.f * __builtin_amdgcn_rcpf(t + 1.f);
}
static __device__ __forceinline__ float bf2f(u16 u){ return __uint_as_float(((u32)u)<<16); }
static __device__ __forceinline__ u16   f2bf(float f){
  u32 x = __float_as_uint(f);
  return (u16)((x + 0x7fffu + ((x>>16)&1u)) >> 16);   // round-to-nearest-even
}

#define MAXBK 512   // buckets of 256 dst nodes; N <= 131072 (src must fit 24 bits)

// ---------------- bucketed CSR build ----------------
__global__ __launch_bounds__(512) void bucket_hist_kernel(const int* __restrict__ dstA,
                                                          int* __restrict__ bhist, int E){
  __shared__ int h[MAXBK];
  for (int i=threadIdx.x; i<MAXBK; i+=512) h[i]=0;
  __syncthreads();
  const int base = blockIdx.x*8192;
  #pragma unroll
  for (int j=0;j<16;++j){
    int e = base + j*512 + threadIdx.x;
    if (e < E) atomicAdd(&h[dstA[e]>>8], 1);
  }
  __syncthreads();
  for (int i=threadIdx.x; i<MAXBK; i+=512) if (h[i]) atomicAdd(&bhist[i], h[i]);
}

// exclusive prefix -> bcur (mutable cursors for bin) AND bstart (immutable)
__global__ __launch_bounds__(512) void bucket_scan_kernel(const int* __restrict__ bhist,
                                                          int* __restrict__ bcur,
                                                          int* __restrict__ bstart){
  __shared__ int ts[MAXBK];
  int v = bhist[threadIdx.x];
  ts[threadIdx.x] = v; __syncthreads();
  for (int off=1; off<MAXBK; off<<=1){
    int t = (threadIdx.x>=off) ? ts[threadIdx.x-off] : 0;
    __syncthreads();
    ts[threadIdx.x] += t;
    __syncthreads();
  }
  int ex = ts[threadIdx.x] - v;
  bcur[threadIdx.x]   = ex;
  bstart[threadIdx.x] = ex;
  if (threadIdx.x == MAXBK-1) bstart[MAXBK] = ts[threadIdx.x];   // = E
}

// bin edges into bucket-contiguous packed stream: src | (dst&255)<<24
__global__ __launch_bounds__(512) void bin_kernel(const int* __restrict__ srcA,
                                                  const int* __restrict__ dstA,
                                                  int* __restrict__ bcur,
                                                  u32* __restrict__ packed, int E){
  __shared__ int h[MAXBK];
  __shared__ int basev[MAXBK];
  for (int i=threadIdx.x; i<MAXBK; i+=512) h[i]=0;
  __syncthreads();
  const int base = blockIdx.x*8192;
  int br[16]; int dv[16];
  #pragma unroll
  for (int j=0;j<16;++j){
    int e = base + j*512 + threadIdx.x;
    if (e < E){
      int d = dstA[e]; int b = d>>8;
      int r = atomicAdd(&h[b], 1);
      br[j] = (b<<16) | r;                 // b<512 (9b) | r<8192 (13b)
      dv[j] = d;
    } else br[j] = -1;
  }
  __syncthreads();
  for (int i=threadIdx.x; i<MAXBK; i+=512){
    int c = h[i];
    basev[i] = c ? atomicAdd(&bcur[i], c) : 0;
  }
  __syncthreads();
  #pragma unroll
  for (int j=0;j<16;++j){
    if (br[j] >= 0){
      int e = base + j*512 + threadIdx.x;
      int pos = basev[br[j]>>16] + (br[j] & 0xffff);
      packed[pos] = (u32)srcA[e] | ((u32)(dv[j] & 255) << 24);
    }
  }
}

// one block per bucket: per-node count -> scan -> offs/dinv -> csr scatter, all LDS
__global__ __launch_bounds__(512) void bucket_finalize_kernel(
    const u32* __restrict__ packed, const int* __restrict__ bstart,
    int* __restrict__ offs, float* __restrict__ dinv,
    int* __restrict__ csr, int n, int E){
  __shared__ int cnt[256];
  __shared__ int sc[256];
  __shared__ int cur[256];
  const int b = blockIdx.x;
  const int start = bstart[b], end = bstart[b+1];
  for (int i=threadIdx.x; i<256; i+=512){ cnt[i]=0; cur[i]=0; }
  __syncthreads();
  for (int e = start + threadIdx.x; e < end; e += 512)
    atomicAdd(&cnt[packed[e] >> 24], 1);
  __syncthreads();
  if (threadIdx.x < 256) sc[threadIdx.x] = cnt[threadIdx.x];
  __syncthreads();
  for (int off=1; off<256; off<<=1){
    int t = 0;
    if (threadIdx.x < 256 && threadIdx.x >= off) t = sc[threadIdx.x-off];
    __syncthreads();
    if (threadIdx.x < 256) sc[threadIdx.x] += t;
    __syncthreads();
  }
  if (threadIdx.x < 256){
    int ex = sc[threadIdx.x] - cnt[threadIdx.x];      // exclusive
    sc[threadIdx.x] = ex;
    int node = b*256 + threadIdx.x;
    if (node < n){
      offs[node] = start + ex;
      dinv[node] = rsqrtf((float)(cnt[threadIdx.x] + 1));
    }
  }
  if (b == 0 && threadIdx.x == 0) offs[n] = E;
  __syncthreads();
  for (int e = start + threadIdx.x; e < end; e += 512){
    u32 v = packed[e];
    int loc = v >> 24;
    int pos = start + sc[loc] + atomicAdd(&cur[loc], 1);
    csr[pos] = (int)(v & 0xFFFFFFu);
  }
}

// fallback (N too large for bucketing) -------------
__global__ void count_kernel(const int* __restrict__ dsts, int* __restrict__ deg, int E){
  int e = blockIdx.x*256 + threadIdx.x;
  if (e < E) atomicAdd(&deg[dsts[e]], 1);
}
__global__ void fill_kernel(const int* __restrict__ ei, int* __restrict__ cursor,
                            int* __restrict__ csr, int E){
  int e = blockIdx.x*256 + threadIdx.x;
  if (e < E){
    int d = ei[E + e];
    int pos = atomicAdd(&cursor[d], 1);
    csr[pos] = ei[e];
  }
}

__global__ void scan_reduce_kernel(const int* __restrict__ deg, int* __restrict__ bsums, int n){
  __shared__ int sd[256];
  int base = blockIdx.x*1024 + threadIdx.x*4;
  int s = 0;
  #pragma unroll
  for (int j=0;j<4;++j){ int idx=base+j; if (idx<n) s += deg[idx]; }
  sd[threadIdx.x] = s; __syncthreads();
  for (int off=128; off>0; off>>=1){
    if (threadIdx.x < off) sd[threadIdx.x] += sd[threadIdx.x+off];
    __syncthreads();
  }
  if (threadIdx.x==0) bsums[blockIdx.x] = sd[0];
}

__global__ void scan_block_kernel(const int* __restrict__ bsums, int* __restrict__ boffs, int nb){
  __shared__ int ts[128];
  if (nb <= 128){
    int v = (threadIdx.x < nb) ? bsums[threadIdx.x] : 0;
    ts[threadIdx.x] = v; __syncthreads();
    for (int off=1; off<128; off<<=1){
      int t = (threadIdx.x>=off) ? ts[threadIdx.x-off] : 0;
      __syncthreads();
      ts[threadIdx.x] += t;
      __syncthreads();
    }
    if (threadIdx.x < nb) boffs[threadIdx.x] = ts[threadIdx.x] - v;
  } else if (threadIdx.x==0){
    int run=0;
    for (int b=0;b<nb;++b){ int t=bsums[b]; boffs[b]=run; run+=t; }
  }
}

__global__ void scan_final_kernel(const int* __restrict__ deg, const int* __restrict__ boffs,
                                  int* __restrict__ offs, int n, int E){
  __shared__ int ts[256];
  int base = blockIdx.x*1024 + threadIdx.x*4;
  int v[4]; int s=0;
  #pragma unroll
  for (int j=0;j<4;++j){ int idx=base+j; v[j] = (idx<n) ? deg[idx] : 0; s += v[j]; }
  ts[threadIdx.x] = s; __syncthreads();
  for (int off=1; off<256; off<<=1){
    int t = (threadIdx.x>=off) ? ts[threadIdx.x-off] : 0;
    __syncthreads();
    ts[threadIdx.x] += t;
    __syncthreads();
  }
  int excl = boffs[blockIdx.x] + (threadIdx.x ? ts[threadIdx.x-1] : 0);
  #pragma unroll
  for (int j=0;j<4;++j){ int idx=base+j; if (idx<n){ offs[idx]=excl; excl+=v[j]; } }
  if (blockIdx.x==0 && threadIdx.x==0) offs[n] = E;
}

__global__ void dinv_kernel(const int* __restrict__ deg, const int* __restrict__ offs,
                            int* __restrict__ cursor, float* __restrict__ dinv, int n){
  int i = blockIdx.x*256 + threadIdx.x;
  if (i < n){
    dinv[i] = rsqrtf((float)(deg[i] + 1));
    cursor[i] = offs[i];
  }
}

// ---------------- run-once weight prep (tail + GCN) ----------------
// wbuf (u16): W0hi[0,6144) W0lo[6144,12288) W1l[12288,15360) WH[15360,17408)
//             BV[17408,17920) BT[17920,18432)
// wgcn (u16): G1[0,8192) G2[8192,12288) G3[12288,16384)  ([k/8][64][8] bf16)
// bbuf (f32): b0[0,96) b1[96,192)
// Also zeroes bhist (removes a separate memset dispatch).
__global__ void prep_tail_kernel(const float* __restrict__ Wih0, const float* __restrict__ Wih1,
                                 const float* __restrict__ Wv1,  const float* __restrict__ Wt1,
                                 const float* __restrict__ Wv2,  const float* __restrict__ Wt2,
                                 const float* __restrict__ bih0, const float* __restrict__ bhh0,
                                 const float* __restrict__ bih1, const float* __restrict__ bhh1,
                                 const float* __restrict__ Wg1,  const float* __restrict__ Wg2,
                                 const float* __restrict__ Wg3,
                                 u16* __restrict__ wbuf, float* __restrict__ bbuf,
                                 u16* __restrict__ wgcn, int* __restrict__ bhist){
  int tid = blockIdx.x*256 + threadIdx.x;
  if (tid < 6144){                                  // Wih0 hi/lo, [k/8][96][8]
    int kg = tid / 768, rem = tid % 768;
    int j = rem >> 3, k = kg*8 + (rem & 7);
    int row = (j < 32) ? j : j + 32;
    float w = Wih0[row*64 + k];
    u16 hi = f2bf(w);
    wbuf[tid] = hi;
    wbuf[6144 + tid] = f2bf(w - bf2f(hi));
  } else if (tid < 9216){                           // Wih1, [k/8][96][8]
    int t = tid - 6144;
    int kg = t / 768, rem = t % 768;
    int j = rem >> 3, k = kg*8 + (rem & 7);
    int row = (j < 32) ? j : j + 32;
    wbuf[12288 + t] = f2bf(Wih1[row*32 + k]);
  } else if (tid < 11264){                          // Wv1|Wt1, [k/8][64][8]
    int t = tid - 9216;
    int kg = t / 512, rem = t % 512;
    int j = rem >> 3, k = kg*8 + (rem & 7);
    float v = (j < 32) ? Wv1[k*32 + j] : Wt1[k*32 + (j-32)];
    wbuf[15360 + t] = f2bf(v);
  } else if (tid < 11360){                          // b0 (i,g,o combined)
    int t = tid - 11264;
    int row = (t < 32) ? t : t + 32;
    bbuf[t] = bih0[row] + bhh0[row];
  } else if (tid < 11456){                          // b1
    int t = tid - 11360;
    int row = (t < 32) ? t : t + 32;
    bbuf[96 + t] = bih1[row] + bhh1[row];
  } else if (tid < 12480){                          // BV/BT lane fragments (K=32)
    int t = tid - 11456;
    int slab = t >> 9, within = t & 511;
    int lane = within >> 3, j = within & 7;
    int cc = lane & 15, gg = lane >> 4;
    float v;
    if (slab == 0) v = (cc == 0) ? Wv2[gg*8 + j] : 0.f;
    else           v = (cc < 10) ? Wt2[(gg*8 + j)*10 + cc] : 0.f;
    wbuf[17408 + slab*512 + within] = f2bf(v);
  } else if (tid < 12992){                          // zero bhist
    bhist[tid - 12480] = 0;
  } else if (tid < 21184){                          // W1 (128x64) -> G1
    int t = tid - 12992;                            // t == ((k>>3)<<9)+(j<<3)+(k&7)
    int kg = t >> 9, rem = t & 511;
    int j = rem >> 3, k = kg*8 + (rem & 7);
    wgcn[t] = f2bf(Wg1[k*64 + j]);
  } else if (tid < 25280){                          // W2 (64x64) -> G2
    int t = tid - 21184;
    int kg = t >> 9, rem = t & 511;
    int j = rem >> 3, k = kg*8 + (rem & 7);
    wgcn[8192 + t] = f2bf(Wg2[k*64 + j]);
  } else if (tid < 29376){                          // W3 (64x64) -> G3
    int t = tid - 25280;
    int kg = t >> 9, rem = t & 511;
    int j = rem >> 3, k = kg*8 + (rem & 7);
    wgcn[12288 + t] = f2bf(Wg3[k*64 + j]);
  }
}

// ---------------- GCN transform via MFMA, W from prepped global slab ----------------
template<int KD, typename TIN>
__global__ __launch_bounds__(256) void transform_mfma(const TIN* __restrict__ X,
                                                      const u16* __restrict__ WG,
                                                      const float* __restrict__ dinv,
                                                      u16* __restrict__ Y, int n){
  constexpr int XLD = KD + 8;
  __shared__ u16 Xl[128*XLD];
  __shared__ float Dl[128];
  const int tid  = threadIdx.x;
  const int base = blockIdx.x*128;

  if (tid < 128){
    int nd = base + tid;
    Dl[tid] = (nd < n) ? dinv[nd] : 0.f;
  }
  if constexpr (sizeof(TIN)==4){
    #pragma unroll
    for (int j = 0; j < (128*KD)/1024; ++j){
      int e4   = tid + j*256;
      int elem = e4*4;
      int row  = elem / KD, k = elem % KD;
      int gn   = base + row;
      uint2 w2 = make_uint2(0u, 0u);
      if (gn < n){
        float4 v = ((const float4*)X)[(size_t)gn*(KD/4) + (k>>2)];
        w2.x = (u32)f2bf(v.x) | ((u32)f2bf(v.y)<<16);
        w2.y = (u32)f2bf(v.z) | ((u32)f2bf(v.w)<<16);
      }
      *((uint2*)&Xl[row*XLD + k]) = w2;
    }
  } else {
    #pragma unroll
    for (int j = 0; j < (128*KD)/1024; ++j){
      int e4   = tid + j*256;
      int elem = e4*4;
      int row  = elem / KD, k = elem % KD;
      int gn   = base + row;
      uint2 v = make_uint2(0u, 0u);
      if (gn < n) v = *((const uint2*)(X + (size_t)gn*KD + k));
      *((uint2*)&Xl[row*XLD + k]) = v;
    }
  }

  const int lane = tid & 63, wv = tid >> 6;
  const int c = lane & 15, g = lane >> 4;

  // preload W fragments from the prepped slab (L2-hot, no LDS, no conversion)
  bfrag wf[KD/32][4];
  #pragma unroll
  for (int kk=0; kk<KD/32; ++kk)
    #pragma unroll
    for (int nt=0; nt<4; ++nt)
      wf[kk][nt] = *((const bfrag*)&WG[((kk*4+g)<<9) + ((nt*16+c)<<3)]);

  __syncthreads();                   // Xl ready

  f32x4 acc[2][4];
  #pragma unroll
  for (int rs=0;rs<2;++rs)
    #pragma unroll
    for (int nt=0;nt<4;++nt)
      acc[rs][nt] = (f32x4){0.f,0.f,0.f,0.f};

  #pragma unroll
  for (int kk=0; kk<KD/32; ++kk){
    bfrag a0 = *((const bfrag*)&Xl[(wv*32      + c)*XLD + kk*32 + g*8]);
    bfrag a1 = *((const bfrag*)&Xl[(wv*32 + 16 + c)*XLD + kk*32 + g*8]);
    #pragma unroll
    for (int nt=0; nt<4; ++nt){
      acc[0][nt] = __builtin_amdgcn_mfma_f32_16x16x32_bf16(a0, wf[kk][nt], acc[0][nt], 0,0,0);
      acc[1][nt] = __builtin_amdgcn_mfma_f32_16x16x32_bf16(a1, wf[kk][nt], acc[1][nt], 0,0,0);
    }
  }

  #pragma unroll
  for (int rs=0;rs<2;++rs){
    int nl0 = wv*32 + rs*16 + g*4;
    #pragma unroll
    for (int r=0;r<4;++r){
      int node = base + nl0 + r;
      if (node < n){
        float dv = Dl[nl0 + r];
        #pragma unroll
        for (int nt=0;nt<4;++nt)
          Y[(size_t)node*64 + nt*16 + c] = f2bf(acc[rs][nt][r] * dv);
      }
    }
  }
}

// ---------------- GCN aggregate: 8 nodes/wave x 8 lanes/row, 4-deep pipelined gather ----------------
__global__ void agg_kernel(const u16* __restrict__ Hts, const float* __restrict__ dinv,
                           const int* __restrict__ offs, const int* __restrict__ csr,
                           const float* __restrict__ bias, u16* __restrict__ Hout, int n){
  const int lane = threadIdx.x & 63;
  const int wv   = threadIdx.x >> 6;
  const int s    = lane >> 3;
  const int c8   = lane & 7;
  const int node = blockIdx.x*32 + wv*8 + s;
  if (node >= n) return;
  const uint4* __restrict__ H = (const uint4*)Hts;
  float acc[8];
  #pragma unroll
  for (int i=0;i<8;++i) acc[i]=0.f;
  const int beg = offs[node], end = offs[node+1];

  #define ACC8(v) do{ \
    acc[0] += __uint_as_float((v).x<<16); acc[1] += __uint_as_float((v).x & 0xffff0000u); \
    acc[2] += __uint_as_float((v).y<<16); acc[3] += __uint_as_float((v).y & 0xffff0000u); \
    acc[4] += __uint_as_float((v).z<<16); acc[5] += __uint_as_float((v).z & 0xffff0000u); \
    acc[6] += __uint_as_float((v).w<<16); acc[7] += __uint_as_float((v).w & 0xffff0000u); }while(0)

  int j = beg;
  for (; j + 4 <= end; j += 4){
    int s0 = csr[j], s1 = csr[j+1], s2 = csr[j+2], s3 = csr[j+3];
    uint4 v0 = H[(size_t)s0*8 + c8];
    uint4 v1 = H[(size_t)s1*8 + c8];
    uint4 v2 = H[(size_t)s2*8 + c8];
    uint4 v3 = H[(size_t)s3*8 + c8];
    ACC8(v0); ACC8(v1); ACC8(v2); ACC8(v3);
  }
  for (; j < end; ++j){
    int src = csr[j];
    uint4 v = H[(size_t)src*8 + c8];
    ACC8(v);
  }
  #undef ACC8

  uint4 sv = H[(size_t)node*8 + c8];       // self-loop (already * dinv[node])
  float sf[8];
  sf[0]=__uint_as_float(sv.x<<16); sf[1]=__uint_as_float(sv.x & 0xffff0000u);
  sf[2]=__uint_as_float(sv.y<<16); sf[3]=__uint_as_float(sv.y & 0xffff0000u);
  sf[4]=__uint_as_float(sv.z<<16); sf[5]=__uint_as_float(sv.z & 0xffff0000u);
  sf[6]=__uint_as_float(sv.w<<16); sf[7]=__uint_as_float(sv.w & 0xffff0000u);
  float4 b0 = ((const float4*)bias)[c8*2];
  float4 b1 = ((const float4*)bias)[c8*2+1];
  const float dv = dinv[node];
  float o[8];
  o[0]=fmaxf(fmaf(acc[0]+sf[0],dv,b0.x),0.f); o[1]=fmaxf(fmaf(acc[1]+sf[1],dv,b0.y),0.f);
  o[2]=fmaxf(fmaf(acc[2]+sf[2],dv,b0.z),0.f); o[3]=fmaxf(fmaf(acc[3]+sf[3],dv,b0.w),0.f);
  o[4]=fmaxf(fmaf(acc[4]+sf[4],dv,b1.x),0.f); o[5]=fmaxf(fmaf(acc[5]+sf[5],dv,b1.y),0.f);
  o[6]=fmaxf(fmaf(acc[6]+sf[6],dv,b1.z),0.f); o[7]=fmaxf(fmaf(acc[7]+sf[7],dv,b1.w),0.f);
  uint4 w;
  w.x = (u32)f2bf(o[0]) | ((u32)f2bf(o[1])<<16);
  w.y = (u32)f2bf(o[2]) | ((u32)f2bf(o[3])<<16);
  w.z = (u32)f2bf(o[4]) | ((u32)f2bf(o[5])<<16);
  w.w = (u32)f2bf(o[6]) | ((u32)f2bf(o[7])<<16);
  ((uint4*)Hout)[(size_t)node*8 + c8] = w;
}

// ---------------- Fused LSTM x2 + heads: 16 rows/wave, zero shuffles (R9, verified) ----------------
__global__ __launch_bounds__(256) void lstm_heads_fused(
    const u16* __restrict__ X,
    const u16* __restrict__ wbuf, const float* __restrict__ bbuf,
    const float* __restrict__ bv1, const float* __restrict__ bv2,
    const float* __restrict__ bt1, const float* __restrict__ bt2,
    float* __restrict__ out, int n)
{
  const u16* W0hi = wbuf;
  const u16* W0lo = wbuf + 6144;
  const u16* W1g  = wbuf + 12288;
  const u16* WHg  = wbuf + 15360;
  const u16* BVg  = wbuf + 17408;
  const u16* BTg  = wbuf + 17920;

  __shared__ u16 Hpool[5120];       // H1hi[0,2560) H1lo[2560,5120); H2 aliases (barrier-sep)
  __shared__ u16 VT[4608];          // 64 rows x 72: relu'd [v1(0-31) | t1(32-63)], bf16
  __shared__ float b0l[96], b1l[96], bv1l[32], bt1l[32], bt2l[10];
  u16* H1hi = Hpool;  u16* H1lo = Hpool + 2560;
  u16* H2hi = Hpool;  u16* H2lo = Hpool + 2560;

  const int tid  = threadIdx.x;
  const int base = blockIdx.x*64;

  if (tid < 96)            b0l[tid] = bbuf[tid];
  else if (tid < 192)      b1l[tid-96] = bbuf[tid];
  else if (tid < 224){ int d=tid-192; bv1l[d]=bv1[d]; }
  else               { int d=tid-224; bt1l[d]=bt1[d]; }
  if (tid < 10) bt2l[tid] = bt2[tid];
  __syncthreads();

  const int lane = tid & 63, wv = tid >> 6;
  const int c = lane & 15, g = lane >> 4;
  const float bv2v = bv2[0];

  // ---- lstm0: gates = X @ W0^T (K=64, 96 cols) ----
  {
    int r0 = base + wv*16 + c; if (r0 > n-1) r0 = n-1;
    bfrag a0[2];
    a0[0] = *((const bfrag*)(X + (size_t)r0*64      + g*8));
    a0[1] = *((const bfrag*)(X + (size_t)r0*64 + 32 + g*8));
    f32x4 acc[6];
    #pragma unroll
    for (int nt=0;nt<6;++nt) acc[nt] = (f32x4){0.f,0.f,0.f,0.f};
    #pragma unroll
    for (int kk=0; kk<2; ++kk){
      #pragma unroll
      for (int nt=0; nt<6; ++nt){
        int widx = (kk*4+g)*768 + ((nt*16+c)<<3);
        bfrag bh = *((const bfrag*)&W0hi[widx]);
        bfrag bl = *((const bfrag*)&W0lo[widx]);
        acc[nt] = __builtin_amdgcn_mfma_f32_16x16x32_bf16(a0[kk], bh, acc[nt], 0,0,0);
        acc[nt] = __builtin_amdgcn_mfma_f32_16x16x32_bf16(a0[kk], bl, acc[nt], 0,0,0);
      }
    }
    #pragma unroll
    for (int r=0;r<4;++r){
      int rl = wv*16 + g*4 + r;
      #pragma unroll
      for (int half=0; half<2; ++half){
        float iv = acc[0+half][r] + b0l[half*16 + c];
        float gv = acc[2+half][r] + b0l[32 + half*16 + c];
        float ov = acc[4+half][r] + b0l[64 + half*16 + c];
        float cc = fast_sigmoid(iv) * fast_tanh(gv);
        float hv = fast_sigmoid(ov) * fast_tanh(cc);
        u16 hi = f2bf(hv);
        H1hi[rl*40 + half*16 + c] = hi;
        H1lo[rl*40 + half*16 + c] = f2bf(hv - bf2f(hi));
      }
    }
  }
  __syncthreads();                           // H1 visible

  // ---- lstm1: gates = H1 @ W1^T (K=32, 96 cols), A-split 2-term ----
  {
    bfrag w1f[6];
    #pragma unroll
    for (int nt=0; nt<6; ++nt)
      w1f[nt] = *((const bfrag*)&W1g[g*768 + ((nt*16+c)<<3)]);
    bfrag ah = *((const bfrag*)&H1hi[(wv*16 + c)*40 + g*8]);
    bfrag al = *((const bfrag*)&H1lo[(wv*16 + c)*40 + g*8]);
    f32x4 acc[6];
    #pragma unroll
    for (int nt=0;nt<6;++nt) acc[nt] = (f32x4){0.f,0.f,0.f,0.f};
    #pragma unroll
    for (int nt=0; nt<6; ++nt){
      acc[nt] = __builtin_amdgcn_mfma_f32_16x16x32_bf16(ah, w1f[nt], acc[nt], 0,0,0);
      acc[nt] = __builtin_amdgcn_mfma_f32_16x16x32_bf16(al, w1f[nt], acc[nt], 0,0,0);
    }
    __syncthreads();                         // all H1 reads complete before H2 overwrite
    #pragma unroll
    for (int r=0;r<4;++r){
      int rl = wv*16 + g*4 + r;
      #pragma unroll
      for (int half=0; half<2; ++half){
        float iv = acc[0+half][r] + b1l[half*16 + c];
        float gv = acc[2+half][r] + b1l[32 + half*16 + c];
        float ov = acc[4+half][r] + b1l[64 + half*16 + c];
        float cc = fast_sigmoid(iv) * fast_tanh(gv);
        float hv = fast_sigmoid(ov) * fast_tanh(cc);
        u16 hi = f2bf(hv);
        H2hi[rl*40 + half*16 + c] = hi;
        H2lo[rl*40 + half*16 + c] = f2bf(hv - bf2f(hi));
      }
    }
  }
  __syncthreads();                           // H2 visible

  // ---- heads p1: [v1|t1] = relu(H2 @ [Wv1|Wt1] + b) -> VT (bf16) ----
  {
    bfrag whf[4];
    #pragma unroll
    for (int nt=0; nt<4; ++nt)
      whf[nt] = *((const bfrag*)&WHg[g*512 + ((nt*16+c)<<3)]);
    bfrag ah = *((const bfrag*)&H2hi[(wv*16 + c)*40 + g*8]);
    bfrag al = *((const bfrag*)&H2lo[(wv*16 + c)*40 + g*8]);
    f32x4 acc[4];
    #pragma unroll
    for (int nt=0;nt<4;++nt) acc[nt] = (f32x4){0.f,0.f,0.f,0.f};
    #pragma unroll
    for (int nt=0; nt<4; ++nt){
      acc[nt] = __builtin_amdgcn_mfma_f32_16x16x32_bf16(ah, whf[nt], acc[nt], 0,0,0);
      acc[nt] = __builtin_amdgcn_mfma_f32_16x16x32_bf16(al, whf[nt], acc[nt], 0,0,0);
    }
    #pragma unroll
    for (int r=0;r<4;++r){
      int rl = wv*16 + g*4 + r;
      VT[rl*72      + c] = f2bf(fmaxf(acc[0][r] + bv1l[c],    0.f));
      VT[rl*72 + 16 + c] = f2bf(fmaxf(acc[1][r] + bv1l[c+16], 0.f));
      VT[rl*72 + 32 + c] = f2bf(fmaxf(acc[2][r] + bt1l[c],    0.f));
      VT[rl*72 + 48 + c] = f2bf(fmaxf(acc[3][r] + bt1l[c+16], 0.f));
    }
  }
  __syncthreads();                           // VT visible

  // ---- heads p2: vol = v1 @ Wv2, type = t1 @ Wt2 via MFMA, direct C-write ----
  {
    bfrag av = *((const bfrag*)&VT[(wv*16 + c)*72      + g*8]);
    bfrag at = *((const bfrag*)&VT[(wv*16 + c)*72 + 32 + g*8]);
    bfrag bv = *((const bfrag*)(BVg + lane*8));
    bfrag bt = *((const bfrag*)(BTg + lane*8));
    f32x4 accv = (f32x4){0.f,0.f,0.f,0.f};
    f32x4 acct = (f32x4){0.f,0.f,0.f,0.f};
    accv = __builtin_amdgcn_mfma_f32_16x16x32_bf16(av, bv, accv, 0,0,0);
    acct = __builtin_amdgcn_mfma_f32_16x16x32_bf16(at, bt, acct, 0,0,0);
    #pragma unroll
    for (int r=0;r<4;++r){
      int node = base + wv*16 + g*4 + r;
      if (node < n){
        if (c == 0)  out[node] = accv[r] + bv2v;
        if (c < 10)  out[n + (size_t)node*10 + c] = acct[r] + bt2l[c];
      }
    }
  }
}

extern "C" void kernel_launch(void* const* d_in, const int* in_sizes, int n_in,
                              void* d_out, int out_size, void* d_ws, size_t ws_size,
                              hipStream_t stream){
  const float* x    = (const float*)d_in[0];
  const int*   ei   = (const int*)  d_in[1];
  const float* W1   = (const float*)d_in[2];  const float* b1   = (const float*)d_in[3];
  const float* W2   = (const float*)d_in[4];  const float* b2   = (const float*)d_in[5];
  const float* W3   = (const float*)d_in[6];  const float* b3   = (const float*)d_in[7];
  const float* Wih0 = (const float*)d_in[8];
  const float* bih0 = (const float*)d_in[10]; const float* bhh0 = (const float*)d_in[11];
  const float* Wih1 = (const float*)d_in[12];
  const float* bih1 = (const float*)d_in[14]; const float* bhh1 = (const float*)d_in[15];
  const float* Wv1  = (const float*)d_in[16]; const float* bv1  = (const float*)d_in[17];
  const float* Wv2  = (const float*)d_in[18]; const float* bv2  = (const float*)d_in[19];
  const float* Wt1  = (const float*)d_in[20]; const float* bt1  = (const float*)d_in[21];
  const float* Wt2  = (const float*)d_in[22]; const float* bt2  = (const float*)d_in[23];

  const int N  = in_sizes[0] / 128;
  const int E  = in_sizes[1] / 2;
  const int NB = (N + 1023) / 1024;
  const int EB = (E + 8191) / 8192;

  char* w = (char*)d_ws;
  auto take = [&](size_t bytes)->char*{ char* p = w; w += (bytes + 255) & ~(size_t)255; return p; };
  int*   deg    = (int*)  take((size_t)N*4);          // fallback only
  int*   offs   = (int*)  take((size_t)(N+1)*4);
  int*   cursor = (int*)  take((size_t)N*4);          // fallback only
  int*   csr    = (int*)  take((size_t)E*4);
  float* dinv   = (float*)take((size_t)N*4);
  int*   bsums  = (int*)  take((size_t)NB*4);         // fallback only
  int*   boffs  = (int*)  take((size_t)NB*4);         // fallback only
  int*   bhist  = (int*)  take((size_t)MAXBK*4);
  int*   bcur   = (int*)  take((size_t)MAXBK*4);
  int*   bstart = (int*)  take((size_t)(MAXBK+1)*4);
  u32*   packed = (u32*)  take((size_t)E*4);
  u16*   wbuf   = (u16*)  take((size_t)18432*2);      // prepped tail weights + BV/BT frags
  float* bbuf   = (float*)take((size_t)192*4);        // prepped tail biases
  u16*   wgcn   = (u16*)  take((size_t)16384*2);      // prepped GCN weights (bf16 subtiled)
  u16*   bufTS  = (u16*)  take((size_t)N*64*2);       // transformed (pre-agg), bf16
  u16*   bufH   = (u16*)  take((size_t)N*64*2);       // post-agg activations, bf16
  (void)ws_size; (void)n_in; (void)out_size;

  // --- run-once weight prep (also zeroes bhist) ---
  prep_tail_kernel<<<115, 256, 0, stream>>>(Wih0, Wih1, Wv1, Wt1, Wv2, Wt2,
                                            bih0, bhh0, bih1, bhh1,
                                            W1, W2, W3,
                                            wbuf, bbuf, wgcn, bhist);

  // --- CSR build ---
  if (N <= MAXBK*256){
    const int NBK = (N + 255) / 256;
    bucket_hist_kernel    <<<EB,  512, 0, stream>>>(ei + E, bhist, E);
    bucket_scan_kernel    <<<1,   512, 0, stream>>>(bhist, bcur, bstart);
    bin_kernel            <<<EB,  512, 0, stream>>>(ei, ei + E, bcur, packed, E);
    bucket_finalize_kernel<<<NBK, 512, 0, stream>>>(packed, bstart, offs, dinv, csr, N, E);
  } else {
    hipMemsetAsync(deg, 0, (size_t)N*4, stream);
    count_kernel      <<<(E+255)/256, 256, 0, stream>>>(ei + E, deg, E);
    scan_reduce_kernel<<<NB,          256, 0, stream>>>(deg, bsums, N);
    scan_block_kernel <<<1,           128, 0, stream>>>(bsums, boffs, NB);
    scan_final_kernel <<<NB,          256, 0, stream>>>(deg, boffs, offs, N, E);
    dinv_kernel       <<<(N+255)/256, 256, 0, stream>>>(deg, offs, cursor, dinv, N);
    fill_kernel       <<<(E+255)/256, 256, 0, stream>>>(ei, cursor, csr, E);
  }

  // --- GCN layers (MFMA transforms, W from prepped slab) ---
  const int TB  = (N + 127) / 128;
  const int AB  = (N + 31) / 32;
  transform_mfma<128,float><<<TB, 256, 0, stream>>>(x,    wgcn,         dinv, bufTS, N);
  agg_kernel               <<<AB, 256, 0, stream>>>(bufTS, dinv, offs, csr, b1, bufH, N);
  transform_mfma<64,u16>   <<<TB, 256, 0, stream>>>(bufH, wgcn + 8192,  dinv, bufTS, N);
  agg_kernel               <<<AB, 256, 0, stream>>>(bufTS, dinv, offs, csr, b2, bufH, N);
  transform_mfma<64,u16>   <<<TB, 256, 0, stream>>>(bufH, wgcn + 12288, dinv, bufTS, N);
  agg_kernel               <<<AB, 256, 0, stream>>>(bufTS, dinv, offs, csr, b3, bufH, N);

  // --- fused LSTM x2 + heads (64 nodes/block) ---
  const int TB2 = (N + 63) / 64;
  lstm_heads_fused<<<TB2, 256, 0, stream>>>(bufH, wbuf, bbuf,
                                            bv1, bv2, bt1, bt2,
                                            (float*)d_out, N);
}

// Round 14
// 189.782 us; speedup vs baseline: 5.0395x; 1.0541x over previous
//
#include <hip/hip_runtime.h>
#include <math.h>

// TemporalWasteGNN: 3x GCNConv (symmetric-norm, self-loops) -> 2x LSTM(seq=1, h0=c0=0)
// -> two MLP heads. fp32 I/O, bf16 intermediate features.
//
// R14: agg fused into its consumer (R13 profile: no kernel >40us; bufH round
//      trips ~77MB + 3 launch gaps were the remaining structural waste):
//      - fused_agg_transform (layers 2,3): gather-agg 128 nodes -> LDS Xl tile
//        -> MFMA transform from prepped W slab. bufH eliminated.
//      - fused_tail: gather-agg 64 nodes (b3) -> LDS -> lstm0/lstm1/heads.
//      Same f2bf rounding at the agg/consumer boundary -> bit-identical.
// R10 packed CSR build, R12 4-deep pipelined gather, R13 prepped GCN slab,
// R7 native transcendentals, R8/R9 zero-shuffle tail math — all retained.

typedef unsigned int  u32;
typedef unsigned short u16;
typedef short bfrag  __attribute__((ext_vector_type(8)));   // 8 bf16 (4 VGPRs)
typedef float f32x4  __attribute__((ext_vector_type(4)));

#define LOG2E 1.44269504088896f
static __device__ __forceinline__ float fast_sigmoid(float x){
  float t = __builtin_amdgcn_exp2f(-x * LOG2E);
  return __builtin_amdgcn_rcpf(1.f + t);
}
static __device__ __forceinline__ float fast_tanh(float x){
  float t = __builtin_amdgcn_exp2f(x * (2.f * LOG2E));
  return 1.f - 2.f * __builtin_amdgcn_rcpf(t + 1.f);
}
static __device__ __forceinline__ float bf2f(u16 u){ return __uint_as_float(((u32)u)<<16); }
static __device__ __forceinline__ u16   f2bf(float f){
  u32 x = __float_as_uint(f);
  return (u16)((x + 0x7fffu + ((x>>16)&1u)) >> 16);   // round-to-nearest-even
}

#define MAXBK 512   // buckets of 256 dst nodes; N <= 131072 (src must fit 24 bits)

// ---------------- bucketed CSR build ----------------
__global__ __launch_bounds__(512) void bucket_hist_kernel(const int* __restrict__ dstA,
                                                          int* __restrict__ bhist, int E){
  __shared__ int h[MAXBK];
  for (int i=threadIdx.x; i<MAXBK; i+=512) h[i]=0;
  __syncthreads();
  const int base = blockIdx.x*8192;
  #pragma unroll
  for (int j=0;j<16;++j){
    int e = base + j*512 + threadIdx.x;
    if (e < E) atomicAdd(&h[dstA[e]>>8], 1);
  }
  __syncthreads();
  for (int i=threadIdx.x; i<MAXBK; i+=512) if (h[i]) atomicAdd(&bhist[i], h[i]);
}

// exclusive prefix -> bcur (mutable cursors for bin) AND bstart (immutable)
__global__ __launch_bounds__(512) void bucket_scan_kernel(const int* __restrict__ bhist,
                                                          int* __restrict__ bcur,
                                                          int* __restrict__ bstart){
  __shared__ int ts[MAXBK];
  int v = bhist[threadIdx.x];
  ts[threadIdx.x] = v; __syncthreads();
  for (int off=1; off<MAXBK; off<<=1){
    int t = (threadIdx.x>=off) ? ts[threadIdx.x-off] : 0;
    __syncthreads();
    ts[threadIdx.x] += t;
    __syncthreads();
  }
  int ex = ts[threadIdx.x] - v;
  bcur[threadIdx.x]   = ex;
  bstart[threadIdx.x] = ex;
  if (threadIdx.x == MAXBK-1) bstart[MAXBK] = ts[threadIdx.x];   // = E
}

// bin edges into bucket-contiguous packed stream: src | (dst&255)<<24
__global__ __launch_bounds__(512) void bin_kernel(const int* __restrict__ srcA,
                                                  const int* __restrict__ dstA,
                                                  int* __restrict__ bcur,
                                                  u32* __restrict__ packed, int E){
  __shared__ int h[MAXBK];
  __shared__ int basev[MAXBK];
  for (int i=threadIdx.x; i<MAXBK; i+=512) h[i]=0;
  __syncthreads();
  const int base = blockIdx.x*8192;
  int br[16]; int dv[16];
  #pragma unroll
  for (int j=0;j<16;++j){
    int e = base + j*512 + threadIdx.x;
    if (e < E){
      int d = dstA[e]; int b = d>>8;
      int r = atomicAdd(&h[b], 1);
      br[j] = (b<<16) | r;                 // b<512 (9b) | r<8192 (13b)
      dv[j] = d;
    } else br[j] = -1;
  }
  __syncthreads();
  for (int i=threadIdx.x; i<MAXBK; i+=512){
    int c = h[i];
    basev[i] = c ? atomicAdd(&bcur[i], c) : 0;
  }
  __syncthreads();
  #pragma unroll
  for (int j=0;j<16;++j){
    if (br[j] >= 0){
      int e = base + j*512 + threadIdx.x;
      int pos = basev[br[j]>>16] + (br[j] & 0xffff);
      packed[pos] = (u32)srcA[e] | ((u32)(dv[j] & 255) << 24);
    }
  }
}

// one block per bucket: per-node count -> scan -> offs/dinv -> csr scatter, all LDS
__global__ __launch_bounds__(512) void bucket_finalize_kernel(
    const u32* __restrict__ packed, const int* __restrict__ bstart,
    int* __restrict__ offs, float* __restrict__ dinv,
    int* __restrict__ csr, int n, int E){
  __shared__ int cnt[256];
  __shared__ int sc[256];
  __shared__ int cur[256];
  const int b = blockIdx.x;
  const int start = bstart[b], end = bstart[b+1];
  for (int i=threadIdx.x; i<256; i+=512){ cnt[i]=0; cur[i]=0; }
  __syncthreads();
  for (int e = start + threadIdx.x; e < end; e += 512)
    atomicAdd(&cnt[packed[e] >> 24], 1);
  __syncthreads();
  if (threadIdx.x < 256) sc[threadIdx.x] = cnt[threadIdx.x];
  __syncthreads();
  for (int off=1; off<256; off<<=1){
    int t = 0;
    if (threadIdx.x < 256 && threadIdx.x >= off) t = sc[threadIdx.x-off];
    __syncthreads();
    if (threadIdx.x < 256) sc[threadIdx.x] += t;
    __syncthreads();
  }
  if (threadIdx.x < 256){
    int ex = sc[threadIdx.x] - cnt[threadIdx.x];      // exclusive
    sc[threadIdx.x] = ex;
    int node = b*256 + threadIdx.x;
    if (node < n){
      offs[node] = start + ex;
      dinv[node] = rsqrtf((float)(cnt[threadIdx.x] + 1));
    }
  }
  if (b == 0 && threadIdx.x == 0) offs[n] = E;
  __syncthreads();
  for (int e = start + threadIdx.x; e < end; e += 512){
    u32 v = packed[e];
    int loc = v >> 24;
    int pos = start + sc[loc] + atomicAdd(&cur[loc], 1);
    csr[pos] = (int)(v & 0xFFFFFFu);
  }
}

// fallback (N too large for bucketing) -------------
__global__ void count_kernel(const int* __restrict__ dsts, int* __restrict__ deg, int E){
  int e = blockIdx.x*256 + threadIdx.x;
  if (e < E) atomicAdd(&deg[dsts[e]], 1);
}
__global__ void fill_kernel(const int* __restrict__ ei, int* __restrict__ cursor,
                            int* __restrict__ csr, int E){
  int e = blockIdx.x*256 + threadIdx.x;
  if (e < E){
    int d = ei[E + e];
    int pos = atomicAdd(&cursor[d], 1);
    csr[pos] = ei[e];
  }
}

__global__ void scan_reduce_kernel(const int* __restrict__ deg, int* __restrict__ bsums, int n){
  __shared__ int sd[256];
  int base = blockIdx.x*1024 + threadIdx.x*4;
  int s = 0;
  #pragma unroll
  for (int j=0;j<4;++j){ int idx=base+j; if (idx<n) s += deg[idx]; }
  sd[threadIdx.x] = s; __syncthreads();
  for (int off=128; off>0; off>>=1){
    if (threadIdx.x < off) sd[threadIdx.x] += sd[threadIdx.x+off];
    __syncthreads();
  }
  if (threadIdx.x==0) bsums[blockIdx.x] = sd[0];
}

__global__ void scan_block_kernel(const int* __restrict__ bsums, int* __restrict__ boffs, int nb){
  __shared__ int ts[128];
  if (nb <= 128){
    int v = (threadIdx.x < nb) ? bsums[threadIdx.x] : 0;
    ts[threadIdx.x] = v; __syncthreads();
    for (int off=1; off<128; off<<=1){
      int t = (threadIdx.x>=off) ? ts[threadIdx.x-off] : 0;
      __syncthreads();
      ts[threadIdx.x] += t;
      __syncthreads();
    }
    if (threadIdx.x < nb) boffs[threadIdx.x] = ts[threadIdx.x] - v;
  } else if (threadIdx.x==0){
    int run=0;
    for (int b=0;b<nb;++b){ int t=bsums[b]; boffs[b]=run; run+=t; }
  }
}

__global__ void scan_final_kernel(const int* __restrict__ deg, const int* __restrict__ boffs,
                                  int* __restrict__ offs, int n, int E){
  __shared__ int ts[256];
  int base = blockIdx.x*1024 + threadIdx.x*4;
  int v[4]; int s=0;
  #pragma unroll
  for (int j=0;j<4;++j){ int idx=base+j; v[j] = (idx<n) ? deg[idx] : 0; s += v[j]; }
  ts[threadIdx.x] = s; __syncthreads();
  for (int off=1; off<256; off<<=1){
    int t = (threadIdx.x>=off) ? ts[threadIdx.x-off] : 0;
    __syncthreads();
    ts[threadIdx.x] += t;
    __syncthreads();
  }
  int excl = boffs[blockIdx.x] + (threadIdx.x ? ts[threadIdx.x-1] : 0);
  #pragma unroll
  for (int j=0;j<4;++j){ int idx=base+j; if (idx<n){ offs[idx]=excl; excl+=v[j]; } }
  if (blockIdx.x==0 && threadIdx.x==0) offs[n] = E;
}

__global__ void dinv_kernel(const int* __restrict__ deg, const int* __restrict__ offs,
                            int* __restrict__ cursor, float* __restrict__ dinv, int n){
  int i = blockIdx.x*256 + threadIdx.x;
  if (i < n){
    dinv[i] = rsqrtf((float)(deg[i] + 1));
    cursor[i] = offs[i];
  }
}

// ---------------- run-once weight prep (tail + GCN) ----------------
__global__ void prep_tail_kernel(const float* __restrict__ Wih0, const float* __restrict__ Wih1,
                                 const float* __restrict__ Wv1,  const float* __restrict__ Wt1,
                                 const float* __restrict__ Wv2,  const float* __restrict__ Wt2,
                                 const float* __restrict__ bih0, const float* __restrict__ bhh0,
                                 const float* __restrict__ bih1, const float* __restrict__ bhh1,
                                 const float* __restrict__ Wg1,  const float* __restrict__ Wg2,
                                 const float* __restrict__ Wg3,
                                 u16* __restrict__ wbuf, float* __restrict__ bbuf,
                                 u16* __restrict__ wgcn, int* __restrict__ bhist){
  int tid = blockIdx.x*256 + threadIdx.x;
  if (tid < 6144){                                  // Wih0 hi/lo, [k/8][96][8]
    int kg = tid / 768, rem = tid % 768;
    int j = rem >> 3, k = kg*8 + (rem & 7);
    int row = (j < 32) ? j : j + 32;
    float w = Wih0[row*64 + k];
    u16 hi = f2bf(w);
    wbuf[tid] = hi;
    wbuf[6144 + tid] = f2bf(w - bf2f(hi));
  } else if (tid < 9216){                           // Wih1, [k/8][96][8]
    int t = tid - 6144;
    int kg = t / 768, rem = t % 768;
    int j = rem >> 3, k = kg*8 + (rem & 7);
    int row = (j < 32) ? j : j + 32;
    wbuf[12288 + t] = f2bf(Wih1[row*32 + k]);
  } else if (tid < 11264){                          // Wv1|Wt1, [k/8][64][8]
    int t = tid - 9216;
    int kg = t / 512, rem = t % 512;
    int j = rem >> 3, k = kg*8 + (rem & 7);
    float v = (j < 32) ? Wv1[k*32 + j] : Wt1[k*32 + (j-32)];
    wbuf[15360 + t] = f2bf(v);
  } else if (tid < 11360){                          // b0 (i,g,o combined)
    int t = tid - 11264;
    int row = (t < 32) ? t : t + 32;
    bbuf[t] = bih0[row] + bhh0[row];
  } else if (tid < 11456){                          // b1
    int t = tid - 11360;
    int row = (t < 32) ? t : t + 32;
    bbuf[96 + t] = bih1[row] + bhh1[row];
  } else if (tid < 12480){                          // BV/BT lane fragments (K=32)
    int t = tid - 11456;
    int slab = t >> 9, within = t & 511;
    int lane = within >> 3, j = within & 7;
    int cc = lane & 15, gg = lane >> 4;
    float v;
    if (slab == 0) v = (cc == 0) ? Wv2[gg*8 + j] : 0.f;
    else           v = (cc < 10) ? Wt2[(gg*8 + j)*10 + cc] : 0.f;
    wbuf[17408 + slab*512 + within] = f2bf(v);
  } else if (tid < 12992){                          // zero bhist
    bhist[tid - 12480] = 0;
  } else if (tid < 21184){                          // W1 (128x64) -> G1
    int t = tid - 12992;
    int kg = t >> 9, rem = t & 511;
    int j = rem >> 3, k = kg*8 + (rem & 7);
    wgcn[t] = f2bf(Wg1[k*64 + j]);
  } else if (tid < 25280){                          // W2 (64x64) -> G2
    int t = tid - 21184;
    int kg = t >> 9, rem = t & 511;
    int j = rem >> 3, k = kg*8 + (rem & 7);
    wgcn[8192 + t] = f2bf(Wg2[k*64 + j]);
  } else if (tid < 29376){                          // W3 (64x64) -> G3
    int t = tid - 25280;
    int kg = t >> 9, rem = t & 511;
    int j = rem >> 3, k = kg*8 + (rem & 7);
    wgcn[12288 + t] = f2bf(Wg3[k*64 + j]);
  }
}

// ---------------- gather-agg helper: acc over adjacency, 4-deep pipelined ----------------
// Returns packed bf16 uint4 of relu(dinv*(sum+self)+bias) for (node, c8).
static __device__ __forceinline__ uint4 agg_row(const uint4* __restrict__ H,
                                                const float* __restrict__ dinv,
                                                const int* __restrict__ offs,
                                                const int* __restrict__ csr,
                                                const float* __restrict__ bias,
                                                int node, int c8){
  float acc[8];
  #pragma unroll
  for (int i=0;i<8;++i) acc[i]=0.f;
  const int beg = offs[node], end = offs[node+1];
  #define ACC8(v) do{ \
    acc[0] += __uint_as_float((v).x<<16); acc[1] += __uint_as_float((v).x & 0xffff0000u); \
    acc[2] += __uint_as_float((v).y<<16); acc[3] += __uint_as_float((v).y & 0xffff0000u); \
    acc[4] += __uint_as_float((v).z<<16); acc[5] += __uint_as_float((v).z & 0xffff0000u); \
    acc[6] += __uint_as_float((v).w<<16); acc[7] += __uint_as_float((v).w & 0xffff0000u); }while(0)
  int j = beg;
  for (; j + 4 <= end; j += 4){
    int s0 = csr[j], s1 = csr[j+1], s2 = csr[j+2], s3 = csr[j+3];
    uint4 v0 = H[(size_t)s0*8 + c8];
    uint4 v1 = H[(size_t)s1*8 + c8];
    uint4 v2 = H[(size_t)s2*8 + c8];
    uint4 v3 = H[(size_t)s3*8 + c8];
    ACC8(v0); ACC8(v1); ACC8(v2); ACC8(v3);
  }
  for (; j < end; ++j){
    int src = csr[j];
    uint4 v = H[(size_t)src*8 + c8];
    ACC8(v);
  }
  #undef ACC8
  uint4 sv = H[(size_t)node*8 + c8];       // self-loop (already * dinv[node])
  float sf[8];
  sf[0]=__uint_as_float(sv.x<<16); sf[1]=__uint_as_float(sv.x & 0xffff0000u);
  sf[2]=__uint_as_float(sv.y<<16); sf[3]=__uint_as_float(sv.y & 0xffff0000u);
  sf[4]=__uint_as_float(sv.z<<16); sf[5]=__uint_as_float(sv.z & 0xffff0000u);
  sf[6]=__uint_as_float(sv.w<<16); sf[7]=__uint_as_float(sv.w & 0xffff0000u);
  float4 b0 = ((const float4*)bias)[c8*2];
  float4 b1 = ((const float4*)bias)[c8*2+1];
  const float dv = dinv[node];
  float o[8];
  o[0]=fmaxf(fmaf(acc[0]+sf[0],dv,b0.x),0.f); o[1]=fmaxf(fmaf(acc[1]+sf[1],dv,b0.y),0.f);
  o[2]=fmaxf(fmaf(acc[2]+sf[2],dv,b0.z),0.f); o[3]=fmaxf(fmaf(acc[3]+sf[3],dv,b0.w),0.f);
  o[4]=fmaxf(fmaf(acc[4]+sf[4],dv,b1.x),0.f); o[5]=fmaxf(fmaf(acc[5]+sf[5],dv,b1.y),0.f);
  o[6]=fmaxf(fmaf(acc[6]+sf[6],dv,b1.z),0.f); o[7]=fmaxf(fmaf(acc[7]+sf[7],dv,b1.w),0.f);
  uint4 w;
  w.x = (u32)f2bf(o[0]) | ((u32)f2bf(o[1])<<16);
  w.y = (u32)f2bf(o[2]) | ((u32)f2bf(o[3])<<16);
  w.z = (u32)f2bf(o[4]) | ((u32)f2bf(o[5])<<16);
  w.w = (u32)f2bf(o[6]) | ((u32)f2bf(o[7])<<16);
  return w;
}

// ---------------- GCN transform via MFMA (layer 1; W from prepped slab) ----------------
template<int KD, typename TIN>
__global__ __launch_bounds__(256) void transform_mfma(const TIN* __restrict__ X,
                                                      const u16* __restrict__ WG,
                                                      const float* __restrict__ dinv,
                                                      u16* __restrict__ Y, int n){
  constexpr int XLD = KD + 8;
  __shared__ u16 Xl[128*XLD];
  __shared__ float Dl[128];
  const int tid  = threadIdx.x;
  const int base = blockIdx.x*128;

  if (tid < 128){
    int nd = base + tid;
    Dl[tid] = (nd < n) ? dinv[nd] : 0.f;
  }
  if constexpr (sizeof(TIN)==4){
    #pragma unroll
    for (int j = 0; j < (128*KD)/1024; ++j){
      int e4   = tid + j*256;
      int elem = e4*4;
      int row  = elem / KD, k = elem % KD;
      int gn   = base + row;
      uint2 w2 = make_uint2(0u, 0u);
      if (gn < n){
        float4 v = ((const float4*)X)[(size_t)gn*(KD/4) + (k>>2)];
        w2.x = (u32)f2bf(v.x) | ((u32)f2bf(v.y)<<16);
        w2.y = (u32)f2bf(v.z) | ((u32)f2bf(v.w)<<16);
      }
      *((uint2*)&Xl[row*XLD + k]) = w2;
    }
  } else {
    #pragma unroll
    for (int j = 0; j < (128*KD)/1024; ++j){
      int e4   = tid + j*256;
      int elem = e4*4;
      int row  = elem / KD, k = elem % KD;
      int gn   = base + row;
      uint2 v = make_uint2(0u, 0u);
      if (gn < n) v = *((const uint2*)(X + (size_t)gn*KD + k));
      *((uint2*)&Xl[row*XLD + k]) = v;
    }
  }

  const int lane = tid & 63, wv = tid >> 6;
  const int c = lane & 15, g = lane >> 4;

  bfrag wf[KD/32][4];
  #pragma unroll
  for (int kk=0; kk<KD/32; ++kk)
    #pragma unroll
    for (int nt=0; nt<4; ++nt)
      wf[kk][nt] = *((const bfrag*)&WG[((kk*4+g)<<9) + ((nt*16+c)<<3)]);

  __syncthreads();                   // Xl ready

  f32x4 acc[2][4];
  #pragma unroll
  for (int rs=0;rs<2;++rs)
    #pragma unroll
    for (int nt=0;nt<4;++nt)
      acc[rs][nt] = (f32x4){0.f,0.f,0.f,0.f};

  #pragma unroll
  for (int kk=0; kk<KD/32; ++kk){
    bfrag a0 = *((const bfrag*)&Xl[(wv*32      + c)*XLD + kk*32 + g*8]);
    bfrag a1 = *((const bfrag*)&Xl[(wv*32 + 16 + c)*XLD + kk*32 + g*8]);
    #pragma unroll
    for (int nt=0; nt<4; ++nt){
      acc[0][nt] = __builtin_amdgcn_mfma_f32_16x16x32_bf16(a0, wf[kk][nt], acc[0][nt], 0,0,0);
      acc[1][nt] = __builtin_amdgcn_mfma_f32_16x16x32_bf16(a1, wf[kk][nt], acc[1][nt], 0,0,0);
    }
  }

  #pragma unroll
  for (int rs=0;rs<2;++rs){
    int nl0 = wv*32 + rs*16 + g*4;
    #pragma unroll
    for (int r=0;r<4;++r){
      int node = base + nl0 + r;
      if (node < n){
        float dv = Dl[nl0 + r];
        #pragma unroll
        for (int nt=0;nt<4;++nt)
          Y[(size_t)node*64 + nt*16 + c] = f2bf(acc[rs][nt][r] * dv);
      }
    }
  }
}

// ---------------- fused agg + transform (layers 2,3): gather -> LDS -> MFMA ----------------
// Phase A: each wave aggregates 8 nodes x 4 iters (block = 128 nodes), writing
// bf16 rows into Xl (same layout transform reads). Phase B: MFMA transform
// from the prepped W slab. bufH round trip eliminated.
__global__ __launch_bounds__(256) void fused_agg_transform(
    const u16* __restrict__ Hsrc, const float* __restrict__ dinv,
    const int* __restrict__ offs, const int* __restrict__ csr,
    const float* __restrict__ bias, const u16* __restrict__ WG,
    u16* __restrict__ Y, int n){
  constexpr int XLD = 72;
  __shared__ u16 Xl[128*XLD];
  __shared__ float Dl[128];
  const int tid  = threadIdx.x;
  const int base = blockIdx.x*128;
  const int lane = tid & 63, wv = tid >> 6;

  if (tid < 128){
    int nd = base + tid;
    Dl[tid] = (nd < n) ? dinv[nd] : 0.f;
  }

  // ---- phase A: aggregate this block's 128 nodes into Xl ----
  {
    const int s  = lane >> 3;
    const int c8 = lane & 7;
    const uint4* __restrict__ H = (const uint4*)Hsrc;
    #pragma unroll
    for (int it=0; it<4; ++it){
      int rl   = it*32 + wv*8 + s;
      int node = base + rl;
      uint4 w = make_uint4(0u,0u,0u,0u);
      if (node < n) w = agg_row(H, dinv, offs, csr, bias, node, c8);
      ((uint4*)&Xl[rl*XLD])[c8] = w;
    }
  }

  const int c = lane & 15, g = lane >> 4;
  bfrag wf[2][4];
  #pragma unroll
  for (int kk=0; kk<2; ++kk)
    #pragma unroll
    for (int nt=0; nt<4; ++nt)
      wf[kk][nt] = *((const bfrag*)&WG[((kk*4+g)<<9) + ((nt*16+c)<<3)]);

  __syncthreads();                   // Xl complete

  // ---- phase B: transform (K=64) ----
  f32x4 acc[2][4];
  #pragma unroll
  for (int rs=0;rs<2;++rs)
    #pragma unroll
    for (int nt=0;nt<4;++nt)
      acc[rs][nt] = (f32x4){0.f,0.f,0.f,0.f};

  #pragma unroll
  for (int kk=0; kk<2; ++kk){
    bfrag a0 = *((const bfrag*)&Xl[(wv*32      + c)*XLD + kk*32 + g*8]);
    bfrag a1 = *((const bfrag*)&Xl[(wv*32 + 16 + c)*XLD + kk*32 + g*8]);
    #pragma unroll
    for (int nt=0; nt<4; ++nt){
      acc[0][nt] = __builtin_amdgcn_mfma_f32_16x16x32_bf16(a0, wf[kk][nt], acc[0][nt], 0,0,0);
      acc[1][nt] = __builtin_amdgcn_mfma_f32_16x16x32_bf16(a1, wf[kk][nt], acc[1][nt], 0,0,0);
    }
  }

  #pragma unroll
  for (int rs=0;rs<2;++rs){
    int nl0 = wv*32 + rs*16 + g*4;
    #pragma unroll
    for (int r=0;r<4;++r){
      int node = base + nl0 + r;
      if (node < n){
        float dv = Dl[nl0 + r];
        #pragma unroll
        for (int nt=0;nt<4;++nt)
          Y[(size_t)node*64 + nt*16 + c] = f2bf(acc[rs][nt][r] * dv);
      }
    }
  }
}

// ---------------- fused agg(layer3) + LSTM x2 + heads ----------------
__global__ __launch_bounds__(256) void fused_tail(
    const u16* __restrict__ Hsrc, const float* __restrict__ dinv,
    const int* __restrict__ offs, const int* __restrict__ csr,
    const float* __restrict__ b3,
    const u16* __restrict__ wbuf, const float* __restrict__ bbuf,
    const float* __restrict__ bv1, const float* __restrict__ bv2,
    const float* __restrict__ bt1, const float* __restrict__ bt2,
    float* __restrict__ out, int n)
{
  const u16* W0hi = wbuf;
  const u16* W0lo = wbuf + 6144;
  const u16* W1g  = wbuf + 12288;
  const u16* WHg  = wbuf + 15360;
  const u16* BVg  = wbuf + 17408;
  const u16* BTg  = wbuf + 17920;

  __shared__ u16 XT[64*72];         // aggregated layer-3 H rows (bf16, padded)
  __shared__ u16 Hpool[5120];       // H1hi[0,2560) H1lo[2560,5120); H2 aliases
  __shared__ u16 VT[4608];          // 64 x 72: relu'd [v1|t1]
  __shared__ float b0l[96], b1l[96], bv1l[32], bt1l[32], bt2l[10];
  u16* H1hi = Hpool;  u16* H1lo = Hpool + 2560;
  u16* H2hi = Hpool;  u16* H2lo = Hpool + 2560;

  const int tid  = threadIdx.x;
  const int base = blockIdx.x*64;
  const int lane = tid & 63, wv = tid >> 6;

  if (tid < 96)            b0l[tid] = bbuf[tid];
  else if (tid < 192)      b1l[tid-96] = bbuf[tid];
  else if (tid < 224){ int d=tid-192; bv1l[d]=bv1[d]; }
  else               { int d=tid-224; bt1l[d]=bt1[d]; }
  if (tid < 10) bt2l[tid] = bt2[tid];

  // ---- phase A: aggregate this block's 64 nodes into XT ----
  {
    const int s  = lane >> 3;
    const int c8 = lane & 7;
    const uint4* __restrict__ H = (const uint4*)Hsrc;
    #pragma unroll
    for (int it=0; it<2; ++it){
      int rl   = it*32 + wv*8 + s;
      int node = base + rl;
      uint4 w = make_uint4(0u,0u,0u,0u);
      if (node < n) w = agg_row(H, dinv, offs, csr, b3, node, c8);
      ((uint4*)&XT[rl*72])[c8] = w;
    }
  }
  __syncthreads();                           // XT + biases ready

  const int c = lane & 15, g = lane >> 4;
  const float bv2v = bv2[0];

  // ---- lstm0: gates = X @ W0^T (K=64, 96 cols), A from XT ----
  {
    int rl0 = wv*16 + c;
    bfrag a0[2];
    a0[0] = *((const bfrag*)&XT[rl0*72      + g*8]);
    a0[1] = *((const bfrag*)&XT[rl0*72 + 32 + g*8]);
    f32x4 acc[6];
    #pragma unroll
    for (int nt=0;nt<6;++nt) acc[nt] = (f32x4){0.f,0.f,0.f,0.f};
    #pragma unroll
    for (int kk=0; kk<2; ++kk){
      #pragma unroll
      for (int nt=0; nt<6; ++nt){
        int widx = (kk*4+g)*768 + ((nt*16+c)<<3);
        bfrag bh = *((const bfrag*)&W0hi[widx]);
        bfrag bl = *((const bfrag*)&W0lo[widx]);
        acc[nt] = __builtin_amdgcn_mfma_f32_16x16x32_bf16(a0[kk], bh, acc[nt], 0,0,0);
        acc[nt] = __builtin_amdgcn_mfma_f32_16x16x32_bf16(a0[kk], bl, acc[nt], 0,0,0);
      }
    }
    #pragma unroll
    for (int r=0;r<4;++r){
      int rl = wv*16 + g*4 + r;
      #pragma unroll
      for (int half=0; half<2; ++half){
        float iv = acc[0+half][r] + b0l[half*16 + c];
        float gv = acc[2+half][r] + b0l[32 + half*16 + c];
        float ov = acc[4+half][r] + b0l[64 + half*16 + c];
        float cc = fast_sigmoid(iv) * fast_tanh(gv);
        float hv = fast_sigmoid(ov) * fast_tanh(cc);
        u16 hi = f2bf(hv);
        H1hi[rl*40 + half*16 + c] = hi;
        H1lo[rl*40 + half*16 + c] = f2bf(hv - bf2f(hi));
      }
    }
  }
  __syncthreads();                           // H1 visible

  // ---- lstm1: gates = H1 @ W1^T (K=32, 96 cols), A-split 2-term ----
  {
    bfrag w1f[6];
    #pragma unroll
    for (int nt=0; nt<6; ++nt)
      w1f[nt] = *((const bfrag*)&W1g[g*768 + ((nt*16+c)<<3)]);
    bfrag ah = *((const bfrag*)&H1hi[(wv*16 + c)*40 + g*8]);
    bfrag al = *((const bfrag*)&H1lo[(wv*16 + c)*40 + g*8]);
    f32x4 acc[6];
    #pragma unroll
    for (int nt=0;nt<6;++nt) acc[nt] = (f32x4){0.f,0.f,0.f,0.f};
    #pragma unroll
    for (int nt=0; nt<6; ++nt){
      acc[nt] = __builtin_amdgcn_mfma_f32_16x16x32_bf16(ah, w1f[nt], acc[nt], 0,0,0);
      acc[nt] = __builtin_amdgcn_mfma_f32_16x16x32_bf16(al, w1f[nt], acc[nt], 0,0,0);
    }
    __syncthreads();                         // all H1 reads complete before H2 overwrite
    #pragma unroll
    for (int r=0;r<4;++r){
      int rl = wv*16 + g*4 + r;
      #pragma unroll
      for (int half=0; half<2; ++half){
        float iv = acc[0+half][r] + b1l[half*16 + c];
        float gv = acc[2+half][r] + b1l[32 + half*16 + c];
        float ov = acc[4+half][r] + b1l[64 + half*16 + c];
        float cc = fast_sigmoid(iv) * fast_tanh(gv);
        float hv = fast_sigmoid(ov) * fast_tanh(cc);
        u16 hi = f2bf(hv);
        H2hi[rl*40 + half*16 + c] = hi;
        H2lo[rl*40 + half*16 + c] = f2bf(hv - bf2f(hi));
      }
    }
  }
  __syncthreads();                           // H2 visible

  // ---- heads p1: [v1|t1] = relu(H2 @ [Wv1|Wt1] + b) -> VT (bf16) ----
  {
    bfrag whf[4];
    #pragma unroll
    for (int nt=0; nt<4; ++nt)
      whf[nt] = *((const bfrag*)&WHg[g*512 + ((nt*16+c)<<3)]);
    bfrag ah = *((const bfrag*)&H2hi[(wv*16 + c)*40 + g*8]);
    bfrag al = *((const bfrag*)&H2lo[(wv*16 + c)*40 + g*8]);
    f32x4 acc[4];
    #pragma unroll
    for (int nt=0;nt<4;++nt) acc[nt] = (f32x4){0.f,0.f,0.f,0.f};
    #pragma unroll
    for (int nt=0; nt<4; ++nt){
      acc[nt] = __builtin_amdgcn_mfma_f32_16x16x32_bf16(ah, whf[nt], acc[nt], 0,0,0);
      acc[nt] = __builtin_amdgcn_mfma_f32_16x16x32_bf16(al, whf[nt], acc[nt], 0,0,0);
    }
    #pragma unroll
    for (int r=0;r<4;++r){
      int rl = wv*16 + g*4 + r;
      VT[rl*72      + c] = f2bf(fmaxf(acc[0][r] + bv1l[c],    0.f));
      VT[rl*72 + 16 + c] = f2bf(fmaxf(acc[1][r] + bv1l[c+16], 0.f));
      VT[rl*72 + 32 + c] = f2bf(fmaxf(acc[2][r] + bt1l[c],    0.f));
      VT[rl*72 + 48 + c] = f2bf(fmaxf(acc[3][r] + bt1l[c+16], 0.f));
    }
  }
  __syncthreads();                           // VT visible

  // ---- heads p2: vol = v1 @ Wv2, type = t1 @ Wt2 via MFMA, direct C-write ----
  {
    bfrag av = *((const bfrag*)&VT[(wv*16 + c)*72      + g*8]);
    bfrag at = *((const bfrag*)&VT[(wv*16 + c)*72 + 32 + g*8]);
    bfrag bv = *((const bfrag*)(BVg + lane*8));
    bfrag bt = *((const bfrag*)(BTg + lane*8));
    f32x4 accv = (f32x4){0.f,0.f,0.f,0.f};
    f32x4 acct = (f32x4){0.f,0.f,0.f,0.f};
    accv = __builtin_amdgcn_mfma_f32_16x16x32_bf16(av, bv, accv, 0,0,0);
    acct = __builtin_amdgcn_mfma_f32_16x16x32_bf16(at, bt, acct, 0,0,0);
    #pragma unroll
    for (int r=0;r<4;++r){
      int node = base + wv*16 + g*4 + r;
      if (node < n){
        if (c == 0)  out[node] = accv[r] + bv2v;
        if (c < 10)  out[n + (size_t)node*10 + c] = acct[r] + bt2l[c];
      }
    }
  }
}

extern "C" void kernel_launch(void* const* d_in, const int* in_sizes, int n_in,
                              void* d_out, int out_size, void* d_ws, size_t ws_size,
                              hipStream_t stream){
  const float* x    = (const float*)d_in[0];
  const int*   ei   = (const int*)  d_in[1];
  const float* W1   = (const float*)d_in[2];  const float* b1   = (const float*)d_in[3];
  const float* W2   = (const float*)d_in[4];  const float* b2   = (const float*)d_in[5];
  const float* W3   = (const float*)d_in[6];  const float* b3   = (const float*)d_in[7];
  const float* Wih0 = (const float*)d_in[8];
  const float* bih0 = (const float*)d_in[10]; const float* bhh0 = (const float*)d_in[11];
  const float* Wih1 = (const float*)d_in[12];
  const float* bih1 = (const float*)d_in[14]; const float* bhh1 = (const float*)d_in[15];
  const float* Wv1  = (const float*)d_in[16]; const float* bv1  = (const float*)d_in[17];
  const float* Wv2  = (const float*)d_in[18]; const float* bv2  = (const float*)d_in[19];
  const float* Wt1  = (const float*)d_in[20]; const float* bt1  = (const float*)d_in[21];
  const float* Wt2  = (const float*)d_in[22]; const float* bt2  = (const float*)d_in[23];

  const int N  = in_sizes[0] / 128;
  const int E  = in_sizes[1] / 2;
  const int NB = (N + 1023) / 1024;
  const int EB = (E + 8191) / 8192;

  char* w = (char*)d_ws;
  auto take = [&](size_t bytes)->char*{ char* p = w; w += (bytes + 255) & ~(size_t)255; return p; };
  int*   deg    = (int*)  take((size_t)N*4);          // fallback only
  int*   offs   = (int*)  take((size_t)(N+1)*4);
  int*   cursor = (int*)  take((size_t)N*4);          // fallback only
  int*   csr    = (int*)  take((size_t)E*4);
  float* dinv   = (float*)take((size_t)N*4);
  int*   bsums  = (int*)  take((size_t)NB*4);         // fallback only
  int*   boffs  = (int*)  take((size_t)NB*4);         // fallback only
  int*   bhist  = (int*)  take((size_t)MAXBK*4);
  int*   bcur   = (int*)  take((size_t)MAXBK*4);
  int*   bstart = (int*)  take((size_t)(MAXBK+1)*4);
  u32*   packed = (u32*)  take((size_t)E*4);
  u16*   wbuf   = (u16*)  take((size_t)18432*2);      // prepped tail weights + BV/BT frags
  float* bbuf   = (float*)take((size_t)192*4);        // prepped tail biases
  u16*   wgcn   = (u16*)  take((size_t)16384*2);      // prepped GCN weights (bf16 subtiled)
  u16*   bufA   = (u16*)  take((size_t)N*64*2);       // pre-agg Hts ping
  u16*   bufB   = (u16*)  take((size_t)N*64*2);       // pre-agg Hts pong
  (void)ws_size; (void)n_in; (void)out_size;

  // --- run-once weight prep (also zeroes bhist) ---
  prep_tail_kernel<<<115, 256, 0, stream>>>(Wih0, Wih1, Wv1, Wt1, Wv2, Wt2,
                                            bih0, bhh0, bih1, bhh1,
                                            W1, W2, W3,
                                            wbuf, bbuf, wgcn, bhist);

  // --- CSR build ---
  if (N <= MAXBK*256){
    const int NBK = (N + 255) / 256;
    bucket_hist_kernel    <<<EB,  512, 0, stream>>>(ei + E, bhist, E);
    bucket_scan_kernel    <<<1,   512, 0, stream>>>(bhist, bcur, bstart);
    bin_kernel            <<<EB,  512, 0, stream>>>(ei, ei + E, bcur, packed, E);
    bucket_finalize_kernel<<<NBK, 512, 0, stream>>>(packed, bstart, offs, dinv, csr, N, E);
  } else {
    hipMemsetAsync(deg, 0, (size_t)N*4, stream);
    count_kernel      <<<(E+255)/256, 256, 0, stream>>>(ei + E, deg, E);
    scan_reduce_kernel<<<NB,          256, 0, stream>>>(deg, bsums, N);
    scan_block_kernel <<<1,           128, 0, stream>>>(bsums, boffs, NB);
    scan_final_kernel <<<NB,          256, 0, stream>>>(deg, boffs, offs, N, E);
    dinv_kernel       <<<(N+255)/256, 256, 0, stream>>>(deg, offs, cursor, dinv, N);
    fill_kernel       <<<(E+255)/256, 256, 0, stream>>>(ei, cursor, csr, E);
  }

  // --- GCN + tail (agg fused into consumers) ---
  const int TB  = (N + 127) / 128;
  const int TB2 = (N + 63) / 64;
  transform_mfma<128,float><<<TB, 256, 0, stream>>>(x, wgcn, dinv, bufA, N);
  fused_agg_transform<<<TB, 256, 0, stream>>>(bufA, dinv, offs, csr, b1,
                                              wgcn + 8192,  bufB, N);
  fused_agg_transform<<<TB, 256, 0, stream>>>(bufB, dinv, offs, csr, b2,
                                              wgcn + 12288, bufA, N);
  fused_tail<<<TB2, 256, 0, stream>>>(bufA, dinv, offs, csr, b3,
                                      wbuf, bbuf, bv1, bv2, bt1, bt2,
                                      (float*)d_out, N);
}

// Round 15
// 188.775 us; speedup vs baseline: 5.0664x; 1.0053x over previous
//
#include <hip/hip_runtime.h>
#include <math.h>

// TemporalWasteGNN: 3x GCNConv (symmetric-norm, self-loops) -> 2x LSTM(seq=1, h0=c0=0)
// -> two MLP heads. fp32 I/O, bf16 intermediate features.
//
// R15: tail fusion reverted (R14 post-mortem: fused_tail = 60us > unfused 45+4;
//      serial per-block gather starved the tail phases at 36% occ). Layer-3
//      agg back to standalone 4-deep pipelined agg_kernel; tail reads global.
//      fused_agg_transform for layers 2/3 RETAINED (that fusion won).
// R10 packed CSR build, R12 pipelined gather, R13 prepped GCN slab, R7 native
// transcendentals, R8/R9 zero-shuffle tail math — all retained.

typedef unsigned int  u32;
typedef unsigned short u16;
typedef short bfrag  __attribute__((ext_vector_type(8)));   // 8 bf16 (4 VGPRs)
typedef float f32x4  __attribute__((ext_vector_type(4)));

#define LOG2E 1.44269504088896f
static __device__ __forceinline__ float fast_sigmoid(float x){
  float t = __builtin_amdgcn_exp2f(-x * LOG2E);
  return __builtin_amdgcn_rcpf(1.f + t);
}
static __device__ __forceinline__ float fast_tanh(float x){
  float t = __builtin_amdgcn_exp2f(x * (2.f * LOG2E));
  return 1.f - 2.f * __builtin_amdgcn_rcpf(t + 1.f);
}
static __device__ __forceinline__ float bf2f(u16 u){ return __uint_as_float(((u32)u)<<16); }
static __device__ __forceinline__ u16   f2bf(float f){
  u32 x = __float_as_uint(f);
  return (u16)((x + 0x7fffu + ((x>>16)&1u)) >> 16);   // round-to-nearest-even
}

#define MAXBK 512   // buckets of 256 dst nodes; N <= 131072 (src must fit 24 bits)

// ---------------- bucketed CSR build ----------------
__global__ __launch_bounds__(512) void bucket_hist_kernel(const int* __restrict__ dstA,
                                                          int* __restrict__ bhist, int E){
  __shared__ int h[MAXBK];
  for (int i=threadIdx.x; i<MAXBK; i+=512) h[i]=0;
  __syncthreads();
  const int base = blockIdx.x*8192;
  #pragma unroll
  for (int j=0;j<16;++j){
    int e = base + j*512 + threadIdx.x;
    if (e < E) atomicAdd(&h[dstA[e]>>8], 1);
  }
  __syncthreads();
  for (int i=threadIdx.x; i<MAXBK; i+=512) if (h[i]) atomicAdd(&bhist[i], h[i]);
}

__global__ __launch_bounds__(512) void bucket_scan_kernel(const int* __restrict__ bhist,
                                                          int* __restrict__ bcur,
                                                          int* __restrict__ bstart){
  __shared__ int ts[MAXBK];
  int v = bhist[threadIdx.x];
  ts[threadIdx.x] = v; __syncthreads();
  for (int off=1; off<MAXBK; off<<=1){
    int t = (threadIdx.x>=off) ? ts[threadIdx.x-off] : 0;
    __syncthreads();
    ts[threadIdx.x] += t;
    __syncthreads();
  }
  int ex = ts[threadIdx.x] - v;
  bcur[threadIdx.x]   = ex;
  bstart[threadIdx.x] = ex;
  if (threadIdx.x == MAXBK-1) bstart[MAXBK] = ts[threadIdx.x];   // = E
}

__global__ __launch_bounds__(512) void bin_kernel(const int* __restrict__ srcA,
                                                  const int* __restrict__ dstA,
                                                  int* __restrict__ bcur,
                                                  u32* __restrict__ packed, int E){
  __shared__ int h[MAXBK];
  __shared__ int basev[MAXBK];
  for (int i=threadIdx.x; i<MAXBK; i+=512) h[i]=0;
  __syncthreads();
  const int base = blockIdx.x*8192;
  int br[16]; int dv[16];
  #pragma unroll
  for (int j=0;j<16;++j){
    int e = base + j*512 + threadIdx.x;
    if (e < E){
      int d = dstA[e]; int b = d>>8;
      int r = atomicAdd(&h[b], 1);
      br[j] = (b<<16) | r;                 // b<512 (9b) | r<8192 (13b)
      dv[j] = d;
    } else br[j] = -1;
  }
  __syncthreads();
  for (int i=threadIdx.x; i<MAXBK; i+=512){
    int c = h[i];
    basev[i] = c ? atomicAdd(&bcur[i], c) : 0;
  }
  __syncthreads();
  #pragma unroll
  for (int j=0;j<16;++j){
    if (br[j] >= 0){
      int e = base + j*512 + threadIdx.x;
      int pos = basev[br[j]>>16] + (br[j] & 0xffff);
      packed[pos] = (u32)srcA[e] | ((u32)(dv[j] & 255) << 24);
    }
  }
}

__global__ __launch_bounds__(512) void bucket_finalize_kernel(
    const u32* __restrict__ packed, const int* __restrict__ bstart,
    int* __restrict__ offs, float* __restrict__ dinv,
    int* __restrict__ csr, int n, int E){
  __shared__ int cnt[256];
  __shared__ int sc[256];
  __shared__ int cur[256];
  const int b = blockIdx.x;
  const int start = bstart[b], end = bstart[b+1];
  for (int i=threadIdx.x; i<256; i+=512){ cnt[i]=0; cur[i]=0; }
  __syncthreads();
  for (int e = start + threadIdx.x; e < end; e += 512)
    atomicAdd(&cnt[packed[e] >> 24], 1);
  __syncthreads();
  if (threadIdx.x < 256) sc[threadIdx.x] = cnt[threadIdx.x];
  __syncthreads();
  for (int off=1; off<256; off<<=1){
    int t = 0;
    if (threadIdx.x < 256 && threadIdx.x >= off) t = sc[threadIdx.x-off];
    __syncthreads();
    if (threadIdx.x < 256) sc[threadIdx.x] += t;
    __syncthreads();
  }
  if (threadIdx.x < 256){
    int ex = sc[threadIdx.x] - cnt[threadIdx.x];      // exclusive
    sc[threadIdx.x] = ex;
    int node = b*256 + threadIdx.x;
    if (node < n){
      offs[node] = start + ex;
      dinv[node] = rsqrtf((float)(cnt[threadIdx.x] + 1));
    }
  }
  if (b == 0 && threadIdx.x == 0) offs[n] = E;
  __syncthreads();
  for (int e = start + threadIdx.x; e < end; e += 512){
    u32 v = packed[e];
    int loc = v >> 24;
    int pos = start + sc[loc] + atomicAdd(&cur[loc], 1);
    csr[pos] = (int)(v & 0xFFFFFFu);
  }
}

// fallback (N too large for bucketing) -------------
__global__ void count_kernel(const int* __restrict__ dsts, int* __restrict__ deg, int E){
  int e = blockIdx.x*256 + threadIdx.x;
  if (e < E) atomicAdd(&deg[dsts[e]], 1);
}
__global__ void fill_kernel(const int* __restrict__ ei, int* __restrict__ cursor,
                            int* __restrict__ csr, int E){
  int e = blockIdx.x*256 + threadIdx.x;
  if (e < E){
    int d = ei[E + e];
    int pos = atomicAdd(&cursor[d], 1);
    csr[pos] = ei[e];
  }
}

__global__ void scan_reduce_kernel(const int* __restrict__ deg, int* __restrict__ bsums, int n){
  __shared__ int sd[256];
  int base = blockIdx.x*1024 + threadIdx.x*4;
  int s = 0;
  #pragma unroll
  for (int j=0;j<4;++j){ int idx=base+j; if (idx<n) s += deg[idx]; }
  sd[threadIdx.x] = s; __syncthreads();
  for (int off=128; off>0; off>>=1){
    if (threadIdx.x < off) sd[threadIdx.x] += sd[threadIdx.x+off];
    __syncthreads();
  }
  if (threadIdx.x==0) bsums[blockIdx.x] = sd[0];
}

__global__ void scan_block_kernel(const int* __restrict__ bsums, int* __restrict__ boffs, int nb){
  __shared__ int ts[128];
  if (nb <= 128){
    int v = (threadIdx.x < nb) ? bsums[threadIdx.x] : 0;
    ts[threadIdx.x] = v; __syncthreads();
    for (int off=1; off<128; off<<=1){
      int t = (threadIdx.x>=off) ? ts[threadIdx.x-off] : 0;
      __syncthreads();
      ts[threadIdx.x] += t;
      __syncthreads();
    }
    if (threadIdx.x < nb) boffs[threadIdx.x] = ts[threadIdx.x] - v;
  } else if (threadIdx.x==0){
    int run=0;
    for (int b=0;b<nb;++b){ int t=bsums[b]; boffs[b]=run; run+=t; }
  }
}

__global__ void scan_final_kernel(const int* __restrict__ deg, const int* __restrict__ boffs,
                                  int* __restrict__ offs, int n, int E){
  __shared__ int ts[256];
  int base = blockIdx.x*1024 + threadIdx.x*4;
  int v[4]; int s=0;
  #pragma unroll
  for (int j=0;j<4;++j){ int idx=base+j; v[j] = (idx<n) ? deg[idx] : 0; s += v[j]; }
  ts[threadIdx.x] = s; __syncthreads();
  for (int off=1; off<256; off<<=1){
    int t = (threadIdx.x>=off) ? ts[threadIdx.x-off] : 0;
    __syncthreads();
    ts[threadIdx.x] += t;
    __syncthreads();
  }
  int excl = boffs[blockIdx.x] + (threadIdx.x ? ts[threadIdx.x-1] : 0);
  #pragma unroll
  for (int j=0;j<4;++j){ int idx=base+j; if (idx<n){ offs[idx]=excl; excl+=v[j]; } }
  if (blockIdx.x==0 && threadIdx.x==0) offs[n] = E;
}

__global__ void dinv_kernel(const int* __restrict__ deg, const int* __restrict__ offs,
                            int* __restrict__ cursor, float* __restrict__ dinv, int n){
  int i = blockIdx.x*256 + threadIdx.x;
  if (i < n){
    dinv[i] = rsqrtf((float)(deg[i] + 1));
    cursor[i] = offs[i];
  }
}

// ---------------- run-once weight prep (tail + GCN) ----------------
__global__ void prep_tail_kernel(const float* __restrict__ Wih0, const float* __restrict__ Wih1,
                                 const float* __restrict__ Wv1,  const float* __restrict__ Wt1,
                                 const float* __restrict__ Wv2,  const float* __restrict__ Wt2,
                                 const float* __restrict__ bih0, const float* __restrict__ bhh0,
                                 const float* __restrict__ bih1, const float* __restrict__ bhh1,
                                 const float* __restrict__ Wg1,  const float* __restrict__ Wg2,
                                 const float* __restrict__ Wg3,
                                 u16* __restrict__ wbuf, float* __restrict__ bbuf,
                                 u16* __restrict__ wgcn, int* __restrict__ bhist){
  int tid = blockIdx.x*256 + threadIdx.x;
  if (tid < 6144){                                  // Wih0 hi/lo, [k/8][96][8]
    int kg = tid / 768, rem = tid % 768;
    int j = rem >> 3, k = kg*8 + (rem & 7);
    int row = (j < 32) ? j : j + 32;
    float w = Wih0[row*64 + k];
    u16 hi = f2bf(w);
    wbuf[tid] = hi;
    wbuf[6144 + tid] = f2bf(w - bf2f(hi));
  } else if (tid < 9216){                           // Wih1, [k/8][96][8]
    int t = tid - 6144;
    int kg = t / 768, rem = t % 768;
    int j = rem >> 3, k = kg*8 + (rem & 7);
    int row = (j < 32) ? j : j + 32;
    wbuf[12288 + t] = f2bf(Wih1[row*32 + k]);
  } else if (tid < 11264){                          // Wv1|Wt1, [k/8][64][8]
    int t = tid - 9216;
    int kg = t / 512, rem = t % 512;
    int j = rem >> 3, k = kg*8 + (rem & 7);
    float v = (j < 32) ? Wv1[k*32 + j] : Wt1[k*32 + (j-32)];
    wbuf[15360 + t] = f2bf(v);
  } else if (tid < 11360){                          // b0 (i,g,o combined)
    int t = tid - 11264;
    int row = (t < 32) ? t : t + 32;
    bbuf[t] = bih0[row] + bhh0[row];
  } else if (tid < 11456){                          // b1
    int t = tid - 11360;
    int row = (t < 32) ? t : t + 32;
    bbuf[96 + t] = bih1[row] + bhh1[row];
  } else if (tid < 12480){                          // BV/BT lane fragments (K=32)
    int t = tid - 11456;
    int slab = t >> 9, within = t & 511;
    int lane = within >> 3, j = within & 7;
    int cc = lane & 15, gg = lane >> 4;
    float v;
    if (slab == 0) v = (cc == 0) ? Wv2[gg*8 + j] : 0.f;
    else           v = (cc < 10) ? Wt2[(gg*8 + j)*10 + cc] : 0.f;
    wbuf[17408 + slab*512 + within] = f2bf(v);
  } else if (tid < 12992){                          // zero bhist
    bhist[tid - 12480] = 0;
  } else if (tid < 21184){                          // W1 (128x64) -> G1
    int t = tid - 12992;
    int kg = t >> 9, rem = t & 511;
    int j = rem >> 3, k = kg*8 + (rem & 7);
    wgcn[t] = f2bf(Wg1[k*64 + j]);
  } else if (tid < 25280){                          // W2 (64x64) -> G2
    int t = tid - 21184;
    int kg = t >> 9, rem = t & 511;
    int j = rem >> 3, k = kg*8 + (rem & 7);
    wgcn[8192 + t] = f2bf(Wg2[k*64 + j]);
  } else if (tid < 29376){                          // W3 (64x64) -> G3
    int t = tid - 25280;
    int kg = t >> 9, rem = t & 511;
    int j = rem >> 3, k = kg*8 + (rem & 7);
    wgcn[12288 + t] = f2bf(Wg3[k*64 + j]);
  }
}

// ---------------- gather-agg helper: acc over adjacency, 4-deep pipelined ----------------
static __device__ __forceinline__ uint4 agg_row(const uint4* __restrict__ H,
                                                const float* __restrict__ dinv,
                                                const int* __restrict__ offs,
                                                const int* __restrict__ csr,
                                                const float* __restrict__ bias,
                                                int node, int c8){
  float acc[8];
  #pragma unroll
  for (int i=0;i<8;++i) acc[i]=0.f;
  const int beg = offs[node], end = offs[node+1];
  #define ACC8(v) do{ \
    acc[0] += __uint_as_float((v).x<<16); acc[1] += __uint_as_float((v).x & 0xffff0000u); \
    acc[2] += __uint_as_float((v).y<<16); acc[3] += __uint_as_float((v).y & 0xffff0000u); \
    acc[4] += __uint_as_float((v).z<<16); acc[5] += __uint_as_float((v).z & 0xffff0000u); \
    acc[6] += __uint_as_float((v).w<<16); acc[7] += __uint_as_float((v).w & 0xffff0000u); }while(0)
  int j = beg;
  for (; j + 4 <= end; j += 4){
    int s0 = csr[j], s1 = csr[j+1], s2 = csr[j+2], s3 = csr[j+3];
    uint4 v0 = H[(size_t)s0*8 + c8];
    uint4 v1 = H[(size_t)s1*8 + c8];
    uint4 v2 = H[(size_t)s2*8 + c8];
    uint4 v3 = H[(size_t)s3*8 + c8];
    ACC8(v0); ACC8(v1); ACC8(v2); ACC8(v3);
  }
  for (; j < end; ++j){
    int src = csr[j];
    uint4 v = H[(size_t)src*8 + c8];
    ACC8(v);
  }
  #undef ACC8
  uint4 sv = H[(size_t)node*8 + c8];       // self-loop (already * dinv[node])
  float sf[8];
  sf[0]=__uint_as_float(sv.x<<16); sf[1]=__uint_as_float(sv.x & 0xffff0000u);
  sf[2]=__uint_as_float(sv.y<<16); sf[3]=__uint_as_float(sv.y & 0xffff0000u);
  sf[4]=__uint_as_float(sv.z<<16); sf[5]=__uint_as_float(sv.z & 0xffff0000u);
  sf[6]=__uint_as_float(sv.w<<16); sf[7]=__uint_as_float(sv.w & 0xffff0000u);
  float4 b0 = ((const float4*)bias)[c8*2];
  float4 b1 = ((const float4*)bias)[c8*2+1];
  const float dv = dinv[node];
  float o[8];
  o[0]=fmaxf(fmaf(acc[0]+sf[0],dv,b0.x),0.f); o[1]=fmaxf(fmaf(acc[1]+sf[1],dv,b0.y),0.f);
  o[2]=fmaxf(fmaf(acc[2]+sf[2],dv,b0.z),0.f); o[3]=fmaxf(fmaf(acc[3]+sf[3],dv,b0.w),0.f);
  o[4]=fmaxf(fmaf(acc[4]+sf[4],dv,b1.x),0.f); o[5]=fmaxf(fmaf(acc[5]+sf[5],dv,b1.y),0.f);
  o[6]=fmaxf(fmaf(acc[6]+sf[6],dv,b1.z),0.f); o[7]=fmaxf(fmaf(acc[7]+sf[7],dv,b1.w),0.f);
  uint4 w;
  w.x = (u32)f2bf(o[0]) | ((u32)f2bf(o[1])<<16);
  w.y = (u32)f2bf(o[2]) | ((u32)f2bf(o[3])<<16);
  w.z = (u32)f2bf(o[4]) | ((u32)f2bf(o[5])<<16);
  w.w = (u32)f2bf(o[6]) | ((u32)f2bf(o[7])<<16);
  return w;
}

// ---------------- standalone agg (layer 3): 8 nodes/wave, 4-deep pipelined ----------------
__global__ void agg_kernel(const u16* __restrict__ Hts, const float* __restrict__ dinv,
                           const int* __restrict__ offs, const int* __restrict__ csr,
                           const float* __restrict__ bias, u16* __restrict__ Hout, int n){
  const int lane = threadIdx.x & 63;
  const int wv   = threadIdx.x >> 6;
  const int s    = lane >> 3;
  const int c8   = lane & 7;
  const int node = blockIdx.x*32 + wv*8 + s;
  if (node >= n) return;
  const uint4* __restrict__ H = (const uint4*)Hts;
  uint4 w = agg_row(H, dinv, offs, csr, bias, node, c8);
  ((uint4*)Hout)[(size_t)node*8 + c8] = w;
}

// ---------------- GCN transform via MFMA (layer 1; W from prepped slab) ----------------
template<int KD, typename TIN>
__global__ __launch_bounds__(256) void transform_mfma(const TIN* __restrict__ X,
                                                      const u16* __restrict__ WG,
                                                      const float* __restrict__ dinv,
                                                      u16* __restrict__ Y, int n){
  constexpr int XLD = KD + 8;
  __shared__ u16 Xl[128*XLD];
  __shared__ float Dl[128];
  const int tid  = threadIdx.x;
  const int base = blockIdx.x*128;

  if (tid < 128){
    int nd = base + tid;
    Dl[tid] = (nd < n) ? dinv[nd] : 0.f;
  }
  if constexpr (sizeof(TIN)==4){
    #pragma unroll
    for (int j = 0; j < (128*KD)/1024; ++j){
      int e4   = tid + j*256;
      int elem = e4*4;
      int row  = elem / KD, k = elem % KD;
      int gn   = base + row;
      uint2 w2 = make_uint2(0u, 0u);
      if (gn < n){
        float4 v = ((const float4*)X)[(size_t)gn*(KD/4) + (k>>2)];
        w2.x = (u32)f2bf(v.x) | ((u32)f2bf(v.y)<<16);
        w2.y = (u32)f2bf(v.z) | ((u32)f2bf(v.w)<<16);
      }
      *((uint2*)&Xl[row*XLD + k]) = w2;
    }
  } else {
    #pragma unroll
    for (int j = 0; j < (128*KD)/1024; ++j){
      int e4   = tid + j*256;
      int elem = e4*4;
      int row  = elem / KD, k = elem % KD;
      int gn   = base + row;
      uint2 v = make_uint2(0u, 0u);
      if (gn < n) v = *((const uint2*)(X + (size_t)gn*KD + k));
      *((uint2*)&Xl[row*XLD + k]) = v;
    }
  }

  const int lane = tid & 63, wv = tid >> 6;
  const int c = lane & 15, g = lane >> 4;

  bfrag wf[KD/32][4];
  #pragma unroll
  for (int kk=0; kk<KD/32; ++kk)
    #pragma unroll
    for (int nt=0; nt<4; ++nt)
      wf[kk][nt] = *((const bfrag*)&WG[((kk*4+g)<<9) + ((nt*16+c)<<3)]);

  __syncthreads();                   // Xl ready

  f32x4 acc[2][4];
  #pragma unroll
  for (int rs=0;rs<2;++rs)
    #pragma unroll
    for (int nt=0;nt<4;++nt)
      acc[rs][nt] = (f32x4){0.f,0.f,0.f,0.f};

  #pragma unroll
  for (int kk=0; kk<KD/32; ++kk){
    bfrag a0 = *((const bfrag*)&Xl[(wv*32      + c)*XLD + kk*32 + g*8]);
    bfrag a1 = *((const bfrag*)&Xl[(wv*32 + 16 + c)*XLD + kk*32 + g*8]);
    #pragma unroll
    for (int nt=0; nt<4; ++nt){
      acc[0][nt] = __builtin_amdgcn_mfma_f32_16x16x32_bf16(a0, wf[kk][nt], acc[0][nt], 0,0,0);
      acc[1][nt] = __builtin_amdgcn_mfma_f32_16x16x32_bf16(a1, wf[kk][nt], acc[1][nt], 0,0,0);
    }
  }

  #pragma unroll
  for (int rs=0;rs<2;++rs){
    int nl0 = wv*32 + rs*16 + g*4;
    #pragma unroll
    for (int r=0;r<4;++r){
      int node = base + nl0 + r;
      if (node < n){
        float dv = Dl[nl0 + r];
        #pragma unroll
        for (int nt=0;nt<4;++nt)
          Y[(size_t)node*64 + nt*16 + c] = f2bf(acc[rs][nt][r] * dv);
      }
    }
  }
}

// ---------------- fused agg + transform (layers 2,3 input): gather -> LDS -> MFMA ----------------
__global__ __launch_bounds__(256) void fused_agg_transform(
    const u16* __restrict__ Hsrc, const float* __restrict__ dinv,
    const int* __restrict__ offs, const int* __restrict__ csr,
    const float* __restrict__ bias, const u16* __restrict__ WG,
    u16* __restrict__ Y, int n){
  constexpr int XLD = 72;
  __shared__ u16 Xl[128*XLD];
  __shared__ float Dl[128];
  const int tid  = threadIdx.x;
  const int base = blockIdx.x*128;
  const int lane = tid & 63, wv = tid >> 6;

  if (tid < 128){
    int nd = base + tid;
    Dl[tid] = (nd < n) ? dinv[nd] : 0.f;
  }

  // ---- phase A: aggregate this block's 128 nodes into Xl ----
  {
    const int s  = lane >> 3;
    const int c8 = lane & 7;
    const uint4* __restrict__ H = (const uint4*)Hsrc;
    #pragma unroll
    for (int it=0; it<4; ++it){
      int rl   = it*32 + wv*8 + s;
      int node = base + rl;
      uint4 w = make_uint4(0u,0u,0u,0u);
      if (node < n) w = agg_row(H, dinv, offs, csr, bias, node, c8);
      ((uint4*)&Xl[rl*XLD])[c8] = w;
    }
  }

  const int c = lane & 15, g = lane >> 4;
  bfrag wf[2][4];
  #pragma unroll
  for (int kk=0; kk<2; ++kk)
    #pragma unroll
    for (int nt=0; nt<4; ++nt)
      wf[kk][nt] = *((const bfrag*)&WG[((kk*4+g)<<9) + ((nt*16+c)<<3)]);

  __syncthreads();                   // Xl complete

  f32x4 acc[2][4];
  #pragma unroll
  for (int rs=0;rs<2;++rs)
    #pragma unroll
    for (int nt=0;nt<4;++nt)
      acc[rs][nt] = (f32x4){0.f,0.f,0.f,0.f};

  #pragma unroll
  for (int kk=0; kk<2; ++kk){
    bfrag a0 = *((const bfrag*)&Xl[(wv*32      + c)*XLD + kk*32 + g*8]);
    bfrag a1 = *((const bfrag*)&Xl[(wv*32 + 16 + c)*XLD + kk*32 + g*8]);
    #pragma unroll
    for (int nt=0; nt<4; ++nt){
      acc[0][nt] = __builtin_amdgcn_mfma_f32_16x16x32_bf16(a0, wf[kk][nt], acc[0][nt], 0,0,0);
      acc[1][nt] = __builtin_amdgcn_mfma_f32_16x16x32_bf16(a1, wf[kk][nt], acc[1][nt], 0,0,0);
    }
  }

  #pragma unroll
  for (int rs=0;rs<2;++rs){
    int nl0 = wv*32 + rs*16 + g*4;
    #pragma unroll
    for (int r=0;r<4;++r){
      int node = base + nl0 + r;
      if (node < n){
        float dv = Dl[nl0 + r];
        #pragma unroll
        for (int nt=0;nt<4;++nt)
          Y[(size_t)node*64 + nt*16 + c] = f2bf(acc[rs][nt][r] * dv);
      }
    }
  }
}

// ---------------- Fused LSTM x2 + heads: 16 rows/wave, zero shuffles (R13, verified) ----------------
__global__ __launch_bounds__(256) void lstm_heads_fused(
    const u16* __restrict__ X,
    const u16* __restrict__ wbuf, const float* __restrict__ bbuf,
    const float* __restrict__ bv1, const float* __restrict__ bv2,
    const float* __restrict__ bt1, const float* __restrict__ bt2,
    float* __restrict__ out, int n)
{
  const u16* W0hi = wbuf;
  const u16* W0lo = wbuf + 6144;
  const u16* W1g  = wbuf + 12288;
  const u16* WHg  = wbuf + 15360;
  const u16* BVg  = wbuf + 17408;
  const u16* BTg  = wbuf + 17920;

  __shared__ u16 Hpool[5120];       // H1hi[0,2560) H1lo[2560,5120); H2 aliases
  __shared__ u16 VT[4608];          // 64 x 72: relu'd [v1|t1]
  __shared__ float b0l[96], b1l[96], bv1l[32], bt1l[32], bt2l[10];
  u16* H1hi = Hpool;  u16* H1lo = Hpool + 2560;
  u16* H2hi = Hpool;  u16* H2lo = Hpool + 2560;

  const int tid  = threadIdx.x;
  const int base = blockIdx.x*64;

  if (tid < 96)            b0l[tid] = bbuf[tid];
  else if (tid < 192)      b1l[tid-96] = bbuf[tid];
  else if (tid < 224){ int d=tid-192; bv1l[d]=bv1[d]; }
  else               { int d=tid-224; bt1l[d]=bt1[d]; }
  if (tid < 10) bt2l[tid] = bt2[tid];
  __syncthreads();

  const int lane = tid & 63, wv = tid >> 6;
  const int c = lane & 15, g = lane >> 4;
  const float bv2v = bv2[0];

  // ---- lstm0: gates = X @ W0^T (K=64, 96 cols) ----
  {
    int r0 = base + wv*16 + c; if (r0 > n-1) r0 = n-1;
    bfrag a0[2];
    a0[0] = *((const bfrag*)(X + (size_t)r0*64      + g*8));
    a0[1] = *((const bfrag*)(X + (size_t)r0*64 + 32 + g*8));
    f32x4 acc[6];
    #pragma unroll
    for (int nt=0;nt<6;++nt) acc[nt] = (f32x4){0.f,0.f,0.f,0.f};
    #pragma unroll
    for (int kk=0; kk<2; ++kk){
      #pragma unroll
      for (int nt=0; nt<6; ++nt){
        int widx = (kk*4+g)*768 + ((nt*16+c)<<3);
        bfrag bh = *((const bfrag*)&W0hi[widx]);
        bfrag bl = *((const bfrag*)&W0lo[widx]);
        acc[nt] = __builtin_amdgcn_mfma_f32_16x16x32_bf16(a0[kk], bh, acc[nt], 0,0,0);
        acc[nt] = __builtin_amdgcn_mfma_f32_16x16x32_bf16(a0[kk], bl, acc[nt], 0,0,0);
      }
    }
    #pragma unroll
    for (int r=0;r<4;++r){
      int rl = wv*16 + g*4 + r;
      #pragma unroll
      for (int half=0; half<2; ++half){
        float iv = acc[0+half][r] + b0l[half*16 + c];
        float gv = acc[2+half][r] + b0l[32 + half*16 + c];
        float ov = acc[4+half][r] + b0l[64 + half*16 + c];
        float cc = fast_sigmoid(iv) * fast_tanh(gv);
        float hv = fast_sigmoid(ov) * fast_tanh(cc);
        u16 hi = f2bf(hv);
        H1hi[rl*40 + half*16 + c] = hi;
        H1lo[rl*40 + half*16 + c] = f2bf(hv - bf2f(hi));
      }
    }
  }
  __syncthreads();                           // H1 visible

  // ---- lstm1: gates = H1 @ W1^T (K=32, 96 cols), A-split 2-term ----
  {
    bfrag w1f[6];
    #pragma unroll
    for (int nt=0; nt<6; ++nt)
      w1f[nt] = *((const bfrag*)&W1g[g*768 + ((nt*16+c)<<3)]);
    bfrag ah = *((const bfrag*)&H1hi[(wv*16 + c)*40 + g*8]);
    bfrag al = *((const bfrag*)&H1lo[(wv*16 + c)*40 + g*8]);
    f32x4 acc[6];
    #pragma unroll
    for (int nt=0;nt<6;++nt) acc[nt] = (f32x4){0.f,0.f,0.f,0.f};
    #pragma unroll
    for (int nt=0; nt<6; ++nt){
      acc[nt] = __builtin_amdgcn_mfma_f32_16x16x32_bf16(ah, w1f[nt], acc[nt], 0,0,0);
      acc[nt] = __builtin_amdgcn_mfma_f32_16x16x32_bf16(al, w1f[nt], acc[nt], 0,0,0);
    }
    __syncthreads();                         // all H1 reads complete before H2 overwrite
    #pragma unroll
    for (int r=0;r<4;++r){
      int rl = wv*16 + g*4 + r;
      #pragma unroll
      for (int half=0; half<2; ++half){
        float iv = acc[0+half][r] + b1l[half*16 + c];
        float gv = acc[2+half][r] + b1l[32 + half*16 + c];
        float ov = acc[4+half][r] + b1l[64 + half*16 + c];
        float cc = fast_sigmoid(iv) * fast_tanh(gv);
        float hv = fast_sigmoid(ov) * fast_tanh(cc);
        u16 hi = f2bf(hv);
        H2hi[rl*40 + half*16 + c] = hi;
        H2lo[rl*40 + half*16 + c] = f2bf(hv - bf2f(hi));
      }
    }
  }
  __syncthreads();                           // H2 visible

  // ---- heads p1: [v1|t1] = relu(H2 @ [Wv1|Wt1] + b) -> VT (bf16) ----
  {
    bfrag whf[4];
    #pragma unroll
    for (int nt=0; nt<4; ++nt)
      whf[nt] = *((const bfrag*)&WHg[g*512 + ((nt*16+c)<<3)]);
    bfrag ah = *((const bfrag*)&H2hi[(wv*16 + c)*40 + g*8]);
    bfrag al = *((const bfrag*)&H2lo[(wv*16 + c)*40 + g*8]);
    f32x4 acc[4];
    #pragma unroll
    for (int nt=0;nt<4;++nt) acc[nt] = (f32x4){0.f,0.f,0.f,0.f};
    #pragma unroll
    for (int nt=0; nt<4; ++nt){
      acc[nt] = __builtin_amdgcn_mfma_f32_16x16x32_bf16(ah, whf[nt], acc[nt], 0,0,0);
      acc[nt] = __builtin_amdgcn_mfma_f32_16x16x32_bf16(al, whf[nt], acc[nt], 0,0,0);
    }
    #pragma unroll
    for (int r=0;r<4;++r){
      int rl = wv*16 + g*4 + r;
      VT[rl*72      + c] = f2bf(fmaxf(acc[0][r] + bv1l[c],    0.f));
      VT[rl*72 + 16 + c] = f2bf(fmaxf(acc[1][r] + bv1l[c+16], 0.f));
      VT[rl*72 + 32 + c] = f2bf(fmaxf(acc[2][r] + bt1l[c],    0.f));
      VT[rl*72 + 48 + c] = f2bf(fmaxf(acc[3][r] + bt1l[c+16], 0.f));
    }
  }
  __syncthreads();                           // VT visible

  // ---- heads p2: vol = v1 @ Wv2, type = t1 @ Wt2 via MFMA, direct C-write ----
  {
    bfrag av = *((const bfrag*)&VT[(wv*16 + c)*72      + g*8]);
    bfrag at = *((const bfrag*)&VT[(wv*16 + c)*72 + 32 + g*8]);
    bfrag bv = *((const bfrag*)(BVg + lane*8));
    bfrag bt = *((const bfrag*)(BTg + lane*8));
    f32x4 accv = (f32x4){0.f,0.f,0.f,0.f};
    f32x4 acct = (f32x4){0.f,0.f,0.f,0.f};
    accv = __builtin_amdgcn_mfma_f32_16x16x32_bf16(av, bv, accv, 0,0,0);
    acct = __builtin_amdgcn_mfma_f32_16x16x32_bf16(at, bt, acct, 0,0,0);
    #pragma unroll
    for (int r=0;r<4;++r){
      int node = base + wv*16 + g*4 + r;
      if (node < n){
        if (c == 0)  out[node] = accv[r] + bv2v;
        if (c < 10)  out[n + (size_t)node*10 + c] = acct[r] + bt2l[c];
      }
    }
  }
}

extern "C" void kernel_launch(void* const* d_in, const int* in_sizes, int n_in,
                              void* d_out, int out_size, void* d_ws, size_t ws_size,
                              hipStream_t stream){
  const float* x    = (const float*)d_in[0];
  const int*   ei   = (const int*)  d_in[1];
  const float* W1   = (const float*)d_in[2];  const float* b1   = (const float*)d_in[3];
  const float* W2   = (const float*)d_in[4];  const float* b2   = (const float*)d_in[5];
  const float* W3   = (const float*)d_in[6];  const float* b3   = (const float*)d_in[7];
  const float* Wih0 = (const float*)d_in[8];
  const float* bih0 = (const float*)d_in[10]; const float* bhh0 = (const float*)d_in[11];
  const float* Wih1 = (const float*)d_in[12];
  const float* bih1 = (const float*)d_in[14]; const float* bhh1 = (const float*)d_in[15];
  const float* Wv1  = (const float*)d_in[16]; const float* bv1  = (const float*)d_in[17];
  const float* Wv2  = (const float*)d_in[18]; const float* bv2  = (const float*)d_in[19];
  const float* Wt1  = (const float*)d_in[20]; const float* bt1  = (const float*)d_in[21];
  const float* Wt2  = (const float*)d_in[22]; const float* bt2  = (const float*)d_in[23];

  const int N  = in_sizes[0] / 128;
  const int E  = in_sizes[1] / 2;
  const int NB = (N + 1023) / 1024;
  const int EB = (E + 8191) / 8192;

  char* w = (char*)d_ws;
  auto take = [&](size_t bytes)->char*{ char* p = w; w += (bytes + 255) & ~(size_t)255; return p; };
  int*   deg    = (int*)  take((size_t)N*4);          // fallback only
  int*   offs   = (int*)  take((size_t)(N+1)*4);
  int*   cursor = (int*)  take((size_t)N*4);          // fallback only
  int*   csr    = (int*)  take((size_t)E*4);
  float* dinv   = (float*)take((size_t)N*4);
  int*   bsums  = (int*)  take((size_t)NB*4);         // fallback only
  int*   boffs  = (int*)  take((size_t)NB*4);         // fallback only
  int*   bhist  = (int*)  take((size_t)MAXBK*4);
  int*   bcur   = (int*)  take((size_t)MAXBK*4);
  int*   bstart = (int*)  take((size_t)(MAXBK+1)*4);
  u32*   packed = (u32*)  take((size_t)E*4);
  u16*   wbuf   = (u16*)  take((size_t)18432*2);      // prepped tail weights + BV/BT frags
  float* bbuf   = (float*)take((size_t)192*4);        // prepped tail biases
  u16*   wgcn   = (u16*)  take((size_t)16384*2);      // prepped GCN weights (bf16 subtiled)
  u16*   bufA   = (u16*)  take((size_t)N*64*2);       // Hts ping
  u16*   bufB   = (u16*)  take((size_t)N*64*2);       // Hts pong
  (void)ws_size; (void)n_in; (void)out_size;

  // --- run-once weight prep (also zeroes bhist) ---
  prep_tail_kernel<<<115, 256, 0, stream>>>(Wih0, Wih1, Wv1, Wt1, Wv2, Wt2,
                                            bih0, bhh0, bih1, bhh1,
                                            W1, W2, W3,
                                            wbuf, bbuf, wgcn, bhist);

  // --- CSR build ---
  if (N <= MAXBK*256){
    const int NBK = (N + 255) / 256;
    bucket_hist_kernel    <<<EB,  512, 0, stream>>>(ei + E, bhist, E);
    bucket_scan_kernel    <<<1,   512, 0, stream>>>(bhist, bcur, bstart);
    bin_kernel            <<<EB,  512, 0, stream>>>(ei, ei + E, bcur, packed, E);
    bucket_finalize_kernel<<<NBK, 512, 0, stream>>>(packed, bstart, offs, dinv, csr, N, E);
  } else {
    hipMemsetAsync(deg, 0, (size_t)N*4, stream);
    count_kernel      <<<(E+255)/256, 256, 0, stream>>>(ei + E, deg, E);
    scan_reduce_kernel<<<NB,          256, 0, stream>>>(deg, bsums, N);
    scan_block_kernel <<<1,           128, 0, stream>>>(bsums, boffs, NB);
    scan_final_kernel <<<NB,          256, 0, stream>>>(deg, boffs, offs, N, E);
    dinv_kernel       <<<(N+255)/256, 256, 0, stream>>>(deg, offs, cursor, dinv, N);
    fill_kernel       <<<(E+255)/256, 256, 0, stream>>>(ei, cursor, csr, E);
  }

  // --- GCN + tail ---
  const int TB  = (N + 127) / 128;
  const int AB  = (N + 31) / 32;
  const int TB2 = (N + 63) / 64;
  transform_mfma<128,float><<<TB, 256, 0, stream>>>(x, wgcn, dinv, bufA, N);
  fused_agg_transform<<<TB, 256, 0, stream>>>(bufA, dinv, offs, csr, b1,
                                              wgcn + 8192,  bufB, N);
  fused_agg_transform<<<TB, 256, 0, stream>>>(bufB, dinv, offs, csr, b2,
                                              wgcn + 12288, bufA, N);
  agg_kernel<<<AB, 256, 0, stream>>>(bufA, dinv, offs, csr, b3, bufB, N);
  lstm_heads_fused<<<TB2, 256, 0, stream>>>(bufB, wbuf, bbuf,
                                            bv1, bv2, bt1, bt2,
                                            (float*)d_out, N);
}

// Round 16
// 182.352 us; speedup vs baseline: 5.2449x; 1.0352x over previous
//
#include <hip/hip_runtime.h>
#include <math.h>

// TemporalWasteGNN: 3x GCNConv (symmetric-norm, self-loops) -> 2x LSTM(seq=1, h0=c0=0)
// -> two MLP heads. fp32 I/O, bf16 intermediate features.
//
// R16: fused_agg_transform widened to 512 threads (8 waves). R15 counters:
//      26% occupancy, 12 waves/CU for the latency-bound gather phase (vs 53%
//      standalone). Now: phase A = 2 iters x 8 nodes/wave (half the serial
//      chain, 2x waves -> ~24/CU); phase B = 16 rows/wave (proven tail
//      layout), same 64 MFMAs/block, bit-identical math.
// R10 packed CSR build, R12 pipelined gather, R13 prepped slabs, R7 native
// transcendentals, R15 standalone agg3 + tail — all retained.

typedef unsigned int  u32;
typedef unsigned short u16;
typedef short bfrag  __attribute__((ext_vector_type(8)));   // 8 bf16 (4 VGPRs)
typedef float f32x4  __attribute__((ext_vector_type(4)));

#define LOG2E 1.44269504088896f
static __device__ __forceinline__ float fast_sigmoid(float x){
  float t = __builtin_amdgcn_exp2f(-x * LOG2E);
  return __builtin_amdgcn_rcpf(1.f + t);
}
static __device__ __forceinline__ float fast_tanh(float x){
  float t = __builtin_amdgcn_exp2f(x * (2.f * LOG2E));
  return 1.f - 2.f * __builtin_amdgcn_rcpf(t + 1.f);
}
static __device__ __forceinline__ float bf2f(u16 u){ return __uint_as_float(((u32)u)<<16); }
static __device__ __forceinline__ u16   f2bf(float f){
  u32 x = __float_as_uint(f);
  return (u16)((x + 0x7fffu + ((x>>16)&1u)) >> 16);   // round-to-nearest-even
}

#define MAXBK 512   // buckets of 256 dst nodes; N <= 131072 (src must fit 24 bits)

// ---------------- bucketed CSR build ----------------
__global__ __launch_bounds__(512) void bucket_hist_kernel(const int* __restrict__ dstA,
                                                          int* __restrict__ bhist, int E){
  __shared__ int h[MAXBK];
  for (int i=threadIdx.x; i<MAXBK; i+=512) h[i]=0;
  __syncthreads();
  const int base = blockIdx.x*8192;
  #pragma unroll
  for (int j=0;j<16;++j){
    int e = base + j*512 + threadIdx.x;
    if (e < E) atomicAdd(&h[dstA[e]>>8], 1);
  }
  __syncthreads();
  for (int i=threadIdx.x; i<MAXBK; i+=512) if (h[i]) atomicAdd(&bhist[i], h[i]);
}

__global__ __launch_bounds__(512) void bucket_scan_kernel(const int* __restrict__ bhist,
                                                          int* __restrict__ bcur,
                                                          int* __restrict__ bstart){
  __shared__ int ts[MAXBK];
  int v = bhist[threadIdx.x];
  ts[threadIdx.x] = v; __syncthreads();
  for (int off=1; off<MAXBK; off<<=1){
    int t = (threadIdx.x>=off) ? ts[threadIdx.x-off] : 0;
    __syncthreads();
    ts[threadIdx.x] += t;
    __syncthreads();
  }
  int ex = ts[threadIdx.x] - v;
  bcur[threadIdx.x]   = ex;
  bstart[threadIdx.x] = ex;
  if (threadIdx.x == MAXBK-1) bstart[MAXBK] = ts[threadIdx.x];   // = E
}

__global__ __launch_bounds__(512) void bin_kernel(const int* __restrict__ srcA,
                                                  const int* __restrict__ dstA,
                                                  int* __restrict__ bcur,
                                                  u32* __restrict__ packed, int E){
  __shared__ int h[MAXBK];
  __shared__ int basev[MAXBK];
  for (int i=threadIdx.x; i<MAXBK; i+=512) h[i]=0;
  __syncthreads();
  const int base = blockIdx.x*8192;
  int br[16]; int dv[16];
  #pragma unroll
  for (int j=0;j<16;++j){
    int e = base + j*512 + threadIdx.x;
    if (e < E){
      int d = dstA[e]; int b = d>>8;
      int r = atomicAdd(&h[b], 1);
      br[j] = (b<<16) | r;                 // b<512 (9b) | r<8192 (13b)
      dv[j] = d;
    } else br[j] = -1;
  }
  __syncthreads();
  for (int i=threadIdx.x; i<MAXBK; i+=512){
    int c = h[i];
    basev[i] = c ? atomicAdd(&bcur[i], c) : 0;
  }
  __syncthreads();
  #pragma unroll
  for (int j=0;j<16;++j){
    if (br[j] >= 0){
      int e = base + j*512 + threadIdx.x;
      int pos = basev[br[j]>>16] + (br[j] & 0xffff);
      packed[pos] = (u32)srcA[e] | ((u32)(dv[j] & 255) << 24);
    }
  }
}

__global__ __launch_bounds__(512) void bucket_finalize_kernel(
    const u32* __restrict__ packed, const int* __restrict__ bstart,
    int* __restrict__ offs, float* __restrict__ dinv,
    int* __restrict__ csr, int n, int E){
  __shared__ int cnt[256];
  __shared__ int sc[256];
  __shared__ int cur[256];
  const int b = blockIdx.x;
  const int start = bstart[b], end = bstart[b+1];
  for (int i=threadIdx.x; i<256; i+=512){ cnt[i]=0; cur[i]=0; }
  __syncthreads();
  for (int e = start + threadIdx.x; e < end; e += 512)
    atomicAdd(&cnt[packed[e] >> 24], 1);
  __syncthreads();
  if (threadIdx.x < 256) sc[threadIdx.x] = cnt[threadIdx.x];
  __syncthreads();
  for (int off=1; off<256; off<<=1){
    int t = 0;
    if (threadIdx.x < 256 && threadIdx.x >= off) t = sc[threadIdx.x-off];
    __syncthreads();
    if (threadIdx.x < 256) sc[threadIdx.x] += t;
    __syncthreads();
  }
  if (threadIdx.x < 256){
    int ex = sc[threadIdx.x] - cnt[threadIdx.x];      // exclusive
    sc[threadIdx.x] = ex;
    int node = b*256 + threadIdx.x;
    if (node < n){
      offs[node] = start + ex;
      dinv[node] = rsqrtf((float)(cnt[threadIdx.x] + 1));
    }
  }
  if (b == 0 && threadIdx.x == 0) offs[n] = E;
  __syncthreads();
  for (int e = start + threadIdx.x; e < end; e += 512){
    u32 v = packed[e];
    int loc = v >> 24;
    int pos = start + sc[loc] + atomicAdd(&cur[loc], 1);
    csr[pos] = (int)(v & 0xFFFFFFu);
  }
}

// fallback (N too large for bucketing) -------------
__global__ void count_kernel(const int* __restrict__ dsts, int* __restrict__ deg, int E){
  int e = blockIdx.x*256 + threadIdx.x;
  if (e < E) atomicAdd(&deg[dsts[e]], 1);
}
__global__ void fill_kernel(const int* __restrict__ ei, int* __restrict__ cursor,
                            int* __restrict__ csr, int E){
  int e = blockIdx.x*256 + threadIdx.x;
  if (e < E){
    int d = ei[E + e];
    int pos = atomicAdd(&cursor[d], 1);
    csr[pos] = ei[e];
  }
}

__global__ void scan_reduce_kernel(const int* __restrict__ deg, int* __restrict__ bsums, int n){
  __shared__ int sd[256];
  int base = blockIdx.x*1024 + threadIdx.x*4;
  int s = 0;
  #pragma unroll
  for (int j=0;j<4;++j){ int idx=base+j; if (idx<n) s += deg[idx]; }
  sd[threadIdx.x] = s; __syncthreads();
  for (int off=128; off>0; off>>=1){
    if (threadIdx.x < off) sd[threadIdx.x] += sd[threadIdx.x+off];
    __syncthreads();
  }
  if (threadIdx.x==0) bsums[blockIdx.x] = sd[0];
}

__global__ void scan_block_kernel(const int* __restrict__ bsums, int* __restrict__ boffs, int nb){
  __shared__ int ts[128];
  if (nb <= 128){
    int v = (threadIdx.x < nb) ? bsums[threadIdx.x] : 0;
    ts[threadIdx.x] = v; __syncthreads();
    for (int off=1; off<128; off<<=1){
      int t = (threadIdx.x>=off) ? ts[threadIdx.x-off] : 0;
      __syncthreads();
      ts[threadIdx.x] += t;
      __syncthreads();
    }
    if (threadIdx.x < nb) boffs[threadIdx.x] = ts[threadIdx.x] - v;
  } else if (threadIdx.x==0){
    int run=0;
    for (int b=0;b<nb;++b){ int t=bsums[b]; boffs[b]=run; run+=t; }
  }
}

__global__ void scan_final_kernel(const int* __restrict__ deg, const int* __restrict__ boffs,
                                  int* __restrict__ offs, int n, int E){
  __shared__ int ts[256];
  int base = blockIdx.x*1024 + threadIdx.x*4;
  int v[4]; int s=0;
  #pragma unroll
  for (int j=0;j<4;++j){ int idx=base+j; v[j] = (idx<n) ? deg[idx] : 0; s += v[j]; }
  ts[threadIdx.x] = s; __syncthreads();
  for (int off=1; off<256; off<<=1){
    int t = (threadIdx.x>=off) ? ts[threadIdx.x-off] : 0;
    __syncthreads();
    ts[threadIdx.x] += t;
    __syncthreads();
  }
  int excl = boffs[blockIdx.x] + (threadIdx.x ? ts[threadIdx.x-1] : 0);
  #pragma unroll
  for (int j=0;j<4;++j){ int idx=base+j; if (idx<n){ offs[idx]=excl; excl+=v[j]; } }
  if (blockIdx.x==0 && threadIdx.x==0) offs[n] = E;
}

__global__ void dinv_kernel(const int* __restrict__ deg, const int* __restrict__ offs,
                            int* __restrict__ cursor, float* __restrict__ dinv, int n){
  int i = blockIdx.x*256 + threadIdx.x;
  if (i < n){
    dinv[i] = rsqrtf((float)(deg[i] + 1));
    cursor[i] = offs[i];
  }
}

// ---------------- run-once weight prep (tail + GCN) ----------------
__global__ void prep_tail_kernel(const float* __restrict__ Wih0, const float* __restrict__ Wih1,
                                 const float* __restrict__ Wv1,  const float* __restrict__ Wt1,
                                 const float* __restrict__ Wv2,  const float* __restrict__ Wt2,
                                 const float* __restrict__ bih0, const float* __restrict__ bhh0,
                                 const float* __restrict__ bih1, const float* __restrict__ bhh1,
                                 const float* __restrict__ Wg1,  const float* __restrict__ Wg2,
                                 const float* __restrict__ Wg3,
                                 u16* __restrict__ wbuf, float* __restrict__ bbuf,
                                 u16* __restrict__ wgcn, int* __restrict__ bhist){
  int tid = blockIdx.x*256 + threadIdx.x;
  if (tid < 6144){                                  // Wih0 hi/lo, [k/8][96][8]
    int kg = tid / 768, rem = tid % 768;
    int j = rem >> 3, k = kg*8 + (rem & 7);
    int row = (j < 32) ? j : j + 32;
    float w = Wih0[row*64 + k];
    u16 hi = f2bf(w);
    wbuf[tid] = hi;
    wbuf[6144 + tid] = f2bf(w - bf2f(hi));
  } else if (tid < 9216){                           // Wih1, [k/8][96][8]
    int t = tid - 6144;
    int kg = t / 768, rem = t % 768;
    int j = rem >> 3, k = kg*8 + (rem & 7);
    int row = (j < 32) ? j : j + 32;
    wbuf[12288 + t] = f2bf(Wih1[row*32 + k]);
  } else if (tid < 11264){                          // Wv1|Wt1, [k/8][64][8]
    int t = tid - 9216;
    int kg = t / 512, rem = t % 512;
    int j = rem >> 3, k = kg*8 + (rem & 7);
    float v = (j < 32) ? Wv1[k*32 + j] : Wt1[k*32 + (j-32)];
    wbuf[15360 + t] = f2bf(v);
  } else if (tid < 11360){                          // b0 (i,g,o combined)
    int t = tid - 11264;
    int row = (t < 32) ? t : t + 32;
    bbuf[t] = bih0[row] + bhh0[row];
  } else if (tid < 11456){                          // b1
    int t = tid - 11360;
    int row = (t < 32) ? t : t + 32;
    bbuf[96 + t] = bih1[row] + bhh1[row];
  } else if (tid < 12480){                          // BV/BT lane fragments (K=32)
    int t = tid - 11456;
    int slab = t >> 9, within = t & 511;
    int lane = within >> 3, j = within & 7;
    int cc = lane & 15, gg = lane >> 4;
    float v;
    if (slab == 0) v = (cc == 0) ? Wv2[gg*8 + j] : 0.f;
    else           v = (cc < 10) ? Wt2[(gg*8 + j)*10 + cc] : 0.f;
    wbuf[17408 + slab*512 + within] = f2bf(v);
  } else if (tid < 12992){                          // zero bhist
    bhist[tid - 12480] = 0;
  } else if (tid < 21184){                          // W1 (128x64) -> G1
    int t = tid - 12992;
    int kg = t >> 9, rem = t & 511;
    int j = rem >> 3, k = kg*8 + (rem & 7);
    wgcn[t] = f2bf(Wg1[k*64 + j]);
  } else if (tid < 25280){                          // W2 (64x64) -> G2
    int t = tid - 21184;
    int kg = t >> 9, rem = t & 511;
    int j = rem >> 3, k = kg*8 + (rem & 7);
    wgcn[8192 + t] = f2bf(Wg2[k*64 + j]);
  } else if (tid < 29376){                          // W3 (64x64) -> G3
    int t = tid - 25280;
    int kg = t >> 9, rem = t & 511;
    int j = rem >> 3, k = kg*8 + (rem & 7);
    wgcn[12288 + t] = f2bf(Wg3[k*64 + j]);
  }
}

// ---------------- gather-agg helper: acc over adjacency, 4-deep pipelined ----------------
static __device__ __forceinline__ uint4 agg_row(const uint4* __restrict__ H,
                                                const float* __restrict__ dinv,
                                                const int* __restrict__ offs,
                                                const int* __restrict__ csr,
                                                const float* __restrict__ bias,
                                                int node, int c8){
  float acc[8];
  #pragma unroll
  for (int i=0;i<8;++i) acc[i]=0.f;
  const int beg = offs[node], end = offs[node+1];
  #define ACC8(v) do{ \
    acc[0] += __uint_as_float((v).x<<16); acc[1] += __uint_as_float((v).x & 0xffff0000u); \
    acc[2] += __uint_as_float((v).y<<16); acc[3] += __uint_as_float((v).y & 0xffff0000u); \
    acc[4] += __uint_as_float((v).z<<16); acc[5] += __uint_as_float((v).z & 0xffff0000u); \
    acc[6] += __uint_as_float((v).w<<16); acc[7] += __uint_as_float((v).w & 0xffff0000u); }while(0)
  int j = beg;
  for (; j + 4 <= end; j += 4){
    int s0 = csr[j], s1 = csr[j+1], s2 = csr[j+2], s3 = csr[j+3];
    uint4 v0 = H[(size_t)s0*8 + c8];
    uint4 v1 = H[(size_t)s1*8 + c8];
    uint4 v2 = H[(size_t)s2*8 + c8];
    uint4 v3 = H[(size_t)s3*8 + c8];
    ACC8(v0); ACC8(v1); ACC8(v2); ACC8(v3);
  }
  for (; j < end; ++j){
    int src = csr[j];
    uint4 v = H[(size_t)src*8 + c8];
    ACC8(v);
  }
  #undef ACC8
  uint4 sv = H[(size_t)node*8 + c8];       // self-loop (already * dinv[node])
  float sf[8];
  sf[0]=__uint_as_float(sv.x<<16); sf[1]=__uint_as_float(sv.x & 0xffff0000u);
  sf[2]=__uint_as_float(sv.y<<16); sf[3]=__uint_as_float(sv.y & 0xffff0000u);
  sf[4]=__uint_as_float(sv.z<<16); sf[5]=__uint_as_float(sv.z & 0xffff0000u);
  sf[6]=__uint_as_float(sv.w<<16); sf[7]=__uint_as_float(sv.w & 0xffff0000u);
  float4 b0 = ((const float4*)bias)[c8*2];
  float4 b1 = ((const float4*)bias)[c8*2+1];
  const float dv = dinv[node];
  float o[8];
  o[0]=fmaxf(fmaf(acc[0]+sf[0],dv,b0.x),0.f); o[1]=fmaxf(fmaf(acc[1]+sf[1],dv,b0.y),0.f);
  o[2]=fmaxf(fmaf(acc[2]+sf[2],dv,b0.z),0.f); o[3]=fmaxf(fmaf(acc[3]+sf[3],dv,b0.w),0.f);
  o[4]=fmaxf(fmaf(acc[4]+sf[4],dv,b1.x),0.f); o[5]=fmaxf(fmaf(acc[5]+sf[5],dv,b1.y),0.f);
  o[6]=fmaxf(fmaf(acc[6]+sf[6],dv,b1.z),0.f); o[7]=fmaxf(fmaf(acc[7]+sf[7],dv,b1.w),0.f);
  uint4 w;
  w.x = (u32)f2bf(o[0]) | ((u32)f2bf(o[1])<<16);
  w.y = (u32)f2bf(o[2]) | ((u32)f2bf(o[3])<<16);
  w.z = (u32)f2bf(o[4]) | ((u32)f2bf(o[5])<<16);
  w.w = (u32)f2bf(o[6]) | ((u32)f2bf(o[7])<<16);
  return w;
}

// ---------------- standalone agg (layer 3): 8 nodes/wave, 4-deep pipelined ----------------
__global__ void agg_kernel(const u16* __restrict__ Hts, const float* __restrict__ dinv,
                           const int* __restrict__ offs, const int* __restrict__ csr,
                           const float* __restrict__ bias, u16* __restrict__ Hout, int n){
  const int lane = threadIdx.x & 63;
  const int wv   = threadIdx.x >> 6;
  const int s    = lane >> 3;
  const int c8   = lane & 7;
  const int node = blockIdx.x*32 + wv*8 + s;
  if (node >= n) return;
  const uint4* __restrict__ H = (const uint4*)Hts;
  uint4 w = agg_row(H, dinv, offs, csr, bias, node, c8);
  ((uint4*)Hout)[(size_t)node*8 + c8] = w;
}

// ---------------- GCN transform via MFMA (layer 1; W from prepped slab) ----------------
template<int KD, typename TIN>
__global__ __launch_bounds__(256) void transform_mfma(const TIN* __restrict__ X,
                                                      const u16* __restrict__ WG,
                                                      const float* __restrict__ dinv,
                                                      u16* __restrict__ Y, int n){
  constexpr int XLD = KD + 8;
  __shared__ u16 Xl[128*XLD];
  __shared__ float Dl[128];
  const int tid  = threadIdx.x;
  const int base = blockIdx.x*128;

  if (tid < 128){
    int nd = base + tid;
    Dl[tid] = (nd < n) ? dinv[nd] : 0.f;
  }
  if constexpr (sizeof(TIN)==4){
    #pragma unroll
    for (int j = 0; j < (128*KD)/1024; ++j){
      int e4   = tid + j*256;
      int elem = e4*4;
      int row  = elem / KD, k = elem % KD;
      int gn   = base + row;
      uint2 w2 = make_uint2(0u, 0u);
      if (gn < n){
        float4 v = ((const float4*)X)[(size_t)gn*(KD/4) + (k>>2)];
        w2.x = (u32)f2bf(v.x) | ((u32)f2bf(v.y)<<16);
        w2.y = (u32)f2bf(v.z) | ((u32)f2bf(v.w)<<16);
      }
      *((uint2*)&Xl[row*XLD + k]) = w2;
    }
  } else {
    #pragma unroll
    for (int j = 0; j < (128*KD)/1024; ++j){
      int e4   = tid + j*256;
      int elem = e4*4;
      int row  = elem / KD, k = elem % KD;
      int gn   = base + row;
      uint2 v = make_uint2(0u, 0u);
      if (gn < n) v = *((const uint2*)(X + (size_t)gn*KD + k));
      *((uint2*)&Xl[row*XLD + k]) = v;
    }
  }

  const int lane = tid & 63, wv = tid >> 6;
  const int c = lane & 15, g = lane >> 4;

  bfrag wf[KD/32][4];
  #pragma unroll
  for (int kk=0; kk<KD/32; ++kk)
    #pragma unroll
    for (int nt=0; nt<4; ++nt)
      wf[kk][nt] = *((const bfrag*)&WG[((kk*4+g)<<9) + ((nt*16+c)<<3)]);

  __syncthreads();                   // Xl ready

  f32x4 acc[2][4];
  #pragma unroll
  for (int rs=0;rs<2;++rs)
    #pragma unroll
    for (int nt=0;nt<4;++nt)
      acc[rs][nt] = (f32x4){0.f,0.f,0.f,0.f};

  #pragma unroll
  for (int kk=0; kk<KD/32; ++kk){
    bfrag a0 = *((const bfrag*)&Xl[(wv*32      + c)*XLD + kk*32 + g*8]);
    bfrag a1 = *((const bfrag*)&Xl[(wv*32 + 16 + c)*XLD + kk*32 + g*8]);
    #pragma unroll
    for (int nt=0; nt<4; ++nt){
      acc[0][nt] = __builtin_amdgcn_mfma_f32_16x16x32_bf16(a0, wf[kk][nt], acc[0][nt], 0,0,0);
      acc[1][nt] = __builtin_amdgcn_mfma_f32_16x16x32_bf16(a1, wf[kk][nt], acc[1][nt], 0,0,0);
    }
  }

  #pragma unroll
  for (int rs=0;rs<2;++rs){
    int nl0 = wv*32 + rs*16 + g*4;
    #pragma unroll
    for (int r=0;r<4;++r){
      int node = base + nl0 + r;
      if (node < n){
        float dv = Dl[nl0 + r];
        #pragma unroll
        for (int nt=0;nt<4;++nt)
          Y[(size_t)node*64 + nt*16 + c] = f2bf(acc[rs][nt][r] * dv);
      }
    }
  }
}

// ---------------- fused agg + transform (layers 2,3 input), 512 threads ----------------
// 8 waves: phase A gathers 2 iters x 8 nodes/wave (2x waves, half the serial
// chain of R15); phase B = 16 rows/wave MFMA transform (8 MFMA/wave).
__global__ __launch_bounds__(512) void fused_agg_transform(
    const u16* __restrict__ Hsrc, const float* __restrict__ dinv,
    const int* __restrict__ offs, const int* __restrict__ csr,
    const float* __restrict__ bias, const u16* __restrict__ WG,
    u16* __restrict__ Y, int n){
  constexpr int XLD = 72;
  __shared__ u16 Xl[128*XLD];
  __shared__ float Dl[128];
  const int tid  = threadIdx.x;
  const int base = blockIdx.x*128;
  const int lane = tid & 63, wv = tid >> 6;   // wv in 0..7

  if (tid < 128){
    int nd = base + tid;
    Dl[tid] = (nd < n) ? dinv[nd] : 0.f;
  }

  // ---- phase A: aggregate this block's 128 nodes into Xl ----
  {
    const int s  = lane >> 3;
    const int c8 = lane & 7;
    const uint4* __restrict__ H = (const uint4*)Hsrc;
    #pragma unroll
    for (int it=0; it<2; ++it){
      int rl   = it*64 + wv*8 + s;
      int node = base + rl;
      uint4 w = make_uint4(0u,0u,0u,0u);
      if (node < n) w = agg_row(H, dinv, offs, csr, bias, node, c8);
      ((uint4*)&Xl[rl*XLD])[c8] = w;
    }
  }

  const int c = lane & 15, g = lane >> 4;
  bfrag wf[2][4];
  #pragma unroll
  for (int kk=0; kk<2; ++kk)
    #pragma unroll
    for (int nt=0; nt<4; ++nt)
      wf[kk][nt] = *((const bfrag*)&WG[((kk*4+g)<<9) + ((nt*16+c)<<3)]);

  __syncthreads();                   // Xl complete

  // ---- phase B: transform, 16 rows/wave (rows [wv*16, wv*16+16)) ----
  f32x4 acc[4];
  #pragma unroll
  for (int nt=0;nt<4;++nt) acc[nt] = (f32x4){0.f,0.f,0.f,0.f};

  #pragma unroll
  for (int kk=0; kk<2; ++kk){
    bfrag a0 = *((const bfrag*)&Xl[(wv*16 + c)*XLD + kk*32 + g*8]);
    #pragma unroll
    for (int nt=0; nt<4; ++nt)
      acc[nt] = __builtin_amdgcn_mfma_f32_16x16x32_bf16(a0, wf[kk][nt], acc[nt], 0,0,0);
  }

  #pragma unroll
  for (int r=0;r<4;++r){
    int nl   = wv*16 + g*4 + r;
    int node = base + nl;
    if (node < n){
      float dv = Dl[nl];
      #pragma unroll
      for (int nt=0;nt<4;++nt)
        Y[(size_t)node*64 + nt*16 + c] = f2bf(acc[nt][r] * dv);
    }
  }
}

// ---------------- Fused LSTM x2 + heads: 16 rows/wave, zero shuffles (R13, verified) ----------------
__global__ __launch_bounds__(256) void lstm_heads_fused(
    const u16* __restrict__ X,
    const u16* __restrict__ wbuf, const float* __restrict__ bbuf,
    const float* __restrict__ bv1, const float* __restrict__ bv2,
    const float* __restrict__ bt1, const float* __restrict__ bt2,
    float* __restrict__ out, int n)
{
  const u16* W0hi = wbuf;
  const u16* W0lo = wbuf + 6144;
  const u16* W1g  = wbuf + 12288;
  const u16* WHg  = wbuf + 15360;
  const u16* BVg  = wbuf + 17408;
  const u16* BTg  = wbuf + 17920;

  __shared__ u16 Hpool[5120];       // H1hi[0,2560) H1lo[2560,5120); H2 aliases
  __shared__ u16 VT[4608];          // 64 x 72: relu'd [v1|t1]
  __shared__ float b0l[96], b1l[96], bv1l[32], bt1l[32], bt2l[10];
  u16* H1hi = Hpool;  u16* H1lo = Hpool + 2560;
  u16* H2hi = Hpool;  u16* H2lo = Hpool + 2560;

  const int tid  = threadIdx.x;
  const int base = blockIdx.x*64;

  if (tid < 96)            b0l[tid] = bbuf[tid];
  else if (tid < 192)      b1l[tid-96] = bbuf[tid];
  else if (tid < 224){ int d=tid-192; bv1l[d]=bv1[d]; }
  else               { int d=tid-224; bt1l[d]=bt1[d]; }
  if (tid < 10) bt2l[tid] = bt2[tid];
  __syncthreads();

  const int lane = tid & 63, wv = tid >> 6;
  const int c = lane & 15, g = lane >> 4;
  const float bv2v = bv2[0];

  // ---- lstm0: gates = X @ W0^T (K=64, 96 cols) ----
  {
    int r0 = base + wv*16 + c; if (r0 > n-1) r0 = n-1;
    bfrag a0[2];
    a0[0] = *((const bfrag*)(X + (size_t)r0*64      + g*8));
    a0[1] = *((const bfrag*)(X + (size_t)r0*64 + 32 + g*8));
    f32x4 acc[6];
    #pragma unroll
    for (int nt=0;nt<6;++nt) acc[nt] = (f32x4){0.f,0.f,0.f,0.f};
    #pragma unroll
    for (int kk=0; kk<2; ++kk){
      #pragma unroll
      for (int nt=0; nt<6; ++nt){
        int widx = (kk*4+g)*768 + ((nt*16+c)<<3);
        bfrag bh = *((const bfrag*)&W0hi[widx]);
        bfrag bl = *((const bfrag*)&W0lo[widx]);
        acc[nt] = __builtin_amdgcn_mfma_f32_16x16x32_bf16(a0[kk], bh, acc[nt], 0,0,0);
        acc[nt] = __builtin_amdgcn_mfma_f32_16x16x32_bf16(a0[kk], bl, acc[nt], 0,0,0);
      }
    }
    #pragma unroll
    for (int r=0;r<4;++r){
      int rl = wv*16 + g*4 + r;
      #pragma unroll
      for (int half=0; half<2; ++half){
        float iv = acc[0+half][r] + b0l[half*16 + c];
        float gv = acc[2+half][r] + b0l[32 + half*16 + c];
        float ov = acc[4+half][r] + b0l[64 + half*16 + c];
        float cc = fast_sigmoid(iv) * fast_tanh(gv);
        float hv = fast_sigmoid(ov) * fast_tanh(cc);
        u16 hi = f2bf(hv);
        H1hi[rl*40 + half*16 + c] = hi;
        H1lo[rl*40 + half*16 + c] = f2bf(hv - bf2f(hi));
      }
    }
  }
  __syncthreads();                           // H1 visible

  // ---- lstm1: gates = H1 @ W1^T (K=32, 96 cols), A-split 2-term ----
  {
    bfrag w1f[6];
    #pragma unroll
    for (int nt=0; nt<6; ++nt)
      w1f[nt] = *((const bfrag*)&W1g[g*768 + ((nt*16+c)<<3)]);
    bfrag ah = *((const bfrag*)&H1hi[(wv*16 + c)*40 + g*8]);
    bfrag al = *((const bfrag*)&H1lo[(wv*16 + c)*40 + g*8]);
    f32x4 acc[6];
    #pragma unroll
    for (int nt=0;nt<6;++nt) acc[nt] = (f32x4){0.f,0.f,0.f,0.f};
    #pragma unroll
    for (int nt=0; nt<6; ++nt){
      acc[nt] = __builtin_amdgcn_mfma_f32_16x16x32_bf16(ah, w1f[nt], acc[nt], 0,0,0);
      acc[nt] = __builtin_amdgcn_mfma_f32_16x16x32_bf16(al, w1f[nt], acc[nt], 0,0,0);
    }
    __syncthreads();                         // all H1 reads complete before H2 overwrite
    #pragma unroll
    for (int r=0;r<4;++r){
      int rl = wv*16 + g*4 + r;
      #pragma unroll
      for (int half=0; half<2; ++half){
        float iv = acc[0+half][r] + b1l[half*16 + c];
        float gv = acc[2+half][r] + b1l[32 + half*16 + c];
        float ov = acc[4+half][r] + b1l[64 + half*16 + c];
        float cc = fast_sigmoid(iv) * fast_tanh(gv);
        float hv = fast_sigmoid(ov) * fast_tanh(cc);
        u16 hi = f2bf(hv);
        H2hi[rl*40 + half*16 + c] = hi;
        H2lo[rl*40 + half*16 + c] = f2bf(hv - bf2f(hi));
      }
    }
  }
  __syncthreads();                           // H2 visible

  // ---- heads p1: [v1|t1] = relu(H2 @ [Wv1|Wt1] + b) -> VT (bf16) ----
  {
    bfrag whf[4];
    #pragma unroll
    for (int nt=0; nt<4; ++nt)
      whf[nt] = *((const bfrag*)&WHg[g*512 + ((nt*16+c)<<3)]);
    bfrag ah = *((const bfrag*)&H2hi[(wv*16 + c)*40 + g*8]);
    bfrag al = *((const bfrag*)&H2lo[(wv*16 + c)*40 + g*8]);
    f32x4 acc[4];
    #pragma unroll
    for (int nt=0;nt<4;++nt) acc[nt] = (f32x4){0.f,0.f,0.f,0.f};
    #pragma unroll
    for (int nt=0; nt<4; ++nt){
      acc[nt] = __builtin_amdgcn_mfma_f32_16x16x32_bf16(ah, whf[nt], acc[nt], 0,0,0);
      acc[nt] = __builtin_amdgcn_mfma_f32_16x16x32_bf16(al, whf[nt], acc[nt], 0,0,0);
    }
    #pragma unroll
    for (int r=0;r<4;++r){
      int rl = wv*16 + g*4 + r;
      VT[rl*72      + c] = f2bf(fmaxf(acc[0][r] + bv1l[c],    0.f));
      VT[rl*72 + 16 + c] = f2bf(fmaxf(acc[1][r] + bv1l[c+16], 0.f));
      VT[rl*72 + 32 + c] = f2bf(fmaxf(acc[2][r] + bt1l[c],    0.f));
      VT[rl*72 + 48 + c] = f2bf(fmaxf(acc[3][r] + bt1l[c+16], 0.f));
    }
  }
  __syncthreads();                           // VT visible

  // ---- heads p2: vol = v1 @ Wv2, type = t1 @ Wt2 via MFMA, direct C-write ----
  {
    bfrag av = *((const bfrag*)&VT[(wv*16 + c)*72      + g*8]);
    bfrag at = *((const bfrag*)&VT[(wv*16 + c)*72 + 32 + g*8]);
    bfrag bv = *((const bfrag*)(BVg + lane*8));
    bfrag bt = *((const bfrag*)(BTg + lane*8));
    f32x4 accv = (f32x4){0.f,0.f,0.f,0.f};
    f32x4 acct = (f32x4){0.f,0.f,0.f,0.f};
    accv = __builtin_amdgcn_mfma_f32_16x16x32_bf16(av, bv, accv, 0,0,0);
    acct = __builtin_amdgcn_mfma_f32_16x16x32_bf16(at, bt, acct, 0,0,0);
    #pragma unroll
    for (int r=0;r<4;++r){
      int node = base + wv*16 + g*4 + r;
      if (node < n){
        if (c == 0)  out[node] = accv[r] + bv2v;
        if (c < 10)  out[n + (size_t)node*10 + c] = acct[r] + bt2l[c];
      }
    }
  }
}

extern "C" void kernel_launch(void* const* d_in, const int* in_sizes, int n_in,
                              void* d_out, int out_size, void* d_ws, size_t ws_size,
                              hipStream_t stream){
  const float* x    = (const float*)d_in[0];
  const int*   ei   = (const int*)  d_in[1];
  const float* W1   = (const float*)d_in[2];  const float* b1   = (const float*)d_in[3];
  const float* W2   = (const float*)d_in[4];  const float* b2   = (const float*)d_in[5];
  const float* W3   = (const float*)d_in[6];  const float* b3   = (const float*)d_in[7];
  const float* Wih0 = (const float*)d_in[8];
  const float* bih0 = (const float*)d_in[10]; const float* bhh0 = (const float*)d_in[11];
  const float* Wih1 = (const float*)d_in[12];
  const float* bih1 = (const float*)d_in[14]; const float* bhh1 = (const float*)d_in[15];
  const float* Wv1  = (const float*)d_in[16]; const float* bv1  = (const float*)d_in[17];
  const float* Wv2  = (const float*)d_in[18]; const float* bv2  = (const float*)d_in[19];
  const float* Wt1  = (const float*)d_in[20]; const float* bt1  = (const float*)d_in[21];
  const float* Wt2  = (const float*)d_in[22]; const float* bt2  = (const float*)d_in[23];

  const int N  = in_sizes[0] / 128;
  const int E  = in_sizes[1] / 2;
  const int NB = (N + 1023) / 1024;
  const int EB = (E + 8191) / 8192;

  char* w = (char*)d_ws;
  auto take = [&](size_t bytes)->char*{ char* p = w; w += (bytes + 255) & ~(size_t)255; return p; };
  int*   deg    = (int*)  take((size_t)N*4);          // fallback only
  int*   offs   = (int*)  take((size_t)(N+1)*4);
  int*   cursor = (int*)  take((size_t)N*4);          // fallback only
  int*   csr    = (int*)  take((size_t)E*4);
  float* dinv   = (float*)take((size_t)N*4);
  int*   bsums  = (int*)  take((size_t)NB*4);         // fallback only
  int*   boffs  = (int*)  take((size_t)NB*4);         // fallback only
  int*   bhist  = (int*)  take((size_t)MAXBK*4);
  int*   bcur   = (int*)  take((size_t)MAXBK*4);
  int*   bstart = (int*)  take((size_t)(MAXBK+1)*4);
  u32*   packed = (u32*)  take((size_t)E*4);
  u16*   wbuf   = (u16*)  take((size_t)18432*2);      // prepped tail weights + BV/BT frags
  float* bbuf   = (float*)take((size_t)192*4);        // prepped tail biases
  u16*   wgcn   = (u16*)  take((size_t)16384*2);      // prepped GCN weights (bf16 subtiled)
  u16*   bufA   = (u16*)  take((size_t)N*64*2);       // Hts ping
  u16*   bufB   = (u16*)  take((size_t)N*64*2);       // Hts pong
  (void)ws_size; (void)n_in; (void)out_size;

  // --- run-once weight prep (also zeroes bhist) ---
  prep_tail_kernel<<<115, 256, 0, stream>>>(Wih0, Wih1, Wv1, Wt1, Wv2, Wt2,
                                            bih0, bhh0, bih1, bhh1,
                                            W1, W2, W3,
                                            wbuf, bbuf, wgcn, bhist);

  // --- CSR build ---
  if (N <= MAXBK*256){
    const int NBK = (N + 255) / 256;
    bucket_hist_kernel    <<<EB,  512, 0, stream>>>(ei + E, bhist, E);
    bucket_scan_kernel    <<<1,   512, 0, stream>>>(bhist, bcur, bstart);
    bin_kernel            <<<EB,  512, 0, stream>>>(ei, ei + E, bcur, packed, E);
    bucket_finalize_kernel<<<NBK, 512, 0, stream>>>(packed, bstart, offs, dinv, csr, N, E);
  } else {
    hipMemsetAsync(deg, 0, (size_t)N*4, stream);
    count_kernel      <<<(E+255)/256, 256, 0, stream>>>(ei + E, deg, E);
    scan_reduce_kernel<<<NB,          256, 0, stream>>>(deg, bsums, N);
    scan_block_kernel <<<1,           128, 0, stream>>>(bsums, boffs, NB);
    scan_final_kernel <<<NB,          256, 0, stream>>>(deg, boffs, offs, N, E);
    dinv_kernel       <<<(N+255)/256, 256, 0, stream>>>(deg, offs, cursor, dinv, N);
    fill_kernel       <<<(E+255)/256, 256, 0, stream>>>(ei, cursor, csr, E);
  }

  // --- GCN + tail ---
  const int TB  = (N + 127) / 128;
  const int AB  = (N + 31) / 32;
  const int TB2 = (N + 63) / 64;
  transform_mfma<128,float><<<TB, 256, 0, stream>>>(x, wgcn, dinv, bufA, N);
  fused_agg_transform<<<TB, 512, 0, stream>>>(bufA, dinv, offs, csr, b1,
                                              wgcn + 8192,  bufB, N);
  fused_agg_transform<<<TB, 512, 0, stream>>>(bufB, dinv, offs, csr, b2,
                                              wgcn + 12288, bufA, N);
  agg_kernel<<<AB, 256, 0, stream>>>(bufA, dinv, offs, csr, b3, bufB, N);
  lstm_heads_fused<<<TB2, 256, 0, stream>>>(bufB, wbuf, bbuf,
                                            bv1, bv2, bt1, bt2,
                                            (float*)d_out, N);
}